// Round 1
// baseline (3918.900 us; speedup 1.0000x reference)
//
#include <hip/hip_runtime.h>
#include <math.h>

static constexpr int T = 4096;   // B*S
static constexpr int D = 1024;

// ======================= small kernels =======================

__global__ void zero1_kernel(float* p) { *p = 0.f; }

__global__ __launch_bounds__(256) void ln_kernel(
    const float* __restrict__ x, const float* __restrict__ scale,
    const float* __restrict__ bias, float* __restrict__ out)
{
  int t = blockIdx.x;
  const float* xr = x + (size_t)t * D;
  float v[4];
  float s1 = 0.f, s2 = 0.f;
#pragma unroll
  for (int i = 0; i < 4; i++) {
    v[i] = xr[threadIdx.x + i * 256];
    s1 += v[i];
    s2 += v[i] * v[i];
  }
#pragma unroll
  for (int o = 1; o < 64; o <<= 1) {
    s1 += __shfl_xor(s1, o);
    s2 += __shfl_xor(s2, o);
  }
  __shared__ float r1[4], r2[4];
  int wid = threadIdx.x >> 6;
  if ((threadIdx.x & 63) == 0) { r1[wid] = s1; r2[wid] = s2; }
  __syncthreads();
  s1 = r1[0] + r1[1] + r1[2] + r1[3];
  s2 = r2[0] + r2[1] + r2[2] + r2[3];
  float mean = s1 * (1.f / D);
  float var = s2 * (1.f / D) - mean * mean;
  float rstd = rsqrtf(var + 1e-6f);
  float* orow = out + (size_t)t * D;
#pragma unroll
  for (int i = 0; i < 4; i++) {
    int d = threadIdx.x + i * 256;
    orow[d] = (v[i] - mean) * rstd * scale[d] + bias[d];
  }
}

// rows of length 128, one wave per row
__global__ __launch_bounds__(64) void norm_rows_kernel(
    const float* __restrict__ e, float* __restrict__ o)
{
  int r = blockIdx.x;
  const float* row = e + (size_t)r * 128;
  float a = row[threadIdx.x], b = row[threadIdx.x + 64];
  float ss = a * a + b * b;
#pragma unroll
  for (int m = 1; m < 64; m <<= 1) ss += __shfl_xor(ss, m);
  float inv = 1.f / (sqrtf(ss) + 1e-8f);
  float* orow = o + (size_t)r * 128;
  orow[threadIdx.x] = a * inv;
  orow[threadIdx.x + 64] = b * inv;
}

// tau = n @ W + b,  W: [D, J], J in {1,3}; one wave per token
__global__ __launch_bounds__(64) void tau_kernel(
    const float* __restrict__ n, const float* __restrict__ W,
    const float* __restrict__ b, float* __restrict__ out, int J)
{
  int t = blockIdx.x;
  const float* nr = n + (size_t)t * D;
  for (int j = 0; j < J; j++) {
    float p = 0.f;
#pragma unroll 4
    for (int i = 0; i < 16; i++) {
      int d = threadIdx.x + i * 64;
      p += nr[d] * W[d * J + j];
    }
#pragma unroll
    for (int m = 1; m < 64; m <<= 1) p += __shfl_xor(p, m);
    if (threadIdx.x == 0) out[t * J + j] = p + b[j];
  }
}

// threshold gate + group gate. scores overwritten in place with normalized g.
// N in {2048,4096}, G = N/128, PER = N/256 (8 or 16)
template <int PER>
__global__ __launch_bounds__(256) void gate_kernel(
    float* __restrict__ g, const float* __restrict__ tau, int tauStride,
    int tauOff, float* __restrict__ gb, int N, int G)
{
  int t = blockIdx.x;
  float tv = tau[t * tauStride + tauOff];
  float* row = g + (size_t)t * N;
  float r[PER];
  int base = threadIdx.x * PER;
  float psum = 0.f;
#pragma unroll
  for (int i = 0; i < PER; i++) {
    float s = row[base + i] - tv;
    s = fmaxf(s, 0.f);
    r[i] = s;
    psum += s;
  }
  __shared__ float red[4];
  __shared__ float grp[32];
  if (threadIdx.x < 32) grp[threadIdx.x] = 0.f;
  float w = psum;
#pragma unroll
  for (int m = 1; m < 64; m <<= 1) w += __shfl_xor(w, m);
  int wid = threadIdx.x >> 6;
  if ((threadIdx.x & 63) == 0) red[wid] = w;
  __syncthreads();
  float Stot = red[0] + red[1] + red[2] + red[3];
  // all PER elements of this thread belong to one group (contiguous chunk)
  atomicAdd(&grp[base >> 7], psum);
  __syncthreads();
  float inv = 1.f / (Stot + 1e-8f);
#pragma unroll
  for (int i = 0; i < PER; i++) row[base + i] = r[i] * inv;
  if (threadIdx.x < G) {
    float Gj = grp[threadIdx.x] * inv;
    float gsum = Stot * inv;  // sum of group sums
    gb[(size_t)t * G + threadIdx.x] = Gj / (gsum + 1e-8f);
  }
}

// column means of g [T,N]; aux += sum_n (mean_n - tinv)^2 * N
__global__ __launch_bounds__(256) void colsum_aux_kernel(
    const float* __restrict__ g, int N, float tinv, float* __restrict__ aux)
{
  int c = blockIdx.x * 256 + threadIdx.x;
  float s = 0.f;
#pragma unroll 8
  for (int t = 0; t < T; t++) s += g[(size_t)t * N + c];
  float mdev = s * (1.f / T) - tinv;
  float p = mdev * mdev * (float)N;
#pragma unroll
  for (int m = 1; m < 64; m <<= 1) p += __shfl_xor(p, m);
  __shared__ float red[4];
  if ((threadIdx.x & 63) == 0) red[threadIdx.x >> 6] = p;
  __syncthreads();
  if (threadIdx.x == 0) atomicAdd(aux, red[0] + red[1] + red[2] + red[3]);
}

// f: [NB,1024,128] -> B2: [1024, NB*128]  (B2[d, n*128+r] = f[n,d,r])
__global__ __launch_bounds__(128) void transpose_f_kernel(
    const float* __restrict__ f, float* __restrict__ B2, int NB)
{
  int d = blockIdx.x;
  int n = blockIdx.y;
  int r = threadIdx.x;
  B2[(size_t)d * (NB * 128) + n * 128 + r] =
      f[((size_t)n * 1024 + d) * 128 + r];
}

// h1[t,r] = sum_n gb1[t,n]*all_h[t, n*128+r]; optional second output
__global__ __launch_bounds__(128) void wsum2_kernel(
    const float* __restrict__ all_h, const float* __restrict__ gb1,
    const float* __restrict__ gb2, float* __restrict__ h1,
    float* __restrict__ h2, int NB)
{
  int t = blockIdx.x;
  int r = threadIdx.x;
  const float* row = all_h + (size_t)t * NB * 128;
  float a1 = 0.f, a2 = 0.f;
  for (int n = 0; n < NB; n++) {
    float v = row[n * 128 + r];
    a1 += gb1[(size_t)t * NB + n] * v;
    if (gb2) a2 += gb2[(size_t)t * NB + n] * v;
  }
  h1[(size_t)t * 128 + r] = a1;
  if (h2) h2[(size_t)t * 128 + r] = a2;
}

// ======================= GEMM kernels (fp32, 64x64x16 tiles) =======================

#define GTM 64
#define GTN 64
#define GTK 16

// C = A[M,K] @ B[K,N] (+bias) (+resid)
__global__ __launch_bounds__(256) void gemm_nn_kernel(
    const float* __restrict__ A, int lda, const float* __restrict__ B, int ldb,
    float* __restrict__ C, int ldc, const float* __restrict__ bias,
    const float* __restrict__ resid, int ldr, int M, int N, int K)
{
  __shared__ __align__(16) float As[GTK][GTM + 4];
  __shared__ __align__(16) float Bs[GTK][GTN + 4];
  int tid = threadIdx.x;
  int tx = tid & 15, ty = tid >> 4;
  int row0 = blockIdx.y * GTM;
  int col0 = blockIdx.x * GTN;
  float acc[4][4] = {};
  for (int k0 = 0; k0 < K; k0 += GTK) {
#pragma unroll
    for (int i = 0; i < 4; i++) {
      int idx = tid + i * 256;
      int r = idx >> 4, kk = idx & 15;
      As[kk][r] = A[(size_t)(row0 + r) * lda + k0 + kk];
    }
#pragma unroll
    for (int i = 0; i < 4; i++) {
      int idx = tid + i * 256;
      int kk = idx >> 6, c = idx & 63;
      Bs[kk][c] = B[(size_t)(k0 + kk) * ldb + col0 + c];
    }
    __syncthreads();
#pragma unroll
    for (int kk = 0; kk < GTK; kk++) {
      float a[4], b[4];
#pragma unroll
      for (int i = 0; i < 4; i++) a[i] = As[kk][ty * 4 + i];
#pragma unroll
      for (int j = 0; j < 4; j++) b[j] = Bs[kk][tx * 4 + j];
#pragma unroll
      for (int i = 0; i < 4; i++)
#pragma unroll
        for (int j = 0; j < 4; j++) acc[i][j] += a[i] * b[j];
    }
    __syncthreads();
  }
#pragma unroll
  for (int i = 0; i < 4; i++) {
    int r = row0 + ty * 4 + i;
#pragma unroll
    for (int j = 0; j < 4; j++) {
      int c = col0 + tx * 4 + j;
      float v = acc[i][j];
      if (bias) v += bias[c];
      if (resid) v += resid[(size_t)r * ldr + c];
      C[(size_t)r * ldc + c] = v;
    }
  }
}

// C = A[M,K] @ B^T, B given [N,K] row-major (K=128 here)
__global__ __launch_bounds__(256) void gemm_nt_kernel(
    const float* __restrict__ A, int lda, const float* __restrict__ B, int ldb,
    float* __restrict__ C, int ldc, int M, int N, int K)
{
  __shared__ __align__(16) float As[GTK][GTM + 4];
  __shared__ __align__(16) float Bs[GTK][GTN + 4];
  int tid = threadIdx.x;
  int tx = tid & 15, ty = tid >> 4;
  int row0 = blockIdx.y * GTM;
  int col0 = blockIdx.x * GTN;
  float acc[4][4] = {};
  for (int k0 = 0; k0 < K; k0 += GTK) {
#pragma unroll
    for (int i = 0; i < 4; i++) {
      int idx = tid + i * 256;
      int r = idx >> 4, kk = idx & 15;
      As[kk][r] = A[(size_t)(row0 + r) * lda + k0 + kk];
    }
#pragma unroll
    for (int i = 0; i < 4; i++) {
      int idx = tid + i * 256;
      int c = idx >> 4, kk = idx & 15;
      Bs[kk][c] = B[(size_t)(col0 + c) * ldb + k0 + kk];
    }
    __syncthreads();
#pragma unroll
    for (int kk = 0; kk < GTK; kk++) {
      float a[4], b[4];
#pragma unroll
      for (int i = 0; i < 4; i++) a[i] = As[kk][ty * 4 + i];
#pragma unroll
      for (int j = 0; j < 4; j++) b[j] = Bs[kk][tx * 4 + j];
#pragma unroll
      for (int i = 0; i < 4; i++)
#pragma unroll
        for (int j = 0; j < 4; j++) acc[i][j] += a[i] * b[j];
    }
    __syncthreads();
  }
#pragma unroll
  for (int i = 0; i < 4; i++) {
    int r = row0 + ty * 4 + i;
#pragma unroll
    for (int j = 0; j < 4; j++) {
      int c = col0 + tx * 4 + j;
      C[(size_t)r * ldc + c] = acc[i][j];
    }
  }
}

// C = A_virt @ B, A_virt[t,k] = gb[t, k>>7] * h[t, k&127]; B [K,1024] row-major
__global__ __launch_bounds__(256) void gemm_restore_kernel(
    const float* __restrict__ h, const float* __restrict__ gb, int NB,
    const float* __restrict__ B, int ldb, float* __restrict__ C, int ldc,
    const float* __restrict__ resid, int ldr, int M, int N, int K)
{
  __shared__ __align__(16) float As[GTK][GTM + 4];
  __shared__ __align__(16) float Bs[GTK][GTN + 4];
  int tid = threadIdx.x;
  int tx = tid & 15, ty = tid >> 4;
  int row0 = blockIdx.y * GTM;
  int col0 = blockIdx.x * GTN;
  float acc[4][4] = {};
  for (int k0 = 0; k0 < K; k0 += GTK) {
#pragma unroll
    for (int i = 0; i < 4; i++) {
      int idx = tid + i * 256;
      int r = idx >> 4, kk = idx & 15;
      int k = k0 + kk;
      float hv = h[(size_t)(row0 + r) * 128 + (k & 127)];
      float gv = gb[(size_t)(row0 + r) * NB + (k >> 7)];
      As[kk][r] = hv * gv;
    }
#pragma unroll
    for (int i = 0; i < 4; i++) {
      int idx = tid + i * 256;
      int kk = idx >> 6, c = idx & 63;
      Bs[kk][c] = B[(size_t)(k0 + kk) * ldb + col0 + c];
    }
    __syncthreads();
#pragma unroll
    for (int kk = 0; kk < GTK; kk++) {
      float a[4], b[4];
#pragma unroll
      for (int i = 0; i < 4; i++) a[i] = As[kk][ty * 4 + i];
#pragma unroll
      for (int j = 0; j < 4; j++) b[j] = Bs[kk][tx * 4 + j];
#pragma unroll
      for (int i = 0; i < 4; i++)
#pragma unroll
        for (int j = 0; j < 4; j++) acc[i][j] += a[i] * b[j];
    }
    __syncthreads();
  }
#pragma unroll
  for (int i = 0; i < 4; i++) {
    int r = row0 + ty * 4 + i;
#pragma unroll
    for (int j = 0; j < 4; j++) {
      int c = col0 + tx * 4 + j;
      float v = acc[i][j];
      if (resid) v += resid[(size_t)r * ldr + c];
      C[(size_t)r * ldc + c] = v;
    }
  }
}

// ======================= flash attention (fp32) =======================
// Q,K,V,O: [T, 1024] token-major, head h at cols h*64..h*64+63
__global__ __launch_bounds__(256) void flash_kernel(
    const float* __restrict__ Q, const float* __restrict__ K,
    const float* __restrict__ V, float* __restrict__ O)
{
  const int S = 1024;
  __shared__ float Qs[64][65];
  __shared__ float KP[64][65];  // K tile, reused for P
  __shared__ float Vs[64][65];
  int tid = threadIdx.x;
  int tx = tid & 15, ty = tid >> 4;
  int qt = blockIdx.x;
  int h = blockIdx.y;
  int b = blockIdx.z;
  int q0 = qt * 64;
  size_t base = ((size_t)b * S) * 1024 + h * 64;
#pragma unroll 4
  for (int i = 0; i < 16; i++) {
    int idx = tid + i * 256;
    int r = idx >> 6, d = idx & 63;
    Qs[r][d] = Q[base + (size_t)(q0 + r) * 1024 + d];
  }
  float m[4], l[4], acc[4][4] = {};
#pragma unroll
  for (int i = 0; i < 4; i++) { m[i] = -INFINITY; l[i] = 0.f; }
  __syncthreads();
  for (int kt = 0; kt <= qt; kt++) {
    int k0 = kt * 64;
#pragma unroll 4
    for (int i = 0; i < 16; i++) {
      int idx = tid + i * 256;
      int r = idx >> 6, d = idx & 63;
      KP[r][d] = K[base + (size_t)(k0 + r) * 1024 + d];
      Vs[r][d] = V[base + (size_t)(k0 + r) * 1024 + d];
    }
    __syncthreads();
    float s[4][4] = {};
    for (int d = 0; d < 64; d++) {
      float a[4], bb[4];
#pragma unroll
      for (int i = 0; i < 4; i++) a[i] = Qs[ty * 4 + i][d];
#pragma unroll
      for (int j = 0; j < 4; j++) bb[j] = KP[tx * 4 + j][d];
#pragma unroll
      for (int i = 0; i < 4; i++)
#pragma unroll
        for (int j = 0; j < 4; j++) s[i][j] += a[i] * bb[j];
    }
    const float scale = 0.125f;
    bool maskt = (kt == qt);
#pragma unroll
    for (int i = 0; i < 4; i++)
#pragma unroll
      for (int j = 0; j < 4; j++) {
        s[i][j] *= scale;
        if (maskt && (k0 + tx * 4 + j > q0 + ty * 4 + i)) s[i][j] = -INFINITY;
      }
#pragma unroll
    for (int i = 0; i < 4; i++) {
      float rm = fmaxf(fmaxf(s[i][0], s[i][1]), fmaxf(s[i][2], s[i][3]));
#pragma unroll
      for (int o = 1; o < 16; o <<= 1) rm = fmaxf(rm, __shfl_xor(rm, o, 16));
      float mnew = fmaxf(m[i], rm);
      float corr = expf(m[i] - mnew);
      float psum = 0.f;
#pragma unroll
      for (int j = 0; j < 4; j++) {
        s[i][j] = expf(s[i][j] - mnew);
        psum += s[i][j];
      }
#pragma unroll
      for (int o = 1; o < 16; o <<= 1) psum += __shfl_xor(psum, o, 16);
      l[i] = l[i] * corr + psum;
      m[i] = mnew;
#pragma unroll
      for (int j = 0; j < 4; j++) acc[i][j] *= corr;
    }
    __syncthreads();  // all done reading K before P overwrites it
#pragma unroll
    for (int i = 0; i < 4; i++)
#pragma unroll
      for (int j = 0; j < 4; j++) KP[ty * 4 + i][tx * 4 + j] = s[i][j];
    __syncthreads();
    for (int c = 0; c < 64; c++) {
      float p[4], vv[4];
#pragma unroll
      for (int i = 0; i < 4; i++) p[i] = KP[ty * 4 + i][c];
#pragma unroll
      for (int j = 0; j < 4; j++) vv[j] = Vs[c][tx * 4 + j];
#pragma unroll
      for (int i = 0; i < 4; i++)
#pragma unroll
        for (int j = 0; j < 4; j++) acc[i][j] += p[i] * vv[j];
    }
    __syncthreads();
  }
#pragma unroll
  for (int i = 0; i < 4; i++) {
    float inv = 1.f / l[i];
    int r = q0 + ty * 4 + i;
#pragma unroll
    for (int j = 0; j < 4; j++)
      O[base + (size_t)r * 1024 + tx * 4 + j] = acc[i][j] * inv;
  }
}

// ======================= launch =======================

extern "C" void kernel_launch(void* const* d_in, const int* in_sizes, int n_in,
                              void* d_out, int out_size, void* d_ws,
                              size_t ws_size, hipStream_t stream) {
  (void)in_sizes; (void)n_in; (void)out_size; (void)ws_size;
  const float* x          = (const float*)d_in[0];
  const float* qk_emb     = (const float*)d_in[1];
  const float* v_emb      = (const float*)d_in[2];
  const float* know_emb   = (const float*)d_in[3];
  const float* qk_f       = (const float*)d_in[4];
  const float* qk_r       = (const float*)d_in[5];
  const float* v_f        = (const float*)d_in[6];
  const float* v_r        = (const float*)d_in[7];
  const float* know_f     = (const float*)d_in[8];
  const float* know_r     = (const float*)d_in[9];
  const float* proj_attn_k = (const float*)d_in[10];
  const float* proj_attn_b = (const float*)d_in[11];
  const float* tau_attn_k  = (const float*)d_in[12];
  const float* tau_attn_b  = (const float*)d_in[13];
  const float* proj_know_k = (const float*)d_in[14];
  const float* proj_know_b = (const float*)d_in[15];
  const float* tau_know_k  = (const float*)d_in[16];
  const float* tau_know_b  = (const float*)d_in[17];
  const float* expand_O    = (const float*)d_in[18];
  const float* ln1_scale   = (const float*)d_in[19];
  const float* ln1_bias    = (const float*)d_in[20];
  const float* ln2_scale   = (const float*)d_in[21];
  const float* ln2_bias    = (const float*)d_in[22];

  float* out = (float*)d_out;          // [T, D] then aux scalar
  float* aux = out + (size_t)T * D;

  // ---- workspace arena ----
  float* ws = (float*)d_ws;
  float* n_buf   = ws;                                  // T*D
  float* h_all   = n_buf + (size_t)T * D;               // T*384 (reused: know h T*128)
  float* tau3    = h_all + (size_t)T * 384;             // 16384
  float* embA    = tau3 + 16384;                        // 524288 (qk_n | v_n ; know_n)
  float* buf_big = embA + 524288;                       // T*4096
  float* gq_b    = buf_big + (size_t)T * 4096;          // T*16
  float* gk_b    = gq_b + (size_t)T * 16;
  float* gv_b    = gk_b + (size_t)T * 16;
  float* gkn_b   = gv_b + (size_t)T * 16;               // T*32
  float* B2      = gkn_b + (size_t)T * 32;              // 1024*4096
  float* hQ      = B2 + (size_t)1024 * 4096;            // T*128
  float* hK      = hQ + (size_t)T * 128;
  float* hV      = hK + (size_t)T * 128;
  float* Qb      = hV + (size_t)T * 128;                // T*D
  float* Kb      = Qb + (size_t)T * D;
  float* Vb      = Kb + (size_t)T * D;
  float* attnb   = Vb + (size_t)T * D;

  float* embQ = embA;
  float* embV = embA + (size_t)2048 * 128;

  dim3 blk(256);

  zero1_kernel<<<1, 1, 0, stream>>>(aux);

  // ---- attention circuit ----
  ln_kernel<<<T, blk, 0, stream>>>(x, ln1_scale, ln1_bias, n_buf);
  norm_rows_kernel<<<2048, 64, 0, stream>>>(qk_emb, embQ);
  norm_rows_kernel<<<2048, 64, 0, stream>>>(v_emb, embV);

  gemm_nn_kernel<<<dim3(384 / 64, T / 64), blk, 0, stream>>>(
      n_buf, 1024, proj_attn_k, 384, h_all, 384, proj_attn_b, nullptr, 0,
      T, 384, 1024);
  tau_kernel<<<T, 64, 0, stream>>>(n_buf, tau_attn_k, tau_attn_b, tau3, 3);

  // g_q
  gemm_nt_kernel<<<dim3(2048 / 64, T / 64), blk, 0, stream>>>(
      h_all + 0, 384, embQ, 128, buf_big, 2048, T, 2048, 128);
  gate_kernel<8><<<T, blk, 0, stream>>>(buf_big, tau3, 3, 0, gq_b, 2048, 16);
  colsum_aux_kernel<<<2048 / 256, blk, 0, stream>>>(buf_big, 2048,
                                                    1.f / 2048.f, aux);
  // g_k
  gemm_nt_kernel<<<dim3(2048 / 64, T / 64), blk, 0, stream>>>(
      h_all + 128, 384, embQ, 128, buf_big, 2048, T, 2048, 128);
  gate_kernel<8><<<T, blk, 0, stream>>>(buf_big, tau3, 3, 1, gk_b, 2048, 16);
  colsum_aux_kernel<<<2048 / 256, blk, 0, stream>>>(buf_big, 2048,
                                                    1.f / 2048.f, aux);
  // g_v
  gemm_nt_kernel<<<dim3(2048 / 64, T / 64), blk, 0, stream>>>(
      h_all + 256, 384, embV, 128, buf_big, 2048, T, 2048, 128);
  gate_kernel<8><<<T, blk, 0, stream>>>(buf_big, tau3, 3, 2, gv_b, 2048, 16);
  colsum_aux_kernel<<<2048 / 256, blk, 0, stream>>>(buf_big, 2048,
                                                    1.f / 2048.f, aux);

  // features (qk basis): all_h = n1 @ B2(qk_f)
  transpose_f_kernel<<<dim3(1024, 16), 128, 0, stream>>>(qk_f, B2, 16);
  gemm_nn_kernel<<<dim3(2048 / 64, T / 64), blk, 0, stream>>>(
      n_buf, 1024, B2, 2048, buf_big, 2048, nullptr, nullptr, 0,
      T, 2048, 1024);
  wsum2_kernel<<<T, 128, 0, stream>>>(buf_big, gq_b, gk_b, hQ, hK, 16);

  // features (v basis)
  transpose_f_kernel<<<dim3(1024, 16), 128, 0, stream>>>(v_f, B2, 16);
  gemm_nn_kernel<<<dim3(2048 / 64, T / 64), blk, 0, stream>>>(
      n_buf, 1024, B2, 2048, buf_big, 2048, nullptr, nullptr, 0,
      T, 2048, 1024);
  wsum2_kernel<<<T, 128, 0, stream>>>(buf_big, gv_b, nullptr, hV, nullptr, 16);

  // restores
  gemm_restore_kernel<<<dim3(1024 / 64, T / 64), blk, 0, stream>>>(
      hQ, gq_b, 16, qk_r, 1024, Qb, 1024, nullptr, 0, T, 1024, 2048);
  gemm_restore_kernel<<<dim3(1024 / 64, T / 64), blk, 0, stream>>>(
      hK, gk_b, 16, qk_r, 1024, Kb, 1024, nullptr, 0, T, 1024, 2048);
  gemm_restore_kernel<<<dim3(1024 / 64, T / 64), blk, 0, stream>>>(
      hV, gv_b, 16, v_r, 1024, Vb, 1024, nullptr, 0, T, 1024, 2048);

  // attention + output proj + residual  (out = x + attn@O)
  flash_kernel<<<dim3(16, 16, 4), blk, 0, stream>>>(Qb, Kb, Vb, attnb);
  gemm_nn_kernel<<<dim3(1024 / 64, T / 64), blk, 0, stream>>>(
      attnb, 1024, expand_O, 1024, out, 1024, nullptr, x, 1024, T, 1024, 1024);

  // ---- knowledge circuit ----
  ln_kernel<<<T, blk, 0, stream>>>(out, ln2_scale, ln2_bias, n_buf);
  norm_rows_kernel<<<4096, 64, 0, stream>>>(know_emb, embA);
  gemm_nn_kernel<<<dim3(128 / 64, T / 64), blk, 0, stream>>>(
      n_buf, 1024, proj_know_k, 128, h_all, 128, proj_know_b, nullptr, 0,
      T, 128, 1024);
  tau_kernel<<<T, 64, 0, stream>>>(n_buf, tau_know_k, tau_know_b, tau3, 1);

  gemm_nt_kernel<<<dim3(4096 / 64, T / 64), blk, 0, stream>>>(
      h_all, 128, embA, 128, buf_big, 4096, T, 4096, 128);
  gate_kernel<16><<<T, blk, 0, stream>>>(buf_big, tau3, 1, 0, gkn_b, 4096, 32);
  colsum_aux_kernel<<<4096 / 256, blk, 0, stream>>>(buf_big, 4096,
                                                    1.f / 4096.f, aux);

  transpose_f_kernel<<<dim3(1024, 32), 128, 0, stream>>>(know_f, B2, 32);
  gemm_nn_kernel<<<dim3(4096 / 64, T / 64), blk, 0, stream>>>(
      n_buf, 1024, B2, 4096, buf_big, 4096, nullptr, nullptr, 0,
      T, 4096, 1024);
  wsum2_kernel<<<T, 128, 0, stream>>>(buf_big, gkn_b, nullptr, hQ, nullptr, 32);

  // know_out + residual, in place into out
  gemm_restore_kernel<<<dim3(1024 / 64, T / 64), blk, 0, stream>>>(
      hQ, gkn_b, 32, know_r, 1024, out, 1024, out, 1024, T, 1024, 4096);
}

// Round 2
// 1794.829 us; speedup vs baseline: 2.1834x; 2.1834x over previous
//
#include <hip/hip_runtime.h>
#include <math.h>

static constexpr int T = 4096;   // B*S
static constexpr int D = 1024;

typedef __bf16 bf16_t;
typedef bf16_t bf16x8 __attribute__((ext_vector_type(8)));
typedef float f32x4 __attribute__((ext_vector_type(4)));

#define GLDS16(g, l)                                                        \
  __builtin_amdgcn_global_load_lds(                                         \
      (const __attribute__((address_space(1))) void*)(g),                   \
      (__attribute__((address_space(3))) void*)(l), 16, 0, 0)

// ======================= small kernels =======================

__global__ void zero1_kernel(float* p) { *p = 0.f; }

__global__ __launch_bounds__(256) void ln_kernel(
    const float* __restrict__ x, const float* __restrict__ scale,
    const float* __restrict__ bias, float* __restrict__ out_f,
    bf16_t* __restrict__ out_b)
{
  int t = blockIdx.x;
  const float* xr = x + (size_t)t * D;
  float v[4];
  float s1 = 0.f, s2 = 0.f;
#pragma unroll
  for (int i = 0; i < 4; i++) {
    v[i] = xr[threadIdx.x + i * 256];
    s1 += v[i];
    s2 += v[i] * v[i];
  }
#pragma unroll
  for (int o = 1; o < 64; o <<= 1) {
    s1 += __shfl_xor(s1, o);
    s2 += __shfl_xor(s2, o);
  }
  __shared__ float r1[4], r2[4];
  int wid = threadIdx.x >> 6;
  if ((threadIdx.x & 63) == 0) { r1[wid] = s1; r2[wid] = s2; }
  __syncthreads();
  s1 = r1[0] + r1[1] + r1[2] + r1[3];
  s2 = r2[0] + r2[1] + r2[2] + r2[3];
  float mean = s1 * (1.f / D);
  float var = s2 * (1.f / D) - mean * mean;
  float rstd = rsqrtf(var + 1e-6f);
  float* orow = out_f + (size_t)t * D;
  bf16_t* brow = out_b + (size_t)t * D;
#pragma unroll
  for (int i = 0; i < 4; i++) {
    int d = threadIdx.x + i * 256;
    float o = (v[i] - mean) * rstd * scale[d] + bias[d];
    orow[d] = o;
    brow[d] = (bf16_t)o;
  }
}

// rows of length 128, one wave per row; bf16 normalized output
__global__ __launch_bounds__(64) void norm_rows_kernel(
    const float* __restrict__ e, bf16_t* __restrict__ o)
{
  int r = blockIdx.x;
  const float* row = e + (size_t)r * 128;
  float a = row[threadIdx.x], b = row[threadIdx.x + 64];
  float ss = a * a + b * b;
#pragma unroll
  for (int m = 1; m < 64; m <<= 1) ss += __shfl_xor(ss, m);
  float inv = 1.f / (sqrtf(ss) + 1e-8f);
  bf16_t* orow = o + (size_t)r * 128;
  orow[threadIdx.x] = (bf16_t)(a * inv);
  orow[threadIdx.x + 64] = (bf16_t)(b * inv);
}

// tau = n @ W + b,  W: [D, J], J in {1,3}; one wave per token (fp32)
__global__ __launch_bounds__(64) void tau_kernel(
    const float* __restrict__ n, const float* __restrict__ W,
    const float* __restrict__ b, float* __restrict__ out, int J)
{
  int t = blockIdx.x;
  const float* nr = n + (size_t)t * D;
  for (int j = 0; j < J; j++) {
    float p = 0.f;
#pragma unroll 4
    for (int i = 0; i < 16; i++) {
      int d = threadIdx.x + i * 64;
      p += nr[d] * W[d * J + j];
    }
#pragma unroll
    for (int m = 1; m < 64; m <<= 1) p += __shfl_xor(p, m);
    if (threadIdx.x == 0) out[t * J + j] = p + b[j];
  }
}

// threshold gate + group gate, in place.
template <int PER>
__global__ __launch_bounds__(256) void gate_kernel(
    float* __restrict__ g, const float* __restrict__ tau, int tauStride,
    int tauOff, float* __restrict__ gb, int N, int G)
{
  int t = blockIdx.x;
  float tv = tau[t * tauStride + tauOff];
  float* row = g + (size_t)t * N;
  float r[PER];
  int base = threadIdx.x * PER;
  float psum = 0.f;
#pragma unroll
  for (int i = 0; i < PER; i++) {
    float s = row[base + i] - tv;
    s = fmaxf(s, 0.f);
    r[i] = s;
    psum += s;
  }
  __shared__ float red[4];
  __shared__ float grp[32];
  if (threadIdx.x < 32) grp[threadIdx.x] = 0.f;
  float w = psum;
#pragma unroll
  for (int m = 1; m < 64; m <<= 1) w += __shfl_xor(w, m);
  int wid = threadIdx.x >> 6;
  if ((threadIdx.x & 63) == 0) red[wid] = w;
  __syncthreads();
  float Stot = red[0] + red[1] + red[2] + red[3];
  atomicAdd(&grp[base >> 7], psum);
  __syncthreads();
  float inv = 1.f / (Stot + 1e-8f);
#pragma unroll
  for (int i = 0; i < PER; i++) row[base + i] = r[i] * inv;
  if (threadIdx.x < G) {
    float Gj = grp[threadIdx.x] * inv;
    float gsum = Stot * inv;
    gb[(size_t)t * G + threadIdx.x] = Gj / (gsum + 1e-8f);
  }
}

// column means of g [T,N]; aux += sum_n (mean_n - tinv)^2 * N
__global__ __launch_bounds__(256) void colsum_aux_kernel(
    const float* __restrict__ g, int N, float tinv, float* __restrict__ aux)
{
  int c = blockIdx.x * 256 + threadIdx.x;
  float s = 0.f;
#pragma unroll 8
  for (int t = 0; t < T; t++) s += g[(size_t)t * N + c];
  float mdev = s * (1.f / T) - tinv;
  float p = mdev * mdev * (float)N;
#pragma unroll
  for (int m = 1; m < 64; m <<= 1) p += __shfl_xor(p, m);
  __shared__ float red[4];
  if ((threadIdx.x & 63) == 0) red[threadIdx.x >> 6] = p;
  __syncthreads();
  if (threadIdx.x == 0) atomicAdd(aux, red[0] + red[1] + red[2] + red[3]);
}

// h1[t,r] = sum_n gb1[t,n]*all_h[t, n*128+r]; optional second output
__global__ __launch_bounds__(128) void wsum2_kernel(
    const float* __restrict__ all_h, const float* __restrict__ gb1,
    const float* __restrict__ gb2, float* __restrict__ h1,
    float* __restrict__ h2, int NB)
{
  int t = blockIdx.x;
  int r = threadIdx.x;
  const float* row = all_h + (size_t)t * NB * 128;
  float a1 = 0.f, a2 = 0.f;
  for (int n = 0; n < NB; n++) {
    float v = row[n * 128 + r];
    a1 += gb1[(size_t)t * NB + n] * v;
    if (gb2) a2 += gb2[(size_t)t * NB + n] * v;
  }
  h1[(size_t)t * 128 + r] = a1;
  if (h2) h2[(size_t)t * 128 + r] = a2;
}

// dst[c][r] = (bf16)src[r][c]; src [R,C] fp32, dst [C,R] bf16; batched
__global__ __launch_bounds__(256) void transpose_to_bf16_kernel(
    const float* __restrict__ src, bf16_t* __restrict__ dst,
    int R, int C, size_t sbs, size_t dbs)
{
  __shared__ float tile[32][33];
  int b = blockIdx.z;
  int c0 = blockIdx.x * 32, r0 = blockIdx.y * 32;
  int tx = threadIdx.x & 31, ty = threadIdx.x >> 5;  // 8 rows/pass
  const float* s = src + (size_t)b * sbs;
  bf16_t* d = dst + (size_t)b * dbs;
#pragma unroll
  for (int i = 0; i < 4; i++)
    tile[ty + i * 8][tx] = s[(size_t)(r0 + ty + i * 8) * C + c0 + tx];
  __syncthreads();
#pragma unroll
  for (int i = 0; i < 4; i++)
    d[(size_t)(c0 + ty + i * 8) * R + r0 + tx] = (bf16_t)tile[tx][ty + i * 8];
}

// A_virt[t,k] = (bf16)(gb[t,k>>7]*h[t,k&127]), row-major [T,K]
__global__ __launch_bounds__(256) void avirt_kernel(
    const float* __restrict__ h, const float* __restrict__ gb, int NB,
    bf16_t* __restrict__ A, int K)
{
  int t = blockIdx.x;
  const float* hr = h + (size_t)t * 128;
  const float* gr = gb + (size_t)t * NB;
  bf16_t* ar = A + (size_t)t * K;
  int noct = K >> 3;
  for (int o = threadIdx.x; o < noct; o += 256) {
    int k = o * 8;
    float g = gr[k >> 7];
    bf16x8 v;
#pragma unroll
    for (int i = 0; i < 8; i++) v[i] = (bf16_t)(hr[(k & 127) + i] * g);
    *(bf16x8*)(ar + k) = v;
  }
}

// ============== MFMA GEMM: C[M,N] = A[M,K]bf16 @ Bt[N,K]bf16^T ==============
// 128x128 tile, BK=32, 4 waves (2x2), 4x4 16x16 fragments per wave.
template <bool HAS_BIAS, bool HAS_RESID, bool OUT_BF16>
__global__ __launch_bounds__(256) void mfma_gemm_kernel(
    const bf16_t* __restrict__ A, int lda,
    const bf16_t* __restrict__ Bt, int ldb,
    void* __restrict__ Cv, int ldc,
    const float* __restrict__ bias,
    const float* __restrict__ resid, int ldr,
    int M, int N, int K)
{
  __shared__ bf16_t As[128 * 32];
  __shared__ bf16_t Bs[128 * 32];
  int tid = threadIdx.x;
  int wave = tid >> 6, lane = tid & 63;
  int row0 = blockIdx.y * 128, col0 = blockIdx.x * 128;
  int wr = (wave >> 1) * 64, wc = (wave & 1) * 64;

  f32x4 acc[4][4] = {};

  // staging geometry: instr i covers rows i*64 + wave*16 + lane/4, k8=(lane&3)*8
  int srow = (wave << 4) + (lane >> 2);
  int skk = (lane & 3) << 3;
  const bf16_t* gA = A + (size_t)(row0 + srow) * lda + skk;
  const bf16_t* gB = Bt + (size_t)(col0 + srow) * ldb + skk;
  size_t a64 = (size_t)64 * lda, b64 = (size_t)64 * ldb;

  int fr = lane & 15, fq = lane >> 4;

  for (int k0 = 0; k0 < K; k0 += 32) {
    GLDS16(gA + k0, &As[wave * 512]);
    GLDS16(gA + a64 + k0, &As[2048 + wave * 512]);
    GLDS16(gB + k0, &Bs[wave * 512]);
    GLDS16(gB + b64 + k0, &Bs[2048 + wave * 512]);
    __syncthreads();
    bf16x8 af[4], bfr[4];
#pragma unroll
    for (int m = 0; m < 4; m++)
      af[m] = *(const bf16x8*)&As[(wr + m * 16 + fr) * 32 + fq * 8];
#pragma unroll
    for (int n = 0; n < 4; n++)
      bfr[n] = *(const bf16x8*)&Bs[(wc + n * 16 + fr) * 32 + fq * 8];
#pragma unroll
    for (int m = 0; m < 4; m++)
#pragma unroll
      for (int n = 0; n < 4; n++)
        acc[m][n] = __builtin_amdgcn_mfma_f32_16x16x32_bf16(af[m], bfr[n],
                                                            acc[m][n], 0, 0, 0);
    __syncthreads();
  }

#pragma unroll
  for (int m = 0; m < 4; m++) {
#pragma unroll
    for (int n = 0; n < 4; n++) {
#pragma unroll
      for (int r = 0; r < 4; r++) {
        int row = row0 + wr + m * 16 + fq * 4 + r;
        int col = col0 + wc + n * 16 + fr;
        float v = acc[m][n][r];
        if (HAS_BIAS) v += bias[col];
        if (HAS_RESID) v += resid[(size_t)row * ldr + col];
        if (OUT_BF16)
          ((bf16_t*)Cv)[(size_t)row * ldc + col] = (bf16_t)v;
        else
          ((float*)Cv)[(size_t)row * ldc + col] = v;
      }
    }
  }
}

// ======================= flash attention (fp32, bf16 out) =======================
__global__ __launch_bounds__(256) void flash_kernel(
    const float* __restrict__ Q, const float* __restrict__ K,
    const float* __restrict__ V, bf16_t* __restrict__ O)
{
  const int S = 1024;
  __shared__ float Qs[64][65];
  __shared__ float KP[64][65];
  __shared__ float Vs[64][65];
  int tid = threadIdx.x;
  int tx = tid & 15, ty = tid >> 4;
  int qt = blockIdx.x;
  int h = blockIdx.y;
  int b = blockIdx.z;
  int q0 = qt * 64;
  size_t base = ((size_t)b * S) * 1024 + h * 64;
#pragma unroll 4
  for (int i = 0; i < 16; i++) {
    int idx = tid + i * 256;
    int r = idx >> 6, d = idx & 63;
    Qs[r][d] = Q[base + (size_t)(q0 + r) * 1024 + d];
  }
  float m[4], l[4], acc[4][4] = {};
#pragma unroll
  for (int i = 0; i < 4; i++) { m[i] = -INFINITY; l[i] = 0.f; }
  __syncthreads();
  for (int kt = 0; kt <= qt; kt++) {
    int k0 = kt * 64;
#pragma unroll 4
    for (int i = 0; i < 16; i++) {
      int idx = tid + i * 256;
      int r = idx >> 6, d = idx & 63;
      KP[r][d] = K[base + (size_t)(k0 + r) * 1024 + d];
      Vs[r][d] = V[base + (size_t)(k0 + r) * 1024 + d];
    }
    __syncthreads();
    float s[4][4] = {};
    for (int d = 0; d < 64; d++) {
      float a[4], bb[4];
#pragma unroll
      for (int i = 0; i < 4; i++) a[i] = Qs[ty * 4 + i][d];
#pragma unroll
      for (int j = 0; j < 4; j++) bb[j] = KP[tx * 4 + j][d];
#pragma unroll
      for (int i = 0; i < 4; i++)
#pragma unroll
        for (int j = 0; j < 4; j++) s[i][j] += a[i] * bb[j];
    }
    const float scale = 0.125f;
    bool maskt = (kt == qt);
#pragma unroll
    for (int i = 0; i < 4; i++)
#pragma unroll
      for (int j = 0; j < 4; j++) {
        s[i][j] *= scale;
        if (maskt && (k0 + tx * 4 + j > q0 + ty * 4 + i)) s[i][j] = -INFINITY;
      }
#pragma unroll
    for (int i = 0; i < 4; i++) {
      float rm = fmaxf(fmaxf(s[i][0], s[i][1]), fmaxf(s[i][2], s[i][3]));
#pragma unroll
      for (int o = 1; o < 16; o <<= 1) rm = fmaxf(rm, __shfl_xor(rm, o, 16));
      float mnew = fmaxf(m[i], rm);
      float corr = expf(m[i] - mnew);
      float psum = 0.f;
#pragma unroll
      for (int j = 0; j < 4; j++) {
        s[i][j] = expf(s[i][j] - mnew);
        psum += s[i][j];
      }
#pragma unroll
      for (int o = 1; o < 16; o <<= 1) psum += __shfl_xor(psum, o, 16);
      l[i] = l[i] * corr + psum;
      m[i] = mnew;
#pragma unroll
      for (int j = 0; j < 4; j++) acc[i][j] *= corr;
    }
    __syncthreads();
#pragma unroll
    for (int i = 0; i < 4; i++)
#pragma unroll
      for (int j = 0; j < 4; j++) KP[ty * 4 + i][tx * 4 + j] = s[i][j];
    __syncthreads();
    for (int c = 0; c < 64; c++) {
      float p[4], vv[4];
#pragma unroll
      for (int i = 0; i < 4; i++) p[i] = KP[ty * 4 + i][c];
#pragma unroll
      for (int j = 0; j < 4; j++) vv[j] = Vs[c][tx * 4 + j];
#pragma unroll
      for (int i = 0; i < 4; i++)
#pragma unroll
        for (int j = 0; j < 4; j++) acc[i][j] += p[i] * vv[j];
    }
    __syncthreads();
  }
#pragma unroll
  for (int i = 0; i < 4; i++) {
    float inv = 1.f / l[i];
    int r = q0 + ty * 4 + i;
#pragma unroll
    for (int j = 0; j < 4; j++)
      O[base + (size_t)r * 1024 + tx * 4 + j] = (bf16_t)(acc[i][j] * inv);
  }
}

// ======================= launch =======================

extern "C" void kernel_launch(void* const* d_in, const int* in_sizes, int n_in,
                              void* d_out, int out_size, void* d_ws,
                              size_t ws_size, hipStream_t stream) {
  (void)in_sizes; (void)n_in; (void)out_size; (void)ws_size;
  const float* x          = (const float*)d_in[0];
  const float* qk_emb     = (const float*)d_in[1];
  const float* v_emb      = (const float*)d_in[2];
  const float* know_emb   = (const float*)d_in[3];
  const float* qk_f       = (const float*)d_in[4];
  const float* qk_r       = (const float*)d_in[5];
  const float* v_f        = (const float*)d_in[6];
  const float* v_r        = (const float*)d_in[7];
  const float* know_f     = (const float*)d_in[8];
  const float* know_r     = (const float*)d_in[9];
  const float* proj_attn_k = (const float*)d_in[10];
  const float* proj_attn_b = (const float*)d_in[11];
  const float* tau_attn_k  = (const float*)d_in[12];
  const float* tau_attn_b  = (const float*)d_in[13];
  const float* proj_know_k = (const float*)d_in[14];
  const float* proj_know_b = (const float*)d_in[15];
  const float* tau_know_k  = (const float*)d_in[16];
  const float* tau_know_b  = (const float*)d_in[17];
  const float* expand_O    = (const float*)d_in[18];
  const float* ln1_scale   = (const float*)d_in[19];
  const float* ln1_bias    = (const float*)d_in[20];
  const float* ln2_scale   = (const float*)d_in[21];
  const float* ln2_bias    = (const float*)d_in[22];

  float* out = (float*)d_out;  // [T,D] + aux scalar
  float* aux = out + (size_t)T * D;

  // ---- workspace arena (fp32 then bf16) ----
  float* ws = (float*)d_ws;
  float* n_f   = ws;                       // 4M
  float* tau3  = n_f + 4194304;            // 16K
  float* gq_b  = tau3 + 16384;             // 64K
  float* gk_b  = gq_b + 65536;
  float* gv_b  = gk_b + 65536;
  float* gkn_b = gv_b + 65536;             // 128K
  float* hQ    = gkn_b + 131072;           // 512K
  float* hK    = hQ + 524288;
  float* hV    = hK + 524288;
  float* Qb    = hV + 524288;              // 4M each
  float* Kb    = Qb + 4194304;
  float* Vb    = Kb + 4194304;
  float* buf_big = Vb + 4194304;           // 16.78M floats (64MB)

  bf16_t* nb   = (bf16_t*)(buf_big + 16777216);  // T*1024
  bf16_t* hab  = nb + 4194304;                   // T*384 (reused know: T*128)
  bf16_t* embB = hab + 1572864;                  // 524288 (qk|v ; know)
  bf16_t* B2t  = embB + 524288;                  // 4096*1024
  bf16_t* wt   = B2t + 4194304;                  // transposed weights arena
  bf16_t* pa_t  = wt;                   // 384*1024
  bf16_t* qkr_t = pa_t + 393216;        // 1024*2048
  bf16_t* vr_t  = qkr_t + 2097152;      // 1024*2048
  bf16_t* knr_t = vr_t + 2097152;       // 1024*4096
  bf16_t* eo_t  = knr_t + 4194304;      // 1024*1024
  bf16_t* pk_t  = eo_t + 1048576;       // 128*1024

  // aliases inside buf_big (lifetimes verified against schedule below)
  bf16_t* avb = (bf16_t*)buf_big;                           // up to T*4096 bf16 (32MB)
  bf16_t* attnb_b = (bf16_t*)(buf_big + 12582912);          // T*1024 bf16 @48MB

  bf16_t* embQ = embB;
  bf16_t* embV = embB + 262144;

  dim3 blk(256);

  zero1_kernel<<<1, 1, 0, stream>>>(aux);

  // one-time (per launch) weight transposes to bf16 [N,K]
  transpose_to_bf16_kernel<<<dim3(12, 32, 1), blk, 0, stream>>>(
      proj_attn_k, pa_t, 1024, 384, 0, 0);
  transpose_to_bf16_kernel<<<dim3(32, 64, 1), blk, 0, stream>>>(
      qk_r, qkr_t, 2048, 1024, 0, 0);
  transpose_to_bf16_kernel<<<dim3(32, 64, 1), blk, 0, stream>>>(
      v_r, vr_t, 2048, 1024, 0, 0);
  transpose_to_bf16_kernel<<<dim3(32, 128, 1), blk, 0, stream>>>(
      know_r, knr_t, 4096, 1024, 0, 0);
  transpose_to_bf16_kernel<<<dim3(32, 32, 1), blk, 0, stream>>>(
      expand_O, eo_t, 1024, 1024, 0, 0);
  transpose_to_bf16_kernel<<<dim3(4, 32, 1), blk, 0, stream>>>(
      proj_know_k, pk_t, 1024, 128, 0, 0);

  // ---- attention circuit ----
  ln_kernel<<<T, blk, 0, stream>>>(x, ln1_scale, ln1_bias, n_f, nb);
  norm_rows_kernel<<<2048, 64, 0, stream>>>(qk_emb, embQ);
  norm_rows_kernel<<<2048, 64, 0, stream>>>(v_emb, embV);

  mfma_gemm_kernel<true, false, true><<<dim3(3, 32), blk, 0, stream>>>(
      nb, 1024, pa_t, 1024, hab, 384, proj_attn_b, nullptr, 0, T, 384, 1024);
  tau_kernel<<<T, 64, 0, stream>>>(n_f, tau_attn_k, tau_attn_b, tau3, 3);

  // gate scores + gates + aux
  mfma_gemm_kernel<false, false, false><<<dim3(16, 32), blk, 0, stream>>>(
      hab + 0, 384, embQ, 128, buf_big, 2048, nullptr, nullptr, 0, T, 2048, 128);
  gate_kernel<8><<<T, blk, 0, stream>>>(buf_big, tau3, 3, 0, gq_b, 2048, 16);
  colsum_aux_kernel<<<8, blk, 0, stream>>>(buf_big, 2048, 1.f / 2048.f, aux);

  mfma_gemm_kernel<false, false, false><<<dim3(16, 32), blk, 0, stream>>>(
      hab + 128, 384, embQ, 128, buf_big, 2048, nullptr, nullptr, 0, T, 2048, 128);
  gate_kernel<8><<<T, blk, 0, stream>>>(buf_big, tau3, 3, 1, gk_b, 2048, 16);
  colsum_aux_kernel<<<8, blk, 0, stream>>>(buf_big, 2048, 1.f / 2048.f, aux);

  mfma_gemm_kernel<false, false, false><<<dim3(16, 32), blk, 0, stream>>>(
      hab + 256, 384, embV, 128, buf_big, 2048, nullptr, nullptr, 0, T, 2048, 128);
  gate_kernel<8><<<T, blk, 0, stream>>>(buf_big, tau3, 3, 2, gv_b, 2048, 16);
  colsum_aux_kernel<<<8, blk, 0, stream>>>(buf_big, 2048, 1.f / 2048.f, aux);

  // features (qk basis)
  transpose_to_bf16_kernel<<<dim3(4, 32, 16), blk, 0, stream>>>(
      qk_f, B2t, 1024, 128, 131072, 131072);
  mfma_gemm_kernel<false, false, false><<<dim3(16, 32), blk, 0, stream>>>(
      nb, 1024, B2t, 1024, buf_big, 2048, nullptr, nullptr, 0, T, 2048, 1024);
  wsum2_kernel<<<T, 128, 0, stream>>>(buf_big, gq_b, gk_b, hQ, hK, 16);

  // features (v basis)
  transpose_to_bf16_kernel<<<dim3(4, 32, 16), blk, 0, stream>>>(
      v_f, B2t, 1024, 128, 131072, 131072);
  mfma_gemm_kernel<false, false, false><<<dim3(16, 32), blk, 0, stream>>>(
      nb, 1024, B2t, 1024, buf_big, 2048, nullptr, nullptr, 0, T, 2048, 1024);
  wsum2_kernel<<<T, 128, 0, stream>>>(buf_big, gv_b, nullptr, hV, nullptr, 16);

  // restores (A_virt materialized bf16 into dead buf_big space)
  avirt_kernel<<<T, blk, 0, stream>>>(hQ, gq_b, 16, avb, 2048);
  mfma_gemm_kernel<false, false, false><<<dim3(8, 32), blk, 0, stream>>>(
      avb, 2048, qkr_t, 2048, Qb, 1024, nullptr, nullptr, 0, T, 1024, 2048);
  avirt_kernel<<<T, blk, 0, stream>>>(hK, gk_b, 16, avb, 2048);
  mfma_gemm_kernel<false, false, false><<<dim3(8, 32), blk, 0, stream>>>(
      avb, 2048, qkr_t, 2048, Kb, 1024, nullptr, nullptr, 0, T, 1024, 2048);
  avirt_kernel<<<T, blk, 0, stream>>>(hV, gv_b, 16, avb, 2048);
  mfma_gemm_kernel<false, false, false><<<dim3(8, 32), blk, 0, stream>>>(
      avb, 2048, vr_t, 2048, Vb, 1024, nullptr, nullptr, 0, T, 1024, 2048);

  // attention (fp32 in, bf16 out) + output proj + residual
  flash_kernel<<<dim3(16, 16, 4), blk, 0, stream>>>(Qb, Kb, Vb, attnb_b);
  mfma_gemm_kernel<false, true, false><<<dim3(8, 32), blk, 0, stream>>>(
      attnb_b, 1024, eo_t, 1024, out, 1024, nullptr, x, 1024, T, 1024, 1024);

  // ---- knowledge circuit ----
  ln_kernel<<<T, blk, 0, stream>>>(out, ln2_scale, ln2_bias, n_f, nb);
  norm_rows_kernel<<<4096, 64, 0, stream>>>(know_emb, embB);
  mfma_gemm_kernel<true, false, true><<<dim3(1, 32), blk, 0, stream>>>(
      nb, 1024, pk_t, 1024, hab, 128, proj_know_b, nullptr, 0, T, 128, 1024);
  tau_kernel<<<T, 64, 0, stream>>>(n_f, tau_know_k, tau_know_b, tau3, 1);

  mfma_gemm_kernel<false, false, false><<<dim3(32, 32), blk, 0, stream>>>(
      hab, 128, embB, 128, buf_big, 4096, nullptr, nullptr, 0, T, 4096, 128);
  gate_kernel<16><<<T, blk, 0, stream>>>(buf_big, tau3, 1, 0, gkn_b, 4096, 32);
  colsum_aux_kernel<<<16, blk, 0, stream>>>(buf_big, 4096, 1.f / 4096.f, aux);

  transpose_to_bf16_kernel<<<dim3(4, 32, 32), blk, 0, stream>>>(
      know_f, B2t, 1024, 128, 131072, 131072);
  mfma_gemm_kernel<false, false, false><<<dim3(32, 32), blk, 0, stream>>>(
      nb, 1024, B2t, 1024, buf_big, 4096, nullptr, nullptr, 0, T, 4096, 1024);
  wsum2_kernel<<<T, 128, 0, stream>>>(buf_big, gkn_b, nullptr, hQ, nullptr, 32);

  avirt_kernel<<<T, blk, 0, stream>>>(hQ, gkn_b, 32, avb, 4096);
  mfma_gemm_kernel<false, true, false><<<dim3(8, 32), blk, 0, stream>>>(
      avb, 4096, knr_t, 4096, out, 1024, nullptr, out, 1024, T, 1024, 4096);
}

// Round 3
// 1522.713 us; speedup vs baseline: 2.5736x; 1.1787x over previous
//
#include <hip/hip_runtime.h>
#include <math.h>

static constexpr int T = 4096;   // B*S
static constexpr int D = 1024;

typedef __bf16 bf16_t;
typedef bf16_t bf16x8 __attribute__((ext_vector_type(8)));
typedef bf16_t bf16x4 __attribute__((ext_vector_type(4)));
typedef float f32x4 __attribute__((ext_vector_type(4)));

#define GLDS16(g, l)                                                        \
  __builtin_amdgcn_global_load_lds(                                         \
      (const __attribute__((address_space(1))) void*)(g),                   \
      (__attribute__((address_space(3))) void*)(l), 16, 0, 0)

// ======================= small kernels =======================

__global__ void zero1_kernel(float* p) { *p = 0.f; }

__global__ __launch_bounds__(256) void ln_kernel(
    const float* __restrict__ x, const float* __restrict__ scale,
    const float* __restrict__ bias, float* __restrict__ out_f,
    bf16_t* __restrict__ out_b)
{
  int t = blockIdx.x;
  const float* xr = x + (size_t)t * D;
  float v[4];
  float s1 = 0.f, s2 = 0.f;
#pragma unroll
  for (int i = 0; i < 4; i++) {
    v[i] = xr[threadIdx.x + i * 256];
    s1 += v[i];
    s2 += v[i] * v[i];
  }
#pragma unroll
  for (int o = 1; o < 64; o <<= 1) {
    s1 += __shfl_xor(s1, o);
    s2 += __shfl_xor(s2, o);
  }
  __shared__ float r1[4], r2[4];
  int wid = threadIdx.x >> 6;
  if ((threadIdx.x & 63) == 0) { r1[wid] = s1; r2[wid] = s2; }
  __syncthreads();
  s1 = r1[0] + r1[1] + r1[2] + r1[3];
  s2 = r2[0] + r2[1] + r2[2] + r2[3];
  float mean = s1 * (1.f / D);
  float var = s2 * (1.f / D) - mean * mean;
  float rstd = rsqrtf(var + 1e-6f);
  float* orow = out_f + (size_t)t * D;
  bf16_t* brow = out_b + (size_t)t * D;
#pragma unroll
  for (int i = 0; i < 4; i++) {
    int d = threadIdx.x + i * 256;
    float o = (v[i] - mean) * rstd * scale[d] + bias[d];
    orow[d] = o;
    brow[d] = (bf16_t)o;
  }
}

// rows of length 128, one wave per row; bf16 normalized output
__global__ __launch_bounds__(64) void norm_rows_kernel(
    const float* __restrict__ e, bf16_t* __restrict__ o)
{
  int r = blockIdx.x;
  const float* row = e + (size_t)r * 128;
  float a = row[threadIdx.x], b = row[threadIdx.x + 64];
  float ss = a * a + b * b;
#pragma unroll
  for (int m = 1; m < 64; m <<= 1) ss += __shfl_xor(ss, m);
  float inv = 1.f / (sqrtf(ss) + 1e-8f);
  bf16_t* orow = o + (size_t)r * 128;
  orow[threadIdx.x] = (bf16_t)(a * inv);
  orow[threadIdx.x + 64] = (bf16_t)(b * inv);
}

// tau = n @ W + b,  W: [D, J], J in {1,3}; one wave per token (fp32)
__global__ __launch_bounds__(64) void tau_kernel(
    const float* __restrict__ n, const float* __restrict__ W,
    const float* __restrict__ b, float* __restrict__ out, int J)
{
  int t = blockIdx.x;
  const float* nr = n + (size_t)t * D;
  for (int j = 0; j < J; j++) {
    float p = 0.f;
#pragma unroll 4
    for (int i = 0; i < 16; i++) {
      int d = threadIdx.x + i * 64;
      p += nr[d] * W[d * J + j];
    }
#pragma unroll
    for (int m = 1; m < 64; m <<= 1) p += __shfl_xor(p, m);
    if (threadIdx.x == 0) out[t * J + j] = p + b[j];
  }
}

// threshold gate + group gate, in place.
template <int PER>
__global__ __launch_bounds__(256) void gate_kernel(
    float* __restrict__ g, const float* __restrict__ tau, int tauStride,
    int tauOff, float* __restrict__ gb, int N, int G)
{
  int t = blockIdx.x;
  float tv = tau[t * tauStride + tauOff];
  float* row = g + (size_t)t * N;
  float r[PER];
  int base = threadIdx.x * PER;
  float psum = 0.f;
#pragma unroll
  for (int i = 0; i < PER; i++) {
    float s = row[base + i] - tv;
    s = fmaxf(s, 0.f);
    r[i] = s;
    psum += s;
  }
  __shared__ float red[4];
  __shared__ float grp[32];
  if (threadIdx.x < 32) grp[threadIdx.x] = 0.f;
  float w = psum;
#pragma unroll
  for (int m = 1; m < 64; m <<= 1) w += __shfl_xor(w, m);
  int wid = threadIdx.x >> 6;
  if ((threadIdx.x & 63) == 0) red[wid] = w;
  __syncthreads();
  float Stot = red[0] + red[1] + red[2] + red[3];
  atomicAdd(&grp[base >> 7], psum);
  __syncthreads();
  float inv = 1.f / (Stot + 1e-8f);
#pragma unroll
  for (int i = 0; i < PER; i++) row[base + i] = r[i] * inv;
  if (threadIdx.x < G) {
    float Gj = grp[threadIdx.x] * inv;
    float gsum = Stot * inv;
    gb[(size_t)t * G + threadIdx.x] = Gj / (gsum + 1e-8f);
  }
}

// column means of g [T,N]; aux += sum_n (mean_n - tinv)^2 * N
__global__ __launch_bounds__(256) void colsum_aux_kernel(
    const float* __restrict__ g, int N, float tinv, float* __restrict__ aux)
{
  int c = blockIdx.x * 256 + threadIdx.x;
  float s = 0.f;
#pragma unroll 8
  for (int t = 0; t < T; t++) s += g[(size_t)t * N + c];
  float mdev = s * (1.f / T) - tinv;
  float p = mdev * mdev * (float)N;
#pragma unroll
  for (int m = 1; m < 64; m <<= 1) p += __shfl_xor(p, m);
  __shared__ float red[4];
  if ((threadIdx.x & 63) == 0) red[threadIdx.x >> 6] = p;
  __syncthreads();
  if (threadIdx.x == 0) atomicAdd(aux, red[0] + red[1] + red[2] + red[3]);
}

// h1[t,r] = sum_n gb1[t,n]*all_h[t, n*128+r]; optional second output
__global__ __launch_bounds__(128) void wsum2_kernel(
    const float* __restrict__ all_h, const float* __restrict__ gb1,
    const float* __restrict__ gb2, float* __restrict__ h1,
    float* __restrict__ h2, int NB)
{
  int t = blockIdx.x;
  int r = threadIdx.x;
  const float* row = all_h + (size_t)t * NB * 128;
  float a1 = 0.f, a2 = 0.f;
  for (int n = 0; n < NB; n++) {
    float v = row[n * 128 + r];
    a1 += gb1[(size_t)t * NB + n] * v;
    if (gb2) a2 += gb2[(size_t)t * NB + n] * v;
  }
  h1[(size_t)t * 128 + r] = a1;
  if (h2) h2[(size_t)t * 128 + r] = a2;
}

// dst[c][r] = (bf16)src[r][c]; src [R,C] fp32, dst [C,R] bf16; batched
__global__ __launch_bounds__(256) void transpose_to_bf16_kernel(
    const float* __restrict__ src, bf16_t* __restrict__ dst,
    int R, int C, size_t sbs, size_t dbs)
{
  __shared__ float tile[32][33];
  int b = blockIdx.z;
  int c0 = blockIdx.x * 32, r0 = blockIdx.y * 32;
  int tx = threadIdx.x & 31, ty = threadIdx.x >> 5;  // 8 rows/pass
  const float* s = src + (size_t)b * sbs;
  bf16_t* d = dst + (size_t)b * dbs;
#pragma unroll
  for (int i = 0; i < 4; i++)
    tile[ty + i * 8][tx] = s[(size_t)(r0 + ty + i * 8) * C + c0 + tx];
  __syncthreads();
#pragma unroll
  for (int i = 0; i < 4; i++)
    d[(size_t)(c0 + ty + i * 8) * R + r0 + tx] = (bf16_t)tile[tx][ty + i * 8];
}

// A_virt[t,k] = (bf16)(gb[t,k>>7]*h[t,k&127]), row-major [T,K]
__global__ __launch_bounds__(256) void avirt_kernel(
    const float* __restrict__ h, const float* __restrict__ gb, int NB,
    bf16_t* __restrict__ A, int K)
{
  int t = blockIdx.x;
  const float* hr = h + (size_t)t * 128;
  const float* gr = gb + (size_t)t * NB;
  bf16_t* ar = A + (size_t)t * K;
  int noct = K >> 3;
  for (int o = threadIdx.x; o < noct; o += 256) {
    int k = o * 8;
    float g = gr[k >> 7];
    bf16x8 v;
#pragma unroll
    for (int i = 0; i < 8; i++) v[i] = (bf16_t)(hr[(k & 127) + i] * g);
    *(bf16x8*)(ar + k) = v;
  }
}

// ============== MFMA GEMM: C[M,N] = A[M,K]bf16 @ Bt[N,K]bf16^T ==============
// 128x128 tile, BK=32, 4 waves (2x2), 4x4 16x16 fragments per wave.
// OUT_MODE: 0 = f32, 1 = bf16, 2 = bf16 transposed V store (Vt[b][col][s])
template <bool HAS_BIAS, bool HAS_RESID, int OUT_MODE>
__global__ __launch_bounds__(256) void mfma_gemm_kernel(
    const bf16_t* __restrict__ A, int lda,
    const bf16_t* __restrict__ Bt, int ldb,
    void* __restrict__ Cv, int ldc,
    const float* __restrict__ bias,
    const float* __restrict__ resid, int ldr,
    int M, int N, int K)
{
  __shared__ bf16_t As[128 * 32];
  __shared__ bf16_t Bs[128 * 32];
  int tid = threadIdx.x;
  int wave = tid >> 6, lane = tid & 63;
  int row0 = blockIdx.y * 128, col0 = blockIdx.x * 128;
  int wr = (wave >> 1) * 64, wc = (wave & 1) * 64;

  f32x4 acc[4][4] = {};

  int srow = (wave << 4) + (lane >> 2);
  int skk = (lane & 3) << 3;
  const bf16_t* gA = A + (size_t)(row0 + srow) * lda + skk;
  const bf16_t* gB = Bt + (size_t)(col0 + srow) * ldb + skk;
  size_t a64 = (size_t)64 * lda, b64 = (size_t)64 * ldb;

  int fr = lane & 15, fq = lane >> 4;

  for (int k0 = 0; k0 < K; k0 += 32) {
    GLDS16(gA + k0, &As[wave * 512]);
    GLDS16(gA + a64 + k0, &As[2048 + wave * 512]);
    GLDS16(gB + k0, &Bs[wave * 512]);
    GLDS16(gB + b64 + k0, &Bs[2048 + wave * 512]);
    __syncthreads();
    bf16x8 af[4], bfr[4];
#pragma unroll
    for (int m = 0; m < 4; m++)
      af[m] = *(const bf16x8*)&As[(wr + m * 16 + fr) * 32 + fq * 8];
#pragma unroll
    for (int n = 0; n < 4; n++)
      bfr[n] = *(const bf16x8*)&Bs[(wc + n * 16 + fr) * 32 + fq * 8];
#pragma unroll
    for (int m = 0; m < 4; m++)
#pragma unroll
      for (int n = 0; n < 4; n++)
        acc[m][n] = __builtin_amdgcn_mfma_f32_16x16x32_bf16(af[m], bfr[n],
                                                            acc[m][n], 0, 0, 0);
    __syncthreads();
  }

#pragma unroll
  for (int m = 0; m < 4; m++) {
#pragma unroll
    for (int n = 0; n < 4; n++) {
      int rowb = row0 + wr + m * 16 + fq * 4;
      int col = col0 + wc + n * 16 + fr;
      if (OUT_MODE == 2) {
        // Vt[b][col][s], b = rowb>>10, s = rowb&1023 (+r), bf16
        bf16x4 v4;
#pragma unroll
        for (int r = 0; r < 4; r++) v4[r] = (bf16_t)acc[m][n][r];
        bf16_t* dst = (bf16_t*)Cv +
            ((size_t)(rowb >> 10) * 1024 + col) * 1024 + (rowb & 1023);
        *(bf16x4*)dst = v4;
      } else {
#pragma unroll
        for (int r = 0; r < 4; r++) {
          int row = rowb + r;
          float v = acc[m][n][r];
          if (HAS_BIAS) v += bias[col];
          if (HAS_RESID) v += resid[(size_t)row * ldr + col];
          if (OUT_MODE == 1)
            ((bf16_t*)Cv)[(size_t)row * ldc + col] = (bf16_t)v;
          else
            ((float*)Cv)[(size_t)row * ldc + col] = v;
        }
      }
    }
  }
}

// ======================= MFMA flash attention (bf16) =======================
// Q,K: [T,1024] bf16 (t = b*1024+s), head h at cols h*64..h*64+63
// Vt:  [4][1024][1024] bf16 = Vt[b][h*64+d][s]
// O:   [T,1024] bf16
__global__ __launch_bounds__(256) void flash_mfma_kernel(
    const bf16_t* __restrict__ Q, const bf16_t* __restrict__ K,
    const bf16_t* __restrict__ Vt, bf16_t* __restrict__ O)
{
  __shared__ bf16_t Pl[4][1024];  // per-wave P[16 q][64 kv], XOR-swizzled
  int tid = threadIdx.x;
  int wave = tid >> 6, lane = tid & 63;
  int fr = lane & 15, fq = lane >> 4;
  int qt = blockIdx.x, h = blockIdx.y, b = blockIdx.z;
  int q0 = qt * 64 + wave * 16;  // this wave's q-strip
  size_t qkbase = ((size_t)b * 1024) * 1024 + (size_t)h * 64;
  size_t vtbase = ((size_t)b * 1024 + (size_t)h * 64) * 1024;

  // Q A-fragments (row = fr, k = fq*8 contiguous)
  bf16x8 qf0 = *(const bf16x8*)&Q[qkbase + (size_t)(q0 + fr) * 1024 + fq * 8];
  bf16x8 qf1 =
      *(const bf16x8*)&Q[qkbase + (size_t)(q0 + fr) * 1024 + 32 + fq * 8];

  f32x4 o_acc[4] = {};  // O^T tiles: d = n*16+fq*4+r, q = fr
  float mrow[4], lrow[4];
#pragma unroll
  for (int r = 0; r < 4; r++) { mrow[r] = -INFINITY; lrow[r] = 0.f; }

  char* P = (char*)&Pl[wave][0];

  for (int kt = 0; kt <= qt; kt++) {
    int k0 = kt * 64;
    f32x4 s[4] = {};
#pragma unroll
    for (int n = 0; n < 4; n++) {
      const bf16_t* krow = &K[qkbase + (size_t)(k0 + n * 16 + fr) * 1024];
      bf16x8 kf0 = *(const bf16x8*)&krow[fq * 8];
      bf16x8 kf1 = *(const bf16x8*)&krow[32 + fq * 8];
      s[n] = __builtin_amdgcn_mfma_f32_16x16x32_bf16(qf0, kf0, s[n], 0, 0, 0);
      s[n] = __builtin_amdgcn_mfma_f32_16x16x32_bf16(qf1, kf1, s[n], 0, 0, 0);
    }
    const float scale = 0.125f;
    bool diag = (kt == qt);
#pragma unroll
    for (int n = 0; n < 4; n++)
#pragma unroll
      for (int r = 0; r < 4; r++) {
        float v = s[n][r] * scale;
        if (diag && (k0 + n * 16 + fr > q0 + fq * 4 + r)) v = -INFINITY;
        s[n][r] = v;
      }
    // online softmax per row (q = fq*4+r), reduce across fr (16-lane groups)
    float corr[4];
#pragma unroll
    for (int r = 0; r < 4; r++) {
      float mx = fmaxf(fmaxf(s[0][r], s[1][r]), fmaxf(s[2][r], s[3][r]));
#pragma unroll
      for (int msk = 1; msk < 16; msk <<= 1) mx = fmaxf(mx, __shfl_xor(mx, msk));
      float mnew = fmaxf(mrow[r], mx);
      corr[r] = __expf(mrow[r] - mnew);
      mrow[r] = mnew;
      float ps = 0.f;
#pragma unroll
      for (int n = 0; n < 4; n++) {
        float p = __expf(s[n][r] - mnew);
        s[n][r] = p;
        ps += p;
      }
#pragma unroll
      for (int msk = 1; msk < 16; msk <<= 1) ps += __shfl_xor(ps, msk);
      lrow[r] = lrow[r] * corr[r] + ps;
    }
    // P -> LDS as P[q][kv] bf16, byte col XOR-swizzled by ((q&7)<<4)
#pragma unroll
    for (int n = 0; n < 4; n++)
#pragma unroll
      for (int r = 0; r < 4; r++) {
        int q = fq * 4 + r;
        int cb = ((n * 16 + fr) * 2) ^ ((q & 7) << 4);
        *(bf16_t*)(P + q * 128 + cb) = (bf16_t)s[n][r];
      }
    // broadcast corr[q] to lanes holding q = fr
    float c0 = __shfl(corr[0], (fr >> 2) << 4);
    float c1 = __shfl(corr[1], (fr >> 2) << 4);
    float c2 = __shfl(corr[2], (fr >> 2) << 4);
    float c3 = __shfl(corr[3], (fr >> 2) << 4);
    int rr = fr & 3;
    float cq = rr == 0 ? c0 : rr == 1 ? c1 : rr == 2 ? c2 : c3;
#pragma unroll
    for (int n = 0; n < 4; n++)
#pragma unroll
      for (int r = 0; r < 4; r++) o_acc[n][r] *= cq;
    // PV: O^T += Vt_frag(A) @ P_frag(B)
#pragma unroll
    for (int c = 0; c < 2; c++) {
      int cb = ((c * 32 + fq * 8) * 2) ^ ((fr & 7) << 4);
      bf16x8 pf = *(const bf16x8*)(P + fr * 128 + cb);
#pragma unroll
      for (int n = 0; n < 4; n++) {
        bf16x8 vf = *(const bf16x8*)&Vt[vtbase + (size_t)(n * 16 + fr) * 1024 +
                                        k0 + c * 32 + fq * 8];
        o_acc[n] =
            __builtin_amdgcn_mfma_f32_16x16x32_bf16(vf, pf, o_acc[n], 0, 0, 0);
      }
    }
  }
  // epilogue: need 1/l for q = fr
  float l0 = __shfl(lrow[0], (fr >> 2) << 4);
  float l1 = __shfl(lrow[1], (fr >> 2) << 4);
  float l2 = __shfl(lrow[2], (fr >> 2) << 4);
  float l3 = __shfl(lrow[3], (fr >> 2) << 4);
  int rr = fr & 3;
  float lq = rr == 0 ? l0 : rr == 1 ? l1 : rr == 2 ? l2 : l3;
  float linv = 1.f / lq;
  size_t orow = qkbase + (size_t)(q0 + fr) * 1024;
#pragma unroll
  for (int n = 0; n < 4; n++) {
    bf16x4 ov;
#pragma unroll
    for (int r = 0; r < 4; r++) ov[r] = (bf16_t)(o_acc[n][r] * linv);
    *(bf16x4*)&O[orow + n * 16 + fq * 4] = ov;
  }
}

// ======================= launch =======================

extern "C" void kernel_launch(void* const* d_in, const int* in_sizes, int n_in,
                              void* d_out, int out_size, void* d_ws,
                              size_t ws_size, hipStream_t stream) {
  (void)in_sizes; (void)n_in; (void)out_size; (void)ws_size;
  const float* x          = (const float*)d_in[0];
  const float* qk_emb     = (const float*)d_in[1];
  const float* v_emb      = (const float*)d_in[2];
  const float* know_emb   = (const float*)d_in[3];
  const float* qk_f       = (const float*)d_in[4];
  const float* qk_r       = (const float*)d_in[5];
  const float* v_f        = (const float*)d_in[6];
  const float* v_r        = (const float*)d_in[7];
  const float* know_f     = (const float*)d_in[8];
  const float* know_r     = (const float*)d_in[9];
  const float* proj_attn_k = (const float*)d_in[10];
  const float* proj_attn_b = (const float*)d_in[11];
  const float* tau_attn_k  = (const float*)d_in[12];
  const float* tau_attn_b  = (const float*)d_in[13];
  const float* proj_know_k = (const float*)d_in[14];
  const float* proj_know_b = (const float*)d_in[15];
  const float* tau_know_k  = (const float*)d_in[16];
  const float* tau_know_b  = (const float*)d_in[17];
  const float* expand_O    = (const float*)d_in[18];
  const float* ln1_scale   = (const float*)d_in[19];
  const float* ln1_bias    = (const float*)d_in[20];
  const float* ln2_scale   = (const float*)d_in[21];
  const float* ln2_bias    = (const float*)d_in[22];

  float* out = (float*)d_out;  // [T,D] + aux scalar
  float* aux = out + (size_t)T * D;

  // ---- workspace arena ----
  float* ws = (float*)d_ws;
  float* n_f   = ws;                       // 4M floats
  float* tau3  = n_f + 4194304;            // 16K
  float* gq_b  = tau3 + 16384;             // 64K
  float* gk_b  = gq_b + 65536;
  float* gv_b  = gk_b + 65536;
  float* gkn_b = gv_b + 65536;             // 128K
  float* hQ    = gkn_b + 131072;           // 512K
  float* hK    = hQ + 524288;
  float* hV    = hK + 524288;
  float* qkvarena = hV + 524288;           // 12M floats (Q,K bf16 + Vt bf16)
  float* buf_big = qkvarena + 12582912;    // 16.78M floats (64MB)

  bf16_t* Qbb = (bf16_t*)qkvarena;                 // T*1024 bf16 (8MB)
  bf16_t* Kbb = Qbb + (size_t)T * 1024;            // 8MB
  bf16_t* Vtb = Kbb + (size_t)T * 1024;            // [4][1024][1024] 8MB

  bf16_t* nb   = (bf16_t*)(buf_big + 16777216);  // T*1024
  bf16_t* hab  = nb + 4194304;                   // T*384 (reused know: T*128)
  bf16_t* embB = hab + 1572864;                  // 524288 (qk|v ; know)
  bf16_t* B2t  = embB + 524288;                  // 4096*1024
  bf16_t* wt   = B2t + 4194304;                  // transposed weights arena
  bf16_t* pa_t  = wt;                   // 384*1024
  bf16_t* qkr_t = pa_t + 393216;        // 1024*2048
  bf16_t* vr_t  = qkr_t + 2097152;      // 1024*2048
  bf16_t* knr_t = vr_t + 2097152;       // 1024*4096
  bf16_t* eo_t  = knr_t + 4194304;      // 1024*1024
  bf16_t* pk_t  = eo_t + 1048576;       // 128*1024

  bf16_t* avb = (bf16_t*)buf_big;                   // up to T*4096 bf16
  bf16_t* attnb_b = (bf16_t*)(buf_big + 12582912);  // T*1024 bf16

  bf16_t* embQ = embB;
  bf16_t* embV = embB + 262144;

  dim3 blk(256);

  zero1_kernel<<<1, 1, 0, stream>>>(aux);

  // weight transposes to bf16 [N,K]
  transpose_to_bf16_kernel<<<dim3(12, 32, 1), blk, 0, stream>>>(
      proj_attn_k, pa_t, 1024, 384, 0, 0);
  transpose_to_bf16_kernel<<<dim3(32, 64, 1), blk, 0, stream>>>(
      qk_r, qkr_t, 2048, 1024, 0, 0);
  transpose_to_bf16_kernel<<<dim3(32, 64, 1), blk, 0, stream>>>(
      v_r, vr_t, 2048, 1024, 0, 0);
  transpose_to_bf16_kernel<<<dim3(32, 128, 1), blk, 0, stream>>>(
      know_r, knr_t, 4096, 1024, 0, 0);
  transpose_to_bf16_kernel<<<dim3(32, 32, 1), blk, 0, stream>>>(
      expand_O, eo_t, 1024, 1024, 0, 0);
  transpose_to_bf16_kernel<<<dim3(4, 32, 1), blk, 0, stream>>>(
      proj_know_k, pk_t, 1024, 128, 0, 0);

  // ---- attention circuit ----
  ln_kernel<<<T, blk, 0, stream>>>(x, ln1_scale, ln1_bias, n_f, nb);
  norm_rows_kernel<<<2048, 64, 0, stream>>>(qk_emb, embQ);
  norm_rows_kernel<<<2048, 64, 0, stream>>>(v_emb, embV);

  mfma_gemm_kernel<true, false, 1><<<dim3(3, 32), blk, 0, stream>>>(
      nb, 1024, pa_t, 1024, hab, 384, proj_attn_b, nullptr, 0, T, 384, 1024);
  tau_kernel<<<T, 64, 0, stream>>>(n_f, tau_attn_k, tau_attn_b, tau3, 3);

  // gate scores + gates + aux
  mfma_gemm_kernel<false, false, 0><<<dim3(16, 32), blk, 0, stream>>>(
      hab + 0, 384, embQ, 128, buf_big, 2048, nullptr, nullptr, 0, T, 2048, 128);
  gate_kernel<8><<<T, blk, 0, stream>>>(buf_big, tau3, 3, 0, gq_b, 2048, 16);
  colsum_aux_kernel<<<8, blk, 0, stream>>>(buf_big, 2048, 1.f / 2048.f, aux);

  mfma_gemm_kernel<false, false, 0><<<dim3(16, 32), blk, 0, stream>>>(
      hab + 128, 384, embQ, 128, buf_big, 2048, nullptr, nullptr, 0, T, 2048, 128);
  gate_kernel<8><<<T, blk, 0, stream>>>(buf_big, tau3, 3, 1, gk_b, 2048, 16);
  colsum_aux_kernel<<<8, blk, 0, stream>>>(buf_big, 2048, 1.f / 2048.f, aux);

  mfma_gemm_kernel<false, false, 0><<<dim3(16, 32), blk, 0, stream>>>(
      hab + 256, 384, embV, 128, buf_big, 2048, nullptr, nullptr, 0, T, 2048, 128);
  gate_kernel<8><<<T, blk, 0, stream>>>(buf_big, tau3, 3, 2, gv_b, 2048, 16);
  colsum_aux_kernel<<<8, blk, 0, stream>>>(buf_big, 2048, 1.f / 2048.f, aux);

  // features (qk basis)
  transpose_to_bf16_kernel<<<dim3(4, 32, 16), blk, 0, stream>>>(
      qk_f, B2t, 1024, 128, 131072, 131072);
  mfma_gemm_kernel<false, false, 0><<<dim3(16, 32), blk, 0, stream>>>(
      nb, 1024, B2t, 1024, buf_big, 2048, nullptr, nullptr, 0, T, 2048, 1024);
  wsum2_kernel<<<T, 128, 0, stream>>>(buf_big, gq_b, gk_b, hQ, hK, 16);

  // features (v basis)
  transpose_to_bf16_kernel<<<dim3(4, 32, 16), blk, 0, stream>>>(
      v_f, B2t, 1024, 128, 131072, 131072);
  mfma_gemm_kernel<false, false, 0><<<dim3(16, 32), blk, 0, stream>>>(
      nb, 1024, B2t, 1024, buf_big, 2048, nullptr, nullptr, 0, T, 2048, 1024);
  wsum2_kernel<<<T, 128, 0, stream>>>(buf_big, gv_b, nullptr, hV, nullptr, 16);

  // restores -> Q,K bf16 and Vt transposed bf16
  avirt_kernel<<<T, blk, 0, stream>>>(hQ, gq_b, 16, avb, 2048);
  mfma_gemm_kernel<false, false, 1><<<dim3(8, 32), blk, 0, stream>>>(
      avb, 2048, qkr_t, 2048, Qbb, 1024, nullptr, nullptr, 0, T, 1024, 2048);
  avirt_kernel<<<T, blk, 0, stream>>>(hK, gk_b, 16, avb, 2048);
  mfma_gemm_kernel<false, false, 1><<<dim3(8, 32), blk, 0, stream>>>(
      avb, 2048, qkr_t, 2048, Kbb, 1024, nullptr, nullptr, 0, T, 1024, 2048);
  avirt_kernel<<<T, blk, 0, stream>>>(hV, gv_b, 16, avb, 2048);
  mfma_gemm_kernel<false, false, 2><<<dim3(8, 32), blk, 0, stream>>>(
      avb, 2048, vr_t, 2048, Vtb, 1024, nullptr, nullptr, 0, T, 1024, 2048);

  // MFMA flash attention + output proj + residual
  flash_mfma_kernel<<<dim3(16, 16, 4), blk, 0, stream>>>(Qbb, Kbb, Vtb,
                                                         attnb_b);
  mfma_gemm_kernel<false, true, 0><<<dim3(8, 32), blk, 0, stream>>>(
      attnb_b, 1024, eo_t, 1024, out, 1024, nullptr, x, 1024, T, 1024, 1024);

  // ---- knowledge circuit ----
  ln_kernel<<<T, blk, 0, stream>>>(out, ln2_scale, ln2_bias, n_f, nb);
  norm_rows_kernel<<<4096, 64, 0, stream>>>(know_emb, embB);
  mfma_gemm_kernel<true, false, 1><<<dim3(1, 32), blk, 0, stream>>>(
      nb, 1024, pk_t, 1024, hab, 128, proj_know_b, nullptr, 0, T, 128, 1024);
  tau_kernel<<<T, 64, 0, stream>>>(n_f, tau_know_k, tau_know_b, tau3, 1);

  mfma_gemm_kernel<false, false, 0><<<dim3(32, 32), blk, 0, stream>>>(
      hab, 128, embB, 128, buf_big, 4096, nullptr, nullptr, 0, T, 4096, 128);
  gate_kernel<16><<<T, blk, 0, stream>>>(buf_big, tau3, 1, 0, gkn_b, 4096, 32);
  colsum_aux_kernel<<<16, blk, 0, stream>>>(buf_big, 4096, 1.f / 4096.f, aux);

  transpose_to_bf16_kernel<<<dim3(4, 32, 32), blk, 0, stream>>>(
      know_f, B2t, 1024, 128, 131072, 131072);
  mfma_gemm_kernel<false, false, 0><<<dim3(32, 32), blk, 0, stream>>>(
      nb, 1024, B2t, 1024, buf_big, 4096, nullptr, nullptr, 0, T, 4096, 1024);
  wsum2_kernel<<<T, 128, 0, stream>>>(buf_big, gkn_b, nullptr, hQ, nullptr, 32);

  avirt_kernel<<<T, blk, 0, stream>>>(hQ, gkn_b, 32, avb, 4096);
  mfma_gemm_kernel<false, true, 0><<<dim3(8, 32), blk, 0, stream>>>(
      avb, 4096, knr_t, 4096, out, 1024, nullptr, out, 1024, T, 1024, 4096);
}

// Round 4
// 881.889 us; speedup vs baseline: 4.4438x; 1.7266x over previous
//
#include <hip/hip_runtime.h>
#include <math.h>

static constexpr int T = 4096;   // B*S
static constexpr int D = 1024;

typedef __bf16 bf16_t;
typedef bf16_t bf16x8 __attribute__((ext_vector_type(8)));
typedef bf16_t bf16x4 __attribute__((ext_vector_type(4)));
typedef float f32x4 __attribute__((ext_vector_type(4)));

#define GLDS16(g, l)                                                        \
  __builtin_amdgcn_global_load_lds(                                         \
      (const __attribute__((address_space(1))) void*)(g),                   \
      (__attribute__((address_space(3))) void*)(l), 16, 0, 0)

// ======================= small kernels =======================

__global__ void zero1_kernel(float* p) { *p = 0.f; }

__global__ __launch_bounds__(256) void ln_kernel(
    const float* __restrict__ x, const float* __restrict__ scale,
    const float* __restrict__ bias, float* __restrict__ out_f,
    bf16_t* __restrict__ out_b)
{
  int t = blockIdx.x;
  const float* xr = x + (size_t)t * D;
  float v[4];
  float s1 = 0.f, s2 = 0.f;
#pragma unroll
  for (int i = 0; i < 4; i++) {
    v[i] = xr[threadIdx.x + i * 256];
    s1 += v[i];
    s2 += v[i] * v[i];
  }
#pragma unroll
  for (int o = 1; o < 64; o <<= 1) {
    s1 += __shfl_xor(s1, o);
    s2 += __shfl_xor(s2, o);
  }
  __shared__ float r1[4], r2[4];
  int wid = threadIdx.x >> 6;
  if ((threadIdx.x & 63) == 0) { r1[wid] = s1; r2[wid] = s2; }
  __syncthreads();
  s1 = r1[0] + r1[1] + r1[2] + r1[3];
  s2 = r2[0] + r2[1] + r2[2] + r2[3];
  float mean = s1 * (1.f / D);
  float var = s2 * (1.f / D) - mean * mean;
  float rstd = rsqrtf(var + 1e-6f);
  float* orow = out_f + (size_t)t * D;
  bf16_t* brow = out_b + (size_t)t * D;
#pragma unroll
  for (int i = 0; i < 4; i++) {
    int d = threadIdx.x + i * 256;
    float o = (v[i] - mean) * rstd * scale[d] + bias[d];
    orow[d] = o;
    brow[d] = (bf16_t)o;
  }
}

// rows of length 128, one wave per row; bf16 normalized output
__global__ __launch_bounds__(64) void norm_rows_kernel(
    const float* __restrict__ e, bf16_t* __restrict__ o)
{
  int r = blockIdx.x;
  const float* row = e + (size_t)r * 128;
  float a = row[threadIdx.x], b = row[threadIdx.x + 64];
  float ss = a * a + b * b;
#pragma unroll
  for (int m = 1; m < 64; m <<= 1) ss += __shfl_xor(ss, m);
  float inv = 1.f / (sqrtf(ss) + 1e-8f);
  bf16_t* orow = o + (size_t)r * 128;
  orow[threadIdx.x] = (bf16_t)(a * inv);
  orow[threadIdx.x + 64] = (bf16_t)(b * inv);
}

// tau = n @ W + b,  W: [D, J], J in {1,3}; one wave per token (fp32)
__global__ __launch_bounds__(64) void tau_kernel(
    const float* __restrict__ n, const float* __restrict__ W,
    const float* __restrict__ b, float* __restrict__ out, int J)
{
  int t = blockIdx.x;
  const float* nr = n + (size_t)t * D;
  for (int j = 0; j < J; j++) {
    float p = 0.f;
#pragma unroll 4
    for (int i = 0; i < 16; i++) {
      int d = threadIdx.x + i * 64;
      p += nr[d] * W[d * J + j];
    }
#pragma unroll
    for (int m = 1; m < 64; m <<= 1) p += __shfl_xor(p, m);
    if (threadIdx.x == 0) out[t * J + j] = p + b[j];
  }
}

// threshold gate + group gate, in place.
template <int PER>
__global__ __launch_bounds__(256) void gate_kernel(
    float* __restrict__ g, const float* __restrict__ tau, int tauStride,
    int tauOff, float* __restrict__ gb, int N, int G)
{
  int t = blockIdx.x;
  float tv = tau[t * tauStride + tauOff];
  float* row = g + (size_t)t * N;
  float r[PER];
  int base = threadIdx.x * PER;
  float psum = 0.f;
#pragma unroll
  for (int i = 0; i < PER; i++) {
    float s = row[base + i] - tv;
    s = fmaxf(s, 0.f);
    r[i] = s;
    psum += s;
  }
  __shared__ float red[4];
  __shared__ float grp[32];
  if (threadIdx.x < 32) grp[threadIdx.x] = 0.f;
  float w = psum;
#pragma unroll
  for (int m = 1; m < 64; m <<= 1) w += __shfl_xor(w, m);
  int wid = threadIdx.x >> 6;
  if ((threadIdx.x & 63) == 0) red[wid] = w;
  __syncthreads();
  float Stot = red[0] + red[1] + red[2] + red[3];
  atomicAdd(&grp[base >> 7], psum);
  __syncthreads();
  float inv = 1.f / (Stot + 1e-8f);
#pragma unroll
  for (int i = 0; i < PER; i++) row[base + i] = r[i] * inv;
  if (threadIdx.x < G) {
    float Gj = grp[threadIdx.x] * inv;
    float gsum = Stot * inv;
    gb[(size_t)t * G + threadIdx.x] = Gj / (gsum + 1e-8f);
  }
}

// stage 1: partial column sums of g [T,N] over 128-row chunks
__global__ __launch_bounds__(256) void colsum_part_kernel(
    const float* __restrict__ g, int N, float* __restrict__ colsum)
{
  int c = blockIdx.x * 256 + threadIdx.x;
  int r0 = blockIdx.y * 128;
  const float* p = g + (size_t)r0 * N + c;
  float s = 0.f;
#pragma unroll 8
  for (int t = 0; t < 128; t++) s += p[(size_t)t * N];
  atomicAdd(&colsum[c], s);
}

// stage 2: aux += sum_c (colsum[c]/T - tinv)^2 * N
__global__ __launch_bounds__(256) void colsum_fin_kernel(
    const float* __restrict__ colsum, int N, float tinv,
    float* __restrict__ aux)
{
  int c = blockIdx.x * 256 + threadIdx.x;
  float mdev = colsum[c] * (1.f / T) - tinv;
  float p = mdev * mdev * (float)N;
#pragma unroll
  for (int m = 1; m < 64; m <<= 1) p += __shfl_xor(p, m);
  __shared__ float red[4];
  if ((threadIdx.x & 63) == 0) red[threadIdx.x >> 6] = p;
  __syncthreads();
  if (threadIdx.x == 0) atomicAdd(aux, red[0] + red[1] + red[2] + red[3]);
}

// h1[t,r] = sum_n gb1[t,n]*all_h[t, n*128+r]; optional second output
__global__ __launch_bounds__(128) void wsum2_kernel(
    const float* __restrict__ all_h, const float* __restrict__ gb1,
    const float* __restrict__ gb2, float* __restrict__ h1,
    float* __restrict__ h2, int NB)
{
  int t = blockIdx.x;
  int r = threadIdx.x;
  const float* row = all_h + (size_t)t * NB * 128;
  float a1 = 0.f, a2 = 0.f;
  for (int n = 0; n < NB; n++) {
    float v = row[n * 128 + r];
    a1 += gb1[(size_t)t * NB + n] * v;
    if (gb2) a2 += gb2[(size_t)t * NB + n] * v;
  }
  h1[(size_t)t * 128 + r] = a1;
  if (h2) h2[(size_t)t * 128 + r] = a2;
}

// dst[c][r] = (bf16)src[r][c]; src [R,C] fp32, dst [C,R] bf16; batched
__global__ __launch_bounds__(256) void transpose_to_bf16_kernel(
    const float* __restrict__ src, bf16_t* __restrict__ dst,
    int R, int C, size_t sbs, size_t dbs)
{
  __shared__ float tile[32][33];
  int b = blockIdx.z;
  int c0 = blockIdx.x * 32, r0 = blockIdx.y * 32;
  int tx = threadIdx.x & 31, ty = threadIdx.x >> 5;  // 8 rows/pass
  const float* s = src + (size_t)b * sbs;
  bf16_t* d = dst + (size_t)b * dbs;
#pragma unroll
  for (int i = 0; i < 4; i++)
    tile[ty + i * 8][tx] = s[(size_t)(r0 + ty + i * 8) * C + c0 + tx];
  __syncthreads();
#pragma unroll
  for (int i = 0; i < 4; i++)
    d[(size_t)(c0 + ty + i * 8) * R + r0 + tx] = (bf16_t)tile[tx][ty + i * 8];
}

// A_virt[t,k] = (bf16)(gb[t,k>>7]*h[t,k&127]), row-major [T,K]
__global__ __launch_bounds__(256) void avirt_kernel(
    const float* __restrict__ h, const float* __restrict__ gb, int NB,
    bf16_t* __restrict__ A, int K)
{
  int t = blockIdx.x;
  const float* hr = h + (size_t)t * 128;
  const float* gr = gb + (size_t)t * NB;
  bf16_t* ar = A + (size_t)t * K;
  int noct = K >> 3;
  for (int o = threadIdx.x; o < noct; o += 256) {
    int k = o * 8;
    float g = gr[k >> 7];
    bf16x8 v;
#pragma unroll
    for (int i = 0; i < 8; i++) v[i] = (bf16_t)(hr[(k & 127) + i] * g);
    *(bf16x8*)(ar + k) = v;
  }
}

// ============== MFMA GEMM: C[M,N] = A[M,K]bf16 @ Bt[N,K]bf16^T ==============
// 128x128 tile, BK=32, 4 waves (2x2), 4x4 16x16 fragments per wave.
// OUT_MODE: 0 = f32, 1 = bf16, 2 = bf16 transposed V store (Vt[b][col][s])
template <bool HAS_BIAS, bool HAS_RESID, int OUT_MODE>
__global__ __launch_bounds__(256) void mfma_gemm_kernel(
    const bf16_t* __restrict__ A, int lda,
    const bf16_t* __restrict__ Bt, int ldb,
    void* __restrict__ Cv, int ldc,
    const float* __restrict__ bias,
    const float* __restrict__ resid, int ldr,
    int M, int N, int K)
{
  __shared__ bf16_t As[128 * 32];
  __shared__ bf16_t Bs[128 * 32];
  int tid = threadIdx.x;
  int wave = tid >> 6, lane = tid & 63;
  int row0 = blockIdx.y * 128, col0 = blockIdx.x * 128;
  int wr = (wave >> 1) * 64, wc = (wave & 1) * 64;

  f32x4 acc[4][4] = {};

  int srow = (wave << 4) + (lane >> 2);
  int skk = (lane & 3) << 3;
  const bf16_t* gA = A + (size_t)(row0 + srow) * lda + skk;
  const bf16_t* gB = Bt + (size_t)(col0 + srow) * ldb + skk;
  size_t a64 = (size_t)64 * lda, b64 = (size_t)64 * ldb;

  int fr = lane & 15, fq = lane >> 4;

  for (int k0 = 0; k0 < K; k0 += 32) {
    GLDS16(gA + k0, &As[wave * 512]);
    GLDS16(gA + a64 + k0, &As[2048 + wave * 512]);
    GLDS16(gB + k0, &Bs[wave * 512]);
    GLDS16(gB + b64 + k0, &Bs[2048 + wave * 512]);
    __syncthreads();
    bf16x8 af[4], bfr[4];
#pragma unroll
    for (int m = 0; m < 4; m++)
      af[m] = *(const bf16x8*)&As[(wr + m * 16 + fr) * 32 + fq * 8];
#pragma unroll
    for (int n = 0; n < 4; n++)
      bfr[n] = *(const bf16x8*)&Bs[(wc + n * 16 + fr) * 32 + fq * 8];
#pragma unroll
    for (int m = 0; m < 4; m++)
#pragma unroll
      for (int n = 0; n < 4; n++)
        acc[m][n] = __builtin_amdgcn_mfma_f32_16x16x32_bf16(af[m], bfr[n],
                                                            acc[m][n], 0, 0, 0);
    __syncthreads();
  }

#pragma unroll
  for (int m = 0; m < 4; m++) {
#pragma unroll
    for (int n = 0; n < 4; n++) {
      int rowb = row0 + wr + m * 16 + fq * 4;
      int col = col0 + wc + n * 16 + fr;
      if (OUT_MODE == 2) {
        bf16x4 v4;
#pragma unroll
        for (int r = 0; r < 4; r++) v4[r] = (bf16_t)acc[m][n][r];
        bf16_t* dst = (bf16_t*)Cv +
            ((size_t)(rowb >> 10) * 1024 + col) * 1024 + (rowb & 1023);
        *(bf16x4*)dst = v4;
      } else {
#pragma unroll
        for (int r = 0; r < 4; r++) {
          int row = rowb + r;
          float v = acc[m][n][r];
          if (HAS_BIAS) v += bias[col];
          if (HAS_RESID) v += resid[(size_t)row * ldr + col];
          if (OUT_MODE == 1)
            ((bf16_t*)Cv)[(size_t)row * ldc + col] = (bf16_t)v;
          else
            ((float*)Cv)[(size_t)row * ldc + col] = v;
        }
      }
    }
  }
}

// ======================= MFMA flash attention (bf16) =======================
__global__ __launch_bounds__(256) void flash_mfma_kernel(
    const bf16_t* __restrict__ Q, const bf16_t* __restrict__ K,
    const bf16_t* __restrict__ Vt, bf16_t* __restrict__ O)
{
  __shared__ bf16_t Pl[4][1024];  // per-wave P[16 q][64 kv], XOR-swizzled
  int tid = threadIdx.x;
  int wave = tid >> 6, lane = tid & 63;
  int fr = lane & 15, fq = lane >> 4;
  int qt = blockIdx.x, h = blockIdx.y, b = blockIdx.z;
  int q0 = qt * 64 + wave * 16;
  size_t qkbase = ((size_t)b * 1024) * 1024 + (size_t)h * 64;
  size_t vtbase = ((size_t)b * 1024 + (size_t)h * 64) * 1024;

  bf16x8 qf0 = *(const bf16x8*)&Q[qkbase + (size_t)(q0 + fr) * 1024 + fq * 8];
  bf16x8 qf1 =
      *(const bf16x8*)&Q[qkbase + (size_t)(q0 + fr) * 1024 + 32 + fq * 8];

  f32x4 o_acc[4] = {};
  float mrow[4], lrow[4];
#pragma unroll
  for (int r = 0; r < 4; r++) { mrow[r] = -INFINITY; lrow[r] = 0.f; }

  char* P = (char*)&Pl[wave][0];

  for (int kt = 0; kt <= qt; kt++) {
    int k0 = kt * 64;
    f32x4 s[4] = {};
#pragma unroll
    for (int n = 0; n < 4; n++) {
      const bf16_t* krow = &K[qkbase + (size_t)(k0 + n * 16 + fr) * 1024];
      bf16x8 kf0 = *(const bf16x8*)&krow[fq * 8];
      bf16x8 kf1 = *(const bf16x8*)&krow[32 + fq * 8];
      s[n] = __builtin_amdgcn_mfma_f32_16x16x32_bf16(qf0, kf0, s[n], 0, 0, 0);
      s[n] = __builtin_amdgcn_mfma_f32_16x16x32_bf16(qf1, kf1, s[n], 0, 0, 0);
    }
    const float scale = 0.125f;
    bool diag = (kt == qt);
#pragma unroll
    for (int n = 0; n < 4; n++)
#pragma unroll
      for (int r = 0; r < 4; r++) {
        float v = s[n][r] * scale;
        if (diag && (k0 + n * 16 + fr > q0 + fq * 4 + r)) v = -INFINITY;
        s[n][r] = v;
      }
    float corr[4];
#pragma unroll
    for (int r = 0; r < 4; r++) {
      float mx = fmaxf(fmaxf(s[0][r], s[1][r]), fmaxf(s[2][r], s[3][r]));
#pragma unroll
      for (int msk = 1; msk < 16; msk <<= 1) mx = fmaxf(mx, __shfl_xor(mx, msk));
      float mnew = fmaxf(mrow[r], mx);
      corr[r] = __expf(mrow[r] - mnew);
      mrow[r] = mnew;
      float ps = 0.f;
#pragma unroll
      for (int n = 0; n < 4; n++) {
        float p = __expf(s[n][r] - mnew);
        s[n][r] = p;
        ps += p;
      }
#pragma unroll
      for (int msk = 1; msk < 16; msk <<= 1) ps += __shfl_xor(ps, msk);
      lrow[r] = lrow[r] * corr[r] + ps;
    }
#pragma unroll
    for (int n = 0; n < 4; n++)
#pragma unroll
      for (int r = 0; r < 4; r++) {
        int q = fq * 4 + r;
        int cb = ((n * 16 + fr) * 2) ^ ((q & 7) << 4);
        *(bf16_t*)(P + q * 128 + cb) = (bf16_t)s[n][r];
      }
    float c0 = __shfl(corr[0], (fr >> 2) << 4);
    float c1 = __shfl(corr[1], (fr >> 2) << 4);
    float c2 = __shfl(corr[2], (fr >> 2) << 4);
    float c3 = __shfl(corr[3], (fr >> 2) << 4);
    int rr = fr & 3;
    float cq = rr == 0 ? c0 : rr == 1 ? c1 : rr == 2 ? c2 : c3;
#pragma unroll
    for (int n = 0; n < 4; n++)
#pragma unroll
      for (int r = 0; r < 4; r++) o_acc[n][r] *= cq;
#pragma unroll
    for (int c = 0; c < 2; c++) {
      int cb = ((c * 32 + fq * 8) * 2) ^ ((fr & 7) << 4);
      bf16x8 pf = *(const bf16x8*)(P + fr * 128 + cb);
#pragma unroll
      for (int n = 0; n < 4; n++) {
        bf16x8 vf = *(const bf16x8*)&Vt[vtbase + (size_t)(n * 16 + fr) * 1024 +
                                        k0 + c * 32 + fq * 8];
        o_acc[n] =
            __builtin_amdgcn_mfma_f32_16x16x32_bf16(vf, pf, o_acc[n], 0, 0, 0);
      }
    }
  }
  float l0 = __shfl(lrow[0], (fr >> 2) << 4);
  float l1 = __shfl(lrow[1], (fr >> 2) << 4);
  float l2 = __shfl(lrow[2], (fr >> 2) << 4);
  float l3 = __shfl(lrow[3], (fr >> 2) << 4);
  int rr = fr & 3;
  float lq = rr == 0 ? l0 : rr == 1 ? l1 : rr == 2 ? l2 : l3;
  float linv = 1.f / lq;
  size_t orow = qkbase + (size_t)(q0 + fr) * 1024;
#pragma unroll
  for (int n = 0; n < 4; n++) {
    bf16x4 ov;
#pragma unroll
    for (int r = 0; r < 4; r++) ov[r] = (bf16_t)(o_acc[n][r] * linv);
    *(bf16x4*)&O[orow + n * 16 + fq * 4] = ov;
  }
}

// ======================= launch =======================

extern "C" void kernel_launch(void* const* d_in, const int* in_sizes, int n_in,
                              void* d_out, int out_size, void* d_ws,
                              size_t ws_size, hipStream_t stream) {
  (void)in_sizes; (void)n_in; (void)out_size; (void)ws_size;
  const float* x          = (const float*)d_in[0];
  const float* qk_emb     = (const float*)d_in[1];
  const float* v_emb      = (const float*)d_in[2];
  const float* know_emb   = (const float*)d_in[3];
  const float* qk_f       = (const float*)d_in[4];
  const float* qk_r       = (const float*)d_in[5];
  const float* v_f        = (const float*)d_in[6];
  const float* v_r        = (const float*)d_in[7];
  const float* know_f     = (const float*)d_in[8];
  const float* know_r     = (const float*)d_in[9];
  const float* proj_attn_k = (const float*)d_in[10];
  const float* proj_attn_b = (const float*)d_in[11];
  const float* tau_attn_k  = (const float*)d_in[12];
  const float* tau_attn_b  = (const float*)d_in[13];
  const float* proj_know_k = (const float*)d_in[14];
  const float* proj_know_b = (const float*)d_in[15];
  const float* tau_know_k  = (const float*)d_in[16];
  const float* tau_know_b  = (const float*)d_in[17];
  const float* expand_O    = (const float*)d_in[18];
  const float* ln1_scale   = (const float*)d_in[19];
  const float* ln1_bias    = (const float*)d_in[20];
  const float* ln2_scale   = (const float*)d_in[21];
  const float* ln2_bias    = (const float*)d_in[22];

  float* out = (float*)d_out;  // [T,D] + aux scalar
  float* aux = out + (size_t)T * D;

  // ---- workspace arena ----
  float* ws = (float*)d_ws;
  float* n_f   = ws;                       // 4M floats
  float* tau3  = n_f + 4194304;            // 16K
  float* gq_b  = tau3 + 16384;             // 64K
  float* gk_b  = gq_b + 65536;
  float* gv_b  = gk_b + 65536;
  float* gkn_b = gv_b + 65536;             // 128K
  float* csum  = gkn_b + 131072;           // 4096 (colsum accumulator)
  float* hQ    = csum + 4096;              // 512K
  float* hK    = hQ + 524288;
  float* hV    = hK + 524288;
  float* qkvarena = hV + 524288;           // 12M floats (Q,K bf16 + Vt bf16)
  float* buf_big = qkvarena + 12582912;    // 16.78M floats (64MB)

  bf16_t* Qbb = (bf16_t*)qkvarena;                 // T*1024 bf16 (8MB)
  bf16_t* Kbb = Qbb + (size_t)T * 1024;            // 8MB
  bf16_t* Vtb = Kbb + (size_t)T * 1024;            // [4][1024][1024] 8MB

  bf16_t* nb   = (bf16_t*)(buf_big + 16777216);  // T*1024
  bf16_t* hab  = nb + 4194304;                   // T*384 (reused know: T*128)
  bf16_t* embB = hab + 1572864;                  // 524288 (qk|v ; know)
  bf16_t* B2t  = embB + 524288;                  // 4096*1024
  bf16_t* wt   = B2t + 4194304;                  // transposed weights arena
  bf16_t* pa_t  = wt;                   // 384*1024
  bf16_t* qkr_t = pa_t + 393216;        // 1024*2048
  bf16_t* vr_t  = qkr_t + 2097152;      // 1024*2048
  bf16_t* knr_t = vr_t + 2097152;       // 1024*4096
  bf16_t* eo_t  = knr_t + 4194304;      // 1024*1024
  bf16_t* pk_t  = eo_t + 1048576;       // 128*1024

  bf16_t* avb = (bf16_t*)buf_big;                   // up to T*4096 bf16
  bf16_t* attnb_b = (bf16_t*)(buf_big + 12582912);  // T*1024 bf16

  bf16_t* embQ = embB;
  bf16_t* embV = embB + 262144;

  dim3 blk(256);

  zero1_kernel<<<1, 1, 0, stream>>>(aux);

  // weight transposes to bf16 [N,K]
  transpose_to_bf16_kernel<<<dim3(12, 32, 1), blk, 0, stream>>>(
      proj_attn_k, pa_t, 1024, 384, 0, 0);
  transpose_to_bf16_kernel<<<dim3(32, 64, 1), blk, 0, stream>>>(
      qk_r, qkr_t, 2048, 1024, 0, 0);
  transpose_to_bf16_kernel<<<dim3(32, 64, 1), blk, 0, stream>>>(
      v_r, vr_t, 2048, 1024, 0, 0);
  transpose_to_bf16_kernel<<<dim3(32, 128, 1), blk, 0, stream>>>(
      know_r, knr_t, 4096, 1024, 0, 0);
  transpose_to_bf16_kernel<<<dim3(32, 32, 1), blk, 0, stream>>>(
      expand_O, eo_t, 1024, 1024, 0, 0);
  transpose_to_bf16_kernel<<<dim3(4, 32, 1), blk, 0, stream>>>(
      proj_know_k, pk_t, 1024, 128, 0, 0);

  // ---- attention circuit ----
  ln_kernel<<<T, blk, 0, stream>>>(x, ln1_scale, ln1_bias, n_f, nb);
  norm_rows_kernel<<<2048, 64, 0, stream>>>(qk_emb, embQ);
  norm_rows_kernel<<<2048, 64, 0, stream>>>(v_emb, embV);

  mfma_gemm_kernel<true, false, 1><<<dim3(3, 32), blk, 0, stream>>>(
      nb, 1024, pa_t, 1024, hab, 384, proj_attn_b, nullptr, 0, T, 384, 1024);
  tau_kernel<<<T, 64, 0, stream>>>(n_f, tau_attn_k, tau_attn_b, tau3, 3);

  // gate scores + gates + aux
  mfma_gemm_kernel<false, false, 0><<<dim3(16, 32), blk, 0, stream>>>(
      hab + 0, 384, embQ, 128, buf_big, 2048, nullptr, nullptr, 0, T, 2048, 128);
  gate_kernel<8><<<T, blk, 0, stream>>>(buf_big, tau3, 3, 0, gq_b, 2048, 16);
  hipMemsetAsync(csum, 0, 2048 * sizeof(float), stream);
  colsum_part_kernel<<<dim3(8, 32), blk, 0, stream>>>(buf_big, 2048, csum);
  colsum_fin_kernel<<<8, blk, 0, stream>>>(csum, 2048, 1.f / 2048.f, aux);

  mfma_gemm_kernel<false, false, 0><<<dim3(16, 32), blk, 0, stream>>>(
      hab + 128, 384, embQ, 128, buf_big, 2048, nullptr, nullptr, 0, T, 2048, 128);
  gate_kernel<8><<<T, blk, 0, stream>>>(buf_big, tau3, 3, 1, gk_b, 2048, 16);
  hipMemsetAsync(csum, 0, 2048 * sizeof(float), stream);
  colsum_part_kernel<<<dim3(8, 32), blk, 0, stream>>>(buf_big, 2048, csum);
  colsum_fin_kernel<<<8, blk, 0, stream>>>(csum, 2048, 1.f / 2048.f, aux);

  mfma_gemm_kernel<false, false, 0><<<dim3(16, 32), blk, 0, stream>>>(
      hab + 256, 384, embV, 128, buf_big, 2048, nullptr, nullptr, 0, T, 2048, 128);
  gate_kernel<8><<<T, blk, 0, stream>>>(buf_big, tau3, 3, 2, gv_b, 2048, 16);
  hipMemsetAsync(csum, 0, 2048 * sizeof(float), stream);
  colsum_part_kernel<<<dim3(8, 32), blk, 0, stream>>>(buf_big, 2048, csum);
  colsum_fin_kernel<<<8, blk, 0, stream>>>(csum, 2048, 1.f / 2048.f, aux);

  // features (qk basis)
  transpose_to_bf16_kernel<<<dim3(4, 32, 16), blk, 0, stream>>>(
      qk_f, B2t, 1024, 128, 131072, 131072);
  mfma_gemm_kernel<false, false, 0><<<dim3(16, 32), blk, 0, stream>>>(
      nb, 1024, B2t, 1024, buf_big, 2048, nullptr, nullptr, 0, T, 2048, 1024);
  wsum2_kernel<<<T, 128, 0, stream>>>(buf_big, gq_b, gk_b, hQ, hK, 16);

  // features (v basis)
  transpose_to_bf16_kernel<<<dim3(4, 32, 16), blk, 0, stream>>>(
      v_f, B2t, 1024, 128, 131072, 131072);
  mfma_gemm_kernel<false, false, 0><<<dim3(16, 32), blk, 0, stream>>>(
      nb, 1024, B2t, 1024, buf_big, 2048, nullptr, nullptr, 0, T, 2048, 1024);
  wsum2_kernel<<<T, 128, 0, stream>>>(buf_big, gv_b, nullptr, hV, nullptr, 16);

  // restores -> Q,K bf16 and Vt transposed bf16
  avirt_kernel<<<T, blk, 0, stream>>>(hQ, gq_b, 16, avb, 2048);
  mfma_gemm_kernel<false, false, 1><<<dim3(8, 32), blk, 0, stream>>>(
      avb, 2048, qkr_t, 2048, Qbb, 1024, nullptr, nullptr, 0, T, 1024, 2048);
  avirt_kernel<<<T, blk, 0, stream>>>(hK, gk_b, 16, avb, 2048);
  mfma_gemm_kernel<false, false, 1><<<dim3(8, 32), blk, 0, stream>>>(
      avb, 2048, qkr_t, 2048, Kbb, 1024, nullptr, nullptr, 0, T, 1024, 2048);
  avirt_kernel<<<T, blk, 0, stream>>>(hV, gv_b, 16, avb, 2048);
  mfma_gemm_kernel<false, false, 2><<<dim3(8, 32), blk, 0, stream>>>(
      avb, 2048, vr_t, 2048, Vtb, 1024, nullptr, nullptr, 0, T, 1024, 2048);

  // MFMA flash attention + output proj + residual
  flash_mfma_kernel<<<dim3(16, 16, 4), blk, 0, stream>>>(Qbb, Kbb, Vtb,
                                                         attnb_b);
  mfma_gemm_kernel<false, true, 0><<<dim3(8, 32), blk, 0, stream>>>(
      attnb_b, 1024, eo_t, 1024, out, 1024, nullptr, x, 1024, T, 1024, 1024);

  // ---- knowledge circuit ----
  ln_kernel<<<T, blk, 0, stream>>>(out, ln2_scale, ln2_bias, n_f, nb);
  norm_rows_kernel<<<4096, 64, 0, stream>>>(know_emb, embB);
  mfma_gemm_kernel<true, false, 1><<<dim3(1, 32), blk, 0, stream>>>(
      nb, 1024, pk_t, 1024, hab, 128, proj_know_b, nullptr, 0, T, 128, 1024);
  tau_kernel<<<T, 64, 0, stream>>>(n_f, tau_know_k, tau_know_b, tau3, 1);

  mfma_gemm_kernel<false, false, 0><<<dim3(32, 32), blk, 0, stream>>>(
      hab, 128, embB, 128, buf_big, 4096, nullptr, nullptr, 0, T, 4096, 128);
  gate_kernel<16><<<T, blk, 0, stream>>>(buf_big, tau3, 1, 0, gkn_b, 4096, 32);
  hipMemsetAsync(csum, 0, 4096 * sizeof(float), stream);
  colsum_part_kernel<<<dim3(16, 32), blk, 0, stream>>>(buf_big, 4096, csum);
  colsum_fin_kernel<<<16, blk, 0, stream>>>(csum, 4096, 1.f / 4096.f, aux);

  transpose_to_bf16_kernel<<<dim3(4, 32, 32), blk, 0, stream>>>(
      know_f, B2t, 1024, 128, 131072, 131072);
  mfma_gemm_kernel<false, false, 0><<<dim3(32, 32), blk, 0, stream>>>(
      nb, 1024, B2t, 1024, buf_big, 4096, nullptr, nullptr, 0, T, 4096, 1024);
  wsum2_kernel<<<T, 128, 0, stream>>>(buf_big, gkn_b, nullptr, hQ, nullptr, 32);

  avirt_kernel<<<T, blk, 0, stream>>>(hQ, gkn_b, 32, avb, 4096);
  mfma_gemm_kernel<false, true, 0><<<dim3(8, 32), blk, 0, stream>>>(
      avb, 4096, knr_t, 4096, out, 1024, nullptr, out, 1024, T, 1024, 4096);
}

// Round 5
// 822.361 us; speedup vs baseline: 4.7654x; 1.0724x over previous
//
#include <hip/hip_runtime.h>
#include <math.h>

static constexpr int T = 4096;   // B*S
static constexpr int D = 1024;

typedef __bf16 bf16_t;
typedef bf16_t bf16x8 __attribute__((ext_vector_type(8)));
typedef bf16_t bf16x4 __attribute__((ext_vector_type(4)));
typedef float f32x4 __attribute__((ext_vector_type(4)));

#define GLDS16(g, l)                                                        \
  __builtin_amdgcn_global_load_lds(                                         \
      (const __attribute__((address_space(1))) void*)(g),                   \
      (__attribute__((address_space(3))) void*)(l), 16, 0, 0)

// ======================= small kernels =======================

__global__ void zero1_kernel(float* p) { *p = 0.f; }

__global__ __launch_bounds__(256) void ln_kernel(
    const float* __restrict__ x, const float* __restrict__ scale,
    const float* __restrict__ bias, float* __restrict__ out_f,
    bf16_t* __restrict__ out_b)
{
  int t = blockIdx.x;
  const float* xr = x + (size_t)t * D;
  float v[4];
  float s1 = 0.f, s2 = 0.f;
#pragma unroll
  for (int i = 0; i < 4; i++) {
    v[i] = xr[threadIdx.x + i * 256];
    s1 += v[i];
    s2 += v[i] * v[i];
  }
#pragma unroll
  for (int o = 1; o < 64; o <<= 1) {
    s1 += __shfl_xor(s1, o);
    s2 += __shfl_xor(s2, o);
  }
  __shared__ float r1[4], r2[4];
  int wid = threadIdx.x >> 6;
  if ((threadIdx.x & 63) == 0) { r1[wid] = s1; r2[wid] = s2; }
  __syncthreads();
  s1 = r1[0] + r1[1] + r1[2] + r1[3];
  s2 = r2[0] + r2[1] + r2[2] + r2[3];
  float mean = s1 * (1.f / D);
  float var = s2 * (1.f / D) - mean * mean;
  float rstd = rsqrtf(var + 1e-6f);
  float* orow = out_f + (size_t)t * D;
  bf16_t* brow = out_b + (size_t)t * D;
#pragma unroll
  for (int i = 0; i < 4; i++) {
    int d = threadIdx.x + i * 256;
    float o = (v[i] - mean) * rstd * scale[d] + bias[d];
    orow[d] = o;
    brow[d] = (bf16_t)o;
  }
}

// rows of length 128, one wave per row; bf16 normalized output
__global__ __launch_bounds__(64) void norm_rows_kernel(
    const float* __restrict__ e, bf16_t* __restrict__ o)
{
  int r = blockIdx.x;
  const float* row = e + (size_t)r * 128;
  float a = row[threadIdx.x], b = row[threadIdx.x + 64];
  float ss = a * a + b * b;
#pragma unroll
  for (int m = 1; m < 64; m <<= 1) ss += __shfl_xor(ss, m);
  float inv = 1.f / (sqrtf(ss) + 1e-8f);
  bf16_t* orow = o + (size_t)r * 128;
  orow[threadIdx.x] = (bf16_t)(a * inv);
  orow[threadIdx.x + 64] = (bf16_t)(b * inv);
}

// tau = n @ W + b,  W: [D, J], J in {1,3}; one wave per token (fp32)
__global__ __launch_bounds__(64) void tau_kernel(
    const float* __restrict__ n, const float* __restrict__ W,
    const float* __restrict__ b, float* __restrict__ out, int J)
{
  int t = blockIdx.x;
  const float* nr = n + (size_t)t * D;
  for (int j = 0; j < J; j++) {
    float p = 0.f;
#pragma unroll 4
    for (int i = 0; i < 16; i++) {
      int d = threadIdx.x + i * 64;
      p += nr[d] * W[d * J + j];
    }
#pragma unroll
    for (int m = 1; m < 64; m <<= 1) p += __shfl_xor(p, m);
    if (threadIdx.x == 0) out[t * J + j] = p + b[j];
  }
}

// threshold gate + group gate, in place.
template <int PER>
__global__ __launch_bounds__(256) void gate_kernel(
    float* __restrict__ g, const float* __restrict__ tau, int tauStride,
    int tauOff, float* __restrict__ gb, int N, int G)
{
  int t = blockIdx.x;
  float tv = tau[t * tauStride + tauOff];
  float* row = g + (size_t)t * N;
  float r[PER];
  int base = threadIdx.x * PER;
  float psum = 0.f;
#pragma unroll
  for (int i = 0; i < PER; i++) {
    float s = row[base + i] - tv;
    s = fmaxf(s, 0.f);
    r[i] = s;
    psum += s;
  }
  __shared__ float red[4];
  __shared__ float grp[32];
  if (threadIdx.x < 32) grp[threadIdx.x] = 0.f;
  float w = psum;
#pragma unroll
  for (int m = 1; m < 64; m <<= 1) w += __shfl_xor(w, m);
  int wid = threadIdx.x >> 6;
  if ((threadIdx.x & 63) == 0) red[wid] = w;
  __syncthreads();
  float Stot = red[0] + red[1] + red[2] + red[3];
  atomicAdd(&grp[base >> 7], psum);
  __syncthreads();
  float inv = 1.f / (Stot + 1e-8f);
#pragma unroll
  for (int i = 0; i < PER; i++) row[base + i] = r[i] * inv;
  if (threadIdx.x < G) {
    float Gj = grp[threadIdx.x] * inv;
    float gsum = Stot * inv;
    gb[(size_t)t * G + threadIdx.x] = Gj / (gsum + 1e-8f);
  }
}

// stage 1: partial column sums of g [T,N] over 128-row chunks
__global__ __launch_bounds__(256) void colsum_part_kernel(
    const float* __restrict__ g, int N, float* __restrict__ colsum)
{
  int c = blockIdx.x * 256 + threadIdx.x;
  int r0 = blockIdx.y * 128;
  const float* p = g + (size_t)r0 * N + c;
  float s = 0.f;
#pragma unroll 8
  for (int t = 0; t < 128; t++) s += p[(size_t)t * N];
  atomicAdd(&colsum[c], s);
}

// stage 2: aux += sum_c (colsum[c]/T - tinv)^2 * N
__global__ __launch_bounds__(256) void colsum_fin_kernel(
    const float* __restrict__ colsum, int N, float tinv,
    float* __restrict__ aux)
{
  int c = blockIdx.x * 256 + threadIdx.x;
  float mdev = colsum[c] * (1.f / T) - tinv;
  float p = mdev * mdev * (float)N;
#pragma unroll
  for (int m = 1; m < 64; m <<= 1) p += __shfl_xor(p, m);
  __shared__ float red[4];
  if ((threadIdx.x & 63) == 0) red[threadIdx.x >> 6] = p;
  __syncthreads();
  if (threadIdx.x == 0) atomicAdd(aux, red[0] + red[1] + red[2] + red[3]);
}

// h1[t,r] = sum_n gb1[t,n]*all_h[t, n*128+r]; optional second output
__global__ __launch_bounds__(128) void wsum2_kernel(
    const float* __restrict__ all_h, const float* __restrict__ gb1,
    const float* __restrict__ gb2, float* __restrict__ h1,
    float* __restrict__ h2, int NB)
{
  int t = blockIdx.x;
  int r = threadIdx.x;
  const float* row = all_h + (size_t)t * NB * 128;
  float a1 = 0.f, a2 = 0.f;
  for (int n = 0; n < NB; n++) {
    float v = row[n * 128 + r];
    a1 += gb1[(size_t)t * NB + n] * v;
    if (gb2) a2 += gb2[(size_t)t * NB + n] * v;
  }
  h1[(size_t)t * 128 + r] = a1;
  if (h2) h2[(size_t)t * 128 + r] = a2;
}

// dst[c][r] = (bf16)src[r][c]; src [R,C] fp32, dst [C,R] bf16; batched
__global__ __launch_bounds__(256) void transpose_to_bf16_kernel(
    const float* __restrict__ src, bf16_t* __restrict__ dst,
    int R, int C, size_t sbs, size_t dbs)
{
  __shared__ float tile[32][33];
  int b = blockIdx.z;
  int c0 = blockIdx.x * 32, r0 = blockIdx.y * 32;
  int tx = threadIdx.x & 31, ty = threadIdx.x >> 5;  // 8 rows/pass
  const float* s = src + (size_t)b * sbs;
  bf16_t* d = dst + (size_t)b * dbs;
#pragma unroll
  for (int i = 0; i < 4; i++)
    tile[ty + i * 8][tx] = s[(size_t)(r0 + ty + i * 8) * C + c0 + tx];
  __syncthreads();
#pragma unroll
  for (int i = 0; i < 4; i++)
    d[(size_t)(c0 + ty + i * 8) * R + r0 + tx] = (bf16_t)tile[tx][ty + i * 8];
}

// A_virt[t,k] = (bf16)(gb[t,k>>7]*h[t,k&127]), row-major [T,K]
__global__ __launch_bounds__(256) void avirt_kernel(
    const float* __restrict__ h, const float* __restrict__ gb, int NB,
    bf16_t* __restrict__ A, int K)
{
  int t = blockIdx.x;
  const float* hr = h + (size_t)t * 128;
  const float* gr = gb + (size_t)t * NB;
  bf16_t* ar = A + (size_t)t * K;
  int noct = K >> 3;
  for (int o = threadIdx.x; o < noct; o += 256) {
    int k = o * 8;
    float g = gr[k >> 7];
    bf16x8 v;
#pragma unroll
    for (int i = 0; i < 8; i++) v[i] = (bf16_t)(hr[(k & 127) + i] * g);
    *(bf16x8*)(ar + k) = v;
  }
}

// ============== MFMA GEMM: C[M,N] = A[M,K]bf16 @ Bt[N,K]bf16^T ==============
// 128x128 tile, BK=32, 4 waves (2x2), 4x4 16x16 fragments per wave.
// OUT_MODE: 0 = f32, 1 = bf16, 2 = bf16 transposed V store (Vt[b][col][s])
template <bool HAS_BIAS, bool HAS_RESID, int OUT_MODE>
__global__ __launch_bounds__(256) void mfma_gemm_kernel(
    const bf16_t* __restrict__ A, int lda,
    const bf16_t* __restrict__ Bt, int ldb,
    void* __restrict__ Cv, int ldc,
    const float* __restrict__ bias,
    const float* __restrict__ resid, int ldr,
    int M, int N, int K)
{
  __shared__ bf16_t As[128 * 32];
  __shared__ bf16_t Bs[128 * 32];
  int tid = threadIdx.x;
  int wave = tid >> 6, lane = tid & 63;
  int row0 = blockIdx.y * 128, col0 = blockIdx.x * 128;
  int wr = (wave >> 1) * 64, wc = (wave & 1) * 64;

  f32x4 acc[4][4] = {};

  int srow = (wave << 4) + (lane >> 2);
  int skk = (lane & 3) << 3;
  const bf16_t* gA = A + (size_t)(row0 + srow) * lda + skk;
  const bf16_t* gB = Bt + (size_t)(col0 + srow) * ldb + skk;
  size_t a64 = (size_t)64 * lda, b64 = (size_t)64 * ldb;

  int fr = lane & 15, fq = lane >> 4;

  for (int k0 = 0; k0 < K; k0 += 32) {
    GLDS16(gA + k0, &As[wave * 512]);
    GLDS16(gA + a64 + k0, &As[2048 + wave * 512]);
    GLDS16(gB + k0, &Bs[wave * 512]);
    GLDS16(gB + b64 + k0, &Bs[2048 + wave * 512]);
    __syncthreads();
    bf16x8 af[4], bfr[4];
#pragma unroll
    for (int m = 0; m < 4; m++)
      af[m] = *(const bf16x8*)&As[(wr + m * 16 + fr) * 32 + fq * 8];
#pragma unroll
    for (int n = 0; n < 4; n++)
      bfr[n] = *(const bf16x8*)&Bs[(wc + n * 16 + fr) * 32 + fq * 8];
#pragma unroll
    for (int m = 0; m < 4; m++)
#pragma unroll
      for (int n = 0; n < 4; n++)
        acc[m][n] = __builtin_amdgcn_mfma_f32_16x16x32_bf16(af[m], bfr[n],
                                                            acc[m][n], 0, 0, 0);
    __syncthreads();
  }

#pragma unroll
  for (int m = 0; m < 4; m++) {
#pragma unroll
    for (int n = 0; n < 4; n++) {
      int rowb = row0 + wr + m * 16 + fq * 4;
      int col = col0 + wc + n * 16 + fr;
      if (OUT_MODE == 2) {
        bf16x4 v4;
#pragma unroll
        for (int r = 0; r < 4; r++) v4[r] = (bf16_t)acc[m][n][r];
        bf16_t* dst = (bf16_t*)Cv +
            ((size_t)(rowb >> 10) * 1024 + col) * 1024 + (rowb & 1023);
        *(bf16x4*)dst = v4;
      } else {
#pragma unroll
        for (int r = 0; r < 4; r++) {
          int row = rowb + r;
          float v = acc[m][n][r];
          if (HAS_BIAS) v += bias[col];
          if (HAS_RESID) v += resid[(size_t)row * ldr + col];
          if (OUT_MODE == 1)
            ((bf16_t*)Cv)[(size_t)row * ldc + col] = (bf16_t)v;
          else
            ((float*)Cv)[(size_t)row * ldc + col] = v;
        }
      }
    }
  }
}

// ======================= MFMA flash attention (bf16, LDS-staged) ============
// Q,K: [T,1024] bf16 (t = b*1024+s), head h at cols h*64..h*64+63
// Vt:  [4][1024][1024] bf16 = Vt[b][h*64+d][s]
// O:   [T,1024] bf16
// Block: 128 q rows (4 waves x 32), KV tiles of 64 double-buffered in LDS.
__global__ __launch_bounds__(256) void flash_mfma_kernel(
    const bf16_t* __restrict__ Q, const bf16_t* __restrict__ K,
    const bf16_t* __restrict__ Vt, bf16_t* __restrict__ O)
{
  __shared__ bf16_t Ks[2][64 * 64];  // [64 kv][128B], XOR-swizzled
  __shared__ bf16_t Vs[2][64 * 64];  // [64 d][128B], XOR-swizzled
  __shared__ bf16_t Pl[4][32 * 64];  // per-wave P [32 q][128B], swizzled

  int tid = threadIdx.x;
  int wave = tid >> 6, lane = tid & 63;
  int fr = lane & 15, fq = lane >> 4;
  int qb = blockIdx.x, h = blockIdx.y, b = blockIdx.z;
  int q0w = qb * 128 + wave * 32;
  size_t qkbase = ((size_t)b * 1024) * 1024 + (size_t)h * 64;
  size_t vtbase = ((size_t)b * 1024 + (size_t)h * 64) * 1024;

  // staging geometry (per wave, 8-row chunks, source col pre-swizzled)
  int srow8 = lane >> 3;                               // 0..7
  int scb = (((lane & 7) << 4) ^ (srow8 << 4)) >> 1;  // element offset

#define FSTAGE(buf, kt)                                                     \
  {                                                                         \
    int k0s = (kt) * 64;                                                    \
    _Pragma("unroll") for (int cc = 0; cc < 2; cc++) {                      \
      int rr0 = wave * 16 + cc * 8;                                         \
      int row = rr0 + srow8;                                                \
      GLDS16(&K[qkbase + (size_t)(k0s + row) * 1024 + scb],                 \
             &Ks[buf][rr0 * 64]);                                           \
      GLDS16(&Vt[vtbase + (size_t)row * 1024 + k0s + scb],                  \
             &Vs[buf][rr0 * 64]);                                           \
    }                                                                       \
  }

  // Q A-fragments: 2 row-groups x 2 k-halves
  bf16x8 qf[2][2];
#pragma unroll
  for (int g = 0; g < 2; g++)
#pragma unroll
    for (int kh = 0; kh < 2; kh++)
      qf[g][kh] = *(const bf16x8*)&Q[qkbase +
                                     (size_t)(q0w + g * 16 + fr) * 1024 +
                                     kh * 32 + fq * 8];

  f32x4 o_acc[2][4] = {};
  float mrow[2][4], lrow[2][4];
#pragma unroll
  for (int g = 0; g < 2; g++)
#pragma unroll
    for (int r = 0; r < 4; r++) { mrow[g][r] = -INFINITY; lrow[g][r] = 0.f; }

  char* P = (char*)&Pl[wave][0];
  int KT = 2 * qb + 2;

  FSTAGE(0, 0);

  for (int kt = 0; kt < KT; kt++) {
    __syncthreads();  // drains vmcnt: buf[kt&1] staged & visible
    if (kt + 1 < KT) FSTAGE((kt + 1) & 1, kt + 1);
    int k0 = kt * 64;
    if (k0 <= q0w + 31) {
      const char* Kb = (const char*)&Ks[kt & 1][0];
      const char* Vb = (const char*)&Vs[kt & 1][0];
      int swz = (fr & 7) << 4;
      // QK^T
      f32x4 s[2][4] = {};
#pragma unroll
      for (int n = 0; n < 4; n++) {
        int rowo = (n * 16 + fr) * 128;
        bf16x8 kf0 = *(const bf16x8*)(Kb + rowo + ((fq * 16) ^ swz));
        bf16x8 kf1 = *(const bf16x8*)(Kb + rowo + ((64 + fq * 16) ^ swz));
#pragma unroll
        for (int g = 0; g < 2; g++) {
          s[g][n] = __builtin_amdgcn_mfma_f32_16x16x32_bf16(qf[g][0], kf0,
                                                            s[g][n], 0, 0, 0);
          s[g][n] = __builtin_amdgcn_mfma_f32_16x16x32_bf16(qf[g][1], kf1,
                                                            s[g][n], 0, 0, 0);
        }
      }
      const float scale = 0.125f;
#pragma unroll
      for (int g = 0; g < 2; g++) {
        bool dm = (k0 + 63 > q0w + g * 16);
#pragma unroll
        for (int n = 0; n < 4; n++)
#pragma unroll
          for (int r = 0; r < 4; r++) {
            float v = s[g][n][r] * scale;
            if (dm && (k0 + n * 16 + fr > q0w + g * 16 + fq * 4 + r))
              v = -INFINITY;
            s[g][n][r] = v;
          }
      }
      // online softmax per row (q = g*16 + fq*4 + r), reduce across fr
      float corr[2][4];
#pragma unroll
      for (int g = 0; g < 2; g++)
#pragma unroll
        for (int r = 0; r < 4; r++) {
          float mx = fmaxf(fmaxf(s[g][0][r], s[g][1][r]),
                           fmaxf(s[g][2][r], s[g][3][r]));
#pragma unroll
          for (int msk = 1; msk < 16; msk <<= 1)
            mx = fmaxf(mx, __shfl_xor(mx, msk));
          float mnew = fmaxf(mrow[g][r], mx);
          corr[g][r] = __expf(mrow[g][r] - mnew);
          mrow[g][r] = mnew;
          float ps = 0.f;
#pragma unroll
          for (int n = 0; n < 4; n++) {
            float p = __expf(s[g][n][r] - mnew);
            s[g][n][r] = p;
            ps += p;
          }
#pragma unroll
          for (int msk = 1; msk < 16; msk <<= 1) ps += __shfl_xor(ps, msk);
          lrow[g][r] = lrow[g][r] * corr[g][r] + ps;
        }
      // P -> LDS (bf16, swizzled by q&7)
#pragma unroll
      for (int g = 0; g < 2; g++)
#pragma unroll
        for (int n = 0; n < 4; n++)
#pragma unroll
          for (int r = 0; r < 4; r++) {
            int q = g * 16 + fq * 4 + r;
            int cb = ((n * 16 + fr) * 2) ^ ((q & 7) << 4);
            *(bf16_t*)(P + q * 128 + cb) = (bf16_t)s[g][n][r];
          }
      // rescale o_acc by corr broadcast to q = fr lanes
      int rr = fr & 3;
      int srcl = (fr >> 2) << 4;
#pragma unroll
      for (int g = 0; g < 2; g++) {
        float c0 = __shfl(corr[g][0], srcl);
        float c1 = __shfl(corr[g][1], srcl);
        float c2 = __shfl(corr[g][2], srcl);
        float c3 = __shfl(corr[g][3], srcl);
        float cq = rr == 0 ? c0 : rr == 1 ? c1 : rr == 2 ? c2 : c3;
#pragma unroll
        for (int n = 0; n < 4; n++)
#pragma unroll
          for (int r = 0; r < 4; r++) o_acc[g][n][r] *= cq;
      }
      // PV: O^T += Vs_frag(A) @ P_frag(B)
#pragma unroll
      for (int c = 0; c < 2; c++) {
        bf16x8 pf[2];
#pragma unroll
        for (int g = 0; g < 2; g++)
          pf[g] = *(const bf16x8*)(P + (g * 16 + fr) * 128 +
                                   ((c * 64 + fq * 16) ^ swz));
#pragma unroll
        for (int n = 0; n < 4; n++) {
          bf16x8 vf = *(const bf16x8*)(Vb + (n * 16 + fr) * 128 +
                                       ((c * 64 + fq * 16) ^ swz));
#pragma unroll
          for (int g = 0; g < 2; g++)
            o_acc[g][n] = __builtin_amdgcn_mfma_f32_16x16x32_bf16(
                vf, pf[g], o_acc[g][n], 0, 0, 0);
        }
      }
    }
  }
  // epilogue
  int rr = fr & 3;
  int srcl = (fr >> 2) << 4;
#pragma unroll
  for (int g = 0; g < 2; g++) {
    float l0 = __shfl(lrow[g][0], srcl);
    float l1 = __shfl(lrow[g][1], srcl);
    float l2 = __shfl(lrow[g][2], srcl);
    float l3 = __shfl(lrow[g][3], srcl);
    float lq = rr == 0 ? l0 : rr == 1 ? l1 : rr == 2 ? l2 : l3;
    float linv = 1.f / lq;
    size_t orow = qkbase + (size_t)(q0w + g * 16 + fr) * 1024;
#pragma unroll
    for (int n = 0; n < 4; n++) {
      bf16x4 ov;
#pragma unroll
      for (int r = 0; r < 4; r++) ov[r] = (bf16_t)(o_acc[g][n][r] * linv);
      *(bf16x4*)&O[orow + n * 16 + fq * 4] = ov;
    }
  }
#undef FSTAGE
}

// ======================= launch =======================

extern "C" void kernel_launch(void* const* d_in, const int* in_sizes, int n_in,
                              void* d_out, int out_size, void* d_ws,
                              size_t ws_size, hipStream_t stream) {
  (void)in_sizes; (void)n_in; (void)out_size; (void)ws_size;
  const float* x          = (const float*)d_in[0];
  const float* qk_emb     = (const float*)d_in[1];
  const float* v_emb      = (const float*)d_in[2];
  const float* know_emb   = (const float*)d_in[3];
  const float* qk_f       = (const float*)d_in[4];
  const float* qk_r       = (const float*)d_in[5];
  const float* v_f        = (const float*)d_in[6];
  const float* v_r        = (const float*)d_in[7];
  const float* know_f     = (const float*)d_in[8];
  const float* know_r     = (const float*)d_in[9];
  const float* proj_attn_k = (const float*)d_in[10];
  const float* proj_attn_b = (const float*)d_in[11];
  const float* tau_attn_k  = (const float*)d_in[12];
  const float* tau_attn_b  = (const float*)d_in[13];
  const float* proj_know_k = (const float*)d_in[14];
  const float* proj_know_b = (const float*)d_in[15];
  const float* tau_know_k  = (const float*)d_in[16];
  const float* tau_know_b  = (const float*)d_in[17];
  const float* expand_O    = (const float*)d_in[18];
  const float* ln1_scale   = (const float*)d_in[19];
  const float* ln1_bias    = (const float*)d_in[20];
  const float* ln2_scale   = (const float*)d_in[21];
  const float* ln2_bias    = (const float*)d_in[22];

  float* out = (float*)d_out;  // [T,D] + aux scalar
  float* aux = out + (size_t)T * D;

  // ---- workspace arena ----
  float* ws = (float*)d_ws;
  float* n_f   = ws;                       // 4M floats
  float* tau3  = n_f + 4194304;            // 16K
  float* gq_b  = tau3 + 16384;             // 64K
  float* gk_b  = gq_b + 65536;
  float* gv_b  = gk_b + 65536;
  float* gkn_b = gv_b + 65536;             // 128K
  float* csum  = gkn_b + 131072;           // 4096 (colsum accumulator)
  float* hQ    = csum + 4096;              // 512K
  float* hK    = hQ + 524288;
  float* hV    = hK + 524288;
  float* qkvarena = hV + 524288;           // 12M floats (Q,K bf16 + Vt bf16)
  float* buf_big = qkvarena + 12582912;    // 16.78M floats (64MB)

  bf16_t* Qbb = (bf16_t*)qkvarena;                 // T*1024 bf16 (8MB)
  bf16_t* Kbb = Qbb + (size_t)T * 1024;            // 8MB
  bf16_t* Vtb = Kbb + (size_t)T * 1024;            // [4][1024][1024] 8MB

  bf16_t* nb   = (bf16_t*)(buf_big + 16777216);  // T*1024
  bf16_t* hab  = nb + 4194304;                   // T*384 (reused know: T*128)
  bf16_t* embB = hab + 1572864;                  // 524288 (qk|v ; know)
  bf16_t* B2t  = embB + 524288;                  // 4096*1024
  bf16_t* wt   = B2t + 4194304;                  // transposed weights arena
  bf16_t* pa_t  = wt;                   // 384*1024
  bf16_t* qkr_t = pa_t + 393216;        // 1024*2048
  bf16_t* vr_t  = qkr_t + 2097152;      // 1024*2048
  bf16_t* knr_t = vr_t + 2097152;       // 1024*4096
  bf16_t* eo_t  = knr_t + 4194304;      // 1024*1024
  bf16_t* pk_t  = eo_t + 1048576;       // 128*1024

  bf16_t* avb = (bf16_t*)buf_big;                   // up to T*4096 bf16
  bf16_t* attnb_b = (bf16_t*)(buf_big + 12582912);  // T*1024 bf16

  bf16_t* embQ = embB;
  bf16_t* embV = embB + 262144;

  dim3 blk(256);

  zero1_kernel<<<1, 1, 0, stream>>>(aux);

  // weight transposes to bf16 [N,K]
  transpose_to_bf16_kernel<<<dim3(12, 32, 1), blk, 0, stream>>>(
      proj_attn_k, pa_t, 1024, 384, 0, 0);
  transpose_to_bf16_kernel<<<dim3(32, 64, 1), blk, 0, stream>>>(
      qk_r, qkr_t, 2048, 1024, 0, 0);
  transpose_to_bf16_kernel<<<dim3(32, 64, 1), blk, 0, stream>>>(
      v_r, vr_t, 2048, 1024, 0, 0);
  transpose_to_bf16_kernel<<<dim3(32, 128, 1), blk, 0, stream>>>(
      know_r, knr_t, 4096, 1024, 0, 0);
  transpose_to_bf16_kernel<<<dim3(32, 32, 1), blk, 0, stream>>>(
      expand_O, eo_t, 1024, 1024, 0, 0);
  transpose_to_bf16_kernel<<<dim3(4, 32, 1), blk, 0, stream>>>(
      proj_know_k, pk_t, 1024, 128, 0, 0);

  // ---- attention circuit ----
  ln_kernel<<<T, blk, 0, stream>>>(x, ln1_scale, ln1_bias, n_f, nb);
  norm_rows_kernel<<<2048, 64, 0, stream>>>(qk_emb, embQ);
  norm_rows_kernel<<<2048, 64, 0, stream>>>(v_emb, embV);

  mfma_gemm_kernel<true, false, 1><<<dim3(3, 32), blk, 0, stream>>>(
      nb, 1024, pa_t, 1024, hab, 384, proj_attn_b, nullptr, 0, T, 384, 1024);
  tau_kernel<<<T, 64, 0, stream>>>(n_f, tau_attn_k, tau_attn_b, tau3, 3);

  // gate scores + gates + aux
  mfma_gemm_kernel<false, false, 0><<<dim3(16, 32), blk, 0, stream>>>(
      hab + 0, 384, embQ, 128, buf_big, 2048, nullptr, nullptr, 0, T, 2048, 128);
  gate_kernel<8><<<T, blk, 0, stream>>>(buf_big, tau3, 3, 0, gq_b, 2048, 16);
  hipMemsetAsync(csum, 0, 2048 * sizeof(float), stream);
  colsum_part_kernel<<<dim3(8, 32), blk, 0, stream>>>(buf_big, 2048, csum);
  colsum_fin_kernel<<<8, blk, 0, stream>>>(csum, 2048, 1.f / 2048.f, aux);

  mfma_gemm_kernel<false, false, 0><<<dim3(16, 32), blk, 0, stream>>>(
      hab + 128, 384, embQ, 128, buf_big, 2048, nullptr, nullptr, 0, T, 2048, 128);
  gate_kernel<8><<<T, blk, 0, stream>>>(buf_big, tau3, 3, 1, gk_b, 2048, 16);
  hipMemsetAsync(csum, 0, 2048 * sizeof(float), stream);
  colsum_part_kernel<<<dim3(8, 32), blk, 0, stream>>>(buf_big, 2048, csum);
  colsum_fin_kernel<<<8, blk, 0, stream>>>(csum, 2048, 1.f / 2048.f, aux);

  mfma_gemm_kernel<false, false, 0><<<dim3(16, 32), blk, 0, stream>>>(
      hab + 256, 384, embV, 128, buf_big, 2048, nullptr, nullptr, 0, T, 2048, 128);
  gate_kernel<8><<<T, blk, 0, stream>>>(buf_big, tau3, 3, 2, gv_b, 2048, 16);
  hipMemsetAsync(csum, 0, 2048 * sizeof(float), stream);
  colsum_part_kernel<<<dim3(8, 32), blk, 0, stream>>>(buf_big, 2048, csum);
  colsum_fin_kernel<<<8, blk, 0, stream>>>(csum, 2048, 1.f / 2048.f, aux);

  // features (qk basis)
  transpose_to_bf16_kernel<<<dim3(4, 32, 16), blk, 0, stream>>>(
      qk_f, B2t, 1024, 128, 131072, 131072);
  mfma_gemm_kernel<false, false, 0><<<dim3(16, 32), blk, 0, stream>>>(
      nb, 1024, B2t, 1024, buf_big, 2048, nullptr, nullptr, 0, T, 2048, 1024);
  wsum2_kernel<<<T, 128, 0, stream>>>(buf_big, gq_b, gk_b, hQ, hK, 16);

  // features (v basis)
  transpose_to_bf16_kernel<<<dim3(4, 32, 16), blk, 0, stream>>>(
      v_f, B2t, 1024, 128, 131072, 131072);
  mfma_gemm_kernel<false, false, 0><<<dim3(16, 32), blk, 0, stream>>>(
      nb, 1024, B2t, 1024, buf_big, 2048, nullptr, nullptr, 0, T, 2048, 1024);
  wsum2_kernel<<<T, 128, 0, stream>>>(buf_big, gv_b, nullptr, hV, nullptr, 16);

  // restores -> Q,K bf16 and Vt transposed bf16
  avirt_kernel<<<T, blk, 0, stream>>>(hQ, gq_b, 16, avb, 2048);
  mfma_gemm_kernel<false, false, 1><<<dim3(8, 32), blk, 0, stream>>>(
      avb, 2048, qkr_t, 2048, Qbb, 1024, nullptr, nullptr, 0, T, 1024, 2048);
  avirt_kernel<<<T, blk, 0, stream>>>(hK, gk_b, 16, avb, 2048);
  mfma_gemm_kernel<false, false, 1><<<dim3(8, 32), blk, 0, stream>>>(
      avb, 2048, qkr_t, 2048, Kbb, 1024, nullptr, nullptr, 0, T, 1024, 2048);
  avirt_kernel<<<T, blk, 0, stream>>>(hV, gv_b, 16, avb, 2048);
  mfma_gemm_kernel<false, false, 2><<<dim3(8, 32), blk, 0, stream>>>(
      avb, 2048, vr_t, 2048, Vtb, 1024, nullptr, nullptr, 0, T, 1024, 2048);

  // MFMA flash attention + output proj + residual
  flash_mfma_kernel<<<dim3(8, 16, 4), blk, 0, stream>>>(Qbb, Kbb, Vtb,
                                                        attnb_b);
  mfma_gemm_kernel<false, true, 0><<<dim3(8, 32), blk, 0, stream>>>(
      attnb_b, 1024, eo_t, 1024, out, 1024, nullptr, x, 1024, T, 1024, 1024);

  // ---- knowledge circuit ----
  ln_kernel<<<T, blk, 0, stream>>>(out, ln2_scale, ln2_bias, n_f, nb);
  norm_rows_kernel<<<4096, 64, 0, stream>>>(know_emb, embB);
  mfma_gemm_kernel<true, false, 1><<<dim3(1, 32), blk, 0, stream>>>(
      nb, 1024, pk_t, 1024, hab, 128, proj_know_b, nullptr, 0, T, 128, 1024);
  tau_kernel<<<T, 64, 0, stream>>>(n_f, tau_know_k, tau_know_b, tau3, 1);

  mfma_gemm_kernel<false, false, 0><<<dim3(32, 32), blk, 0, stream>>>(
      hab, 128, embB, 128, buf_big, 4096, nullptr, nullptr, 0, T, 4096, 128);
  gate_kernel<16><<<T, blk, 0, stream>>>(buf_big, tau3, 1, 0, gkn_b, 4096, 32);
  hipMemsetAsync(csum, 0, 4096 * sizeof(float), stream);
  colsum_part_kernel<<<dim3(16, 32), blk, 0, stream>>>(buf_big, 4096, csum);
  colsum_fin_kernel<<<16, blk, 0, stream>>>(csum, 4096, 1.f / 4096.f, aux);

  transpose_to_bf16_kernel<<<dim3(4, 32, 32), blk, 0, stream>>>(
      know_f, B2t, 1024, 128, 131072, 131072);
  mfma_gemm_kernel<false, false, 0><<<dim3(32, 32), blk, 0, stream>>>(
      nb, 1024, B2t, 1024, buf_big, 4096, nullptr, nullptr, 0, T, 4096, 1024);
  wsum2_kernel<<<T, 128, 0, stream>>>(buf_big, gkn_b, nullptr, hQ, nullptr, 32);

  avirt_kernel<<<T, blk, 0, stream>>>(hQ, gkn_b, 32, avb, 4096);
  mfma_gemm_kernel<false, true, 0><<<dim3(8, 32), blk, 0, stream>>>(
      avb, 4096, knr_t, 4096, out, 1024, nullptr, out, 1024, T, 1024, 4096);
}

// Round 6
// 801.918 us; speedup vs baseline: 4.8869x; 1.0255x over previous
//
#include <hip/hip_runtime.h>
#include <math.h>

static constexpr int T = 4096;   // B*S
static constexpr int D = 1024;

typedef __bf16 bf16_t;
typedef bf16_t bf16x8 __attribute__((ext_vector_type(8)));
typedef bf16_t bf16x4 __attribute__((ext_vector_type(4)));
typedef float f32x4 __attribute__((ext_vector_type(4)));

#define GLDS16(g, l)                                                        \
  __builtin_amdgcn_global_load_lds(                                         \
      (const __attribute__((address_space(1))) void*)(g),                   \
      (__attribute__((address_space(3))) void*)(l), 16, 0, 0)

// ======================= small kernels =======================

__global__ void zero1_kernel(float* p) { *p = 0.f; }

__global__ __launch_bounds__(256) void ln_kernel(
    const float* __restrict__ x, const float* __restrict__ scale,
    const float* __restrict__ bias, float* __restrict__ out_f,
    bf16_t* __restrict__ out_b)
{
  int t = blockIdx.x;
  const float* xr = x + (size_t)t * D;
  float v[4];
  float s1 = 0.f, s2 = 0.f;
#pragma unroll
  for (int i = 0; i < 4; i++) {
    v[i] = xr[threadIdx.x + i * 256];
    s1 += v[i];
    s2 += v[i] * v[i];
  }
#pragma unroll
  for (int o = 1; o < 64; o <<= 1) {
    s1 += __shfl_xor(s1, o);
    s2 += __shfl_xor(s2, o);
  }
  __shared__ float r1[4], r2[4];
  int wid = threadIdx.x >> 6;
  if ((threadIdx.x & 63) == 0) { r1[wid] = s1; r2[wid] = s2; }
  __syncthreads();
  s1 = r1[0] + r1[1] + r1[2] + r1[3];
  s2 = r2[0] + r2[1] + r2[2] + r2[3];
  float mean = s1 * (1.f / D);
  float var = s2 * (1.f / D) - mean * mean;
  float rstd = rsqrtf(var + 1e-6f);
  float* orow = out_f + (size_t)t * D;
  bf16_t* brow = out_b + (size_t)t * D;
#pragma unroll
  for (int i = 0; i < 4; i++) {
    int d = threadIdx.x + i * 256;
    float o = (v[i] - mean) * rstd * scale[d] + bias[d];
    orow[d] = o;
    brow[d] = (bf16_t)o;
  }
}

// rows of length 128, one wave per row; bf16 normalized output
__global__ __launch_bounds__(64) void norm_rows_kernel(
    const float* __restrict__ e, bf16_t* __restrict__ o)
{
  int r = blockIdx.x;
  const float* row = e + (size_t)r * 128;
  float a = row[threadIdx.x], b = row[threadIdx.x + 64];
  float ss = a * a + b * b;
#pragma unroll
  for (int m = 1; m < 64; m <<= 1) ss += __shfl_xor(ss, m);
  float inv = 1.f / (sqrtf(ss) + 1e-8f);
  bf16_t* orow = o + (size_t)r * 128;
  orow[threadIdx.x] = (bf16_t)(a * inv);
  orow[threadIdx.x + 64] = (bf16_t)(b * inv);
}

// tau = n @ W + b,  W: [D, J], J in {1,3}; one wave per token (fp32)
__global__ __launch_bounds__(64) void tau_kernel(
    const float* __restrict__ n, const float* __restrict__ W,
    const float* __restrict__ b, float* __restrict__ out, int J)
{
  int t = blockIdx.x;
  const float* nr = n + (size_t)t * D;
  for (int j = 0; j < J; j++) {
    float p = 0.f;
#pragma unroll 4
    for (int i = 0; i < 16; i++) {
      int d = threadIdx.x + i * 64;
      p += nr[d] * W[d * J + j];
    }
#pragma unroll
    for (int m = 1; m < 64; m <<= 1) p += __shfl_xor(p, m);
    if (threadIdx.x == 0) out[t * J + j] = p + b[j];
  }
}

// threshold gate + group gate, in place.
template <int PER>
__global__ __launch_bounds__(256) void gate_kernel(
    float* __restrict__ g, const float* __restrict__ tau, int tauStride,
    int tauOff, float* __restrict__ gb, int N, int G)
{
  int t = blockIdx.x;
  float tv = tau[t * tauStride + tauOff];
  float* row = g + (size_t)t * N;
  float r[PER];
  int base = threadIdx.x * PER;
  float psum = 0.f;
#pragma unroll
  for (int i = 0; i < PER; i++) {
    float s = row[base + i] - tv;
    s = fmaxf(s, 0.f);
    r[i] = s;
    psum += s;
  }
  __shared__ float red[4];
  __shared__ float grp[32];
  if (threadIdx.x < 32) grp[threadIdx.x] = 0.f;
  float w = psum;
#pragma unroll
  for (int m = 1; m < 64; m <<= 1) w += __shfl_xor(w, m);
  int wid = threadIdx.x >> 6;
  if ((threadIdx.x & 63) == 0) red[wid] = w;
  __syncthreads();
  float Stot = red[0] + red[1] + red[2] + red[3];
  atomicAdd(&grp[base >> 7], psum);
  __syncthreads();
  float inv = 1.f / (Stot + 1e-8f);
#pragma unroll
  for (int i = 0; i < PER; i++) row[base + i] = r[i] * inv;
  if (threadIdx.x < G) {
    float Gj = grp[threadIdx.x] * inv;
    float gsum = Stot * inv;
    gb[(size_t)t * G + threadIdx.x] = Gj / (gsum + 1e-8f);
  }
}

// stage 1: partial column sums of g [T,N] over 128-row chunks
__global__ __launch_bounds__(256) void colsum_part_kernel(
    const float* __restrict__ g, int N, float* __restrict__ colsum)
{
  int c = blockIdx.x * 256 + threadIdx.x;
  int r0 = blockIdx.y * 128;
  const float* p = g + (size_t)r0 * N + c;
  float s = 0.f;
#pragma unroll 8
  for (int t = 0; t < 128; t++) s += p[(size_t)t * N];
  atomicAdd(&colsum[c], s);
}

// stage 2: aux += sum_c (colsum[c]/T - tinv)^2 * N
__global__ __launch_bounds__(256) void colsum_fin_kernel(
    const float* __restrict__ colsum, int N, float tinv,
    float* __restrict__ aux)
{
  int c = blockIdx.x * 256 + threadIdx.x;
  float mdev = colsum[c] * (1.f / T) - tinv;
  float p = mdev * mdev * (float)N;
#pragma unroll
  for (int m = 1; m < 64; m <<= 1) p += __shfl_xor(p, m);
  __shared__ float red[4];
  if ((threadIdx.x & 63) == 0) red[threadIdx.x >> 6] = p;
  __syncthreads();
  if (threadIdx.x == 0) atomicAdd(aux, red[0] + red[1] + red[2] + red[3]);
}

// h1[t,r] = sum_n gb1[t,n]*all_h[t, n*128+r] (all_h bf16); optional 2nd out
__global__ __launch_bounds__(128) void wsum2_kernel(
    const bf16_t* __restrict__ all_h, const float* __restrict__ gb1,
    const float* __restrict__ gb2, float* __restrict__ h1,
    float* __restrict__ h2, int NB)
{
  int t = blockIdx.x;
  int r = threadIdx.x;
  const bf16_t* row = all_h + (size_t)t * NB * 128;
  float a1 = 0.f, a2 = 0.f;
  for (int n = 0; n < NB; n++) {
    float v = (float)row[n * 128 + r];
    a1 += gb1[(size_t)t * NB + n] * v;
    if (gb2) a2 += gb2[(size_t)t * NB + n] * v;
  }
  h1[(size_t)t * 128 + r] = a1;
  if (h2) h2[(size_t)t * 128 + r] = a2;
}

// dst[c][r] = (bf16)src[r][c]; src [R,C] fp32, dst [C,R] bf16; batched
__global__ __launch_bounds__(256) void transpose_to_bf16_kernel(
    const float* __restrict__ src, bf16_t* __restrict__ dst,
    int R, int C, size_t sbs, size_t dbs)
{
  __shared__ float tile[32][33];
  int b = blockIdx.z;
  int c0 = blockIdx.x * 32, r0 = blockIdx.y * 32;
  int tx = threadIdx.x & 31, ty = threadIdx.x >> 5;  // 8 rows/pass
  const float* s = src + (size_t)b * sbs;
  bf16_t* d = dst + (size_t)b * dbs;
#pragma unroll
  for (int i = 0; i < 4; i++)
    tile[ty + i * 8][tx] = s[(size_t)(r0 + ty + i * 8) * C + c0 + tx];
  __syncthreads();
#pragma unroll
  for (int i = 0; i < 4; i++)
    d[(size_t)(c0 + ty + i * 8) * R + r0 + tx] = (bf16_t)tile[tx][ty + i * 8];
}

// A_virt[t,k] = (bf16)(gb[t,k>>7]*h[t,k&127]), row-major [T,K]
__global__ __launch_bounds__(256) void avirt_kernel(
    const float* __restrict__ h, const float* __restrict__ gb, int NB,
    bf16_t* __restrict__ A, int K)
{
  int t = blockIdx.x;
  const float* hr = h + (size_t)t * 128;
  const float* gr = gb + (size_t)t * NB;
  bf16_t* ar = A + (size_t)t * K;
  int noct = K >> 3;
  for (int o = threadIdx.x; o < noct; o += 256) {
    int k = o * 8;
    float g = gr[k >> 7];
    bf16x8 v;
#pragma unroll
    for (int i = 0; i < 8; i++) v[i] = (bf16_t)(hr[(k & 127) + i] * g);
    *(bf16x8*)(ar + k) = v;
  }
}

// ============== MFMA GEMM: C[M,N] = A[M,K]bf16 @ Bt[N,K]bf16^T ==============
// 128x128 tile, BK=32, 4 waves (2x2), 4x4 16x16 fragments per wave.
// XCD-chunked block swizzle: each XCD gets contiguous tile-rows (L2 A reuse).
// OUT_MODE: 0 = f32, 1 = bf16, 2 = bf16 transposed V store (Vt[b][col][s])
template <bool HAS_BIAS, bool HAS_RESID, int OUT_MODE>
__global__ __launch_bounds__(256) void mfma_gemm_kernel(
    const bf16_t* __restrict__ A, int lda,
    const bf16_t* __restrict__ Bt, int ldb,
    void* __restrict__ Cv, int ldc,
    const float* __restrict__ bias,
    const float* __restrict__ resid, int ldr,
    int M, int N, int K)
{
  __shared__ bf16_t As[128 * 32];
  __shared__ bf16_t Bs[128 * 32];
  int tid = threadIdx.x;
  int wave = tid >> 6, lane = tid & 63;

  unsigned lid = blockIdx.y * gridDim.x + blockIdx.x;
  unsigned nwg = gridDim.x * gridDim.y;
  unsigned swzb = lid;
  if ((nwg & 7u) == 0u) swzb = (lid & 7u) * (nwg >> 3) + (lid >> 3);
  int row0 = (int)(swzb / gridDim.x) * 128;
  int col0 = (int)(swzb % gridDim.x) * 128;

  int wr = (wave >> 1) * 64, wc = (wave & 1) * 64;

  f32x4 acc[4][4] = {};

  int srow = (wave << 4) + (lane >> 2);
  int skk = (lane & 3) << 3;
  const bf16_t* gA = A + (size_t)(row0 + srow) * lda + skk;
  const bf16_t* gB = Bt + (size_t)(col0 + srow) * ldb + skk;
  size_t a64 = (size_t)64 * lda, b64 = (size_t)64 * ldb;

  int fr = lane & 15, fq = lane >> 4;

  for (int k0 = 0; k0 < K; k0 += 32) {
    GLDS16(gA + k0, &As[wave * 512]);
    GLDS16(gA + a64 + k0, &As[2048 + wave * 512]);
    GLDS16(gB + k0, &Bs[wave * 512]);
    GLDS16(gB + b64 + k0, &Bs[2048 + wave * 512]);
    __syncthreads();
    bf16x8 af[4], bfr[4];
#pragma unroll
    for (int m = 0; m < 4; m++)
      af[m] = *(const bf16x8*)&As[(wr + m * 16 + fr) * 32 + fq * 8];
#pragma unroll
    for (int n = 0; n < 4; n++)
      bfr[n] = *(const bf16x8*)&Bs[(wc + n * 16 + fr) * 32 + fq * 8];
#pragma unroll
    for (int m = 0; m < 4; m++)
#pragma unroll
      for (int n = 0; n < 4; n++)
        acc[m][n] = __builtin_amdgcn_mfma_f32_16x16x32_bf16(af[m], bfr[n],
                                                            acc[m][n], 0, 0, 0);
    __syncthreads();
  }

#pragma unroll
  for (int m = 0; m < 4; m++) {
#pragma unroll
    for (int n = 0; n < 4; n++) {
      int rowb = row0 + wr + m * 16 + fq * 4;
      int col = col0 + wc + n * 16 + fr;
      if (OUT_MODE == 2) {
        bf16x4 v4;
#pragma unroll
        for (int r = 0; r < 4; r++) v4[r] = (bf16_t)acc[m][n][r];
        bf16_t* dst = (bf16_t*)Cv +
            ((size_t)(rowb >> 10) * 1024 + col) * 1024 + (rowb & 1023);
        *(bf16x4*)dst = v4;
      } else {
#pragma unroll
        for (int r = 0; r < 4; r++) {
          int row = rowb + r;
          float v = acc[m][n][r];
          if (HAS_BIAS) v += bias[col];
          if (HAS_RESID) v += resid[(size_t)row * ldr + col];
          if (OUT_MODE == 1)
            ((bf16_t*)Cv)[(size_t)row * ldc + col] = (bf16_t)v;
          else
            ((float*)Cv)[(size_t)row * ldc + col] = v;
        }
      }
    }
  }
}

// ======================= MFMA flash attention (bf16, LDS-staged) ============
// Block: 128 q rows (4 waves x 32), KV tiles of 64 double-buffered in LDS.
__global__ __launch_bounds__(256) void flash_mfma_kernel(
    const bf16_t* __restrict__ Q, const bf16_t* __restrict__ K,
    const bf16_t* __restrict__ Vt, bf16_t* __restrict__ O)
{
  __shared__ bf16_t Ks[2][64 * 64];  // [64 kv][128B], XOR-swizzled
  __shared__ bf16_t Vs[2][64 * 64];  // [64 d][128B], XOR-swizzled
  __shared__ bf16_t Pl[4][32 * 64];  // per-wave P [32 q][128B], swizzled

  int tid = threadIdx.x;
  int wave = tid >> 6, lane = tid & 63;
  int fr = lane & 15, fq = lane >> 4;
  // XCD-chunked swizzle: co-locate the 8 q-tiles of each (h,b) on one XCD
  unsigned lid = blockIdx.x + blockIdx.y * 8 + blockIdx.z * 128;  // 512 wgs
  unsigned swz9 = (lid & 7u) * 64 + (lid >> 3);
  int qb = swz9 & 7, h = (swz9 >> 3) & 15, b = swz9 >> 7;
  int q0w = qb * 128 + wave * 32;
  size_t qkbase = ((size_t)b * 1024) * 1024 + (size_t)h * 64;
  size_t vtbase = ((size_t)b * 1024 + (size_t)h * 64) * 1024;

  // staging geometry (per wave, 8-row chunks, source col pre-swizzled)
  int srow8 = lane >> 3;                               // 0..7
  int scb = (((lane & 7) << 4) ^ (srow8 << 4)) >> 1;  // element offset

#define FSTAGE(buf, kt)                                                     \
  {                                                                         \
    int k0s = (kt) * 64;                                                    \
    _Pragma("unroll") for (int cc = 0; cc < 2; cc++) {                      \
      int rr0 = wave * 16 + cc * 8;                                         \
      int row = rr0 + srow8;                                                \
      GLDS16(&K[qkbase + (size_t)(k0s + row) * 1024 + scb],                 \
             &Ks[buf][rr0 * 64]);                                           \
      GLDS16(&Vt[vtbase + (size_t)row * 1024 + k0s + scb],                  \
             &Vs[buf][rr0 * 64]);                                           \
    }                                                                       \
  }

  // Q A-fragments: 2 row-groups x 2 k-halves
  bf16x8 qf[2][2];
#pragma unroll
  for (int g = 0; g < 2; g++)
#pragma unroll
    for (int kh = 0; kh < 2; kh++)
      qf[g][kh] = *(const bf16x8*)&Q[qkbase +
                                     (size_t)(q0w + g * 16 + fr) * 1024 +
                                     kh * 32 + fq * 8];

  f32x4 o_acc[2][4] = {};
  float mrow[2][4], lrow[2][4];
#pragma unroll
  for (int g = 0; g < 2; g++)
#pragma unroll
    for (int r = 0; r < 4; r++) { mrow[g][r] = -INFINITY; lrow[g][r] = 0.f; }

  char* P = (char*)&Pl[wave][0];
  int KT = 2 * qb + 2;

  FSTAGE(0, 0);

  for (int kt = 0; kt < KT; kt++) {
    __syncthreads();  // drains vmcnt: buf[kt&1] staged & visible
    if (kt + 1 < KT) FSTAGE((kt + 1) & 1, kt + 1);
    int k0 = kt * 64;
    if (k0 <= q0w + 31) {
      const char* Kb = (const char*)&Ks[kt & 1][0];
      const char* Vb = (const char*)&Vs[kt & 1][0];
      int swz = (fr & 7) << 4;
      // QK^T
      f32x4 s[2][4] = {};
#pragma unroll
      for (int n = 0; n < 4; n++) {
        int rowo = (n * 16 + fr) * 128;
        bf16x8 kf0 = *(const bf16x8*)(Kb + rowo + ((fq * 16) ^ swz));
        bf16x8 kf1 = *(const bf16x8*)(Kb + rowo + ((64 + fq * 16) ^ swz));
#pragma unroll
        for (int g = 0; g < 2; g++) {
          s[g][n] = __builtin_amdgcn_mfma_f32_16x16x32_bf16(qf[g][0], kf0,
                                                            s[g][n], 0, 0, 0);
          s[g][n] = __builtin_amdgcn_mfma_f32_16x16x32_bf16(qf[g][1], kf1,
                                                            s[g][n], 0, 0, 0);
        }
      }
      const float scale = 0.125f;
#pragma unroll
      for (int g = 0; g < 2; g++) {
        bool dm = (k0 + 63 > q0w + g * 16);
#pragma unroll
        for (int n = 0; n < 4; n++)
#pragma unroll
          for (int r = 0; r < 4; r++) {
            float v = s[g][n][r] * scale;
            if (dm && (k0 + n * 16 + fr > q0w + g * 16 + fq * 4 + r))
              v = -INFINITY;
            s[g][n][r] = v;
          }
      }
      // online softmax per row (q = g*16 + fq*4 + r), reduce across fr
      float corr[2][4];
#pragma unroll
      for (int g = 0; g < 2; g++)
#pragma unroll
        for (int r = 0; r < 4; r++) {
          float mx = fmaxf(fmaxf(s[g][0][r], s[g][1][r]),
                           fmaxf(s[g][2][r], s[g][3][r]));
#pragma unroll
          for (int msk = 1; msk < 16; msk <<= 1)
            mx = fmaxf(mx, __shfl_xor(mx, msk));
          float mnew = fmaxf(mrow[g][r], mx);
          corr[g][r] = __expf(mrow[g][r] - mnew);
          mrow[g][r] = mnew;
          float ps = 0.f;
#pragma unroll
          for (int n = 0; n < 4; n++) {
            float p = __expf(s[g][n][r] - mnew);
            s[g][n][r] = p;
            ps += p;
          }
#pragma unroll
          for (int msk = 1; msk < 16; msk <<= 1) ps += __shfl_xor(ps, msk);
          lrow[g][r] = lrow[g][r] * corr[g][r] + ps;
        }
      // P -> LDS (bf16, swizzled by q&7)
#pragma unroll
      for (int g = 0; g < 2; g++)
#pragma unroll
        for (int n = 0; n < 4; n++)
#pragma unroll
          for (int r = 0; r < 4; r++) {
            int q = g * 16 + fq * 4 + r;
            int cb = ((n * 16 + fr) * 2) ^ ((q & 7) << 4);
            *(bf16_t*)(P + q * 128 + cb) = (bf16_t)s[g][n][r];
          }
      // rescale o_acc by corr broadcast to q = fr lanes
      int rr = fr & 3;
      int srcl = (fr >> 2) << 4;
#pragma unroll
      for (int g = 0; g < 2; g++) {
        float c0 = __shfl(corr[g][0], srcl);
        float c1 = __shfl(corr[g][1], srcl);
        float c2 = __shfl(corr[g][2], srcl);
        float c3 = __shfl(corr[g][3], srcl);
        float cq = rr == 0 ? c0 : rr == 1 ? c1 : rr == 2 ? c2 : c3;
#pragma unroll
        for (int n = 0; n < 4; n++)
#pragma unroll
          for (int r = 0; r < 4; r++) o_acc[g][n][r] *= cq;
      }
      // PV: O^T += Vs_frag(A) @ P_frag(B)
#pragma unroll
      for (int c = 0; c < 2; c++) {
        bf16x8 pf[2];
#pragma unroll
        for (int g = 0; g < 2; g++)
          pf[g] = *(const bf16x8*)(P + (g * 16 + fr) * 128 +
                                   ((c * 64 + fq * 16) ^ swz));
#pragma unroll
        for (int n = 0; n < 4; n++) {
          bf16x8 vf = *(const bf16x8*)(Vb + (n * 16 + fr) * 128 +
                                       ((c * 64 + fq * 16) ^ swz));
#pragma unroll
          for (int g = 0; g < 2; g++)
            o_acc[g][n] = __builtin_amdgcn_mfma_f32_16x16x32_bf16(
                vf, pf[g], o_acc[g][n], 0, 0, 0);
        }
      }
    }
  }
  // epilogue
  int rr = fr & 3;
  int srcl = (fr >> 2) << 4;
#pragma unroll
  for (int g = 0; g < 2; g++) {
    float l0 = __shfl(lrow[g][0], srcl);
    float l1 = __shfl(lrow[g][1], srcl);
    float l2 = __shfl(lrow[g][2], srcl);
    float l3 = __shfl(lrow[g][3], srcl);
    float lq = rr == 0 ? l0 : rr == 1 ? l1 : rr == 2 ? l2 : l3;
    float linv = 1.f / lq;
    size_t orow = qkbase + (size_t)(q0w + g * 16 + fr) * 1024;
#pragma unroll
    for (int n = 0; n < 4; n++) {
      bf16x4 ov;
#pragma unroll
      for (int r = 0; r < 4; r++) ov[r] = (bf16_t)(o_acc[g][n][r] * linv);
      *(bf16x4*)&O[orow + n * 16 + fq * 4] = ov;
    }
  }
#undef FSTAGE
}

// ======================= launch =======================

extern "C" void kernel_launch(void* const* d_in, const int* in_sizes, int n_in,
                              void* d_out, int out_size, void* d_ws,
                              size_t ws_size, hipStream_t stream) {
  (void)in_sizes; (void)n_in; (void)out_size; (void)ws_size;
  const float* x          = (const float*)d_in[0];
  const float* qk_emb     = (const float*)d_in[1];
  const float* v_emb      = (const float*)d_in[2];
  const float* know_emb   = (const float*)d_in[3];
  const float* qk_f       = (const float*)d_in[4];
  const float* qk_r       = (const float*)d_in[5];
  const float* v_f        = (const float*)d_in[6];
  const float* v_r        = (const float*)d_in[7];
  const float* know_f     = (const float*)d_in[8];
  const float* know_r     = (const float*)d_in[9];
  const float* proj_attn_k = (const float*)d_in[10];
  const float* proj_attn_b = (const float*)d_in[11];
  const float* tau_attn_k  = (const float*)d_in[12];
  const float* tau_attn_b  = (const float*)d_in[13];
  const float* proj_know_k = (const float*)d_in[14];
  const float* proj_know_b = (const float*)d_in[15];
  const float* tau_know_k  = (const float*)d_in[16];
  const float* tau_know_b  = (const float*)d_in[17];
  const float* expand_O    = (const float*)d_in[18];
  const float* ln1_scale   = (const float*)d_in[19];
  const float* ln1_bias    = (const float*)d_in[20];
  const float* ln2_scale   = (const float*)d_in[21];
  const float* ln2_bias    = (const float*)d_in[22];

  float* out = (float*)d_out;  // [T,D] + aux scalar
  float* aux = out + (size_t)T * D;

  // ---- workspace arena ----
  float* ws = (float*)d_ws;
  float* n_f   = ws;                       // 4M floats
  float* tau3  = n_f + 4194304;            // 16K
  float* gq_b  = tau3 + 16384;             // 64K
  float* gk_b  = gq_b + 65536;
  float* gv_b  = gk_b + 65536;
  float* gkn_b = gv_b + 65536;             // 128K
  float* csum  = gkn_b + 131072;           // 4096 (colsum accumulator)
  float* hQ    = csum + 4096;              // 512K
  float* hK    = hQ + 524288;
  float* hV    = hK + 524288;
  float* qkvarena = hV + 524288;           // 12M floats (Q,K bf16 + Vt bf16)
  float* buf_big = qkvarena + 12582912;    // 16.78M floats (64MB)

  bf16_t* Qbb = (bf16_t*)qkvarena;                 // T*1024 bf16 (8MB)
  bf16_t* Kbb = Qbb + (size_t)T * 1024;            // 8MB
  bf16_t* Vtb = Kbb + (size_t)T * 1024;            // [4][1024][1024] 8MB

  bf16_t* nb   = (bf16_t*)(buf_big + 16777216);  // T*1024
  bf16_t* hab  = nb + 4194304;                   // T*384 (reused know: T*128)
  bf16_t* embB = hab + 1572864;                  // 524288 (qk|v ; know)
  bf16_t* B2t  = embB + 524288;                  // 4096*1024
  bf16_t* wt   = B2t + 4194304;                  // transposed weights arena
  bf16_t* pa_t  = wt;                   // 384*1024
  bf16_t* qkr_t = pa_t + 393216;        // 1024*2048
  bf16_t* vr_t  = qkr_t + 2097152;      // 1024*2048
  bf16_t* knr_t = vr_t + 2097152;       // 1024*4096
  bf16_t* eo_t  = knr_t + 4194304;      // 1024*1024
  bf16_t* pk_t  = eo_t + 1048576;       // 128*1024

  bf16_t* avb = (bf16_t*)buf_big;                   // up to T*4096 bf16
  bf16_t* allh_b = (bf16_t*)buf_big;                // feature all_h bf16
  bf16_t* attnb_b = (bf16_t*)(buf_big + 12582912);  // T*1024 bf16

  bf16_t* embQ = embB;
  bf16_t* embV = embB + 262144;

  dim3 blk(256);

  zero1_kernel<<<1, 1, 0, stream>>>(aux);

  // weight transposes to bf16 [N,K]
  transpose_to_bf16_kernel<<<dim3(12, 32, 1), blk, 0, stream>>>(
      proj_attn_k, pa_t, 1024, 384, 0, 0);
  transpose_to_bf16_kernel<<<dim3(32, 64, 1), blk, 0, stream>>>(
      qk_r, qkr_t, 2048, 1024, 0, 0);
  transpose_to_bf16_kernel<<<dim3(32, 64, 1), blk, 0, stream>>>(
      v_r, vr_t, 2048, 1024, 0, 0);
  transpose_to_bf16_kernel<<<dim3(32, 128, 1), blk, 0, stream>>>(
      know_r, knr_t, 4096, 1024, 0, 0);
  transpose_to_bf16_kernel<<<dim3(32, 32, 1), blk, 0, stream>>>(
      expand_O, eo_t, 1024, 1024, 0, 0);
  transpose_to_bf16_kernel<<<dim3(4, 32, 1), blk, 0, stream>>>(
      proj_know_k, pk_t, 1024, 128, 0, 0);

  // ---- attention circuit ----
  ln_kernel<<<T, blk, 0, stream>>>(x, ln1_scale, ln1_bias, n_f, nb);
  norm_rows_kernel<<<2048, 64, 0, stream>>>(qk_emb, embQ);
  norm_rows_kernel<<<2048, 64, 0, stream>>>(v_emb, embV);

  mfma_gemm_kernel<true, false, 1><<<dim3(3, 32), blk, 0, stream>>>(
      nb, 1024, pa_t, 1024, hab, 384, proj_attn_b, nullptr, 0, T, 384, 1024);
  tau_kernel<<<T, 64, 0, stream>>>(n_f, tau_attn_k, tau_attn_b, tau3, 3);

  // gate scores + gates + aux
  mfma_gemm_kernel<false, false, 0><<<dim3(16, 32), blk, 0, stream>>>(
      hab + 0, 384, embQ, 128, buf_big, 2048, nullptr, nullptr, 0, T, 2048, 128);
  gate_kernel<8><<<T, blk, 0, stream>>>(buf_big, tau3, 3, 0, gq_b, 2048, 16);
  hipMemsetAsync(csum, 0, 2048 * sizeof(float), stream);
  colsum_part_kernel<<<dim3(8, 32), blk, 0, stream>>>(buf_big, 2048, csum);
  colsum_fin_kernel<<<8, blk, 0, stream>>>(csum, 2048, 1.f / 2048.f, aux);

  mfma_gemm_kernel<false, false, 0><<<dim3(16, 32), blk, 0, stream>>>(
      hab + 128, 384, embQ, 128, buf_big, 2048, nullptr, nullptr, 0, T, 2048, 128);
  gate_kernel<8><<<T, blk, 0, stream>>>(buf_big, tau3, 3, 1, gk_b, 2048, 16);
  hipMemsetAsync(csum, 0, 2048 * sizeof(float), stream);
  colsum_part_kernel<<<dim3(8, 32), blk, 0, stream>>>(buf_big, 2048, csum);
  colsum_fin_kernel<<<8, blk, 0, stream>>>(csum, 2048, 1.f / 2048.f, aux);

  mfma_gemm_kernel<false, false, 0><<<dim3(16, 32), blk, 0, stream>>>(
      hab + 256, 384, embV, 128, buf_big, 2048, nullptr, nullptr, 0, T, 2048, 128);
  gate_kernel<8><<<T, blk, 0, stream>>>(buf_big, tau3, 3, 2, gv_b, 2048, 16);
  hipMemsetAsync(csum, 0, 2048 * sizeof(float), stream);
  colsum_part_kernel<<<dim3(8, 32), blk, 0, stream>>>(buf_big, 2048, csum);
  colsum_fin_kernel<<<8, blk, 0, stream>>>(csum, 2048, 1.f / 2048.f, aux);

  // features (qk basis) -> bf16 all_h
  transpose_to_bf16_kernel<<<dim3(4, 32, 16), blk, 0, stream>>>(
      qk_f, B2t, 1024, 128, 131072, 131072);
  mfma_gemm_kernel<false, false, 1><<<dim3(16, 32), blk, 0, stream>>>(
      nb, 1024, B2t, 1024, allh_b, 2048, nullptr, nullptr, 0, T, 2048, 1024);
  wsum2_kernel<<<T, 128, 0, stream>>>(allh_b, gq_b, gk_b, hQ, hK, 16);

  // features (v basis)
  transpose_to_bf16_kernel<<<dim3(4, 32, 16), blk, 0, stream>>>(
      v_f, B2t, 1024, 128, 131072, 131072);
  mfma_gemm_kernel<false, false, 1><<<dim3(16, 32), blk, 0, stream>>>(
      nb, 1024, B2t, 1024, allh_b, 2048, nullptr, nullptr, 0, T, 2048, 1024);
  wsum2_kernel<<<T, 128, 0, stream>>>(allh_b, gv_b, nullptr, hV, nullptr, 16);

  // restores -> Q,K bf16 and Vt transposed bf16
  avirt_kernel<<<T, blk, 0, stream>>>(hQ, gq_b, 16, avb, 2048);
  mfma_gemm_kernel<false, false, 1><<<dim3(8, 32), blk, 0, stream>>>(
      avb, 2048, qkr_t, 2048, Qbb, 1024, nullptr, nullptr, 0, T, 1024, 2048);
  avirt_kernel<<<T, blk, 0, stream>>>(hK, gk_b, 16, avb, 2048);
  mfma_gemm_kernel<false, false, 1><<<dim3(8, 32), blk, 0, stream>>>(
      avb, 2048, qkr_t, 2048, Kbb, 1024, nullptr, nullptr, 0, T, 1024, 2048);
  avirt_kernel<<<T, blk, 0, stream>>>(hV, gv_b, 16, avb, 2048);
  mfma_gemm_kernel<false, false, 2><<<dim3(8, 32), blk, 0, stream>>>(
      avb, 2048, vr_t, 2048, Vtb, 1024, nullptr, nullptr, 0, T, 1024, 2048);

  // MFMA flash attention + output proj + residual
  flash_mfma_kernel<<<dim3(8, 16, 4), blk, 0, stream>>>(Qbb, Kbb, Vtb,
                                                        attnb_b);
  mfma_gemm_kernel<false, true, 0><<<dim3(8, 32), blk, 0, stream>>>(
      attnb_b, 1024, eo_t, 1024, out, 1024, nullptr, x, 1024, T, 1024, 1024);

  // ---- knowledge circuit ----
  ln_kernel<<<T, blk, 0, stream>>>(out, ln2_scale, ln2_bias, n_f, nb);
  norm_rows_kernel<<<4096, 64, 0, stream>>>(know_emb, embB);
  mfma_gemm_kernel<true, false, 1><<<dim3(1, 32), blk, 0, stream>>>(
      nb, 1024, pk_t, 1024, hab, 128, proj_know_b, nullptr, 0, T, 128, 1024);
  tau_kernel<<<T, 64, 0, stream>>>(n_f, tau_know_k, tau_know_b, tau3, 1);

  mfma_gemm_kernel<false, false, 0><<<dim3(32, 32), blk, 0, stream>>>(
      hab, 128, embB, 128, buf_big, 4096, nullptr, nullptr, 0, T, 4096, 128);
  gate_kernel<16><<<T, blk, 0, stream>>>(buf_big, tau3, 1, 0, gkn_b, 4096, 32);
  hipMemsetAsync(csum, 0, 4096 * sizeof(float), stream);
  colsum_part_kernel<<<dim3(16, 32), blk, 0, stream>>>(buf_big, 4096, csum);
  colsum_fin_kernel<<<16, blk, 0, stream>>>(csum, 4096, 1.f / 4096.f, aux);

  transpose_to_bf16_kernel<<<dim3(4, 32, 32), blk, 0, stream>>>(
      know_f, B2t, 1024, 128, 131072, 131072);
  mfma_gemm_kernel<false, false, 1><<<dim3(32, 32), blk, 0, stream>>>(
      nb, 1024, B2t, 1024, allh_b, 4096, nullptr, nullptr, 0, T, 4096, 1024);
  wsum2_kernel<<<T, 128, 0, stream>>>(allh_b, gkn_b, nullptr, hQ, nullptr, 32);

  avirt_kernel<<<T, blk, 0, stream>>>(hQ, gkn_b, 32, avb, 4096);
  mfma_gemm_kernel<false, true, 0><<<dim3(8, 32), blk, 0, stream>>>(
      avb, 4096, knr_t, 4096, out, 1024, nullptr, out, 1024, T, 1024, 4096);
}

// Round 7
// 761.044 us; speedup vs baseline: 5.1494x; 1.0537x over previous
//
#include <hip/hip_runtime.h>
#include <math.h>

static constexpr int T = 4096;   // B*S
static constexpr int D = 1024;

typedef __bf16 bf16_t;
typedef bf16_t bf16x8 __attribute__((ext_vector_type(8)));
typedef bf16_t bf16x4 __attribute__((ext_vector_type(4)));
typedef float f32x4 __attribute__((ext_vector_type(4)));

#define GLDS16(g, l)                                                        \
  __builtin_amdgcn_global_load_lds(                                         \
      (const __attribute__((address_space(1))) void*)(g),                   \
      (__attribute__((address_space(3))) void*)(l), 16, 0, 0)

// ======================= small kernels =======================

__global__ void zero1_kernel(float* p) { *p = 0.f; }

__global__ __launch_bounds__(256) void ln_kernel(
    const float* __restrict__ x, const float* __restrict__ scale,
    const float* __restrict__ bias, float* __restrict__ out_f,
    bf16_t* __restrict__ out_b)
{
  int t = blockIdx.x;
  const float* xr = x + (size_t)t * D;
  float v[4];
  float s1 = 0.f, s2 = 0.f;
#pragma unroll
  for (int i = 0; i < 4; i++) {
    v[i] = xr[threadIdx.x + i * 256];
    s1 += v[i];
    s2 += v[i] * v[i];
  }
#pragma unroll
  for (int o = 1; o < 64; o <<= 1) {
    s1 += __shfl_xor(s1, o);
    s2 += __shfl_xor(s2, o);
  }
  __shared__ float r1[4], r2[4];
  int wid = threadIdx.x >> 6;
  if ((threadIdx.x & 63) == 0) { r1[wid] = s1; r2[wid] = s2; }
  __syncthreads();
  s1 = r1[0] + r1[1] + r1[2] + r1[3];
  s2 = r2[0] + r2[1] + r2[2] + r2[3];
  float mean = s1 * (1.f / D);
  float var = s2 * (1.f / D) - mean * mean;
  float rstd = rsqrtf(var + 1e-6f);
  float* orow = out_f + (size_t)t * D;
  bf16_t* brow = out_b + (size_t)t * D;
#pragma unroll
  for (int i = 0; i < 4; i++) {
    int d = threadIdx.x + i * 256;
    float o = (v[i] - mean) * rstd * scale[d] + bias[d];
    orow[d] = o;
    brow[d] = (bf16_t)o;
  }
}

// rows of length 128, one wave per row; bf16 normalized output
__global__ __launch_bounds__(64) void norm_rows_kernel(
    const float* __restrict__ e, bf16_t* __restrict__ o)
{
  int r = blockIdx.x;
  const float* row = e + (size_t)r * 128;
  float a = row[threadIdx.x], b = row[threadIdx.x + 64];
  float ss = a * a + b * b;
#pragma unroll
  for (int m = 1; m < 64; m <<= 1) ss += __shfl_xor(ss, m);
  float inv = 1.f / (sqrtf(ss) + 1e-8f);
  bf16_t* orow = o + (size_t)r * 128;
  orow[threadIdx.x] = (bf16_t)(a * inv);
  orow[threadIdx.x + 64] = (bf16_t)(b * inv);
}

// tau = n @ W + b,  W: [D, J], J in {1,3}; one wave per token (fp32)
__global__ __launch_bounds__(64) void tau_kernel(
    const float* __restrict__ n, const float* __restrict__ W,
    const float* __restrict__ b, float* __restrict__ out, int J)
{
  int t = blockIdx.x;
  const float* nr = n + (size_t)t * D;
  for (int j = 0; j < J; j++) {
    float p = 0.f;
#pragma unroll 4
    for (int i = 0; i < 16; i++) {
      int d = threadIdx.x + i * 64;
      p += nr[d] * W[d * J + j];
    }
#pragma unroll
    for (int m = 1; m < 64; m <<= 1) p += __shfl_xor(p, m);
    if (threadIdx.x == 0) out[t * J + j] = p + b[j];
  }
}

// threshold gate + group gate, in place.
template <int PER>
__global__ __launch_bounds__(256) void gate_kernel(
    float* __restrict__ g, const float* __restrict__ tau, int tauStride,
    int tauOff, float* __restrict__ gb, int N, int G)
{
  int t = blockIdx.x;
  float tv = tau[t * tauStride + tauOff];
  float* row = g + (size_t)t * N;
  float r[PER];
  int base = threadIdx.x * PER;
  float psum = 0.f;
#pragma unroll
  for (int i = 0; i < PER; i++) {
    float s = row[base + i] - tv;
    s = fmaxf(s, 0.f);
    r[i] = s;
    psum += s;
  }
  __shared__ float red[4];
  __shared__ float grp[32];
  if (threadIdx.x < 32) grp[threadIdx.x] = 0.f;
  float w = psum;
#pragma unroll
  for (int m = 1; m < 64; m <<= 1) w += __shfl_xor(w, m);
  int wid = threadIdx.x >> 6;
  if ((threadIdx.x & 63) == 0) red[wid] = w;
  __syncthreads();
  float Stot = red[0] + red[1] + red[2] + red[3];
  atomicAdd(&grp[base >> 7], psum);
  __syncthreads();
  float inv = 1.f / (Stot + 1e-8f);
#pragma unroll
  for (int i = 0; i < PER; i++) row[base + i] = r[i] * inv;
  if (threadIdx.x < G) {
    float Gj = grp[threadIdx.x] * inv;
    float gsum = Stot * inv;
    gb[(size_t)t * G + threadIdx.x] = Gj / (gsum + 1e-8f);
  }
}

// stage 1: partial column sums of g [T,N] over 128-row chunks
__global__ __launch_bounds__(256) void colsum_part_kernel(
    const float* __restrict__ g, int N, float* __restrict__ colsum)
{
  int c = blockIdx.x * 256 + threadIdx.x;
  int r0 = blockIdx.y * 128;
  const float* p = g + (size_t)r0 * N + c;
  float s = 0.f;
#pragma unroll 8
  for (int t = 0; t < 128; t++) s += p[(size_t)t * N];
  atomicAdd(&colsum[c], s);
}

// stage 2: aux += sum_c (colsum[c]/T - tinv)^2 * N
__global__ __launch_bounds__(256) void colsum_fin_kernel(
    const float* __restrict__ colsum, int N, float tinv,
    float* __restrict__ aux)
{
  int c = blockIdx.x * 256 + threadIdx.x;
  float mdev = colsum[c] * (1.f / T) - tinv;
  float p = mdev * mdev * (float)N;
#pragma unroll
  for (int m = 1; m < 64; m <<= 1) p += __shfl_xor(p, m);
  __shared__ float red[4];
  if ((threadIdx.x & 63) == 0) red[threadIdx.x >> 6] = p;
  __syncthreads();
  if (threadIdx.x == 0) atomicAdd(aux, red[0] + red[1] + red[2] + red[3]);
}

// h1[t,r] = sum_n gb1[t,n]*all_h[t, n*128+r] (all_h bf16); optional 2nd out
__global__ __launch_bounds__(128) void wsum2_kernel(
    const bf16_t* __restrict__ all_h, const float* __restrict__ gb1,
    const float* __restrict__ gb2, float* __restrict__ h1,
    float* __restrict__ h2, int NB)
{
  int t = blockIdx.x;
  int r = threadIdx.x;
  const bf16_t* row = all_h + (size_t)t * NB * 128;
  float a1 = 0.f, a2 = 0.f;
  for (int n = 0; n < NB; n++) {
    float v = (float)row[n * 128 + r];
    a1 += gb1[(size_t)t * NB + n] * v;
    if (gb2) a2 += gb2[(size_t)t * NB + n] * v;
  }
  h1[(size_t)t * 128 + r] = a1;
  if (h2) h2[(size_t)t * 128 + r] = a2;
}

// dst[c][r] = (bf16)src[r][c]; src [R,C] fp32, dst [C,R] bf16; batched
__global__ __launch_bounds__(256) void transpose_to_bf16_kernel(
    const float* __restrict__ src, bf16_t* __restrict__ dst,
    int R, int C, size_t sbs, size_t dbs)
{
  __shared__ float tile[32][33];
  int b = blockIdx.z;
  int c0 = blockIdx.x * 32, r0 = blockIdx.y * 32;
  int tx = threadIdx.x & 31, ty = threadIdx.x >> 5;  // 8 rows/pass
  const float* s = src + (size_t)b * sbs;
  bf16_t* d = dst + (size_t)b * dbs;
#pragma unroll
  for (int i = 0; i < 4; i++)
    tile[ty + i * 8][tx] = s[(size_t)(r0 + ty + i * 8) * C + c0 + tx];
  __syncthreads();
#pragma unroll
  for (int i = 0; i < 4; i++)
    d[(size_t)(c0 + ty + i * 8) * R + r0 + tx] = (bf16_t)tile[tx][ty + i * 8];
}

// A_virt[t,k] = (bf16)(gb[t,k>>7]*h[t,k&127]), row-major [T,K]
__global__ __launch_bounds__(256) void avirt_kernel(
    const float* __restrict__ h, const float* __restrict__ gb, int NB,
    bf16_t* __restrict__ A, int K)
{
  int t = blockIdx.x;
  const float* hr = h + (size_t)t * 128;
  const float* gr = gb + (size_t)t * NB;
  bf16_t* ar = A + (size_t)t * K;
  int noct = K >> 3;
  for (int o = threadIdx.x; o < noct; o += 256) {
    int k = o * 8;
    float g = gr[k >> 7];
    bf16x8 v;
#pragma unroll
    for (int i = 0; i < 8; i++) v[i] = (bf16_t)(hr[(k & 127) + i] * g);
    *(bf16x8*)(ar + k) = v;
  }
}

// ============== MFMA GEMM: C[M,N] = A[M,K]bf16 @ Bt[N,K]bf16^T ==============
// 128x128 tile, BK=32, 4 waves (2x2), 4x4 16x16 fragments per wave.
// Double-buffered LDS with stage-ahead prefetch (one barrier per K-step).
// LDS chunk-XOR swizzle (chunk ^= (row>>1)&3) via pre-swizzled global source.
// XCD-chunked block swizzle for L2 A-panel reuse.
// OUT_MODE: 0 = f32, 1 = bf16, 2 = bf16 transposed V store (Vt[b][col][s])
template <bool HAS_BIAS, bool HAS_RESID, int OUT_MODE>
__global__ __launch_bounds__(256) void mfma_gemm_kernel(
    const bf16_t* __restrict__ A, int lda,
    const bf16_t* __restrict__ Bt, int ldb,
    void* __restrict__ Cv, int ldc,
    const float* __restrict__ bias,
    const float* __restrict__ resid, int ldr,
    int M, int N, int K)
{
  __shared__ bf16_t As[2][128 * 32];
  __shared__ bf16_t Bs[2][128 * 32];
  int tid = threadIdx.x;
  int wave = tid >> 6, lane = tid & 63;

  unsigned lid = blockIdx.y * gridDim.x + blockIdx.x;
  unsigned nwg = gridDim.x * gridDim.y;
  unsigned swzb = lid;
  if ((nwg & 7u) == 0u) swzb = (lid & 7u) * (nwg >> 3) + (lid >> 3);
  int row0 = (int)(swzb / gridDim.x) * 128;
  int col0 = (int)(swzb % gridDim.x) * 128;

  int wr = (wave >> 1) * 64, wc = (wave & 1) * 64;

  f32x4 acc[4][4] = {};

  // staging: row srow (0..63 per 64-row half), 16B chunk (lane&3).
  // LDS layout: chunk position p of row r holds global chunk p ^ ((r>>1)&3).
  int srow = (wave << 4) + (lane >> 2);
  int g8 = (((lane & 3) ^ ((srow >> 1) & 3)) << 3);  // swizzled src elem off
  const bf16_t* gA = A + (size_t)(row0 + srow) * lda + g8;
  const bf16_t* gB = Bt + (size_t)(col0 + srow) * ldb + g8;
  size_t a64 = (size_t)64 * lda, b64 = (size_t)64 * ldb;

  int fr = lane & 15, fq = lane >> 4;

#define GSTAGE(buf, k0s)                                  \
  {                                                       \
    GLDS16(gA + (k0s), &As[buf][wave * 512]);             \
    GLDS16(gA + a64 + (k0s), &As[buf][2048 + wave * 512]);\
    GLDS16(gB + (k0s), &Bs[buf][wave * 512]);             \
    GLDS16(gB + b64 + (k0s), &Bs[buf][2048 + wave * 512]);\
  }

  GSTAGE(0, 0);
  int cur = 0;
  for (int k0 = 0; k0 < K; k0 += 32) {
    __syncthreads();  // buf[cur] loads complete; prior reads done
    if (k0 + 32 < K) GSTAGE(cur ^ 1, k0 + 32);
    bf16x8 af[4], bfr[4];
#pragma unroll
    for (int m = 0; m < 4; m++) {
      int R = wr + m * 16 + fr;
      af[m] = *(const bf16x8*)&As[cur][R * 32 + ((fq ^ ((R >> 1) & 3)) << 3)];
    }
#pragma unroll
    for (int n = 0; n < 4; n++) {
      int R = wc + n * 16 + fr;
      bfr[n] = *(const bf16x8*)&Bs[cur][R * 32 + ((fq ^ ((R >> 1) & 3)) << 3)];
    }
#pragma unroll
    for (int m = 0; m < 4; m++)
#pragma unroll
      for (int n = 0; n < 4; n++)
        acc[m][n] = __builtin_amdgcn_mfma_f32_16x16x32_bf16(af[m], bfr[n],
                                                            acc[m][n], 0, 0, 0);
    cur ^= 1;
  }
#undef GSTAGE

#pragma unroll
  for (int m = 0; m < 4; m++) {
#pragma unroll
    for (int n = 0; n < 4; n++) {
      int rowb = row0 + wr + m * 16 + fq * 4;
      int col = col0 + wc + n * 16 + fr;
      if (OUT_MODE == 2) {
        bf16x4 v4;
#pragma unroll
        for (int r = 0; r < 4; r++) v4[r] = (bf16_t)acc[m][n][r];
        bf16_t* dst = (bf16_t*)Cv +
            ((size_t)(rowb >> 10) * 1024 + col) * 1024 + (rowb & 1023);
        *(bf16x4*)dst = v4;
      } else {
#pragma unroll
        for (int r = 0; r < 4; r++) {
          int row = rowb + r;
          float v = acc[m][n][r];
          if (HAS_BIAS) v += bias[col];
          if (HAS_RESID) v += resid[(size_t)row * ldr + col];
          if (OUT_MODE == 1)
            ((bf16_t*)Cv)[(size_t)row * ldc + col] = (bf16_t)v;
          else
            ((float*)Cv)[(size_t)row * ldc + col] = v;
        }
      }
    }
  }
}

// ======================= MFMA flash attention (bf16, LDS-staged) ============
// Block: 128 q rows (4 waves x 32), KV tiles of 64 double-buffered in LDS.
__global__ __launch_bounds__(256) void flash_mfma_kernel(
    const bf16_t* __restrict__ Q, const bf16_t* __restrict__ K,
    const bf16_t* __restrict__ Vt, bf16_t* __restrict__ O)
{
  __shared__ bf16_t Ks[2][64 * 64];  // [64 kv][128B], XOR-swizzled
  __shared__ bf16_t Vs[2][64 * 64];  // [64 d][128B], XOR-swizzled
  __shared__ bf16_t Pl[4][32 * 64];  // per-wave P [32 q][128B], swizzled

  int tid = threadIdx.x;
  int wave = tid >> 6, lane = tid & 63;
  int fr = lane & 15, fq = lane >> 4;
  // XCD-chunked swizzle: co-locate the 8 q-tiles of each (h,b) on one XCD
  unsigned lid = blockIdx.x + blockIdx.y * 8 + blockIdx.z * 128;  // 512 wgs
  unsigned swz9 = (lid & 7u) * 64 + (lid >> 3);
  int qb = swz9 & 7, h = (swz9 >> 3) & 15, b = swz9 >> 7;
  int q0w = qb * 128 + wave * 32;
  size_t qkbase = ((size_t)b * 1024) * 1024 + (size_t)h * 64;
  size_t vtbase = ((size_t)b * 1024 + (size_t)h * 64) * 1024;

  // staging geometry (per wave, 8-row chunks, source col pre-swizzled)
  int srow8 = lane >> 3;                               // 0..7
  int scb = (((lane & 7) << 4) ^ (srow8 << 4)) >> 1;  // element offset

#define FSTAGE(buf, kt)                                                     \
  {                                                                         \
    int k0s = (kt) * 64;                                                    \
    _Pragma("unroll") for (int cc = 0; cc < 2; cc++) {                      \
      int rr0 = wave * 16 + cc * 8;                                         \
      int row = rr0 + srow8;                                                \
      GLDS16(&K[qkbase + (size_t)(k0s + row) * 1024 + scb],                 \
             &Ks[buf][rr0 * 64]);                                           \
      GLDS16(&Vt[vtbase + (size_t)row * 1024 + k0s + scb],                  \
             &Vs[buf][rr0 * 64]);                                           \
    }                                                                       \
  }

  // Q A-fragments: 2 row-groups x 2 k-halves
  bf16x8 qf[2][2];
#pragma unroll
  for (int g = 0; g < 2; g++)
#pragma unroll
    for (int kh = 0; kh < 2; kh++)
      qf[g][kh] = *(const bf16x8*)&Q[qkbase +
                                     (size_t)(q0w + g * 16 + fr) * 1024 +
                                     kh * 32 + fq * 8];

  f32x4 o_acc[2][4] = {};
  float mrow[2][4], lrow[2][4];
#pragma unroll
  for (int g = 0; g < 2; g++)
#pragma unroll
    for (int r = 0; r < 4; r++) { mrow[g][r] = -INFINITY; lrow[g][r] = 0.f; }

  char* P = (char*)&Pl[wave][0];
  int KT = 2 * qb + 2;

  FSTAGE(0, 0);

  for (int kt = 0; kt < KT; kt++) {
    __syncthreads();  // drains vmcnt: buf[kt&1] staged & visible
    if (kt + 1 < KT) FSTAGE((kt + 1) & 1, kt + 1);
    int k0 = kt * 64;
    if (k0 <= q0w + 31) {
      const char* Kb = (const char*)&Ks[kt & 1][0];
      const char* Vb = (const char*)&Vs[kt & 1][0];
      int swz = (fr & 7) << 4;
      // QK^T
      f32x4 s[2][4] = {};
#pragma unroll
      for (int n = 0; n < 4; n++) {
        int rowo = (n * 16 + fr) * 128;
        bf16x8 kf0 = *(const bf16x8*)(Kb + rowo + ((fq * 16) ^ swz));
        bf16x8 kf1 = *(const bf16x8*)(Kb + rowo + ((64 + fq * 16) ^ swz));
#pragma unroll
        for (int g = 0; g < 2; g++) {
          s[g][n] = __builtin_amdgcn_mfma_f32_16x16x32_bf16(qf[g][0], kf0,
                                                            s[g][n], 0, 0, 0);
          s[g][n] = __builtin_amdgcn_mfma_f32_16x16x32_bf16(qf[g][1], kf1,
                                                            s[g][n], 0, 0, 0);
        }
      }
      const float scale = 0.125f;
#pragma unroll
      for (int g = 0; g < 2; g++) {
        bool dm = (k0 + 63 > q0w + g * 16);
#pragma unroll
        for (int n = 0; n < 4; n++)
#pragma unroll
          for (int r = 0; r < 4; r++) {
            float v = s[g][n][r] * scale;
            if (dm && (k0 + n * 16 + fr > q0w + g * 16 + fq * 4 + r))
              v = -INFINITY;
            s[g][n][r] = v;
          }
      }
      // online softmax per row (q = g*16 + fq*4 + r), reduce across fr
      float corr[2][4];
#pragma unroll
      for (int g = 0; g < 2; g++)
#pragma unroll
        for (int r = 0; r < 4; r++) {
          float mx = fmaxf(fmaxf(s[g][0][r], s[g][1][r]),
                           fmaxf(s[g][2][r], s[g][3][r]));
#pragma unroll
          for (int msk = 1; msk < 16; msk <<= 1)
            mx = fmaxf(mx, __shfl_xor(mx, msk));
          float mnew = fmaxf(mrow[g][r], mx);
          corr[g][r] = __expf(mrow[g][r] - mnew);
          mrow[g][r] = mnew;
          float ps = 0.f;
#pragma unroll
          for (int n = 0; n < 4; n++) {
            float p = __expf(s[g][n][r] - mnew);
            s[g][n][r] = p;
            ps += p;
          }
#pragma unroll
          for (int msk = 1; msk < 16; msk <<= 1) ps += __shfl_xor(ps, msk);
          lrow[g][r] = lrow[g][r] * corr[g][r] + ps;
        }
      // P -> LDS (bf16, swizzled by q&7)
#pragma unroll
      for (int g = 0; g < 2; g++)
#pragma unroll
        for (int n = 0; n < 4; n++)
#pragma unroll
          for (int r = 0; r < 4; r++) {
            int q = g * 16 + fq * 4 + r;
            int cb = ((n * 16 + fr) * 2) ^ ((q & 7) << 4);
            *(bf16_t*)(P + q * 128 + cb) = (bf16_t)s[g][n][r];
          }
      // rescale o_acc by corr broadcast to q = fr lanes
      int rr = fr & 3;
      int srcl = (fr >> 2) << 4;
#pragma unroll
      for (int g = 0; g < 2; g++) {
        float c0 = __shfl(corr[g][0], srcl);
        float c1 = __shfl(corr[g][1], srcl);
        float c2 = __shfl(corr[g][2], srcl);
        float c3 = __shfl(corr[g][3], srcl);
        float cq = rr == 0 ? c0 : rr == 1 ? c1 : rr == 2 ? c2 : c3;
#pragma unroll
        for (int n = 0; n < 4; n++)
#pragma unroll
          for (int r = 0; r < 4; r++) o_acc[g][n][r] *= cq;
      }
      // PV: O^T += Vs_frag(A) @ P_frag(B)
#pragma unroll
      for (int c = 0; c < 2; c++) {
        bf16x8 pf[2];
#pragma unroll
        for (int g = 0; g < 2; g++)
          pf[g] = *(const bf16x8*)(P + (g * 16 + fr) * 128 +
                                   ((c * 64 + fq * 16) ^ swz));
#pragma unroll
        for (int n = 0; n < 4; n++) {
          bf16x8 vf = *(const bf16x8*)(Vb + (n * 16 + fr) * 128 +
                                       ((c * 64 + fq * 16) ^ swz));
#pragma unroll
          for (int g = 0; g < 2; g++)
            o_acc[g][n] = __builtin_amdgcn_mfma_f32_16x16x32_bf16(
                vf, pf[g], o_acc[g][n], 0, 0, 0);
        }
      }
    }
  }
  // epilogue
  int rr = fr & 3;
  int srcl = (fr >> 2) << 4;
#pragma unroll
  for (int g = 0; g < 2; g++) {
    float l0 = __shfl(lrow[g][0], srcl);
    float l1 = __shfl(lrow[g][1], srcl);
    float l2 = __shfl(lrow[g][2], srcl);
    float l3 = __shfl(lrow[g][3], srcl);
    float lq = rr == 0 ? l0 : rr == 1 ? l1 : rr == 2 ? l2 : l3;
    float linv = 1.f / lq;
    size_t orow = qkbase + (size_t)(q0w + g * 16 + fr) * 1024;
#pragma unroll
    for (int n = 0; n < 4; n++) {
      bf16x4 ov;
#pragma unroll
      for (int r = 0; r < 4; r++) ov[r] = (bf16_t)(o_acc[g][n][r] * linv);
      *(bf16x4*)&O[orow + n * 16 + fq * 4] = ov;
    }
  }
#undef FSTAGE
}

// ======================= launch =======================

extern "C" void kernel_launch(void* const* d_in, const int* in_sizes, int n_in,
                              void* d_out, int out_size, void* d_ws,
                              size_t ws_size, hipStream_t stream) {
  (void)in_sizes; (void)n_in; (void)out_size; (void)ws_size;
  const float* x          = (const float*)d_in[0];
  const float* qk_emb     = (const float*)d_in[1];
  const float* v_emb      = (const float*)d_in[2];
  const float* know_emb   = (const float*)d_in[3];
  const float* qk_f       = (const float*)d_in[4];
  const float* qk_r       = (const float*)d_in[5];
  const float* v_f        = (const float*)d_in[6];
  const float* v_r        = (const float*)d_in[7];
  const float* know_f     = (const float*)d_in[8];
  const float* know_r     = (const float*)d_in[9];
  const float* proj_attn_k = (const float*)d_in[10];
  const float* proj_attn_b = (const float*)d_in[11];
  const float* tau_attn_k  = (const float*)d_in[12];
  const float* tau_attn_b  = (const float*)d_in[13];
  const float* proj_know_k = (const float*)d_in[14];
  const float* proj_know_b = (const float*)d_in[15];
  const float* tau_know_k  = (const float*)d_in[16];
  const float* tau_know_b  = (const float*)d_in[17];
  const float* expand_O    = (const float*)d_in[18];
  const float* ln1_scale   = (const float*)d_in[19];
  const float* ln1_bias    = (const float*)d_in[20];
  const float* ln2_scale   = (const float*)d_in[21];
  const float* ln2_bias    = (const float*)d_in[22];

  float* out = (float*)d_out;  // [T,D] + aux scalar
  float* aux = out + (size_t)T * D;

  // ---- workspace arena ----
  float* ws = (float*)d_ws;
  float* n_f   = ws;                       // 4M floats
  float* tau3  = n_f + 4194304;            // 16K
  float* gq_b  = tau3 + 16384;             // 64K
  float* gk_b  = gq_b + 65536;
  float* gv_b  = gk_b + 65536;
  float* gkn_b = gv_b + 65536;             // 128K
  float* csum  = gkn_b + 131072;           // 4096 (colsum accumulator)
  float* hQ    = csum + 4096;              // 512K
  float* hK    = hQ + 524288;
  float* hV    = hK + 524288;
  float* qkvarena = hV + 524288;           // 12M floats (Q,K bf16 + Vt bf16)
  float* buf_big = qkvarena + 12582912;    // 16.78M floats (64MB)

  bf16_t* Qbb = (bf16_t*)qkvarena;                 // T*1024 bf16 (8MB)
  bf16_t* Kbb = Qbb + (size_t)T * 1024;            // 8MB
  bf16_t* Vtb = Kbb + (size_t)T * 1024;            // [4][1024][1024] 8MB

  bf16_t* nb   = (bf16_t*)(buf_big + 16777216);  // T*1024
  bf16_t* hab  = nb + 4194304;                   // T*384 (reused know: T*128)
  bf16_t* embB = hab + 1572864;                  // 524288 (qk|v ; know)
  bf16_t* B2t  = embB + 524288;                  // 4096*1024
  bf16_t* wt   = B2t + 4194304;                  // transposed weights arena
  bf16_t* pa_t  = wt;                   // 384*1024
  bf16_t* qkr_t = pa_t + 393216;        // 1024*2048
  bf16_t* vr_t  = qkr_t + 2097152;      // 1024*2048
  bf16_t* knr_t = vr_t + 2097152;       // 1024*4096
  bf16_t* eo_t  = knr_t + 4194304;      // 1024*1024
  bf16_t* pk_t  = eo_t + 1048576;       // 128*1024

  bf16_t* avb = (bf16_t*)buf_big;                   // up to T*4096 bf16
  bf16_t* allh_b = (bf16_t*)buf_big;                // feature all_h bf16
  bf16_t* attnb_b = (bf16_t*)(buf_big + 12582912);  // T*1024 bf16

  bf16_t* embQ = embB;
  bf16_t* embV = embB + 262144;

  dim3 blk(256);

  zero1_kernel<<<1, 1, 0, stream>>>(aux);

  // weight transposes to bf16 [N,K]
  transpose_to_bf16_kernel<<<dim3(12, 32, 1), blk, 0, stream>>>(
      proj_attn_k, pa_t, 1024, 384, 0, 0);
  transpose_to_bf16_kernel<<<dim3(32, 64, 1), blk, 0, stream>>>(
      qk_r, qkr_t, 2048, 1024, 0, 0);
  transpose_to_bf16_kernel<<<dim3(32, 64, 1), blk, 0, stream>>>(
      v_r, vr_t, 2048, 1024, 0, 0);
  transpose_to_bf16_kernel<<<dim3(32, 128, 1), blk, 0, stream>>>(
      know_r, knr_t, 4096, 1024, 0, 0);
  transpose_to_bf16_kernel<<<dim3(32, 32, 1), blk, 0, stream>>>(
      expand_O, eo_t, 1024, 1024, 0, 0);
  transpose_to_bf16_kernel<<<dim3(4, 32, 1), blk, 0, stream>>>(
      proj_know_k, pk_t, 1024, 128, 0, 0);

  // ---- attention circuit ----
  ln_kernel<<<T, blk, 0, stream>>>(x, ln1_scale, ln1_bias, n_f, nb);
  norm_rows_kernel<<<2048, 64, 0, stream>>>(qk_emb, embQ);
  norm_rows_kernel<<<2048, 64, 0, stream>>>(v_emb, embV);

  mfma_gemm_kernel<true, false, 1><<<dim3(3, 32), blk, 0, stream>>>(
      nb, 1024, pa_t, 1024, hab, 384, proj_attn_b, nullptr, 0, T, 384, 1024);
  tau_kernel<<<T, 64, 0, stream>>>(n_f, tau_attn_k, tau_attn_b, tau3, 3);

  // gate scores + gates + aux
  mfma_gemm_kernel<false, false, 0><<<dim3(16, 32), blk, 0, stream>>>(
      hab + 0, 384, embQ, 128, buf_big, 2048, nullptr, nullptr, 0, T, 2048, 128);
  gate_kernel<8><<<T, blk, 0, stream>>>(buf_big, tau3, 3, 0, gq_b, 2048, 16);
  hipMemsetAsync(csum, 0, 2048 * sizeof(float), stream);
  colsum_part_kernel<<<dim3(8, 32), blk, 0, stream>>>(buf_big, 2048, csum);
  colsum_fin_kernel<<<8, blk, 0, stream>>>(csum, 2048, 1.f / 2048.f, aux);

  mfma_gemm_kernel<false, false, 0><<<dim3(16, 32), blk, 0, stream>>>(
      hab + 128, 384, embQ, 128, buf_big, 2048, nullptr, nullptr, 0, T, 2048, 128);
  gate_kernel<8><<<T, blk, 0, stream>>>(buf_big, tau3, 3, 1, gk_b, 2048, 16);
  hipMemsetAsync(csum, 0, 2048 * sizeof(float), stream);
  colsum_part_kernel<<<dim3(8, 32), blk, 0, stream>>>(buf_big, 2048, csum);
  colsum_fin_kernel<<<8, blk, 0, stream>>>(csum, 2048, 1.f / 2048.f, aux);

  mfma_gemm_kernel<false, false, 0><<<dim3(16, 32), blk, 0, stream>>>(
      hab + 256, 384, embV, 128, buf_big, 2048, nullptr, nullptr, 0, T, 2048, 128);
  gate_kernel<8><<<T, blk, 0, stream>>>(buf_big, tau3, 3, 2, gv_b, 2048, 16);
  hipMemsetAsync(csum, 0, 2048 * sizeof(float), stream);
  colsum_part_kernel<<<dim3(8, 32), blk, 0, stream>>>(buf_big, 2048, csum);
  colsum_fin_kernel<<<8, blk, 0, stream>>>(csum, 2048, 1.f / 2048.f, aux);

  // features (qk basis) -> bf16 all_h
  transpose_to_bf16_kernel<<<dim3(4, 32, 16), blk, 0, stream>>>(
      qk_f, B2t, 1024, 128, 131072, 131072);
  mfma_gemm_kernel<false, false, 1><<<dim3(16, 32), blk, 0, stream>>>(
      nb, 1024, B2t, 1024, allh_b, 2048, nullptr, nullptr, 0, T, 2048, 1024);
  wsum2_kernel<<<T, 128, 0, stream>>>(allh_b, gq_b, gk_b, hQ, hK, 16);

  // features (v basis)
  transpose_to_bf16_kernel<<<dim3(4, 32, 16), blk, 0, stream>>>(
      v_f, B2t, 1024, 128, 131072, 131072);
  mfma_gemm_kernel<false, false, 1><<<dim3(16, 32), blk, 0, stream>>>(
      nb, 1024, B2t, 1024, allh_b, 2048, nullptr, nullptr, 0, T, 2048, 1024);
  wsum2_kernel<<<T, 128, 0, stream>>>(allh_b, gv_b, nullptr, hV, nullptr, 16);

  // restores -> Q,K bf16 and Vt transposed bf16
  avirt_kernel<<<T, blk, 0, stream>>>(hQ, gq_b, 16, avb, 2048);
  mfma_gemm_kernel<false, false, 1><<<dim3(8, 32), blk, 0, stream>>>(
      avb, 2048, qkr_t, 2048, Qbb, 1024, nullptr, nullptr, 0, T, 1024, 2048);
  avirt_kernel<<<T, blk, 0, stream>>>(hK, gk_b, 16, avb, 2048);
  mfma_gemm_kernel<false, false, 1><<<dim3(8, 32), blk, 0, stream>>>(
      avb, 2048, qkr_t, 2048, Kbb, 1024, nullptr, nullptr, 0, T, 1024, 2048);
  avirt_kernel<<<T, blk, 0, stream>>>(hV, gv_b, 16, avb, 2048);
  mfma_gemm_kernel<false, false, 2><<<dim3(8, 32), blk, 0, stream>>>(
      avb, 2048, vr_t, 2048, Vtb, 1024, nullptr, nullptr, 0, T, 1024, 2048);

  // MFMA flash attention + output proj + residual
  flash_mfma_kernel<<<dim3(8, 16, 4), blk, 0, stream>>>(Qbb, Kbb, Vtb,
                                                        attnb_b);
  mfma_gemm_kernel<false, true, 0><<<dim3(8, 32), blk, 0, stream>>>(
      attnb_b, 1024, eo_t, 1024, out, 1024, nullptr, x, 1024, T, 1024, 1024);

  // ---- knowledge circuit ----
  ln_kernel<<<T, blk, 0, stream>>>(out, ln2_scale, ln2_bias, n_f, nb);
  norm_rows_kernel<<<4096, 64, 0, stream>>>(know_emb, embB);
  mfma_gemm_kernel<true, false, 1><<<dim3(1, 32), blk, 0, stream>>>(
      nb, 1024, pk_t, 1024, hab, 128, proj_know_b, nullptr, 0, T, 128, 1024);
  tau_kernel<<<T, 64, 0, stream>>>(n_f, tau_know_k, tau_know_b, tau3, 1);

  mfma_gemm_kernel<false, false, 0><<<dim3(32, 32), blk, 0, stream>>>(
      hab, 128, embB, 128, buf_big, 4096, nullptr, nullptr, 0, T, 4096, 128);
  gate_kernel<16><<<T, blk, 0, stream>>>(buf_big, tau3, 1, 0, gkn_b, 4096, 32);
  hipMemsetAsync(csum, 0, 4096 * sizeof(float), stream);
  colsum_part_kernel<<<dim3(16, 32), blk, 0, stream>>>(buf_big, 4096, csum);
  colsum_fin_kernel<<<16, blk, 0, stream>>>(csum, 4096, 1.f / 4096.f, aux);

  transpose_to_bf16_kernel<<<dim3(4, 32, 32), blk, 0, stream>>>(
      know_f, B2t, 1024, 128, 131072, 131072);
  mfma_gemm_kernel<false, false, 1><<<dim3(32, 32), blk, 0, stream>>>(
      nb, 1024, B2t, 1024, allh_b, 4096, nullptr, nullptr, 0, T, 4096, 1024);
  wsum2_kernel<<<T, 128, 0, stream>>>(allh_b, gkn_b, nullptr, hQ, nullptr, 32);

  avirt_kernel<<<T, blk, 0, stream>>>(hQ, gkn_b, 32, avb, 4096);
  mfma_gemm_kernel<false, true, 0><<<dim3(8, 32), blk, 0, stream>>>(
      avb, 4096, knr_t, 4096, out, 1024, nullptr, out, 1024, T, 1024, 4096);
}

// Round 8
// 716.265 us; speedup vs baseline: 5.4713x; 1.0625x over previous
//
#include <hip/hip_runtime.h>
#include <math.h>

static constexpr int T = 4096;   // B*S
static constexpr int D = 1024;

typedef __bf16 bf16_t;
typedef bf16_t bf16x8 __attribute__((ext_vector_type(8)));
typedef bf16_t bf16x4 __attribute__((ext_vector_type(4)));
typedef float f32x4 __attribute__((ext_vector_type(4)));

#define GLDS16(g, l)                                                        \
  __builtin_amdgcn_global_load_lds(                                         \
      (const __attribute__((address_space(1))) void*)(g),                   \
      (__attribute__((address_space(3))) void*)(l), 16, 0, 0)

// ======================= small kernels =======================

__global__ void zero1_kernel(float* p) { *p = 0.f; }

__global__ __launch_bounds__(256) void ln_kernel(
    const float* __restrict__ x, const float* __restrict__ scale,
    const float* __restrict__ bias, float* __restrict__ out_f,
    bf16_t* __restrict__ out_b)
{
  int t = blockIdx.x;
  const float* xr = x + (size_t)t * D;
  float v[4];
  float s1 = 0.f, s2 = 0.f;
#pragma unroll
  for (int i = 0; i < 4; i++) {
    v[i] = xr[threadIdx.x + i * 256];
    s1 += v[i];
    s2 += v[i] * v[i];
  }
#pragma unroll
  for (int o = 1; o < 64; o <<= 1) {
    s1 += __shfl_xor(s1, o);
    s2 += __shfl_xor(s2, o);
  }
  __shared__ float r1[4], r2[4];
  int wid = threadIdx.x >> 6;
  if ((threadIdx.x & 63) == 0) { r1[wid] = s1; r2[wid] = s2; }
  __syncthreads();
  s1 = r1[0] + r1[1] + r1[2] + r1[3];
  s2 = r2[0] + r2[1] + r2[2] + r2[3];
  float mean = s1 * (1.f / D);
  float var = s2 * (1.f / D) - mean * mean;
  float rstd = rsqrtf(var + 1e-6f);
  float* orow = out_f + (size_t)t * D;
  bf16_t* brow = out_b + (size_t)t * D;
#pragma unroll
  for (int i = 0; i < 4; i++) {
    int d = threadIdx.x + i * 256;
    float o = (v[i] - mean) * rstd * scale[d] + bias[d];
    orow[d] = o;
    brow[d] = (bf16_t)o;
  }
}

// rows of length 128, one wave per row; bf16 normalized output
__global__ __launch_bounds__(64) void norm_rows_kernel(
    const float* __restrict__ e, bf16_t* __restrict__ o)
{
  int r = blockIdx.x;
  const float* row = e + (size_t)r * 128;
  float a = row[threadIdx.x], b = row[threadIdx.x + 64];
  float ss = a * a + b * b;
#pragma unroll
  for (int m = 1; m < 64; m <<= 1) ss += __shfl_xor(ss, m);
  float inv = 1.f / (sqrtf(ss) + 1e-8f);
  bf16_t* orow = o + (size_t)r * 128;
  orow[threadIdx.x] = (bf16_t)(a * inv);
  orow[threadIdx.x + 64] = (bf16_t)(b * inv);
}

// tau = n @ W + b,  W: [D, J], J in {1,3}; one wave per token (fp32)
__global__ __launch_bounds__(64) void tau_kernel(
    const float* __restrict__ n, const float* __restrict__ W,
    const float* __restrict__ b, float* __restrict__ out, int J)
{
  int t = blockIdx.x;
  const float* nr = n + (size_t)t * D;
  for (int j = 0; j < J; j++) {
    float p = 0.f;
#pragma unroll 4
    for (int i = 0; i < 16; i++) {
      int d = threadIdx.x + i * 64;
      p += nr[d] * W[d * J + j];
    }
#pragma unroll
    for (int m = 1; m < 64; m <<= 1) p += __shfl_xor(p, m);
    if (threadIdx.x == 0) out[t * J + j] = p + b[j];
  }
}

// threshold gate + group gate, in place.
template <int PER>
__global__ __launch_bounds__(256) void gate_kernel(
    float* __restrict__ g, const float* __restrict__ tau, int tauStride,
    int tauOff, float* __restrict__ gb, int N, int G)
{
  int t = blockIdx.x;
  float tv = tau[t * tauStride + tauOff];
  float* row = g + (size_t)t * N;
  float r[PER];
  int base = threadIdx.x * PER;
  float psum = 0.f;
#pragma unroll
  for (int i = 0; i < PER; i++) {
    float s = row[base + i] - tv;
    s = fmaxf(s, 0.f);
    r[i] = s;
    psum += s;
  }
  __shared__ float red[4];
  __shared__ float grp[32];
  if (threadIdx.x < 32) grp[threadIdx.x] = 0.f;
  float w = psum;
#pragma unroll
  for (int m = 1; m < 64; m <<= 1) w += __shfl_xor(w, m);
  int wid = threadIdx.x >> 6;
  if ((threadIdx.x & 63) == 0) red[wid] = w;
  __syncthreads();
  float Stot = red[0] + red[1] + red[2] + red[3];
  atomicAdd(&grp[base >> 7], psum);
  __syncthreads();
  float inv = 1.f / (Stot + 1e-8f);
#pragma unroll
  for (int i = 0; i < PER; i++) row[base + i] = r[i] * inv;
  if (threadIdx.x < G) {
    float Gj = grp[threadIdx.x] * inv;
    float gsum = Stot * inv;
    gb[(size_t)t * G + threadIdx.x] = Gj / (gsum + 1e-8f);
  }
}

// stage 1: partial column sums of g [T,N] over 128-row chunks
__global__ __launch_bounds__(256) void colsum_part_kernel(
    const float* __restrict__ g, int N, float* __restrict__ colsum)
{
  int c = blockIdx.x * 256 + threadIdx.x;
  int r0 = blockIdx.y * 128;
  const float* p = g + (size_t)r0 * N + c;
  float s = 0.f;
#pragma unroll 8
  for (int t = 0; t < 128; t++) s += p[(size_t)t * N];
  atomicAdd(&colsum[c], s);
}

// stage 2: aux += sum_c (colsum[c]/T - tinv)^2 * N
__global__ __launch_bounds__(256) void colsum_fin_kernel(
    const float* __restrict__ colsum, int N, float tinv,
    float* __restrict__ aux)
{
  int c = blockIdx.x * 256 + threadIdx.x;
  float mdev = colsum[c] * (1.f / T) - tinv;
  float p = mdev * mdev * (float)N;
#pragma unroll
  for (int m = 1; m < 64; m <<= 1) p += __shfl_xor(p, m);
  __shared__ float red[4];
  if ((threadIdx.x & 63) == 0) red[threadIdx.x >> 6] = p;
  __syncthreads();
  if (threadIdx.x == 0) atomicAdd(aux, red[0] + red[1] + red[2] + red[3]);
}

// h1[t,r] = sum_n gb1[t,n]*all_h[t, n*128+r] (all_h bf16); optional 2nd out
__global__ __launch_bounds__(128) void wsum2_kernel(
    const bf16_t* __restrict__ all_h, const float* __restrict__ gb1,
    const float* __restrict__ gb2, float* __restrict__ h1,
    float* __restrict__ h2, int NB)
{
  int t = blockIdx.x;
  int r = threadIdx.x;
  const bf16_t* row = all_h + (size_t)t * NB * 128;
  float a1 = 0.f, a2 = 0.f;
  for (int n = 0; n < NB; n++) {
    float v = (float)row[n * 128 + r];
    a1 += gb1[(size_t)t * NB + n] * v;
    if (gb2) a2 += gb2[(size_t)t * NB + n] * v;
  }
  h1[(size_t)t * 128 + r] = a1;
  if (h2) h2[(size_t)t * 128 + r] = a2;
}

// dst[c][r] = (bf16)src[r][c]; src [R,C] fp32, dst [C,R] bf16; batched
__global__ __launch_bounds__(256) void transpose_to_bf16_kernel(
    const float* __restrict__ src, bf16_t* __restrict__ dst,
    int R, int C, size_t sbs, size_t dbs)
{
  __shared__ float tile[32][33];
  int b = blockIdx.z;
  int c0 = blockIdx.x * 32, r0 = blockIdx.y * 32;
  int tx = threadIdx.x & 31, ty = threadIdx.x >> 5;  // 8 rows/pass
  const float* s = src + (size_t)b * sbs;
  bf16_t* d = dst + (size_t)b * dbs;
#pragma unroll
  for (int i = 0; i < 4; i++)
    tile[ty + i * 8][tx] = s[(size_t)(r0 + ty + i * 8) * C + c0 + tx];
  __syncthreads();
#pragma unroll
  for (int i = 0; i < 4; i++)
    d[(size_t)(c0 + ty + i * 8) * R + r0 + tx] = (bf16_t)tile[tx][ty + i * 8];
}

// A_virt[t,k] = (bf16)(gb[t,k>>7]*h[t,k&127]), row-major [T,K]
__global__ __launch_bounds__(256) void avirt_kernel(
    const float* __restrict__ h, const float* __restrict__ gb, int NB,
    bf16_t* __restrict__ A, int K)
{
  int t = blockIdx.x;
  const float* hr = h + (size_t)t * 128;
  const float* gr = gb + (size_t)t * NB;
  bf16_t* ar = A + (size_t)t * K;
  int noct = K >> 3;
  for (int o = threadIdx.x; o < noct; o += 256) {
    int k = o * 8;
    float g = gr[k >> 7];
    bf16x8 v;
#pragma unroll
    for (int i = 0; i < 8; i++) v[i] = (bf16_t)(hr[(k & 127) + i] * g);
    *(bf16x8*)(ar + k) = v;
  }
}

// ============== MFMA GEMM: C[M,N] = A[M,K]bf16 @ Bt[N,K]bf16^T ==============
// 64x128 tile, BK=32, 4 waves (2x2: 32 rows x 64 cols each), 2x4 fragments.
// Double-buffered LDS, stage-ahead prefetch, chunk-XOR swizzle, XCD-chunked
// block swizzle. Grid: x = N/128, y = M/64 (2-4 blocks/CU for TLP overlap).
// OUT_MODE: 0 = f32, 1 = bf16, 2 = bf16 transposed V store (Vt[b][col][s])
template <bool HAS_BIAS, bool HAS_RESID, int OUT_MODE>
__global__ __launch_bounds__(256) void mfma_gemm_kernel(
    const bf16_t* __restrict__ A, int lda,
    const bf16_t* __restrict__ Bt, int ldb,
    void* __restrict__ Cv, int ldc,
    const float* __restrict__ bias,
    const float* __restrict__ resid, int ldr,
    int M, int N, int K)
{
  __shared__ bf16_t As[2][64 * 32];
  __shared__ bf16_t Bs[2][128 * 32];
  int tid = threadIdx.x;
  int wave = tid >> 6, lane = tid & 63;

  unsigned lid = blockIdx.y * gridDim.x + blockIdx.x;
  unsigned nwg = gridDim.x * gridDim.y;
  unsigned swzb = lid;
  if ((nwg & 7u) == 0u) swzb = (lid & 7u) * (nwg >> 3) + (lid >> 3);
  int row0 = (int)(swzb / gridDim.x) * 64;
  int col0 = (int)(swzb % gridDim.x) * 128;

  int wr = (wave >> 1) * 32, wc = (wave & 1) * 64;

  f32x4 acc[2][4] = {};

  // staging: per wave 16 rows, 16B chunk (lane&3); LDS chunk p of row r
  // holds global chunk p ^ ((r>>1)&3).
  int srow = (wave << 4) + (lane >> 2);
  int g8 = (((lane & 3) ^ ((srow >> 1) & 3)) << 3);
  const bf16_t* gA = A + (size_t)(row0 + srow) * lda + g8;
  const bf16_t* gB = Bt + (size_t)(col0 + srow) * ldb + g8;
  size_t b64 = (size_t)64 * ldb;

  int fr = lane & 15, fq = lane >> 4;

#define GSTAGE(buf, k0s)                                  \
  {                                                       \
    GLDS16(gA + (k0s), &As[buf][wave * 512]);             \
    GLDS16(gB + (k0s), &Bs[buf][wave * 512]);             \
    GLDS16(gB + b64 + (k0s), &Bs[buf][2048 + wave * 512]);\
  }

  GSTAGE(0, 0);
  int cur = 0;
  for (int k0 = 0; k0 < K; k0 += 32) {
    __syncthreads();  // buf[cur] loads complete; prior reads done
    if (k0 + 32 < K) GSTAGE(cur ^ 1, k0 + 32);
    bf16x8 af[2], bfr[4];
#pragma unroll
    for (int m = 0; m < 2; m++) {
      int R = wr + m * 16 + fr;
      af[m] = *(const bf16x8*)&As[cur][R * 32 + ((fq ^ ((R >> 1) & 3)) << 3)];
    }
#pragma unroll
    for (int n = 0; n < 4; n++) {
      int R = wc + n * 16 + fr;
      bfr[n] = *(const bf16x8*)&Bs[cur][R * 32 + ((fq ^ ((R >> 1) & 3)) << 3)];
    }
#pragma unroll
    for (int m = 0; m < 2; m++)
#pragma unroll
      for (int n = 0; n < 4; n++)
        acc[m][n] = __builtin_amdgcn_mfma_f32_16x16x32_bf16(af[m], bfr[n],
                                                            acc[m][n], 0, 0, 0);
    cur ^= 1;
  }
#undef GSTAGE

#pragma unroll
  for (int m = 0; m < 2; m++) {
#pragma unroll
    for (int n = 0; n < 4; n++) {
      int rowb = row0 + wr + m * 16 + fq * 4;
      int col = col0 + wc + n * 16 + fr;
      if (OUT_MODE == 2) {
        bf16x4 v4;
#pragma unroll
        for (int r = 0; r < 4; r++) v4[r] = (bf16_t)acc[m][n][r];
        bf16_t* dst = (bf16_t*)Cv +
            ((size_t)(rowb >> 10) * 1024 + col) * 1024 + (rowb & 1023);
        *(bf16x4*)dst = v4;
      } else {
#pragma unroll
        for (int r = 0; r < 4; r++) {
          int row = rowb + r;
          float v = acc[m][n][r];
          if (HAS_BIAS) v += bias[col];
          if (HAS_RESID) v += resid[(size_t)row * ldr + col];
          if (OUT_MODE == 1)
            ((bf16_t*)Cv)[(size_t)row * ldc + col] = (bf16_t)v;
          else
            ((float*)Cv)[(size_t)row * ldc + col] = v;
        }
      }
    }
  }
}

// ======================= MFMA flash attention (bf16, LDS-staged) ============
// Block: 128 q rows (4 waves x 32), KV tiles of 64 double-buffered in LDS.
__global__ __launch_bounds__(256) void flash_mfma_kernel(
    const bf16_t* __restrict__ Q, const bf16_t* __restrict__ K,
    const bf16_t* __restrict__ Vt, bf16_t* __restrict__ O)
{
  __shared__ bf16_t Ks[2][64 * 64];  // [64 kv][128B], XOR-swizzled
  __shared__ bf16_t Vs[2][64 * 64];  // [64 d][128B], XOR-swizzled
  __shared__ bf16_t Pl[4][32 * 64];  // per-wave P [32 q][128B], swizzled

  int tid = threadIdx.x;
  int wave = tid >> 6, lane = tid & 63;
  int fr = lane & 15, fq = lane >> 4;
  // XCD-chunked swizzle: co-locate the 8 q-tiles of each (h,b) on one XCD
  unsigned lid = blockIdx.x + blockIdx.y * 8 + blockIdx.z * 128;  // 512 wgs
  unsigned swz9 = (lid & 7u) * 64 + (lid >> 3);
  int qb = swz9 & 7, h = (swz9 >> 3) & 15, b = swz9 >> 7;
  int q0w = qb * 128 + wave * 32;
  size_t qkbase = ((size_t)b * 1024) * 1024 + (size_t)h * 64;
  size_t vtbase = ((size_t)b * 1024 + (size_t)h * 64) * 1024;

  // staging geometry (per wave, 8-row chunks, source col pre-swizzled)
  int srow8 = lane >> 3;                               // 0..7
  int scb = (((lane & 7) << 4) ^ (srow8 << 4)) >> 1;  // element offset

#define FSTAGE(buf, kt)                                                     \
  {                                                                         \
    int k0s = (kt) * 64;                                                    \
    _Pragma("unroll") for (int cc = 0; cc < 2; cc++) {                      \
      int rr0 = wave * 16 + cc * 8;                                         \
      int row = rr0 + srow8;                                                \
      GLDS16(&K[qkbase + (size_t)(k0s + row) * 1024 + scb],                 \
             &Ks[buf][rr0 * 64]);                                           \
      GLDS16(&Vt[vtbase + (size_t)row * 1024 + k0s + scb],                  \
             &Vs[buf][rr0 * 64]);                                           \
    }                                                                       \
  }

  // Q A-fragments: 2 row-groups x 2 k-halves
  bf16x8 qf[2][2];
#pragma unroll
  for (int g = 0; g < 2; g++)
#pragma unroll
    for (int kh = 0; kh < 2; kh++)
      qf[g][kh] = *(const bf16x8*)&Q[qkbase +
                                     (size_t)(q0w + g * 16 + fr) * 1024 +
                                     kh * 32 + fq * 8];

  f32x4 o_acc[2][4] = {};
  float mrow[2][4], lrow[2][4];
#pragma unroll
  for (int g = 0; g < 2; g++)
#pragma unroll
    for (int r = 0; r < 4; r++) { mrow[g][r] = -INFINITY; lrow[g][r] = 0.f; }

  char* P = (char*)&Pl[wave][0];
  int KT = 2 * qb + 2;

  FSTAGE(0, 0);

  for (int kt = 0; kt < KT; kt++) {
    __syncthreads();  // drains vmcnt: buf[kt&1] staged & visible
    if (kt + 1 < KT) FSTAGE((kt + 1) & 1, kt + 1);
    int k0 = kt * 64;
    if (k0 <= q0w + 31) {
      const char* Kb = (const char*)&Ks[kt & 1][0];
      const char* Vb = (const char*)&Vs[kt & 1][0];
      int swz = (fr & 7) << 4;
      // QK^T
      f32x4 s[2][4] = {};
#pragma unroll
      for (int n = 0; n < 4; n++) {
        int rowo = (n * 16 + fr) * 128;
        bf16x8 kf0 = *(const bf16x8*)(Kb + rowo + ((fq * 16) ^ swz));
        bf16x8 kf1 = *(const bf16x8*)(Kb + rowo + ((64 + fq * 16) ^ swz));
#pragma unroll
        for (int g = 0; g < 2; g++) {
          s[g][n] = __builtin_amdgcn_mfma_f32_16x16x32_bf16(qf[g][0], kf0,
                                                            s[g][n], 0, 0, 0);
          s[g][n] = __builtin_amdgcn_mfma_f32_16x16x32_bf16(qf[g][1], kf1,
                                                            s[g][n], 0, 0, 0);
        }
      }
      const float scale = 0.125f;
#pragma unroll
      for (int g = 0; g < 2; g++) {
        bool dm = (k0 + 63 > q0w + g * 16);
#pragma unroll
        for (int n = 0; n < 4; n++)
#pragma unroll
          for (int r = 0; r < 4; r++) {
            float v = s[g][n][r] * scale;
            if (dm && (k0 + n * 16 + fr > q0w + g * 16 + fq * 4 + r))
              v = -INFINITY;
            s[g][n][r] = v;
          }
      }
      // online softmax per row (q = g*16 + fq*4 + r), reduce across fr
      float corr[2][4];
#pragma unroll
      for (int g = 0; g < 2; g++)
#pragma unroll
        for (int r = 0; r < 4; r++) {
          float mx = fmaxf(fmaxf(s[g][0][r], s[g][1][r]),
                           fmaxf(s[g][2][r], s[g][3][r]));
#pragma unroll
          for (int msk = 1; msk < 16; msk <<= 1)
            mx = fmaxf(mx, __shfl_xor(mx, msk));
          float mnew = fmaxf(mrow[g][r], mx);
          corr[g][r] = __expf(mrow[g][r] - mnew);
          mrow[g][r] = mnew;
          float ps = 0.f;
#pragma unroll
          for (int n = 0; n < 4; n++) {
            float p = __expf(s[g][n][r] - mnew);
            s[g][n][r] = p;
            ps += p;
          }
#pragma unroll
          for (int msk = 1; msk < 16; msk <<= 1) ps += __shfl_xor(ps, msk);
          lrow[g][r] = lrow[g][r] * corr[g][r] + ps;
        }
      // P -> LDS (bf16, swizzled by q&7)
#pragma unroll
      for (int g = 0; g < 2; g++)
#pragma unroll
        for (int n = 0; n < 4; n++)
#pragma unroll
          for (int r = 0; r < 4; r++) {
            int q = g * 16 + fq * 4 + r;
            int cb = ((n * 16 + fr) * 2) ^ ((q & 7) << 4);
            *(bf16_t*)(P + q * 128 + cb) = (bf16_t)s[g][n][r];
          }
      // rescale o_acc by corr broadcast to q = fr lanes
      int rr = fr & 3;
      int srcl = (fr >> 2) << 4;
#pragma unroll
      for (int g = 0; g < 2; g++) {
        float c0 = __shfl(corr[g][0], srcl);
        float c1 = __shfl(corr[g][1], srcl);
        float c2 = __shfl(corr[g][2], srcl);
        float c3 = __shfl(corr[g][3], srcl);
        float cq = rr == 0 ? c0 : rr == 1 ? c1 : rr == 2 ? c2 : c3;
#pragma unroll
        for (int n = 0; n < 4; n++)
#pragma unroll
          for (int r = 0; r < 4; r++) o_acc[g][n][r] *= cq;
      }
      // PV: O^T += Vs_frag(A) @ P_frag(B)
#pragma unroll
      for (int c = 0; c < 2; c++) {
        bf16x8 pf[2];
#pragma unroll
        for (int g = 0; g < 2; g++)
          pf[g] = *(const bf16x8*)(P + (g * 16 + fr) * 128 +
                                   ((c * 64 + fq * 16) ^ swz));
#pragma unroll
        for (int n = 0; n < 4; n++) {
          bf16x8 vf = *(const bf16x8*)(Vb + (n * 16 + fr) * 128 +
                                       ((c * 64 + fq * 16) ^ swz));
#pragma unroll
          for (int g = 0; g < 2; g++)
            o_acc[g][n] = __builtin_amdgcn_mfma_f32_16x16x32_bf16(
                vf, pf[g], o_acc[g][n], 0, 0, 0);
        }
      }
    }
  }
  // epilogue
  int rr = fr & 3;
  int srcl = (fr >> 2) << 4;
#pragma unroll
  for (int g = 0; g < 2; g++) {
    float l0 = __shfl(lrow[g][0], srcl);
    float l1 = __shfl(lrow[g][1], srcl);
    float l2 = __shfl(lrow[g][2], srcl);
    float l3 = __shfl(lrow[g][3], srcl);
    float lq = rr == 0 ? l0 : rr == 1 ? l1 : rr == 2 ? l2 : l3;
    float linv = 1.f / lq;
    size_t orow = qkbase + (size_t)(q0w + g * 16 + fr) * 1024;
#pragma unroll
    for (int n = 0; n < 4; n++) {
      bf16x4 ov;
#pragma unroll
      for (int r = 0; r < 4; r++) ov[r] = (bf16_t)(o_acc[g][n][r] * linv);
      *(bf16x4*)&O[orow + n * 16 + fq * 4] = ov;
    }
  }
#undef FSTAGE
}

// ======================= launch =======================

extern "C" void kernel_launch(void* const* d_in, const int* in_sizes, int n_in,
                              void* d_out, int out_size, void* d_ws,
                              size_t ws_size, hipStream_t stream) {
  (void)in_sizes; (void)n_in; (void)out_size; (void)ws_size;
  const float* x          = (const float*)d_in[0];
  const float* qk_emb     = (const float*)d_in[1];
  const float* v_emb      = (const float*)d_in[2];
  const float* know_emb   = (const float*)d_in[3];
  const float* qk_f       = (const float*)d_in[4];
  const float* qk_r       = (const float*)d_in[5];
  const float* v_f        = (const float*)d_in[6];
  const float* v_r        = (const float*)d_in[7];
  const float* know_f     = (const float*)d_in[8];
  const float* know_r     = (const float*)d_in[9];
  const float* proj_attn_k = (const float*)d_in[10];
  const float* proj_attn_b = (const float*)d_in[11];
  const float* tau_attn_k  = (const float*)d_in[12];
  const float* tau_attn_b  = (const float*)d_in[13];
  const float* proj_know_k = (const float*)d_in[14];
  const float* proj_know_b = (const float*)d_in[15];
  const float* tau_know_k  = (const float*)d_in[16];
  const float* tau_know_b  = (const float*)d_in[17];
  const float* expand_O    = (const float*)d_in[18];
  const float* ln1_scale   = (const float*)d_in[19];
  const float* ln1_bias    = (const float*)d_in[20];
  const float* ln2_scale   = (const float*)d_in[21];
  const float* ln2_bias    = (const float*)d_in[22];

  float* out = (float*)d_out;  // [T,D] + aux scalar
  float* aux = out + (size_t)T * D;

  // ---- workspace arena ----
  float* ws = (float*)d_ws;
  float* n_f   = ws;                       // 4M floats
  float* tau3  = n_f + 4194304;            // 16K
  float* gq_b  = tau3 + 16384;             // 64K
  float* gk_b  = gq_b + 65536;
  float* gv_b  = gk_b + 65536;
  float* gkn_b = gv_b + 65536;             // 128K
  float* csum  = gkn_b + 131072;           // 4096 (colsum accumulator)
  float* hQ    = csum + 4096;              // 512K
  float* hK    = hQ + 524288;
  float* hV    = hK + 524288;
  float* qkvarena = hV + 524288;           // 12M floats (Q,K bf16 + Vt bf16)
  float* buf_big = qkvarena + 12582912;    // 16.78M floats (64MB)

  bf16_t* Qbb = (bf16_t*)qkvarena;                 // T*1024 bf16 (8MB)
  bf16_t* Kbb = Qbb + (size_t)T * 1024;            // 8MB
  bf16_t* Vtb = Kbb + (size_t)T * 1024;            // [4][1024][1024] 8MB

  bf16_t* nb   = (bf16_t*)(buf_big + 16777216);  // T*1024
  bf16_t* hab  = nb + 4194304;                   // T*384 (reused know: T*128)
  bf16_t* embB = hab + 1572864;                  // 524288 (qk|v ; know)
  bf16_t* B2t  = embB + 524288;                  // 4096*1024
  bf16_t* wt   = B2t + 4194304;                  // transposed weights arena
  bf16_t* pa_t  = wt;                   // 384*1024
  bf16_t* qkr_t = pa_t + 393216;        // 1024*2048
  bf16_t* vr_t  = qkr_t + 2097152;      // 1024*2048
  bf16_t* knr_t = vr_t + 2097152;       // 1024*4096
  bf16_t* eo_t  = knr_t + 4194304;      // 1024*1024
  bf16_t* pk_t  = eo_t + 1048576;       // 128*1024

  bf16_t* avb = (bf16_t*)buf_big;                   // up to T*4096 bf16
  bf16_t* allh_b = (bf16_t*)buf_big;                // feature all_h bf16
  bf16_t* attnb_b = (bf16_t*)(buf_big + 12582912);  // T*1024 bf16

  bf16_t* embQ = embB;
  bf16_t* embV = embB + 262144;

  dim3 blk(256);

  zero1_kernel<<<1, 1, 0, stream>>>(aux);

  // weight transposes to bf16 [N,K]
  transpose_to_bf16_kernel<<<dim3(12, 32, 1), blk, 0, stream>>>(
      proj_attn_k, pa_t, 1024, 384, 0, 0);
  transpose_to_bf16_kernel<<<dim3(32, 64, 1), blk, 0, stream>>>(
      qk_r, qkr_t, 2048, 1024, 0, 0);
  transpose_to_bf16_kernel<<<dim3(32, 64, 1), blk, 0, stream>>>(
      v_r, vr_t, 2048, 1024, 0, 0);
  transpose_to_bf16_kernel<<<dim3(32, 128, 1), blk, 0, stream>>>(
      know_r, knr_t, 4096, 1024, 0, 0);
  transpose_to_bf16_kernel<<<dim3(32, 32, 1), blk, 0, stream>>>(
      expand_O, eo_t, 1024, 1024, 0, 0);
  transpose_to_bf16_kernel<<<dim3(4, 32, 1), blk, 0, stream>>>(
      proj_know_k, pk_t, 1024, 128, 0, 0);

  // ---- attention circuit ----
  ln_kernel<<<T, blk, 0, stream>>>(x, ln1_scale, ln1_bias, n_f, nb);
  norm_rows_kernel<<<2048, 64, 0, stream>>>(qk_emb, embQ);
  norm_rows_kernel<<<2048, 64, 0, stream>>>(v_emb, embV);

  mfma_gemm_kernel<true, false, 1><<<dim3(3, 64), blk, 0, stream>>>(
      nb, 1024, pa_t, 1024, hab, 384, proj_attn_b, nullptr, 0, T, 384, 1024);
  tau_kernel<<<T, 64, 0, stream>>>(n_f, tau_attn_k, tau_attn_b, tau3, 3);

  // gate scores + gates + aux
  mfma_gemm_kernel<false, false, 0><<<dim3(16, 64), blk, 0, stream>>>(
      hab + 0, 384, embQ, 128, buf_big, 2048, nullptr, nullptr, 0, T, 2048, 128);
  gate_kernel<8><<<T, blk, 0, stream>>>(buf_big, tau3, 3, 0, gq_b, 2048, 16);
  hipMemsetAsync(csum, 0, 2048 * sizeof(float), stream);
  colsum_part_kernel<<<dim3(8, 32), blk, 0, stream>>>(buf_big, 2048, csum);
  colsum_fin_kernel<<<8, blk, 0, stream>>>(csum, 2048, 1.f / 2048.f, aux);

  mfma_gemm_kernel<false, false, 0><<<dim3(16, 64), blk, 0, stream>>>(
      hab + 128, 384, embQ, 128, buf_big, 2048, nullptr, nullptr, 0, T, 2048, 128);
  gate_kernel<8><<<T, blk, 0, stream>>>(buf_big, tau3, 3, 1, gk_b, 2048, 16);
  hipMemsetAsync(csum, 0, 2048 * sizeof(float), stream);
  colsum_part_kernel<<<dim3(8, 32), blk, 0, stream>>>(buf_big, 2048, csum);
  colsum_fin_kernel<<<8, blk, 0, stream>>>(csum, 2048, 1.f / 2048.f, aux);

  mfma_gemm_kernel<false, false, 0><<<dim3(16, 64), blk, 0, stream>>>(
      hab + 256, 384, embV, 128, buf_big, 2048, nullptr, nullptr, 0, T, 2048, 128);
  gate_kernel<8><<<T, blk, 0, stream>>>(buf_big, tau3, 3, 2, gv_b, 2048, 16);
  hipMemsetAsync(csum, 0, 2048 * sizeof(float), stream);
  colsum_part_kernel<<<dim3(8, 32), blk, 0, stream>>>(buf_big, 2048, csum);
  colsum_fin_kernel<<<8, blk, 0, stream>>>(csum, 2048, 1.f / 2048.f, aux);

  // features (qk basis) -> bf16 all_h
  transpose_to_bf16_kernel<<<dim3(4, 32, 16), blk, 0, stream>>>(
      qk_f, B2t, 1024, 128, 131072, 131072);
  mfma_gemm_kernel<false, false, 1><<<dim3(16, 64), blk, 0, stream>>>(
      nb, 1024, B2t, 1024, allh_b, 2048, nullptr, nullptr, 0, T, 2048, 1024);
  wsum2_kernel<<<T, 128, 0, stream>>>(allh_b, gq_b, gk_b, hQ, hK, 16);

  // features (v basis)
  transpose_to_bf16_kernel<<<dim3(4, 32, 16), blk, 0, stream>>>(
      v_f, B2t, 1024, 128, 131072, 131072);
  mfma_gemm_kernel<false, false, 1><<<dim3(16, 64), blk, 0, stream>>>(
      nb, 1024, B2t, 1024, allh_b, 2048, nullptr, nullptr, 0, T, 2048, 1024);
  wsum2_kernel<<<T, 128, 0, stream>>>(allh_b, gv_b, nullptr, hV, nullptr, 16);

  // restores -> Q,K bf16 and Vt transposed bf16
  avirt_kernel<<<T, blk, 0, stream>>>(hQ, gq_b, 16, avb, 2048);
  mfma_gemm_kernel<false, false, 1><<<dim3(8, 64), blk, 0, stream>>>(
      avb, 2048, qkr_t, 2048, Qbb, 1024, nullptr, nullptr, 0, T, 1024, 2048);
  avirt_kernel<<<T, blk, 0, stream>>>(hK, gk_b, 16, avb, 2048);
  mfma_gemm_kernel<false, false, 1><<<dim3(8, 64), blk, 0, stream>>>(
      avb, 2048, qkr_t, 2048, Kbb, 1024, nullptr, nullptr, 0, T, 1024, 2048);
  avirt_kernel<<<T, blk, 0, stream>>>(hV, gv_b, 16, avb, 2048);
  mfma_gemm_kernel<false, false, 2><<<dim3(8, 64), blk, 0, stream>>>(
      avb, 2048, vr_t, 2048, Vtb, 1024, nullptr, nullptr, 0, T, 1024, 2048);

  // MFMA flash attention + output proj + residual
  flash_mfma_kernel<<<dim3(8, 16, 4), blk, 0, stream>>>(Qbb, Kbb, Vtb,
                                                        attnb_b);
  mfma_gemm_kernel<false, true, 0><<<dim3(8, 64), blk, 0, stream>>>(
      attnb_b, 1024, eo_t, 1024, out, 1024, nullptr, x, 1024, T, 1024, 1024);

  // ---- knowledge circuit ----
  ln_kernel<<<T, blk, 0, stream>>>(out, ln2_scale, ln2_bias, n_f, nb);
  norm_rows_kernel<<<4096, 64, 0, stream>>>(know_emb, embB);
  mfma_gemm_kernel<true, false, 1><<<dim3(1, 64), blk, 0, stream>>>(
      nb, 1024, pk_t, 1024, hab, 128, proj_know_b, nullptr, 0, T, 128, 1024);
  tau_kernel<<<T, 64, 0, stream>>>(n_f, tau_know_k, tau_know_b, tau3, 1);

  mfma_gemm_kernel<false, false, 0><<<dim3(32, 64), blk, 0, stream>>>(
      hab, 128, embB, 128, buf_big, 4096, nullptr, nullptr, 0, T, 4096, 128);
  gate_kernel<16><<<T, blk, 0, stream>>>(buf_big, tau3, 1, 0, gkn_b, 4096, 32);
  hipMemsetAsync(csum, 0, 4096 * sizeof(float), stream);
  colsum_part_kernel<<<dim3(16, 32), blk, 0, stream>>>(buf_big, 4096, csum);
  colsum_fin_kernel<<<16, blk, 0, stream>>>(csum, 4096, 1.f / 4096.f, aux);

  transpose_to_bf16_kernel<<<dim3(4, 32, 32), blk, 0, stream>>>(
      know_f, B2t, 1024, 128, 131072, 131072);
  mfma_gemm_kernel<false, false, 1><<<dim3(32, 64), blk, 0, stream>>>(
      nb, 1024, B2t, 1024, allh_b, 4096, nullptr, nullptr, 0, T, 4096, 1024);
  wsum2_kernel<<<T, 128, 0, stream>>>(allh_b, gkn_b, nullptr, hQ, nullptr, 32);

  avirt_kernel<<<T, blk, 0, stream>>>(hQ, gkn_b, 32, avb, 4096);
  mfma_gemm_kernel<false, true, 0><<<dim3(8, 64), blk, 0, stream>>>(
      avb, 4096, knr_t, 4096, out, 1024, nullptr, out, 1024, T, 1024, 4096);
}

// Round 9
// 704.703 us; speedup vs baseline: 5.5611x; 1.0164x over previous
//
#include <hip/hip_runtime.h>
#include <math.h>

static constexpr int T = 4096;   // B*S
static constexpr int D = 1024;

typedef __bf16 bf16_t;
typedef bf16_t bf16x8 __attribute__((ext_vector_type(8)));
typedef bf16_t bf16x4 __attribute__((ext_vector_type(4)));
typedef float f32x4 __attribute__((ext_vector_type(4)));

#define GLDS16(g, l)                                                        \
  __builtin_amdgcn_global_load_lds(                                         \
      (const __attribute__((address_space(1))) void*)(g),                   \
      (__attribute__((address_space(3))) void*)(l), 16, 0, 0)

// ======================= small kernels =======================

__global__ void zero1_kernel(float* p) { *p = 0.f; }

__global__ __launch_bounds__(256) void ln_kernel(
    const float* __restrict__ x, const float* __restrict__ scale,
    const float* __restrict__ bias, float* __restrict__ out_f,
    bf16_t* __restrict__ out_b)
{
  int t = blockIdx.x;
  const float* xr = x + (size_t)t * D;
  float v[4];
  float s1 = 0.f, s2 = 0.f;
#pragma unroll
  for (int i = 0; i < 4; i++) {
    v[i] = xr[threadIdx.x + i * 256];
    s1 += v[i];
    s2 += v[i] * v[i];
  }
#pragma unroll
  for (int o = 1; o < 64; o <<= 1) {
    s1 += __shfl_xor(s1, o);
    s2 += __shfl_xor(s2, o);
  }
  __shared__ float r1[4], r2[4];
  int wid = threadIdx.x >> 6;
  if ((threadIdx.x & 63) == 0) { r1[wid] = s1; r2[wid] = s2; }
  __syncthreads();
  s1 = r1[0] + r1[1] + r1[2] + r1[3];
  s2 = r2[0] + r2[1] + r2[2] + r2[3];
  float mean = s1 * (1.f / D);
  float var = s2 * (1.f / D) - mean * mean;
  float rstd = rsqrtf(var + 1e-6f);
  float* orow = out_f + (size_t)t * D;
  bf16_t* brow = out_b + (size_t)t * D;
#pragma unroll
  for (int i = 0; i < 4; i++) {
    int d = threadIdx.x + i * 256;
    float o = (v[i] - mean) * rstd * scale[d] + bias[d];
    orow[d] = o;
    brow[d] = (bf16_t)o;
  }
}

// rows of length 128, one wave per row; bf16 normalized output
__global__ __launch_bounds__(64) void norm_rows_kernel(
    const float* __restrict__ e, bf16_t* __restrict__ o)
{
  int r = blockIdx.x;
  const float* row = e + (size_t)r * 128;
  float a = row[threadIdx.x], b = row[threadIdx.x + 64];
  float ss = a * a + b * b;
#pragma unroll
  for (int m = 1; m < 64; m <<= 1) ss += __shfl_xor(ss, m);
  float inv = 1.f / (sqrtf(ss) + 1e-8f);
  bf16_t* orow = o + (size_t)r * 128;
  orow[threadIdx.x] = (bf16_t)(a * inv);
  orow[threadIdx.x + 64] = (bf16_t)(b * inv);
}

// tau = n @ W + b,  W: [D, J], J in {1,3}; one wave per token (fp32)
__global__ __launch_bounds__(64) void tau_kernel(
    const float* __restrict__ n, const float* __restrict__ W,
    const float* __restrict__ b, float* __restrict__ out, int J)
{
  int t = blockIdx.x;
  const float* nr = n + (size_t)t * D;
  for (int j = 0; j < J; j++) {
    float p = 0.f;
#pragma unroll 4
    for (int i = 0; i < 16; i++) {
      int d = threadIdx.x + i * 64;
      p += nr[d] * W[d * J + j];
    }
#pragma unroll
    for (int m = 1; m < 64; m <<= 1) p += __shfl_xor(p, m);
    if (threadIdx.x == 0) out[t * J + j] = p + b[j];
  }
}

// threshold gate + group gate, in place.
template <int PER>
__global__ __launch_bounds__(256) void gate_kernel(
    float* __restrict__ g, const float* __restrict__ tau, int tauStride,
    int tauOff, float* __restrict__ gb, int N, int G)
{
  int t = blockIdx.x;
  float tv = tau[t * tauStride + tauOff];
  float* row = g + (size_t)t * N;
  float r[PER];
  int base = threadIdx.x * PER;
  float psum = 0.f;
#pragma unroll
  for (int i = 0; i < PER; i++) {
    float s = row[base + i] - tv;
    s = fmaxf(s, 0.f);
    r[i] = s;
    psum += s;
  }
  __shared__ float red[4];
  __shared__ float grp[32];
  if (threadIdx.x < 32) grp[threadIdx.x] = 0.f;
  float w = psum;
#pragma unroll
  for (int m = 1; m < 64; m <<= 1) w += __shfl_xor(w, m);
  int wid = threadIdx.x >> 6;
  if ((threadIdx.x & 63) == 0) red[wid] = w;
  __syncthreads();
  float Stot = red[0] + red[1] + red[2] + red[3];
  atomicAdd(&grp[base >> 7], psum);
  __syncthreads();
  float inv = 1.f / (Stot + 1e-8f);
#pragma unroll
  for (int i = 0; i < PER; i++) row[base + i] = r[i] * inv;
  if (threadIdx.x < G) {
    float Gj = grp[threadIdx.x] * inv;
    float gsum = Stot * inv;
    gb[(size_t)t * G + threadIdx.x] = Gj / (gsum + 1e-8f);
  }
}

// stage 1: partial column sums of g [T,N] over 128-row chunks
__global__ __launch_bounds__(256) void colsum_part_kernel(
    const float* __restrict__ g, int N, float* __restrict__ colsum)
{
  int c = blockIdx.x * 256 + threadIdx.x;
  int r0 = blockIdx.y * 128;
  const float* p = g + (size_t)r0 * N + c;
  float s = 0.f;
#pragma unroll 8
  for (int t = 0; t < 128; t++) s += p[(size_t)t * N];
  atomicAdd(&colsum[c], s);
}

// stage 2: aux += sum_c (colsum[c]/T - tinv)^2 * N
__global__ __launch_bounds__(256) void colsum_fin_kernel(
    const float* __restrict__ colsum, int N, float tinv,
    float* __restrict__ aux)
{
  int c = blockIdx.x * 256 + threadIdx.x;
  float mdev = colsum[c] * (1.f / T) - tinv;
  float p = mdev * mdev * (float)N;
#pragma unroll
  for (int m = 1; m < 64; m <<= 1) p += __shfl_xor(p, m);
  __shared__ float red[4];
  if ((threadIdx.x & 63) == 0) red[threadIdx.x >> 6] = p;
  __syncthreads();
  if (threadIdx.x == 0) atomicAdd(aux, red[0] + red[1] + red[2] + red[3]);
}

// h1[t,r] = sum_n gb1[t,n]*all_h[t, n*128+r] (all_h bf16); optional 2nd out
__global__ __launch_bounds__(128) void wsum2_kernel(
    const bf16_t* __restrict__ all_h, const float* __restrict__ gb1,
    const float* __restrict__ gb2, float* __restrict__ h1,
    float* __restrict__ h2, int NB)
{
  int t = blockIdx.x;
  int r = threadIdx.x;
  const bf16_t* row = all_h + (size_t)t * NB * 128;
  float a1 = 0.f, a2 = 0.f;
  for (int n = 0; n < NB; n++) {
    float v = (float)row[n * 128 + r];
    a1 += gb1[(size_t)t * NB + n] * v;
    if (gb2) a2 += gb2[(size_t)t * NB + n] * v;
  }
  h1[(size_t)t * 128 + r] = a1;
  if (h2) h2[(size_t)t * 128 + r] = a2;
}

// dst[c][r] = (bf16)src[r][c]; src [R,C] fp32, dst [C,R] bf16; batched
__global__ __launch_bounds__(256) void transpose_to_bf16_kernel(
    const float* __restrict__ src, bf16_t* __restrict__ dst,
    int R, int C, size_t sbs, size_t dbs)
{
  __shared__ float tile[32][33];
  int b = blockIdx.z;
  int c0 = blockIdx.x * 32, r0 = blockIdx.y * 32;
  int tx = threadIdx.x & 31, ty = threadIdx.x >> 5;  // 8 rows/pass
  const float* s = src + (size_t)b * sbs;
  bf16_t* d = dst + (size_t)b * dbs;
#pragma unroll
  for (int i = 0; i < 4; i++)
    tile[ty + i * 8][tx] = s[(size_t)(r0 + ty + i * 8) * C + c0 + tx];
  __syncthreads();
#pragma unroll
  for (int i = 0; i < 4; i++)
    d[(size_t)(c0 + ty + i * 8) * R + r0 + tx] = (bf16_t)tile[tx][ty + i * 8];
}

// A_virt[t,k] = (bf16)(gb[t,k>>7]*h[t,k&127]), row-major [T,K]
__global__ __launch_bounds__(256) void avirt_kernel(
    const float* __restrict__ h, const float* __restrict__ gb, int NB,
    bf16_t* __restrict__ A, int K)
{
  int t = blockIdx.x;
  const float* hr = h + (size_t)t * 128;
  const float* gr = gb + (size_t)t * NB;
  bf16_t* ar = A + (size_t)t * K;
  int noct = K >> 3;
  for (int o = threadIdx.x; o < noct; o += 256) {
    int k = o * 8;
    float g = gr[k >> 7];
    bf16x8 v;
#pragma unroll
    for (int i = 0; i < 8; i++) v[i] = (bf16_t)(hr[(k & 127) + i] * g);
    *(bf16x8*)(ar + k) = v;
  }
}

// ============== MFMA GEMM: C[M,N] = A[M,K]bf16 @ Bt[N,K]bf16^T ==============
// 64x128 tile, BK=32, 4 waves (2x2: 32 rows x 64 cols each), 2x4 fragments.
// Double-buffered LDS, stage-ahead prefetch, chunk-XOR swizzle, XCD-chunked
// block swizzle. Grid: x = N/128, y = M/64 (2-4 blocks/CU for TLP overlap).
// OUT_MODE: 0 = f32, 1 = bf16, 2 = bf16 transposed V store (Vt[b][col][s])
template <bool HAS_BIAS, bool HAS_RESID, int OUT_MODE>
__global__ __launch_bounds__(256) void mfma_gemm_kernel(
    const bf16_t* __restrict__ A, int lda,
    const bf16_t* __restrict__ Bt, int ldb,
    void* __restrict__ Cv, int ldc,
    const float* __restrict__ bias,
    const float* __restrict__ resid, int ldr,
    int M, int N, int K)
{
  __shared__ bf16_t As[2][64 * 32];
  __shared__ bf16_t Bs[2][128 * 32];
  int tid = threadIdx.x;
  int wave = tid >> 6, lane = tid & 63;

  unsigned lid = blockIdx.y * gridDim.x + blockIdx.x;
  unsigned nwg = gridDim.x * gridDim.y;
  unsigned swzb = lid;
  if ((nwg & 7u) == 0u) swzb = (lid & 7u) * (nwg >> 3) + (lid >> 3);
  int row0 = (int)(swzb / gridDim.x) * 64;
  int col0 = (int)(swzb % gridDim.x) * 128;

  int wr = (wave >> 1) * 32, wc = (wave & 1) * 64;

  f32x4 acc[2][4] = {};

  // staging: per wave 16 rows, 16B chunk (lane&3); LDS chunk p of row r
  // holds global chunk p ^ ((r>>1)&3).
  int srow = (wave << 4) + (lane >> 2);
  int g8 = (((lane & 3) ^ ((srow >> 1) & 3)) << 3);
  const bf16_t* gA = A + (size_t)(row0 + srow) * lda + g8;
  const bf16_t* gB = Bt + (size_t)(col0 + srow) * ldb + g8;
  size_t b64 = (size_t)64 * ldb;

  int fr = lane & 15, fq = lane >> 4;

#define GSTAGE(buf, k0s)                                  \
  {                                                       \
    GLDS16(gA + (k0s), &As[buf][wave * 512]);             \
    GLDS16(gB + (k0s), &Bs[buf][wave * 512]);             \
    GLDS16(gB + b64 + (k0s), &Bs[buf][2048 + wave * 512]);\
  }

  GSTAGE(0, 0);
  int cur = 0;
  for (int k0 = 0; k0 < K; k0 += 32) {
    __syncthreads();  // buf[cur] loads complete; prior reads done
    if (k0 + 32 < K) GSTAGE(cur ^ 1, k0 + 32);
    bf16x8 af[2], bfr[4];
#pragma unroll
    for (int m = 0; m < 2; m++) {
      int R = wr + m * 16 + fr;
      af[m] = *(const bf16x8*)&As[cur][R * 32 + ((fq ^ ((R >> 1) & 3)) << 3)];
    }
#pragma unroll
    for (int n = 0; n < 4; n++) {
      int R = wc + n * 16 + fr;
      bfr[n] = *(const bf16x8*)&Bs[cur][R * 32 + ((fq ^ ((R >> 1) & 3)) << 3)];
    }
#pragma unroll
    for (int m = 0; m < 2; m++)
#pragma unroll
      for (int n = 0; n < 4; n++)
        acc[m][n] = __builtin_amdgcn_mfma_f32_16x16x32_bf16(af[m], bfr[n],
                                                            acc[m][n], 0, 0, 0);
    cur ^= 1;
  }
#undef GSTAGE

#pragma unroll
  for (int m = 0; m < 2; m++) {
#pragma unroll
    for (int n = 0; n < 4; n++) {
      int rowb = row0 + wr + m * 16 + fq * 4;
      int col = col0 + wc + n * 16 + fr;
      if (OUT_MODE == 2) {
        bf16x4 v4;
#pragma unroll
        for (int r = 0; r < 4; r++) v4[r] = (bf16_t)acc[m][n][r];
        bf16_t* dst = (bf16_t*)Cv +
            ((size_t)(rowb >> 10) * 1024 + col) * 1024 + (rowb & 1023);
        *(bf16x4*)dst = v4;
      } else {
#pragma unroll
        for (int r = 0; r < 4; r++) {
          int row = rowb + r;
          float v = acc[m][n][r];
          if (HAS_BIAS) v += bias[col];
          if (HAS_RESID) v += resid[(size_t)row * ldr + col];
          if (OUT_MODE == 1)
            ((bf16_t*)Cv)[(size_t)row * ldc + col] = (bf16_t)v;
          else
            ((float*)Cv)[(size_t)row * ldc + col] = v;
        }
      }
    }
  }
}

// ======================= MFMA flash attention (bf16, LDS-staged) ============
// 8 waves (512 thr). Causal-pair balancing: waves 0-3 own q-tile s (128 rows),
// waves 4-7 own q-tile 7-s. Per-SIMD work = (2s+2)+(16-2s) = 18 tile-units,
// identical for every block and SIMD. One block per CU (grid 4x16x4).
__global__ __launch_bounds__(512) void flash_mfma_kernel(
    const bf16_t* __restrict__ Q, const bf16_t* __restrict__ K,
    const bf16_t* __restrict__ Vt, bf16_t* __restrict__ O)
{
  __shared__ bf16_t Ks[2][64 * 64];  // [64 kv][128B], XOR-swizzled
  __shared__ bf16_t Vs[2][64 * 64];  // [64 d][128B], XOR-swizzled
  __shared__ bf16_t Pl[8][32 * 64];  // per-wave P [32 q][128B], swizzled

  int tid = threadIdx.x;
  int wave = tid >> 6, lane = tid & 63;
  int fr = lane & 15, fq = lane >> 4;
  // XCD-chunked swizzle: 8 (h,b) per XCD, all 4 pair-slots co-located
  unsigned lid = blockIdx.x + blockIdx.y * 4 + blockIdx.z * 64;  // 256 wgs
  unsigned swz8 = (lid & 7u) * 32 + (lid >> 3);
  int s_slot = swz8 & 3;
  unsigned hb = swz8 >> 2;
  int h = hb & 15, b = hb >> 4;
  int half = wave >> 2, w4 = wave & 3;
  int qb = half ? (7 - s_slot) : s_slot;
  int q0w = qb * 128 + w4 * 32;
  int KT = 16 - 2 * s_slot;  // kv tiles staged (covers the high tile)
  size_t qkbase = ((size_t)b * 1024) * 1024 + (size_t)h * 64;
  size_t vtbase = ((size_t)b * 1024 + (size_t)h * 64) * 1024;

  // staging geometry: each of 8 waves stages 8 rows of K and of V
  int srow8 = lane >> 3;                               // 0..7
  int scb = (((lane & 7) << 4) ^ (srow8 << 4)) >> 1;  // element offset

#define FSTAGE(buf, kt)                                                     \
  {                                                                         \
    int k0s = (kt) * 64;                                                    \
    int row = wave * 8 + srow8;                                             \
    GLDS16(&K[qkbase + (size_t)(k0s + row) * 1024 + scb],                   \
           &Ks[buf][wave * 512]);                                           \
    GLDS16(&Vt[vtbase + (size_t)row * 1024 + k0s + scb],                    \
           &Vs[buf][wave * 512]);                                           \
  }

  // Q A-fragments: 2 row-groups x 2 k-halves
  bf16x8 qf[2][2];
#pragma unroll
  for (int g = 0; g < 2; g++)
#pragma unroll
    for (int kh = 0; kh < 2; kh++)
      qf[g][kh] = *(const bf16x8*)&Q[qkbase +
                                     (size_t)(q0w + g * 16 + fr) * 1024 +
                                     kh * 32 + fq * 8];

  f32x4 o_acc[2][4] = {};
  float mrow[2][4], lrow[2][4];
#pragma unroll
  for (int g = 0; g < 2; g++)
#pragma unroll
    for (int r = 0; r < 4; r++) { mrow[g][r] = -INFINITY; lrow[g][r] = 0.f; }

  char* P = (char*)&Pl[wave][0];

  FSTAGE(0, 0);

  for (int kt = 0; kt < KT; kt++) {
    __syncthreads();  // drains vmcnt: buf[kt&1] staged & visible
    if (kt + 1 < KT) FSTAGE((kt + 1) & 1, kt + 1);
    int k0 = kt * 64;
    if (k0 <= q0w + 31) {
      const char* Kb = (const char*)&Ks[kt & 1][0];
      const char* Vb = (const char*)&Vs[kt & 1][0];
      int swz = (fr & 7) << 4;
      // QK^T
      f32x4 s[2][4] = {};
#pragma unroll
      for (int n = 0; n < 4; n++) {
        int rowo = (n * 16 + fr) * 128;
        bf16x8 kf0 = *(const bf16x8*)(Kb + rowo + ((fq * 16) ^ swz));
        bf16x8 kf1 = *(const bf16x8*)(Kb + rowo + ((64 + fq * 16) ^ swz));
#pragma unroll
        for (int g = 0; g < 2; g++) {
          s[g][n] = __builtin_amdgcn_mfma_f32_16x16x32_bf16(qf[g][0], kf0,
                                                            s[g][n], 0, 0, 0);
          s[g][n] = __builtin_amdgcn_mfma_f32_16x16x32_bf16(qf[g][1], kf1,
                                                            s[g][n], 0, 0, 0);
        }
      }
      const float scale = 0.125f;
#pragma unroll
      for (int g = 0; g < 2; g++) {
        bool dm = (k0 + 63 > q0w + g * 16);
#pragma unroll
        for (int n = 0; n < 4; n++)
#pragma unroll
          for (int r = 0; r < 4; r++) {
            float v = s[g][n][r] * scale;
            if (dm && (k0 + n * 16 + fr > q0w + g * 16 + fq * 4 + r))
              v = -INFINITY;
            s[g][n][r] = v;
          }
      }
      // online softmax per row (q = g*16 + fq*4 + r), reduce across fr
      float corr[2][4];
#pragma unroll
      for (int g = 0; g < 2; g++)
#pragma unroll
        for (int r = 0; r < 4; r++) {
          float mx = fmaxf(fmaxf(s[g][0][r], s[g][1][r]),
                           fmaxf(s[g][2][r], s[g][3][r]));
#pragma unroll
          for (int msk = 1; msk < 16; msk <<= 1)
            mx = fmaxf(mx, __shfl_xor(mx, msk));
          float mnew = fmaxf(mrow[g][r], mx);
          corr[g][r] = __expf(mrow[g][r] - mnew);
          mrow[g][r] = mnew;
          float ps = 0.f;
#pragma unroll
          for (int n = 0; n < 4; n++) {
            float p = __expf(s[g][n][r] - mnew);
            s[g][n][r] = p;
            ps += p;
          }
#pragma unroll
          for (int msk = 1; msk < 16; msk <<= 1) ps += __shfl_xor(ps, msk);
          lrow[g][r] = lrow[g][r] * corr[g][r] + ps;
        }
      // P -> LDS (bf16, swizzled by q&7)
#pragma unroll
      for (int g = 0; g < 2; g++)
#pragma unroll
        for (int n = 0; n < 4; n++)
#pragma unroll
          for (int r = 0; r < 4; r++) {
            int q = g * 16 + fq * 4 + r;
            int cb = ((n * 16 + fr) * 2) ^ ((q & 7) << 4);
            *(bf16_t*)(P + q * 128 + cb) = (bf16_t)s[g][n][r];
          }
      // rescale o_acc by corr broadcast to q = fr lanes
      int rr = fr & 3;
      int srcl = (fr >> 2) << 4;
#pragma unroll
      for (int g = 0; g < 2; g++) {
        float c0 = __shfl(corr[g][0], srcl);
        float c1 = __shfl(corr[g][1], srcl);
        float c2 = __shfl(corr[g][2], srcl);
        float c3 = __shfl(corr[g][3], srcl);
        float cq = rr == 0 ? c0 : rr == 1 ? c1 : rr == 2 ? c2 : c3;
#pragma unroll
        for (int n = 0; n < 4; n++)
#pragma unroll
          for (int r = 0; r < 4; r++) o_acc[g][n][r] *= cq;
      }
      // PV: O^T += Vs_frag(A) @ P_frag(B)
#pragma unroll
      for (int c = 0; c < 2; c++) {
        bf16x8 pf[2];
#pragma unroll
        for (int g = 0; g < 2; g++)
          pf[g] = *(const bf16x8*)(P + (g * 16 + fr) * 128 +
                                   ((c * 64 + fq * 16) ^ swz));
#pragma unroll
        for (int n = 0; n < 4; n++) {
          bf16x8 vf = *(const bf16x8*)(Vb + (n * 16 + fr) * 128 +
                                       ((c * 64 + fq * 16) ^ swz));
#pragma unroll
          for (int g = 0; g < 2; g++)
            o_acc[g][n] = __builtin_amdgcn_mfma_f32_16x16x32_bf16(
                vf, pf[g], o_acc[g][n], 0, 0, 0);
        }
      }
    }
  }
  // epilogue
  int rr = fr & 3;
  int srcl = (fr >> 2) << 4;
#pragma unroll
  for (int g = 0; g < 2; g++) {
    float l0 = __shfl(lrow[g][0], srcl);
    float l1 = __shfl(lrow[g][1], srcl);
    float l2 = __shfl(lrow[g][2], srcl);
    float l3 = __shfl(lrow[g][3], srcl);
    float lq = rr == 0 ? l0 : rr == 1 ? l1 : rr == 2 ? l2 : l3;
    float linv = 1.f / lq;
    size_t orow = qkbase + (size_t)(q0w + g * 16 + fr) * 1024;
#pragma unroll
    for (int n = 0; n < 4; n++) {
      bf16x4 ov;
#pragma unroll
      for (int r = 0; r < 4; r++) ov[r] = (bf16_t)(o_acc[g][n][r] * linv);
      *(bf16x4*)&O[orow + n * 16 + fq * 4] = ov;
    }
  }
#undef FSTAGE
}

// ======================= launch =======================

extern "C" void kernel_launch(void* const* d_in, const int* in_sizes, int n_in,
                              void* d_out, int out_size, void* d_ws,
                              size_t ws_size, hipStream_t stream) {
  (void)in_sizes; (void)n_in; (void)out_size; (void)ws_size;
  const float* x          = (const float*)d_in[0];
  const float* qk_emb     = (const float*)d_in[1];
  const float* v_emb      = (const float*)d_in[2];
  const float* know_emb   = (const float*)d_in[3];
  const float* qk_f       = (const float*)d_in[4];
  const float* qk_r       = (const float*)d_in[5];
  const float* v_f        = (const float*)d_in[6];
  const float* v_r        = (const float*)d_in[7];
  const float* know_f     = (const float*)d_in[8];
  const float* know_r     = (const float*)d_in[9];
  const float* proj_attn_k = (const float*)d_in[10];
  const float* proj_attn_b = (const float*)d_in[11];
  const float* tau_attn_k  = (const float*)d_in[12];
  const float* tau_attn_b  = (const float*)d_in[13];
  const float* proj_know_k = (const float*)d_in[14];
  const float* proj_know_b = (const float*)d_in[15];
  const float* tau_know_k  = (const float*)d_in[16];
  const float* tau_know_b  = (const float*)d_in[17];
  const float* expand_O    = (const float*)d_in[18];
  const float* ln1_scale   = (const float*)d_in[19];
  const float* ln1_bias    = (const float*)d_in[20];
  const float* ln2_scale   = (const float*)d_in[21];
  const float* ln2_bias    = (const float*)d_in[22];

  float* out = (float*)d_out;  // [T,D] + aux scalar
  float* aux = out + (size_t)T * D;

  // ---- workspace arena ----
  float* ws = (float*)d_ws;
  float* n_f   = ws;                       // 4M floats
  float* tau3  = n_f + 4194304;            // 16K
  float* gq_b  = tau3 + 16384;             // 64K
  float* gk_b  = gq_b + 65536;
  float* gv_b  = gk_b + 65536;
  float* gkn_b = gv_b + 65536;             // 128K
  float* csum  = gkn_b + 131072;           // 4096 (colsum accumulator)
  float* hQ    = csum + 4096;              // 512K
  float* hK    = hQ + 524288;
  float* hV    = hK + 524288;
  float* qkvarena = hV + 524288;           // 12M floats (Q,K bf16 + Vt bf16)
  float* buf_big = qkvarena + 12582912;    // 16.78M floats (64MB)

  bf16_t* Qbb = (bf16_t*)qkvarena;                 // T*1024 bf16 (8MB)
  bf16_t* Kbb = Qbb + (size_t)T * 1024;            // 8MB
  bf16_t* Vtb = Kbb + (size_t)T * 1024;            // [4][1024][1024] 8MB

  bf16_t* nb   = (bf16_t*)(buf_big + 16777216);  // T*1024
  bf16_t* hab  = nb + 4194304;                   // T*384 (reused know: T*128)
  bf16_t* embB = hab + 1572864;                  // 524288 (qk|v ; know)
  bf16_t* B2t  = embB + 524288;                  // 4096*1024
  bf16_t* wt   = B2t + 4194304;                  // transposed weights arena
  bf16_t* pa_t  = wt;                   // 384*1024
  bf16_t* qkr_t = pa_t + 393216;        // 1024*2048
  bf16_t* vr_t  = qkr_t + 2097152;      // 1024*2048
  bf16_t* knr_t = vr_t + 2097152;       // 1024*4096
  bf16_t* eo_t  = knr_t + 4194304;      // 1024*1024
  bf16_t* pk_t  = eo_t + 1048576;       // 128*1024

  bf16_t* avb = (bf16_t*)buf_big;                   // up to T*4096 bf16
  bf16_t* allh_b = (bf16_t*)buf_big;                // feature all_h bf16
  bf16_t* attnb_b = (bf16_t*)(buf_big + 12582912);  // T*1024 bf16

  bf16_t* embQ = embB;
  bf16_t* embV = embB + 262144;

  dim3 blk(256);

  zero1_kernel<<<1, 1, 0, stream>>>(aux);

  // weight transposes to bf16 [N,K]
  transpose_to_bf16_kernel<<<dim3(12, 32, 1), blk, 0, stream>>>(
      proj_attn_k, pa_t, 1024, 384, 0, 0);
  transpose_to_bf16_kernel<<<dim3(32, 64, 1), blk, 0, stream>>>(
      qk_r, qkr_t, 2048, 1024, 0, 0);
  transpose_to_bf16_kernel<<<dim3(32, 64, 1), blk, 0, stream>>>(
      v_r, vr_t, 2048, 1024, 0, 0);
  transpose_to_bf16_kernel<<<dim3(32, 128, 1), blk, 0, stream>>>(
      know_r, knr_t, 4096, 1024, 0, 0);
  transpose_to_bf16_kernel<<<dim3(32, 32, 1), blk, 0, stream>>>(
      expand_O, eo_t, 1024, 1024, 0, 0);
  transpose_to_bf16_kernel<<<dim3(4, 32, 1), blk, 0, stream>>>(
      proj_know_k, pk_t, 1024, 128, 0, 0);

  // ---- attention circuit ----
  ln_kernel<<<T, blk, 0, stream>>>(x, ln1_scale, ln1_bias, n_f, nb);
  norm_rows_kernel<<<2048, 64, 0, stream>>>(qk_emb, embQ);
  norm_rows_kernel<<<2048, 64, 0, stream>>>(v_emb, embV);

  mfma_gemm_kernel<true, false, 1><<<dim3(3, 64), blk, 0, stream>>>(
      nb, 1024, pa_t, 1024, hab, 384, proj_attn_b, nullptr, 0, T, 384, 1024);
  tau_kernel<<<T, 64, 0, stream>>>(n_f, tau_attn_k, tau_attn_b, tau3, 3);

  // gate scores + gates + aux
  mfma_gemm_kernel<false, false, 0><<<dim3(16, 64), blk, 0, stream>>>(
      hab + 0, 384, embQ, 128, buf_big, 2048, nullptr, nullptr, 0, T, 2048, 128);
  gate_kernel<8><<<T, blk, 0, stream>>>(buf_big, tau3, 3, 0, gq_b, 2048, 16);
  hipMemsetAsync(csum, 0, 2048 * sizeof(float), stream);
  colsum_part_kernel<<<dim3(8, 32), blk, 0, stream>>>(buf_big, 2048, csum);
  colsum_fin_kernel<<<8, blk, 0, stream>>>(csum, 2048, 1.f / 2048.f, aux);

  mfma_gemm_kernel<false, false, 0><<<dim3(16, 64), blk, 0, stream>>>(
      hab + 128, 384, embQ, 128, buf_big, 2048, nullptr, nullptr, 0, T, 2048, 128);
  gate_kernel<8><<<T, blk, 0, stream>>>(buf_big, tau3, 3, 1, gk_b, 2048, 16);
  hipMemsetAsync(csum, 0, 2048 * sizeof(float), stream);
  colsum_part_kernel<<<dim3(8, 32), blk, 0, stream>>>(buf_big, 2048, csum);
  colsum_fin_kernel<<<8, blk, 0, stream>>>(csum, 2048, 1.f / 2048.f, aux);

  mfma_gemm_kernel<false, false, 0><<<dim3(16, 64), blk, 0, stream>>>(
      hab + 256, 384, embV, 128, buf_big, 2048, nullptr, nullptr, 0, T, 2048, 128);
  gate_kernel<8><<<T, blk, 0, stream>>>(buf_big, tau3, 3, 2, gv_b, 2048, 16);
  hipMemsetAsync(csum, 0, 2048 * sizeof(float), stream);
  colsum_part_kernel<<<dim3(8, 32), blk, 0, stream>>>(buf_big, 2048, csum);
  colsum_fin_kernel<<<8, blk, 0, stream>>>(csum, 2048, 1.f / 2048.f, aux);

  // features (qk basis) -> bf16 all_h
  transpose_to_bf16_kernel<<<dim3(4, 32, 16), blk, 0, stream>>>(
      qk_f, B2t, 1024, 128, 131072, 131072);
  mfma_gemm_kernel<false, false, 1><<<dim3(16, 64), blk, 0, stream>>>(
      nb, 1024, B2t, 1024, allh_b, 2048, nullptr, nullptr, 0, T, 2048, 1024);
  wsum2_kernel<<<T, 128, 0, stream>>>(allh_b, gq_b, gk_b, hQ, hK, 16);

  // features (v basis)
  transpose_to_bf16_kernel<<<dim3(4, 32, 16), blk, 0, stream>>>(
      v_f, B2t, 1024, 128, 131072, 131072);
  mfma_gemm_kernel<false, false, 1><<<dim3(16, 64), blk, 0, stream>>>(
      nb, 1024, B2t, 1024, allh_b, 2048, nullptr, nullptr, 0, T, 2048, 1024);
  wsum2_kernel<<<T, 128, 0, stream>>>(allh_b, gv_b, nullptr, hV, nullptr, 16);

  // restores -> Q,K bf16 and Vt transposed bf16
  avirt_kernel<<<T, blk, 0, stream>>>(hQ, gq_b, 16, avb, 2048);
  mfma_gemm_kernel<false, false, 1><<<dim3(8, 64), blk, 0, stream>>>(
      avb, 2048, qkr_t, 2048, Qbb, 1024, nullptr, nullptr, 0, T, 1024, 2048);
  avirt_kernel<<<T, blk, 0, stream>>>(hK, gk_b, 16, avb, 2048);
  mfma_gemm_kernel<false, false, 1><<<dim3(8, 64), blk, 0, stream>>>(
      avb, 2048, qkr_t, 2048, Kbb, 1024, nullptr, nullptr, 0, T, 1024, 2048);
  avirt_kernel<<<T, blk, 0, stream>>>(hV, gv_b, 16, avb, 2048);
  mfma_gemm_kernel<false, false, 2><<<dim3(8, 64), blk, 0, stream>>>(
      avb, 2048, vr_t, 2048, Vtb, 1024, nullptr, nullptr, 0, T, 1024, 2048);

  // MFMA flash attention (causal-paired, 512 thr) + output proj + residual
  flash_mfma_kernel<<<dim3(4, 16, 4), dim3(512), 0, stream>>>(Qbb, Kbb, Vtb,
                                                              attnb_b);
  mfma_gemm_kernel<false, true, 0><<<dim3(8, 64), blk, 0, stream>>>(
      attnb_b, 1024, eo_t, 1024, out, 1024, nullptr, x, 1024, T, 1024, 1024);

  // ---- knowledge circuit ----
  ln_kernel<<<T, blk, 0, stream>>>(out, ln2_scale, ln2_bias, n_f, nb);
  norm_rows_kernel<<<4096, 64, 0, stream>>>(know_emb, embB);
  mfma_gemm_kernel<true, false, 1><<<dim3(1, 64), blk, 0, stream>>>(
      nb, 1024, pk_t, 1024, hab, 128, proj_know_b, nullptr, 0, T, 128, 1024);
  tau_kernel<<<T, 64, 0, stream>>>(n_f, tau_know_k, tau_know_b, tau3, 1);

  mfma_gemm_kernel<false, false, 0><<<dim3(32, 64), blk, 0, stream>>>(
      hab, 128, embB, 128, buf_big, 4096, nullptr, nullptr, 0, T, 4096, 128);
  gate_kernel<16><<<T, blk, 0, stream>>>(buf_big, tau3, 1, 0, gkn_b, 4096, 32);
  hipMemsetAsync(csum, 0, 4096 * sizeof(float), stream);
  colsum_part_kernel<<<dim3(16, 32), blk, 0, stream>>>(buf_big, 4096, csum);
  colsum_fin_kernel<<<16, blk, 0, stream>>>(csum, 4096, 1.f / 4096.f, aux);

  transpose_to_bf16_kernel<<<dim3(4, 32, 32), blk, 0, stream>>>(
      know_f, B2t, 1024, 128, 131072, 131072);
  mfma_gemm_kernel<false, false, 1><<<dim3(32, 64), blk, 0, stream>>>(
      nb, 1024, B2t, 1024, allh_b, 4096, nullptr, nullptr, 0, T, 4096, 1024);
  wsum2_kernel<<<T, 128, 0, stream>>>(allh_b, gkn_b, nullptr, hQ, nullptr, 32);

  avirt_kernel<<<T, blk, 0, stream>>>(hQ, gkn_b, 32, avb, 4096);
  mfma_gemm_kernel<false, true, 0><<<dim3(8, 64), blk, 0, stream>>>(
      avb, 4096, knr_t, 4096, out, 1024, nullptr, out, 1024, T, 1024, 4096);
}

// Round 10
// 672.004 us; speedup vs baseline: 5.8317x; 1.0487x over previous
//
#include <hip/hip_runtime.h>
#include <math.h>

static constexpr int T = 4096;   // B*S
static constexpr int D = 1024;

typedef __bf16 bf16_t;
typedef bf16_t bf16x8 __attribute__((ext_vector_type(8)));
typedef bf16_t bf16x4 __attribute__((ext_vector_type(4)));
typedef float f32x4 __attribute__((ext_vector_type(4)));

#define GLDS16(g, l)                                                        \
  __builtin_amdgcn_global_load_lds(                                         \
      (const __attribute__((address_space(1))) void*)(g),                   \
      (__attribute__((address_space(3))) void*)(l), 16, 0, 0)

// ======================= small kernels =======================

__global__ void zero1_kernel(float* p) { *p = 0.f; }

__global__ __launch_bounds__(256) void ln_kernel(
    const float* __restrict__ x, const float* __restrict__ scale,
    const float* __restrict__ bias, float* __restrict__ out_f,
    bf16_t* __restrict__ out_b)
{
  int t = blockIdx.x;
  const float* xr = x + (size_t)t * D;
  float v[4];
  float s1 = 0.f, s2 = 0.f;
#pragma unroll
  for (int i = 0; i < 4; i++) {
    v[i] = xr[threadIdx.x + i * 256];
    s1 += v[i];
    s2 += v[i] * v[i];
  }
#pragma unroll
  for (int o = 1; o < 64; o <<= 1) {
    s1 += __shfl_xor(s1, o);
    s2 += __shfl_xor(s2, o);
  }
  __shared__ float r1[4], r2[4];
  int wid = threadIdx.x >> 6;
  if ((threadIdx.x & 63) == 0) { r1[wid] = s1; r2[wid] = s2; }
  __syncthreads();
  s1 = r1[0] + r1[1] + r1[2] + r1[3];
  s2 = r2[0] + r2[1] + r2[2] + r2[3];
  float mean = s1 * (1.f / D);
  float var = s2 * (1.f / D) - mean * mean;
  float rstd = rsqrtf(var + 1e-6f);
  float* orow = out_f + (size_t)t * D;
  bf16_t* brow = out_b + (size_t)t * D;
#pragma unroll
  for (int i = 0; i < 4; i++) {
    int d = threadIdx.x + i * 256;
    float o = (v[i] - mean) * rstd * scale[d] + bias[d];
    orow[d] = o;
    brow[d] = (bf16_t)o;
  }
}

// rows of length 128, one wave per row; bf16 normalized output
__global__ __launch_bounds__(64) void norm_rows_kernel(
    const float* __restrict__ e, bf16_t* __restrict__ o)
{
  int r = blockIdx.x;
  const float* row = e + (size_t)r * 128;
  float a = row[threadIdx.x], b = row[threadIdx.x + 64];
  float ss = a * a + b * b;
#pragma unroll
  for (int m = 1; m < 64; m <<= 1) ss += __shfl_xor(ss, m);
  float inv = 1.f / (sqrtf(ss) + 1e-8f);
  bf16_t* orow = o + (size_t)r * 128;
  orow[threadIdx.x] = (bf16_t)(a * inv);
  orow[threadIdx.x + 64] = (bf16_t)(b * inv);
}

// tau = n @ W + b,  W: [D, J], J in {1,3}; one wave per token (fp32)
__global__ __launch_bounds__(64) void tau_kernel(
    const float* __restrict__ n, const float* __restrict__ W,
    const float* __restrict__ b, float* __restrict__ out, int J)
{
  int t = blockIdx.x;
  const float* nr = n + (size_t)t * D;
  for (int j = 0; j < J; j++) {
    float p = 0.f;
#pragma unroll 4
    for (int i = 0; i < 16; i++) {
      int d = threadIdx.x + i * 64;
      p += nr[d] * W[d * J + j];
    }
#pragma unroll
    for (int m = 1; m < 64; m <<= 1) p += __shfl_xor(p, m);
    if (threadIdx.x == 0) out[t * J + j] = p + b[j];
  }
}

// threshold gate + group gate, in place.
template <int PER>
__global__ __launch_bounds__(256) void gate_kernel(
    float* __restrict__ g, const float* __restrict__ tau, int tauStride,
    int tauOff, float* __restrict__ gb, int N, int G)
{
  int t = blockIdx.x;
  float tv = tau[t * tauStride + tauOff];
  float* row = g + (size_t)t * N;
  float r[PER];
  int base = threadIdx.x * PER;
  float psum = 0.f;
#pragma unroll
  for (int i = 0; i < PER; i++) {
    float s = row[base + i] - tv;
    s = fmaxf(s, 0.f);
    r[i] = s;
    psum += s;
  }
  __shared__ float red[4];
  __shared__ float grp[32];
  if (threadIdx.x < 32) grp[threadIdx.x] = 0.f;
  float w = psum;
#pragma unroll
  for (int m = 1; m < 64; m <<= 1) w += __shfl_xor(w, m);
  int wid = threadIdx.x >> 6;
  if ((threadIdx.x & 63) == 0) red[wid] = w;
  __syncthreads();
  float Stot = red[0] + red[1] + red[2] + red[3];
  atomicAdd(&grp[base >> 7], psum);
  __syncthreads();
  float inv = 1.f / (Stot + 1e-8f);
#pragma unroll
  for (int i = 0; i < PER; i++) row[base + i] = r[i] * inv;
  if (threadIdx.x < G) {
    float Gj = grp[threadIdx.x] * inv;
    float gsum = Stot * inv;
    gb[(size_t)t * G + threadIdx.x] = Gj / (gsum + 1e-8f);
  }
}

// stage 1: partial column sums of g [T,N] over 128-row chunks
__global__ __launch_bounds__(256) void colsum_part_kernel(
    const float* __restrict__ g, int N, float* __restrict__ colsum)
{
  int c = blockIdx.x * 256 + threadIdx.x;
  int r0 = blockIdx.y * 128;
  const float* p = g + (size_t)r0 * N + c;
  float s = 0.f;
#pragma unroll 8
  for (int t = 0; t < 128; t++) s += p[(size_t)t * N];
  atomicAdd(&colsum[c], s);
}

// stage 2: aux += sum_c (colsum[c]/T - tinv)^2 * N
__global__ __launch_bounds__(256) void colsum_fin_kernel(
    const float* __restrict__ colsum, int N, float tinv,
    float* __restrict__ aux)
{
  int c = blockIdx.x * 256 + threadIdx.x;
  float mdev = colsum[c] * (1.f / T) - tinv;
  float p = mdev * mdev * (float)N;
#pragma unroll
  for (int m = 1; m < 64; m <<= 1) p += __shfl_xor(p, m);
  __shared__ float red[4];
  if ((threadIdx.x & 63) == 0) red[threadIdx.x >> 6] = p;
  __syncthreads();
  if (threadIdx.x == 0) atomicAdd(aux, red[0] + red[1] + red[2] + red[3]);
}

// h1[t,r] = sum_n gb1[t,n]*all_h[t, n*128+r] (all_h bf16); optional 2nd out
__global__ __launch_bounds__(128) void wsum2_kernel(
    const bf16_t* __restrict__ all_h, const float* __restrict__ gb1,
    const float* __restrict__ gb2, float* __restrict__ h1,
    float* __restrict__ h2, int NB)
{
  int t = blockIdx.x;
  int r = threadIdx.x;
  const bf16_t* row = all_h + (size_t)t * NB * 128;
  float a1 = 0.f, a2 = 0.f;
  for (int n = 0; n < NB; n++) {
    float v = (float)row[n * 128 + r];
    a1 += gb1[(size_t)t * NB + n] * v;
    if (gb2) a2 += gb2[(size_t)t * NB + n] * v;
  }
  h1[(size_t)t * 128 + r] = a1;
  if (h2) h2[(size_t)t * 128 + r] = a2;
}

// dst[c][r] = (bf16)src[r][c]; src [R,C] fp32, dst [C,R] bf16; batched
__global__ __launch_bounds__(256) void transpose_to_bf16_kernel(
    const float* __restrict__ src, bf16_t* __restrict__ dst,
    int R, int C, size_t sbs, size_t dbs)
{
  __shared__ float tile[32][33];
  int b = blockIdx.z;
  int c0 = blockIdx.x * 32, r0 = blockIdx.y * 32;
  int tx = threadIdx.x & 31, ty = threadIdx.x >> 5;  // 8 rows/pass
  const float* s = src + (size_t)b * sbs;
  bf16_t* d = dst + (size_t)b * dbs;
#pragma unroll
  for (int i = 0; i < 4; i++)
    tile[ty + i * 8][tx] = s[(size_t)(r0 + ty + i * 8) * C + c0 + tx];
  __syncthreads();
#pragma unroll
  for (int i = 0; i < 4; i++)
    d[(size_t)(c0 + ty + i * 8) * R + r0 + tx] = (bf16_t)tile[tx][ty + i * 8];
}

// A_virt[t,k] = (bf16)(gb[t,k>>7]*h[t,k&127]), row-major [T,K]
__global__ __launch_bounds__(256) void avirt_kernel(
    const float* __restrict__ h, const float* __restrict__ gb, int NB,
    bf16_t* __restrict__ A, int K)
{
  int t = blockIdx.x;
  const float* hr = h + (size_t)t * 128;
  const float* gr = gb + (size_t)t * NB;
  bf16_t* ar = A + (size_t)t * K;
  int noct = K >> 3;
  for (int o = threadIdx.x; o < noct; o += 256) {
    int k = o * 8;
    float g = gr[k >> 7];
    bf16x8 v;
#pragma unroll
    for (int i = 0; i < 8; i++) v[i] = (bf16_t)(hr[(k & 127) + i] * g);
    *(bf16x8*)(ar + k) = v;
  }
}

// out[i] += p0[i] + p1[i]  (float4-vectorized, n/4 elements)
__global__ __launch_bounds__(256) void combine2_kernel(
    const float* __restrict__ p0, const float* __restrict__ p1,
    float* __restrict__ out)
{
  int i = blockIdx.x * 256 + threadIdx.x;
  float4 a = ((const float4*)p0)[i];
  float4 b = ((const float4*)p1)[i];
  float4 o = ((float4*)out)[i];
  o.x += a.x + b.x;
  o.y += a.y + b.y;
  o.z += a.z + b.z;
  o.w += a.w + b.w;
  ((float4*)out)[i] = o;
}

// ============== MFMA GEMM: C[M,N] = A[M,K]bf16 @ Bt[N,K]bf16^T ==============
// 64x128 tile, BK=32, 4 waves (2x2: 32 rows x 64 cols each), 2x4 fragments.
// Double-buffered LDS, stage-ahead prefetch, chunk-XOR swizzle, XCD-chunked
// block swizzle. Grid: x = N/128, y = M/64.
// OUT_MODE: 0 = f32, 1 = bf16, 2 = bf16 transposed V store (Vt[b][col][s])
template <bool HAS_BIAS, bool HAS_RESID, int OUT_MODE>
__global__ __launch_bounds__(256) void mfma_gemm_kernel(
    const bf16_t* __restrict__ A, int lda,
    const bf16_t* __restrict__ Bt, int ldb,
    void* __restrict__ Cv, int ldc,
    const float* __restrict__ bias,
    const float* __restrict__ resid, int ldr,
    int M, int N, int K)
{
  __shared__ bf16_t As[2][64 * 32];
  __shared__ bf16_t Bs[2][128 * 32];
  int tid = threadIdx.x;
  int wave = tid >> 6, lane = tid & 63;

  unsigned lid = blockIdx.y * gridDim.x + blockIdx.x;
  unsigned nwg = gridDim.x * gridDim.y;
  unsigned swzb = lid;
  if ((nwg & 7u) == 0u) swzb = (lid & 7u) * (nwg >> 3) + (lid >> 3);
  int row0 = (int)(swzb / gridDim.x) * 64;
  int col0 = (int)(swzb % gridDim.x) * 128;

  int wr = (wave >> 1) * 32, wc = (wave & 1) * 64;

  f32x4 acc[2][4] = {};

  int srow = (wave << 4) + (lane >> 2);
  int g8 = (((lane & 3) ^ ((srow >> 1) & 3)) << 3);
  const bf16_t* gA = A + (size_t)(row0 + srow) * lda + g8;
  const bf16_t* gB = Bt + (size_t)(col0 + srow) * ldb + g8;
  size_t b64 = (size_t)64 * ldb;

  int fr = lane & 15, fq = lane >> 4;

#define GSTAGE(buf, k0s)                                  \
  {                                                       \
    GLDS16(gA + (k0s), &As[buf][wave * 512]);             \
    GLDS16(gB + (k0s), &Bs[buf][wave * 512]);             \
    GLDS16(gB + b64 + (k0s), &Bs[buf][2048 + wave * 512]);\
  }

  GSTAGE(0, 0);
  int cur = 0;
  for (int k0 = 0; k0 < K; k0 += 32) {
    __syncthreads();
    if (k0 + 32 < K) GSTAGE(cur ^ 1, k0 + 32);
    bf16x8 af[2], bfr[4];
#pragma unroll
    for (int m = 0; m < 2; m++) {
      int R = wr + m * 16 + fr;
      af[m] = *(const bf16x8*)&As[cur][R * 32 + ((fq ^ ((R >> 1) & 3)) << 3)];
    }
#pragma unroll
    for (int n = 0; n < 4; n++) {
      int R = wc + n * 16 + fr;
      bfr[n] = *(const bf16x8*)&Bs[cur][R * 32 + ((fq ^ ((R >> 1) & 3)) << 3)];
    }
#pragma unroll
    for (int m = 0; m < 2; m++)
#pragma unroll
      for (int n = 0; n < 4; n++)
        acc[m][n] = __builtin_amdgcn_mfma_f32_16x16x32_bf16(af[m], bfr[n],
                                                            acc[m][n], 0, 0, 0);
    cur ^= 1;
  }
#undef GSTAGE

#pragma unroll
  for (int m = 0; m < 2; m++) {
#pragma unroll
    for (int n = 0; n < 4; n++) {
      int rowb = row0 + wr + m * 16 + fq * 4;
      int col = col0 + wc + n * 16 + fr;
      if (OUT_MODE == 2) {
        bf16x4 v4;
#pragma unroll
        for (int r = 0; r < 4; r++) v4[r] = (bf16_t)acc[m][n][r];
        bf16_t* dst = (bf16_t*)Cv +
            ((size_t)(rowb >> 10) * 1024 + col) * 1024 + (rowb & 1023);
        *(bf16x4*)dst = v4;
      } else {
#pragma unroll
        for (int r = 0; r < 4; r++) {
          int row = rowb + r;
          float v = acc[m][n][r];
          if (HAS_BIAS) v += bias[col];
          if (HAS_RESID) v += resid[(size_t)row * ldr + col];
          if (OUT_MODE == 1)
            ((bf16_t*)Cv)[(size_t)row * ldc + col] = (bf16_t)v;
          else
            ((float*)Cv)[(size_t)row * ldc + col] = v;
        }
      }
    }
  }
}

// ============== batched MFMA GEMM: z-indexed {A, Bt, C, mode} ==============
// Same 64x128 structure; blockIdx.z selects the problem; swizzle spans the
// whole batched grid so all z's blocks co-reside (latency hiding).
struct ZArg { const bf16_t* A; const bf16_t* Bt; void* C; int mode; };

__global__ __launch_bounds__(256) void mfma_gemm_batched_kernel(
    ZArg za, ZArg zb, ZArg zc, int lda, int ldb, int ldc, int K)
{
  __shared__ bf16_t As[2][64 * 32];
  __shared__ bf16_t Bs[2][128 * 32];
  int tid = threadIdx.x;
  int wave = tid >> 6, lane = tid & 63;

  unsigned gx = gridDim.x;
  unsigned gxy = gridDim.x * gridDim.y;
  unsigned lid = (blockIdx.z * gridDim.y + blockIdx.y) * gx + blockIdx.x;
  unsigned nwg = gxy * gridDim.z;
  unsigned swzb = lid;
  if ((nwg & 7u) == 0u) swzb = (lid & 7u) * (nwg >> 3) + (lid >> 3);
  unsigned zi = swzb / gxy;
  unsigned rem = swzb % gxy;
  int row0 = (int)(rem / gx) * 64;
  int col0 = (int)(rem % gx) * 128;
  ZArg Z = (zi == 0) ? za : (zi == 1) ? zb : zc;

  int wr = (wave >> 1) * 32, wc = (wave & 1) * 64;
  f32x4 acc[2][4] = {};

  int srow = (wave << 4) + (lane >> 2);
  int g8 = (((lane & 3) ^ ((srow >> 1) & 3)) << 3);
  const bf16_t* gA = Z.A + (size_t)(row0 + srow) * lda + g8;
  const bf16_t* gB = Z.Bt + (size_t)(col0 + srow) * ldb + g8;
  size_t b64 = (size_t)64 * ldb;

  int fr = lane & 15, fq = lane >> 4;

#define GSTAGE(buf, k0s)                                  \
  {                                                       \
    GLDS16(gA + (k0s), &As[buf][wave * 512]);             \
    GLDS16(gB + (k0s), &Bs[buf][wave * 512]);             \
    GLDS16(gB + b64 + (k0s), &Bs[buf][2048 + wave * 512]);\
  }

  GSTAGE(0, 0);
  int cur = 0;
  for (int k0 = 0; k0 < K; k0 += 32) {
    __syncthreads();
    if (k0 + 32 < K) GSTAGE(cur ^ 1, k0 + 32);
    bf16x8 af[2], bfr[4];
#pragma unroll
    for (int m = 0; m < 2; m++) {
      int R = wr + m * 16 + fr;
      af[m] = *(const bf16x8*)&As[cur][R * 32 + ((fq ^ ((R >> 1) & 3)) << 3)];
    }
#pragma unroll
    for (int n = 0; n < 4; n++) {
      int R = wc + n * 16 + fr;
      bfr[n] = *(const bf16x8*)&Bs[cur][R * 32 + ((fq ^ ((R >> 1) & 3)) << 3)];
    }
#pragma unroll
    for (int m = 0; m < 2; m++)
#pragma unroll
      for (int n = 0; n < 4; n++)
        acc[m][n] = __builtin_amdgcn_mfma_f32_16x16x32_bf16(af[m], bfr[n],
                                                            acc[m][n], 0, 0, 0);
    cur ^= 1;
  }
#undef GSTAGE

#pragma unroll
  for (int m = 0; m < 2; m++) {
#pragma unroll
    for (int n = 0; n < 4; n++) {
      int rowb = row0 + wr + m * 16 + fq * 4;
      int col = col0 + wc + n * 16 + fr;
      if (Z.mode == 2) {
        bf16x4 v4;
#pragma unroll
        for (int r = 0; r < 4; r++) v4[r] = (bf16_t)acc[m][n][r];
        bf16_t* dst = (bf16_t*)Z.C +
            ((size_t)(rowb >> 10) * 1024 + col) * 1024 + (rowb & 1023);
        *(bf16x4*)dst = v4;
      } else if (Z.mode == 1) {
#pragma unroll
        for (int r = 0; r < 4; r++)
          ((bf16_t*)Z.C)[(size_t)(rowb + r) * ldc + col] =
              (bf16_t)acc[m][n][r];
      } else {
#pragma unroll
        for (int r = 0; r < 4; r++)
          ((float*)Z.C)[(size_t)(rowb + r) * ldc + col] = acc[m][n][r];
      }
    }
  }
}

// ======================= MFMA flash attention (bf16, LDS-staged) ============
// 8 waves (512 thr). Causal-pair balancing: waves 0-3 own q-tile s (128 rows),
// waves 4-7 own q-tile 7-s. Per-SIMD work = (2s+2)+(16-2s) = 18 tile-units,
// identical for every block and SIMD. One block per CU (grid 4x16x4).
__global__ __launch_bounds__(512) void flash_mfma_kernel(
    const bf16_t* __restrict__ Q, const bf16_t* __restrict__ K,
    const bf16_t* __restrict__ Vt, bf16_t* __restrict__ O)
{
  __shared__ bf16_t Ks[2][64 * 64];
  __shared__ bf16_t Vs[2][64 * 64];
  __shared__ bf16_t Pl[8][32 * 64];

  int tid = threadIdx.x;
  int wave = tid >> 6, lane = tid & 63;
  int fr = lane & 15, fq = lane >> 4;
  unsigned lid = blockIdx.x + blockIdx.y * 4 + blockIdx.z * 64;  // 256 wgs
  unsigned swz8 = (lid & 7u) * 32 + (lid >> 3);
  int s_slot = swz8 & 3;
  unsigned hb = swz8 >> 2;
  int h = hb & 15, b = hb >> 4;
  int half = wave >> 2, w4 = wave & 3;
  int qb = half ? (7 - s_slot) : s_slot;
  int q0w = qb * 128 + w4 * 32;
  int KT = 16 - 2 * s_slot;
  size_t qkbase = ((size_t)b * 1024) * 1024 + (size_t)h * 64;
  size_t vtbase = ((size_t)b * 1024 + (size_t)h * 64) * 1024;

  int srow8 = lane >> 3;
  int scb = (((lane & 7) << 4) ^ (srow8 << 4)) >> 1;

#define FSTAGE(buf, kt)                                                     \
  {                                                                         \
    int k0s = (kt) * 64;                                                    \
    int row = wave * 8 + srow8;                                             \
    GLDS16(&K[qkbase + (size_t)(k0s + row) * 1024 + scb],                   \
           &Ks[buf][wave * 512]);                                           \
    GLDS16(&Vt[vtbase + (size_t)row * 1024 + k0s + scb],                    \
           &Vs[buf][wave * 512]);                                           \
  }

  bf16x8 qf[2][2];
#pragma unroll
  for (int g = 0; g < 2; g++)
#pragma unroll
    for (int kh = 0; kh < 2; kh++)
      qf[g][kh] = *(const bf16x8*)&Q[qkbase +
                                     (size_t)(q0w + g * 16 + fr) * 1024 +
                                     kh * 32 + fq * 8];

  f32x4 o_acc[2][4] = {};
  float mrow[2][4], lrow[2][4];
#pragma unroll
  for (int g = 0; g < 2; g++)
#pragma unroll
    for (int r = 0; r < 4; r++) { mrow[g][r] = -INFINITY; lrow[g][r] = 0.f; }

  char* P = (char*)&Pl[wave][0];

  FSTAGE(0, 0);

  for (int kt = 0; kt < KT; kt++) {
    __syncthreads();
    if (kt + 1 < KT) FSTAGE((kt + 1) & 1, kt + 1);
    int k0 = kt * 64;
    if (k0 <= q0w + 31) {
      const char* Kb = (const char*)&Ks[kt & 1][0];
      const char* Vb = (const char*)&Vs[kt & 1][0];
      int swz = (fr & 7) << 4;
      f32x4 s[2][4] = {};
#pragma unroll
      for (int n = 0; n < 4; n++) {
        int rowo = (n * 16 + fr) * 128;
        bf16x8 kf0 = *(const bf16x8*)(Kb + rowo + ((fq * 16) ^ swz));
        bf16x8 kf1 = *(const bf16x8*)(Kb + rowo + ((64 + fq * 16) ^ swz));
#pragma unroll
        for (int g = 0; g < 2; g++) {
          s[g][n] = __builtin_amdgcn_mfma_f32_16x16x32_bf16(qf[g][0], kf0,
                                                            s[g][n], 0, 0, 0);
          s[g][n] = __builtin_amdgcn_mfma_f32_16x16x32_bf16(qf[g][1], kf1,
                                                            s[g][n], 0, 0, 0);
        }
      }
      const float scale = 0.125f;
#pragma unroll
      for (int g = 0; g < 2; g++) {
        bool dm = (k0 + 63 > q0w + g * 16);
#pragma unroll
        for (int n = 0; n < 4; n++)
#pragma unroll
          for (int r = 0; r < 4; r++) {
            float v = s[g][n][r] * scale;
            if (dm && (k0 + n * 16 + fr > q0w + g * 16 + fq * 4 + r))
              v = -INFINITY;
            s[g][n][r] = v;
          }
      }
      float corr[2][4];
#pragma unroll
      for (int g = 0; g < 2; g++)
#pragma unroll
        for (int r = 0; r < 4; r++) {
          float mx = fmaxf(fmaxf(s[g][0][r], s[g][1][r]),
                           fmaxf(s[g][2][r], s[g][3][r]));
#pragma unroll
          for (int msk = 1; msk < 16; msk <<= 1)
            mx = fmaxf(mx, __shfl_xor(mx, msk));
          float mnew = fmaxf(mrow[g][r], mx);
          corr[g][r] = __expf(mrow[g][r] - mnew);
          mrow[g][r] = mnew;
          float ps = 0.f;
#pragma unroll
          for (int n = 0; n < 4; n++) {
            float p = __expf(s[g][n][r] - mnew);
            s[g][n][r] = p;
            ps += p;
          }
#pragma unroll
          for (int msk = 1; msk < 16; msk <<= 1) ps += __shfl_xor(ps, msk);
          lrow[g][r] = lrow[g][r] * corr[g][r] + ps;
        }
#pragma unroll
      for (int g = 0; g < 2; g++)
#pragma unroll
        for (int n = 0; n < 4; n++)
#pragma unroll
          for (int r = 0; r < 4; r++) {
            int q = g * 16 + fq * 4 + r;
            int cb = ((n * 16 + fr) * 2) ^ ((q & 7) << 4);
            *(bf16_t*)(P + q * 128 + cb) = (bf16_t)s[g][n][r];
          }
      int rr = fr & 3;
      int srcl = (fr >> 2) << 4;
#pragma unroll
      for (int g = 0; g < 2; g++) {
        float c0 = __shfl(corr[g][0], srcl);
        float c1 = __shfl(corr[g][1], srcl);
        float c2 = __shfl(corr[g][2], srcl);
        float c3 = __shfl(corr[g][3], srcl);
        float cq = rr == 0 ? c0 : rr == 1 ? c1 : rr == 2 ? c2 : c3;
#pragma unroll
        for (int n = 0; n < 4; n++)
#pragma unroll
          for (int r = 0; r < 4; r++) o_acc[g][n][r] *= cq;
      }
#pragma unroll
      for (int c = 0; c < 2; c++) {
        bf16x8 pf[2];
#pragma unroll
        for (int g = 0; g < 2; g++)
          pf[g] = *(const bf16x8*)(P + (g * 16 + fr) * 128 +
                                   ((c * 64 + fq * 16) ^ swz));
#pragma unroll
        for (int n = 0; n < 4; n++) {
          bf16x8 vf = *(const bf16x8*)(Vb + (n * 16 + fr) * 128 +
                                       ((c * 64 + fq * 16) ^ swz));
#pragma unroll
          for (int g = 0; g < 2; g++)
            o_acc[g][n] = __builtin_amdgcn_mfma_f32_16x16x32_bf16(
                vf, pf[g], o_acc[g][n], 0, 0, 0);
        }
      }
    }
  }
  int rr = fr & 3;
  int srcl = (fr >> 2) << 4;
#pragma unroll
  for (int g = 0; g < 2; g++) {
    float l0 = __shfl(lrow[g][0], srcl);
    float l1 = __shfl(lrow[g][1], srcl);
    float l2 = __shfl(lrow[g][2], srcl);
    float l3 = __shfl(lrow[g][3], srcl);
    float lq = rr == 0 ? l0 : rr == 1 ? l1 : rr == 2 ? l2 : l3;
    float linv = 1.f / lq;
    size_t orow = qkbase + (size_t)(q0w + g * 16 + fr) * 1024;
#pragma unroll
    for (int n = 0; n < 4; n++) {
      bf16x4 ov;
#pragma unroll
      for (int r = 0; r < 4; r++) ov[r] = (bf16_t)(o_acc[g][n][r] * linv);
      *(bf16x4*)&O[orow + n * 16 + fq * 4] = ov;
    }
  }
#undef FSTAGE
}

// ======================= launch =======================

extern "C" void kernel_launch(void* const* d_in, const int* in_sizes, int n_in,
                              void* d_out, int out_size, void* d_ws,
                              size_t ws_size, hipStream_t stream) {
  (void)in_sizes; (void)n_in; (void)out_size; (void)ws_size;
  const float* x          = (const float*)d_in[0];
  const float* qk_emb     = (const float*)d_in[1];
  const float* v_emb      = (const float*)d_in[2];
  const float* know_emb   = (const float*)d_in[3];
  const float* qk_f       = (const float*)d_in[4];
  const float* qk_r       = (const float*)d_in[5];
  const float* v_f        = (const float*)d_in[6];
  const float* v_r        = (const float*)d_in[7];
  const float* know_f     = (const float*)d_in[8];
  const float* know_r     = (const float*)d_in[9];
  const float* proj_attn_k = (const float*)d_in[10];
  const float* proj_attn_b = (const float*)d_in[11];
  const float* tau_attn_k  = (const float*)d_in[12];
  const float* tau_attn_b  = (const float*)d_in[13];
  const float* proj_know_k = (const float*)d_in[14];
  const float* proj_know_b = (const float*)d_in[15];
  const float* tau_know_k  = (const float*)d_in[16];
  const float* tau_know_b  = (const float*)d_in[17];
  const float* expand_O    = (const float*)d_in[18];
  const float* ln1_scale   = (const float*)d_in[19];
  const float* ln1_bias    = (const float*)d_in[20];
  const float* ln2_scale   = (const float*)d_in[21];
  const float* ln2_bias    = (const float*)d_in[22];

  float* out = (float*)d_out;  // [T,D] + aux scalar
  float* aux = out + (size_t)T * D;

  // ---- workspace arena ----
  float* ws = (float*)d_ws;
  float* n_f   = ws;                       // 4M floats
  float* tau3  = n_f + 4194304;            // 16K
  float* gq_b  = tau3 + 16384;             // 64K
  float* gk_b  = gq_b + 65536;
  float* gv_b  = gk_b + 65536;
  float* gkn_b = gv_b + 65536;             // 128K
  float* csum  = gkn_b + 131072;           // 4096 (colsum accumulator)
  float* hQ    = csum + 4096;              // 512K
  float* hK    = hQ + 524288;
  float* hV    = hK + 524288;
  float* qkvarena = hV + 524288;           // 12M floats (Q,K bf16 + Vt bf16)
  float* buf_big = qkvarena + 12582912;    // 16.78M floats (64MB)

  bf16_t* Qbb = (bf16_t*)qkvarena;                 // T*1024 bf16 (8MB)
  bf16_t* Kbb = Qbb + (size_t)T * 1024;            // 8MB
  bf16_t* Vtb = Kbb + (size_t)T * 1024;            // [4][1024][1024] 8MB

  bf16_t* nb   = (bf16_t*)(buf_big + 16777216);  // T*1024
  bf16_t* hab  = nb + 4194304;                   // T*384 (reused know: T*128)
  bf16_t* embB = hab + 1572864;                  // 524288 (qk|v ; know)
  bf16_t* B2t  = embB + 524288;                  // 4096*1024
  bf16_t* wt   = B2t + 4194304;                  // transposed weights arena
  bf16_t* pa_t  = wt;                   // 384*1024
  bf16_t* qkr_t = pa_t + 393216;        // 1024*2048
  bf16_t* vr_t  = qkr_t + 2097152;      // 1024*2048
  bf16_t* knr_t = vr_t + 2097152;       // 1024*4096
  bf16_t* eo_t  = knr_t + 4194304;      // 1024*1024
  bf16_t* pk_t  = eo_t + 1048576;       // 128*1024

  // buf_big overlays (lifetimes checked):
  bf16_t* avbQ = (bf16_t*)buf_big;                  // [T,2048] bf16, 16MB
  bf16_t* avbK = avbQ + (size_t)T * 2048;           // 16MB
  bf16_t* avbV = avbK + (size_t)T * 2048;           // 16MB (32..48MB)
  bf16_t* avbN = (bf16_t*)buf_big;                  // knowledge [T,4096] bf16
  float* kp0 = buf_big + 8388608;                   // 32..48MB f32 partial
  float* kp1 = kp0 + 4194304;                       // 48..64MB f32 partial
  bf16_t* allh_b = (bf16_t*)buf_big;                // feature all_h bf16
  bf16_t* attnb_b = (bf16_t*)(buf_big + 12582912);  // T*1024 bf16 (48..56MB)

  bf16_t* embQ = embB;
  bf16_t* embV = embB + 262144;

  dim3 blk(256);

  zero1_kernel<<<1, 1, 0, stream>>>(aux);

  // weight transposes to bf16 [N,K]
  transpose_to_bf16_kernel<<<dim3(12, 32, 1), blk, 0, stream>>>(
      proj_attn_k, pa_t, 1024, 384, 0, 0);
  transpose_to_bf16_kernel<<<dim3(32, 64, 1), blk, 0, stream>>>(
      qk_r, qkr_t, 2048, 1024, 0, 0);
  transpose_to_bf16_kernel<<<dim3(32, 64, 1), blk, 0, stream>>>(
      v_r, vr_t, 2048, 1024, 0, 0);
  transpose_to_bf16_kernel<<<dim3(32, 128, 1), blk, 0, stream>>>(
      know_r, knr_t, 4096, 1024, 0, 0);
  transpose_to_bf16_kernel<<<dim3(32, 32, 1), blk, 0, stream>>>(
      expand_O, eo_t, 1024, 1024, 0, 0);
  transpose_to_bf16_kernel<<<dim3(4, 32, 1), blk, 0, stream>>>(
      proj_know_k, pk_t, 1024, 128, 0, 0);

  // ---- attention circuit ----
  ln_kernel<<<T, blk, 0, stream>>>(x, ln1_scale, ln1_bias, n_f, nb);
  norm_rows_kernel<<<2048, 64, 0, stream>>>(qk_emb, embQ);
  norm_rows_kernel<<<2048, 64, 0, stream>>>(v_emb, embV);

  mfma_gemm_kernel<true, false, 1><<<dim3(3, 64), blk, 0, stream>>>(
      nb, 1024, pa_t, 1024, hab, 384, proj_attn_b, nullptr, 0, T, 384, 1024);
  tau_kernel<<<T, 64, 0, stream>>>(n_f, tau_attn_k, tau_attn_b, tau3, 3);

  // gate scores + gates + aux
  mfma_gemm_kernel<false, false, 0><<<dim3(16, 64), blk, 0, stream>>>(
      hab + 0, 384, embQ, 128, buf_big, 2048, nullptr, nullptr, 0, T, 2048, 128);
  gate_kernel<8><<<T, blk, 0, stream>>>(buf_big, tau3, 3, 0, gq_b, 2048, 16);
  hipMemsetAsync(csum, 0, 2048 * sizeof(float), stream);
  colsum_part_kernel<<<dim3(8, 32), blk, 0, stream>>>(buf_big, 2048, csum);
  colsum_fin_kernel<<<8, blk, 0, stream>>>(csum, 2048, 1.f / 2048.f, aux);

  mfma_gemm_kernel<false, false, 0><<<dim3(16, 64), blk, 0, stream>>>(
      hab + 128, 384, embQ, 128, buf_big, 2048, nullptr, nullptr, 0, T, 2048, 128);
  gate_kernel<8><<<T, blk, 0, stream>>>(buf_big, tau3, 3, 1, gk_b, 2048, 16);
  hipMemsetAsync(csum, 0, 2048 * sizeof(float), stream);
  colsum_part_kernel<<<dim3(8, 32), blk, 0, stream>>>(buf_big, 2048, csum);
  colsum_fin_kernel<<<8, blk, 0, stream>>>(csum, 2048, 1.f / 2048.f, aux);

  mfma_gemm_kernel<false, false, 0><<<dim3(16, 64), blk, 0, stream>>>(
      hab + 256, 384, embV, 128, buf_big, 2048, nullptr, nullptr, 0, T, 2048, 128);
  gate_kernel<8><<<T, blk, 0, stream>>>(buf_big, tau3, 3, 2, gv_b, 2048, 16);
  hipMemsetAsync(csum, 0, 2048 * sizeof(float), stream);
  colsum_part_kernel<<<dim3(8, 32), blk, 0, stream>>>(buf_big, 2048, csum);
  colsum_fin_kernel<<<8, blk, 0, stream>>>(csum, 2048, 1.f / 2048.f, aux);

  // features (qk basis) -> bf16 all_h
  transpose_to_bf16_kernel<<<dim3(4, 32, 16), blk, 0, stream>>>(
      qk_f, B2t, 1024, 128, 131072, 131072);
  mfma_gemm_kernel<false, false, 1><<<dim3(16, 64), blk, 0, stream>>>(
      nb, 1024, B2t, 1024, allh_b, 2048, nullptr, nullptr, 0, T, 2048, 1024);
  wsum2_kernel<<<T, 128, 0, stream>>>(allh_b, gq_b, gk_b, hQ, hK, 16);

  // features (v basis)
  transpose_to_bf16_kernel<<<dim3(4, 32, 16), blk, 0, stream>>>(
      v_f, B2t, 1024, 128, 131072, 131072);
  mfma_gemm_kernel<false, false, 1><<<dim3(16, 64), blk, 0, stream>>>(
      nb, 1024, B2t, 1024, allh_b, 2048, nullptr, nullptr, 0, T, 2048, 1024);
  wsum2_kernel<<<T, 128, 0, stream>>>(allh_b, gv_b, nullptr, hV, nullptr, 16);

  // restores -> Q,K bf16 and Vt transposed bf16 (batched, z = {Q,K,V})
  avirt_kernel<<<T, blk, 0, stream>>>(hQ, gq_b, 16, avbQ, 2048);
  avirt_kernel<<<T, blk, 0, stream>>>(hK, gk_b, 16, avbK, 2048);
  avirt_kernel<<<T, blk, 0, stream>>>(hV, gv_b, 16, avbV, 2048);
  {
    ZArg zq{avbQ, qkr_t, Qbb, 1};
    ZArg zk{avbK, qkr_t, Kbb, 1};
    ZArg zv{avbV, vr_t, Vtb, 2};
    mfma_gemm_batched_kernel<<<dim3(8, 64, 3), blk, 0, stream>>>(
        zq, zk, zv, 2048, 2048, 1024, 2048);
  }

  // MFMA flash attention (causal-paired, 512 thr) + output proj + residual
  flash_mfma_kernel<<<dim3(4, 16, 4), dim3(512), 0, stream>>>(Qbb, Kbb, Vtb,
                                                              attnb_b);
  mfma_gemm_kernel<false, true, 0><<<dim3(8, 64), blk, 0, stream>>>(
      attnb_b, 1024, eo_t, 1024, out, 1024, nullptr, x, 1024, T, 1024, 1024);

  // ---- knowledge circuit ----
  ln_kernel<<<T, blk, 0, stream>>>(out, ln2_scale, ln2_bias, n_f, nb);
  norm_rows_kernel<<<4096, 64, 0, stream>>>(know_emb, embB);
  mfma_gemm_kernel<true, false, 1><<<dim3(1, 64), blk, 0, stream>>>(
      nb, 1024, pk_t, 1024, hab, 128, proj_know_b, nullptr, 0, T, 128, 1024);
  tau_kernel<<<T, 64, 0, stream>>>(n_f, tau_know_k, tau_know_b, tau3, 1);

  mfma_gemm_kernel<false, false, 0><<<dim3(32, 64), blk, 0, stream>>>(
      hab, 128, embB, 128, buf_big, 4096, nullptr, nullptr, 0, T, 4096, 128);
  gate_kernel<16><<<T, blk, 0, stream>>>(buf_big, tau3, 1, 0, gkn_b, 4096, 32);
  hipMemsetAsync(csum, 0, 4096 * sizeof(float), stream);
  colsum_part_kernel<<<dim3(16, 32), blk, 0, stream>>>(buf_big, 4096, csum);
  colsum_fin_kernel<<<16, blk, 0, stream>>>(csum, 4096, 1.f / 4096.f, aux);

  transpose_to_bf16_kernel<<<dim3(4, 32, 32), blk, 0, stream>>>(
      know_f, B2t, 1024, 128, 131072, 131072);
  mfma_gemm_kernel<false, false, 1><<<dim3(32, 64), blk, 0, stream>>>(
      nb, 1024, B2t, 1024, allh_b, 4096, nullptr, nullptr, 0, T, 4096, 1024);
  wsum2_kernel<<<T, 128, 0, stream>>>(allh_b, gkn_b, nullptr, hQ, nullptr, 32);

  // knowledge restore: split-K=2 via batched kernel -> f32 partials + combine
  avirt_kernel<<<T, blk, 0, stream>>>(hQ, gkn_b, 32, avbN, 4096);
  {
    ZArg z0{avbN, knr_t, kp0, 0};
    ZArg z1{avbN + 2048, knr_t + 2048, kp1, 0};
    mfma_gemm_batched_kernel<<<dim3(8, 64, 2), blk, 0, stream>>>(
        z0, z1, z0, 4096, 4096, 1024, 2048);
  }
  combine2_kernel<<<4096, blk, 0, stream>>>(kp0, kp1, out);
}

// Round 11
// 628.174 us; speedup vs baseline: 6.2386x; 1.0698x over previous
//
#include <hip/hip_runtime.h>
#include <math.h>

static constexpr int T = 4096;   // B*S
static constexpr int D = 1024;

typedef __bf16 bf16_t;
typedef bf16_t bf16x8 __attribute__((ext_vector_type(8)));
typedef bf16_t bf16x4 __attribute__((ext_vector_type(4)));
typedef float f32x4 __attribute__((ext_vector_type(4)));

#define GLDS16(g, l)                                                        \
  __builtin_amdgcn_global_load_lds(                                         \
      (const __attribute__((address_space(1))) void*)(g),                   \
      (__attribute__((address_space(3))) void*)(l), 16, 0, 0)

// ======================= small kernels =======================

__global__ void zero1_kernel(float* p) { *p = 0.f; }

__global__ __launch_bounds__(256) void ln_kernel(
    const float* __restrict__ x, const float* __restrict__ scale,
    const float* __restrict__ bias, float* __restrict__ out_f,
    bf16_t* __restrict__ out_b)
{
  int t = blockIdx.x;
  const float* xr = x + (size_t)t * D;
  float v[4];
  float s1 = 0.f, s2 = 0.f;
#pragma unroll
  for (int i = 0; i < 4; i++) {
    v[i] = xr[threadIdx.x + i * 256];
    s1 += v[i];
    s2 += v[i] * v[i];
  }
#pragma unroll
  for (int o = 1; o < 64; o <<= 1) {
    s1 += __shfl_xor(s1, o);
    s2 += __shfl_xor(s2, o);
  }
  __shared__ float r1[4], r2[4];
  int wid = threadIdx.x >> 6;
  if ((threadIdx.x & 63) == 0) { r1[wid] = s1; r2[wid] = s2; }
  __syncthreads();
  s1 = r1[0] + r1[1] + r1[2] + r1[3];
  s2 = r2[0] + r2[1] + r2[2] + r2[3];
  float mean = s1 * (1.f / D);
  float var = s2 * (1.f / D) - mean * mean;
  float rstd = rsqrtf(var + 1e-6f);
  float* orow = out_f + (size_t)t * D;
  bf16_t* brow = out_b + (size_t)t * D;
#pragma unroll
  for (int i = 0; i < 4; i++) {
    int d = threadIdx.x + i * 256;
    float o = (v[i] - mean) * rstd * scale[d] + bias[d];
    orow[d] = o;
    brow[d] = (bf16_t)o;
  }
}

// rows of length 128, one wave per row; bf16 normalized output
__global__ __launch_bounds__(64) void norm_rows_kernel(
    const float* __restrict__ e, bf16_t* __restrict__ o)
{
  int r = blockIdx.x;
  const float* row = e + (size_t)r * 128;
  float a = row[threadIdx.x], b = row[threadIdx.x + 64];
  float ss = a * a + b * b;
#pragma unroll
  for (int m = 1; m < 64; m <<= 1) ss += __shfl_xor(ss, m);
  float inv = 1.f / (sqrtf(ss) + 1e-8f);
  bf16_t* orow = o + (size_t)r * 128;
  orow[threadIdx.x] = (bf16_t)(a * inv);
  orow[threadIdx.x + 64] = (bf16_t)(b * inv);
}

// tau = n @ W + b,  W: [D, J], J in {1,3}; one wave per token (fp32)
__global__ __launch_bounds__(64) void tau_kernel(
    const float* __restrict__ n, const float* __restrict__ W,
    const float* __restrict__ b, float* __restrict__ out, int J)
{
  int t = blockIdx.x;
  const float* nr = n + (size_t)t * D;
  for (int j = 0; j < J; j++) {
    float p = 0.f;
#pragma unroll 4
    for (int i = 0; i < 16; i++) {
      int d = threadIdx.x + i * 64;
      p += nr[d] * W[d * J + j];
    }
#pragma unroll
    for (int m = 1; m < 64; m <<= 1) p += __shfl_xor(p, m);
    if (threadIdx.x == 0) out[t * J + j] = p + b[j];
  }
}

// gate body shared by single & batched variants
template <int PER>
__device__ __forceinline__ void gate_body(
    float* __restrict__ row, float tv, float* __restrict__ gb, int G)
{
  float r[PER];
  int base = threadIdx.x * PER;
  float psum = 0.f;
#pragma unroll
  for (int i = 0; i < PER; i++) {
    float s = row[base + i] - tv;
    s = fmaxf(s, 0.f);
    r[i] = s;
    psum += s;
  }
  __shared__ float red[4];
  __shared__ float grp[32];
  if (threadIdx.x < 32) grp[threadIdx.x] = 0.f;
  float w = psum;
#pragma unroll
  for (int m = 1; m < 64; m <<= 1) w += __shfl_xor(w, m);
  int wid = threadIdx.x >> 6;
  if ((threadIdx.x & 63) == 0) red[wid] = w;
  __syncthreads();
  float Stot = red[0] + red[1] + red[2] + red[3];
  atomicAdd(&grp[base >> 7], psum);
  __syncthreads();
  float inv = 1.f / (Stot + 1e-8f);
#pragma unroll
  for (int i = 0; i < PER; i++) row[base + i] = r[i] * inv;
  if (threadIdx.x < G) {
    float Gj = grp[threadIdx.x] * inv;
    float gsum = Stot * inv;
    gb[threadIdx.x] = Gj / (gsum + 1e-8f);
  }
}

template <int PER>
__global__ __launch_bounds__(256) void gate_kernel(
    float* __restrict__ g, const float* __restrict__ tau, int tauStride,
    int tauOff, float* __restrict__ gb, int N, int G)
{
  int t = blockIdx.x;
  gate_body<PER>(g + (size_t)t * N, tau[t * tauStride + tauOff],
                 gb + (size_t)t * G, G);
}

// batched: y selects {scores, tauOff=y, gb}
template <int PER>
__global__ __launch_bounds__(256) void gate3_kernel(
    float* __restrict__ s0, float* __restrict__ s1, float* __restrict__ s2,
    const float* __restrict__ tau, float* __restrict__ g0,
    float* __restrict__ g1, float* __restrict__ g2, int N, int G)
{
  int t = blockIdx.x, y = blockIdx.y;
  float* g = y == 0 ? s0 : y == 1 ? s1 : s2;
  float* gb = y == 0 ? g0 : y == 1 ? g1 : g2;
  gate_body<PER>(g + (size_t)t * N, tau[t * 3 + y], gb + (size_t)t * G, G);
}

// stage 1: partial column sums of g [T,N] over 128-row chunks
__global__ __launch_bounds__(256) void colsum_part_kernel(
    const float* __restrict__ g, int N, float* __restrict__ colsum)
{
  int c = blockIdx.x * 256 + threadIdx.x;
  int r0 = blockIdx.y * 128;
  const float* p = g + (size_t)r0 * N + c;
  float s = 0.f;
#pragma unroll 8
  for (int t = 0; t < 128; t++) s += p[(size_t)t * N];
  atomicAdd(&colsum[c], s);
}

// batched over z = 3 score buffers
__global__ __launch_bounds__(256) void colsum_part3_kernel(
    const float* __restrict__ s0, const float* __restrict__ s1,
    const float* __restrict__ s2, int N, float* __restrict__ colsum)
{
  int z = blockIdx.z;
  const float* g = z == 0 ? s0 : z == 1 ? s1 : s2;
  int c = blockIdx.x * 256 + threadIdx.x;
  int r0 = blockIdx.y * 128;
  const float* p = g + (size_t)r0 * N + c;
  float s = 0.f;
#pragma unroll 8
  for (int t = 0; t < 128; t++) s += p[(size_t)t * N];
  atomicAdd(&colsum[z * N + c], s);
}

// stage 2: aux += sum_c (colsum[c]/T - tinv)^2 * N
__global__ __launch_bounds__(256) void colsum_fin_kernel(
    const float* __restrict__ colsum, int N, float tinv,
    float* __restrict__ aux)
{
  int c = blockIdx.x * 256 + threadIdx.x;
  float mdev = colsum[c] * (1.f / T) - tinv;
  float p = mdev * mdev * (float)N;
#pragma unroll
  for (int m = 1; m < 64; m <<= 1) p += __shfl_xor(p, m);
  __shared__ float red[4];
  if ((threadIdx.x & 63) == 0) red[threadIdx.x >> 6] = p;
  __syncthreads();
  if (threadIdx.x == 0) atomicAdd(aux, red[0] + red[1] + red[2] + red[3]);
}

// h1[t,r] = sum_n gb1[t,n]*all_h[t, n*128+r] (all_h bf16); optional 2nd out
__global__ __launch_bounds__(128) void wsum2_kernel(
    const bf16_t* __restrict__ all_h, const float* __restrict__ gb1,
    const float* __restrict__ gb2, float* __restrict__ h1,
    float* __restrict__ h2, int NB)
{
  int t = blockIdx.x;
  int r = threadIdx.x;
  const bf16_t* row = all_h + (size_t)t * NB * 128;
  float a1 = 0.f, a2 = 0.f;
  for (int n = 0; n < NB; n++) {
    float v = (float)row[n * 128 + r];
    a1 += gb1[(size_t)t * NB + n] * v;
    if (gb2) a2 += gb2[(size_t)t * NB + n] * v;
  }
  h1[(size_t)t * 128 + r] = a1;
  if (h2) h2[(size_t)t * 128 + r] = a2;
}

// batched: y=0 -> allh_q with gq,gk -> hQ,hK; y=1 -> allh_v with gv -> hV
__global__ __launch_bounds__(128) void wsum2b_kernel(
    const bf16_t* __restrict__ aq, const bf16_t* __restrict__ av,
    const float* __restrict__ gq, const float* __restrict__ gk,
    const float* __restrict__ gv, float* __restrict__ hQ,
    float* __restrict__ hK, float* __restrict__ hV, int NB)
{
  int t = blockIdx.x, y = blockIdx.y;
  int r = threadIdx.x;
  const bf16_t* row = (y == 0 ? aq : av) + (size_t)t * NB * 128;
  const float* g1 = (y == 0 ? gq : gv) + (size_t)t * NB;
  const float* g2 = y == 0 ? gk + (size_t)t * NB : nullptr;
  float a1 = 0.f, a2 = 0.f;
  for (int n = 0; n < NB; n++) {
    float v = (float)row[n * 128 + r];
    a1 += g1[n] * v;
    if (g2) a2 += g2[n] * v;
  }
  if (y == 0) {
    hQ[(size_t)t * 128 + r] = a1;
    hK[(size_t)t * 128 + r] = a2;
  } else {
    hV[(size_t)t * 128 + r] = a1;
  }
}

// dst[c][r] = (bf16)src[r][c]; src [R,C] fp32, dst [C,R] bf16; batched
__global__ __launch_bounds__(256) void transpose_to_bf16_kernel(
    const float* __restrict__ src, bf16_t* __restrict__ dst,
    int R, int C, size_t sbs, size_t dbs)
{
  __shared__ float tile[32][33];
  int b = blockIdx.z;
  int c0 = blockIdx.x * 32, r0 = blockIdx.y * 32;
  int tx = threadIdx.x & 31, ty = threadIdx.x >> 5;  // 8 rows/pass
  const float* s = src + (size_t)b * sbs;
  bf16_t* d = dst + (size_t)b * dbs;
#pragma unroll
  for (int i = 0; i < 4; i++)
    tile[ty + i * 8][tx] = s[(size_t)(r0 + ty + i * 8) * C + c0 + tx];
  __syncthreads();
#pragma unroll
  for (int i = 0; i < 4; i++)
    d[(size_t)(c0 + ty + i * 8) * R + r0 + tx] = (bf16_t)tile[tx][ty + i * 8];
}

// A_virt[t,k] = (bf16)(gb[t,k>>7]*h[t,k&127]), row-major [T,K]
__device__ __forceinline__ void avirt_body(
    const float* hr, const float* gr, bf16_t* ar, int K)
{
  int noct = K >> 3;
  for (int o = threadIdx.x; o < noct; o += 256) {
    int k = o * 8;
    float g = gr[k >> 7];
    bf16x8 v;
#pragma unroll
    for (int i = 0; i < 8; i++) v[i] = (bf16_t)(hr[(k & 127) + i] * g);
    *(bf16x8*)(ar + k) = v;
  }
}

__global__ __launch_bounds__(256) void avirt_kernel(
    const float* __restrict__ h, const float* __restrict__ gb, int NB,
    bf16_t* __restrict__ A, int K)
{
  int t = blockIdx.x;
  avirt_body(h + (size_t)t * 128, gb + (size_t)t * NB, A + (size_t)t * K, K);
}

__global__ __launch_bounds__(256) void avirt3_kernel(
    const float* __restrict__ h0, const float* __restrict__ h1,
    const float* __restrict__ h2, const float* __restrict__ g0,
    const float* __restrict__ g1, const float* __restrict__ g2, int NB,
    bf16_t* __restrict__ A0, bf16_t* __restrict__ A1,
    bf16_t* __restrict__ A2, int K)
{
  int t = blockIdx.x, y = blockIdx.y;
  const float* h = y == 0 ? h0 : y == 1 ? h1 : h2;
  const float* g = y == 0 ? g0 : y == 1 ? g1 : g2;
  bf16_t* A = y == 0 ? A0 : y == 1 ? A1 : A2;
  avirt_body(h + (size_t)t * 128, g + (size_t)t * NB, A + (size_t)t * K, K);
}

// out[i] += p0[i] + p1[i]  (float4-vectorized)
__global__ __launch_bounds__(256) void combine2_kernel(
    const float* __restrict__ p0, const float* __restrict__ p1,
    float* __restrict__ out)
{
  int i = blockIdx.x * 256 + threadIdx.x;
  float4 a = ((const float4*)p0)[i];
  float4 b = ((const float4*)p1)[i];
  float4 o = ((float4*)out)[i];
  o.x += a.x + b.x;
  o.y += a.y + b.y;
  o.z += a.z + b.z;
  o.w += a.w + b.w;
  ((float4*)out)[i] = o;
}

// ============== MFMA GEMM: C[M,N] = A[M,K]bf16 @ Bt[N,K]bf16^T ==============
// 64x128 tile, BK=32, 4 waves, dbuf LDS, chunk-XOR swizzle, XCD block swizzle.
template <bool HAS_BIAS, bool HAS_RESID, int OUT_MODE>
__global__ __launch_bounds__(256) void mfma_gemm_kernel(
    const bf16_t* __restrict__ A, int lda,
    const bf16_t* __restrict__ Bt, int ldb,
    void* __restrict__ Cv, int ldc,
    const float* __restrict__ bias,
    const float* __restrict__ resid, int ldr,
    int M, int N, int K)
{
  __shared__ bf16_t As[2][64 * 32];
  __shared__ bf16_t Bs[2][128 * 32];
  int tid = threadIdx.x;
  int wave = tid >> 6, lane = tid & 63;

  unsigned lid = blockIdx.y * gridDim.x + blockIdx.x;
  unsigned nwg = gridDim.x * gridDim.y;
  unsigned swzb = lid;
  if ((nwg & 7u) == 0u) swzb = (lid & 7u) * (nwg >> 3) + (lid >> 3);
  int row0 = (int)(swzb / gridDim.x) * 64;
  int col0 = (int)(swzb % gridDim.x) * 128;

  int wr = (wave >> 1) * 32, wc = (wave & 1) * 64;
  f32x4 acc[2][4] = {};

  int srow = (wave << 4) + (lane >> 2);
  int g8 = (((lane & 3) ^ ((srow >> 1) & 3)) << 3);
  const bf16_t* gA = A + (size_t)(row0 + srow) * lda + g8;
  const bf16_t* gB = Bt + (size_t)(col0 + srow) * ldb + g8;
  size_t b64 = (size_t)64 * ldb;

  int fr = lane & 15, fq = lane >> 4;

#define GSTAGE(buf, k0s)                                  \
  {                                                       \
    GLDS16(gA + (k0s), &As[buf][wave * 512]);             \
    GLDS16(gB + (k0s), &Bs[buf][wave * 512]);             \
    GLDS16(gB + b64 + (k0s), &Bs[buf][2048 + wave * 512]);\
  }

  GSTAGE(0, 0);
  int cur = 0;
  for (int k0 = 0; k0 < K; k0 += 32) {
    __syncthreads();
    if (k0 + 32 < K) GSTAGE(cur ^ 1, k0 + 32);
    bf16x8 af[2], bfr[4];
#pragma unroll
    for (int m = 0; m < 2; m++) {
      int R = wr + m * 16 + fr;
      af[m] = *(const bf16x8*)&As[cur][R * 32 + ((fq ^ ((R >> 1) & 3)) << 3)];
    }
#pragma unroll
    for (int n = 0; n < 4; n++) {
      int R = wc + n * 16 + fr;
      bfr[n] = *(const bf16x8*)&Bs[cur][R * 32 + ((fq ^ ((R >> 1) & 3)) << 3)];
    }
#pragma unroll
    for (int m = 0; m < 2; m++)
#pragma unroll
      for (int n = 0; n < 4; n++)
        acc[m][n] = __builtin_amdgcn_mfma_f32_16x16x32_bf16(af[m], bfr[n],
                                                            acc[m][n], 0, 0, 0);
    cur ^= 1;
  }
#undef GSTAGE

#pragma unroll
  for (int m = 0; m < 2; m++) {
#pragma unroll
    for (int n = 0; n < 4; n++) {
      int rowb = row0 + wr + m * 16 + fq * 4;
      int col = col0 + wc + n * 16 + fr;
      if (OUT_MODE == 2) {
        bf16x4 v4;
#pragma unroll
        for (int r = 0; r < 4; r++) v4[r] = (bf16_t)acc[m][n][r];
        bf16_t* dst = (bf16_t*)Cv +
            ((size_t)(rowb >> 10) * 1024 + col) * 1024 + (rowb & 1023);
        *(bf16x4*)dst = v4;
      } else {
#pragma unroll
        for (int r = 0; r < 4; r++) {
          int row = rowb + r;
          float v = acc[m][n][r];
          if (HAS_BIAS) v += bias[col];
          if (HAS_RESID) v += resid[(size_t)row * ldr + col];
          if (OUT_MODE == 1)
            ((bf16_t*)Cv)[(size_t)row * ldc + col] = (bf16_t)v;
          else
            ((float*)Cv)[(size_t)row * ldc + col] = v;
        }
      }
    }
  }
}

// ============== batched MFMA GEMM: z-indexed {A, Bt, C, mode} ==============
struct ZArg { const bf16_t* A; const bf16_t* Bt; void* C; int mode; };

__global__ __launch_bounds__(256) void mfma_gemm_batched_kernel(
    ZArg za, ZArg zb, ZArg zc, int lda, int ldb, int ldc, int K)
{
  __shared__ bf16_t As[2][64 * 32];
  __shared__ bf16_t Bs[2][128 * 32];
  int tid = threadIdx.x;
  int wave = tid >> 6, lane = tid & 63;

  unsigned gx = gridDim.x;
  unsigned gxy = gridDim.x * gridDim.y;
  unsigned lid = (blockIdx.z * gridDim.y + blockIdx.y) * gx + blockIdx.x;
  unsigned nwg = gxy * gridDim.z;
  unsigned swzb = lid;
  if ((nwg & 7u) == 0u) swzb = (lid & 7u) * (nwg >> 3) + (lid >> 3);
  unsigned zi = swzb / gxy;
  unsigned rem = swzb % gxy;
  int row0 = (int)(rem / gx) * 64;
  int col0 = (int)(rem % gx) * 128;
  ZArg Z = (zi == 0) ? za : (zi == 1) ? zb : zc;

  int wr = (wave >> 1) * 32, wc = (wave & 1) * 64;
  f32x4 acc[2][4] = {};

  int srow = (wave << 4) + (lane >> 2);
  int g8 = (((lane & 3) ^ ((srow >> 1) & 3)) << 3);
  const bf16_t* gA = Z.A + (size_t)(row0 + srow) * lda + g8;
  const bf16_t* gB = Z.Bt + (size_t)(col0 + srow) * ldb + g8;
  size_t b64 = (size_t)64 * ldb;

  int fr = lane & 15, fq = lane >> 4;

#define GSTAGE(buf, k0s)                                  \
  {                                                       \
    GLDS16(gA + (k0s), &As[buf][wave * 512]);             \
    GLDS16(gB + (k0s), &Bs[buf][wave * 512]);             \
    GLDS16(gB + b64 + (k0s), &Bs[buf][2048 + wave * 512]);\
  }

  GSTAGE(0, 0);
  int cur = 0;
  for (int k0 = 0; k0 < K; k0 += 32) {
    __syncthreads();
    if (k0 + 32 < K) GSTAGE(cur ^ 1, k0 + 32);
    bf16x8 af[2], bfr[4];
#pragma unroll
    for (int m = 0; m < 2; m++) {
      int R = wr + m * 16 + fr;
      af[m] = *(const bf16x8*)&As[cur][R * 32 + ((fq ^ ((R >> 1) & 3)) << 3)];
    }
#pragma unroll
    for (int n = 0; n < 4; n++) {
      int R = wc + n * 16 + fr;
      bfr[n] = *(const bf16x8*)&Bs[cur][R * 32 + ((fq ^ ((R >> 1) & 3)) << 3)];
    }
#pragma unroll
    for (int m = 0; m < 2; m++)
#pragma unroll
      for (int n = 0; n < 4; n++)
        acc[m][n] = __builtin_amdgcn_mfma_f32_16x16x32_bf16(af[m], bfr[n],
                                                            acc[m][n], 0, 0, 0);
    cur ^= 1;
  }
#undef GSTAGE

#pragma unroll
  for (int m = 0; m < 2; m++) {
#pragma unroll
    for (int n = 0; n < 4; n++) {
      int rowb = row0 + wr + m * 16 + fq * 4;
      int col = col0 + wc + n * 16 + fr;
      if (Z.mode == 2) {
        bf16x4 v4;
#pragma unroll
        for (int r = 0; r < 4; r++) v4[r] = (bf16_t)acc[m][n][r];
        bf16_t* dst = (bf16_t*)Z.C +
            ((size_t)(rowb >> 10) * 1024 + col) * 1024 + (rowb & 1023);
        *(bf16x4*)dst = v4;
      } else if (Z.mode == 1) {
#pragma unroll
        for (int r = 0; r < 4; r++)
          ((bf16_t*)Z.C)[(size_t)(rowb + r) * ldc + col] =
              (bf16_t)acc[m][n][r];
      } else {
#pragma unroll
        for (int r = 0; r < 4; r++)
          ((float*)Z.C)[(size_t)(rowb + r) * ldc + col] = acc[m][n][r];
      }
    }
  }
}

// ======================= MFMA flash attention (bf16, LDS-staged) ============
// 8 waves (512 thr), causal-pair balancing.
__global__ __launch_bounds__(512) void flash_mfma_kernel(
    const bf16_t* __restrict__ Q, const bf16_t* __restrict__ K,
    const bf16_t* __restrict__ Vt, bf16_t* __restrict__ O)
{
  __shared__ bf16_t Ks[2][64 * 64];
  __shared__ bf16_t Vs[2][64 * 64];
  __shared__ bf16_t Pl[8][32 * 64];

  int tid = threadIdx.x;
  int wave = tid >> 6, lane = tid & 63;
  int fr = lane & 15, fq = lane >> 4;
  unsigned lid = blockIdx.x + blockIdx.y * 4 + blockIdx.z * 64;  // 256 wgs
  unsigned swz8 = (lid & 7u) * 32 + (lid >> 3);
  int s_slot = swz8 & 3;
  unsigned hb = swz8 >> 2;
  int h = hb & 15, b = hb >> 4;
  int half = wave >> 2, w4 = wave & 3;
  int qb = half ? (7 - s_slot) : s_slot;
  int q0w = qb * 128 + w4 * 32;
  int KT = 16 - 2 * s_slot;
  size_t qkbase = ((size_t)b * 1024) * 1024 + (size_t)h * 64;
  size_t vtbase = ((size_t)b * 1024 + (size_t)h * 64) * 1024;

  int srow8 = lane >> 3;
  int scb = (((lane & 7) << 4) ^ (srow8 << 4)) >> 1;

#define FSTAGE(buf, kt)                                                     \
  {                                                                         \
    int k0s = (kt) * 64;                                                    \
    int row = wave * 8 + srow8;                                             \
    GLDS16(&K[qkbase + (size_t)(k0s + row) * 1024 + scb],                   \
           &Ks[buf][wave * 512]);                                           \
    GLDS16(&Vt[vtbase + (size_t)row * 1024 + k0s + scb],                    \
           &Vs[buf][wave * 512]);                                           \
  }

  bf16x8 qf[2][2];
#pragma unroll
  for (int g = 0; g < 2; g++)
#pragma unroll
    for (int kh = 0; kh < 2; kh++)
      qf[g][kh] = *(const bf16x8*)&Q[qkbase +
                                     (size_t)(q0w + g * 16 + fr) * 1024 +
                                     kh * 32 + fq * 8];

  f32x4 o_acc[2][4] = {};
  float mrow[2][4], lrow[2][4];
#pragma unroll
  for (int g = 0; g < 2; g++)
#pragma unroll
    for (int r = 0; r < 4; r++) { mrow[g][r] = -INFINITY; lrow[g][r] = 0.f; }

  char* P = (char*)&Pl[wave][0];

  FSTAGE(0, 0);

  for (int kt = 0; kt < KT; kt++) {
    __syncthreads();
    if (kt + 1 < KT) FSTAGE((kt + 1) & 1, kt + 1);
    int k0 = kt * 64;
    if (k0 <= q0w + 31) {
      const char* Kb = (const char*)&Ks[kt & 1][0];
      const char* Vb = (const char*)&Vs[kt & 1][0];
      int swz = (fr & 7) << 4;
      f32x4 s[2][4] = {};
#pragma unroll
      for (int n = 0; n < 4; n++) {
        int rowo = (n * 16 + fr) * 128;
        bf16x8 kf0 = *(const bf16x8*)(Kb + rowo + ((fq * 16) ^ swz));
        bf16x8 kf1 = *(const bf16x8*)(Kb + rowo + ((64 + fq * 16) ^ swz));
#pragma unroll
        for (int g = 0; g < 2; g++) {
          s[g][n] = __builtin_amdgcn_mfma_f32_16x16x32_bf16(qf[g][0], kf0,
                                                            s[g][n], 0, 0, 0);
          s[g][n] = __builtin_amdgcn_mfma_f32_16x16x32_bf16(qf[g][1], kf1,
                                                            s[g][n], 0, 0, 0);
        }
      }
      const float scale = 0.125f;
#pragma unroll
      for (int g = 0; g < 2; g++) {
        bool dm = (k0 + 63 > q0w + g * 16);
#pragma unroll
        for (int n = 0; n < 4; n++)
#pragma unroll
          for (int r = 0; r < 4; r++) {
            float v = s[g][n][r] * scale;
            if (dm && (k0 + n * 16 + fr > q0w + g * 16 + fq * 4 + r))
              v = -INFINITY;
            s[g][n][r] = v;
          }
      }
      float corr[2][4];
#pragma unroll
      for (int g = 0; g < 2; g++)
#pragma unroll
        for (int r = 0; r < 4; r++) {
          float mx = fmaxf(fmaxf(s[g][0][r], s[g][1][r]),
                           fmaxf(s[g][2][r], s[g][3][r]));
#pragma unroll
          for (int msk = 1; msk < 16; msk <<= 1)
            mx = fmaxf(mx, __shfl_xor(mx, msk));
          float mnew = fmaxf(mrow[g][r], mx);
          corr[g][r] = __expf(mrow[g][r] - mnew);
          mrow[g][r] = mnew;
          float ps = 0.f;
#pragma unroll
          for (int n = 0; n < 4; n++) {
            float p = __expf(s[g][n][r] - mnew);
            s[g][n][r] = p;
            ps += p;
          }
#pragma unroll
          for (int msk = 1; msk < 16; msk <<= 1) ps += __shfl_xor(ps, msk);
          lrow[g][r] = lrow[g][r] * corr[g][r] + ps;
        }
#pragma unroll
      for (int g = 0; g < 2; g++)
#pragma unroll
        for (int n = 0; n < 4; n++)
#pragma unroll
          for (int r = 0; r < 4; r++) {
            int q = g * 16 + fq * 4 + r;
            int cb = ((n * 16 + fr) * 2) ^ ((q & 7) << 4);
            *(bf16_t*)(P + q * 128 + cb) = (bf16_t)s[g][n][r];
          }
      int rr = fr & 3;
      int srcl = (fr >> 2) << 4;
#pragma unroll
      for (int g = 0; g < 2; g++) {
        float c0 = __shfl(corr[g][0], srcl);
        float c1 = __shfl(corr[g][1], srcl);
        float c2 = __shfl(corr[g][2], srcl);
        float c3 = __shfl(corr[g][3], srcl);
        float cq = rr == 0 ? c0 : rr == 1 ? c1 : rr == 2 ? c2 : c3;
#pragma unroll
        for (int n = 0; n < 4; n++)
#pragma unroll
          for (int r = 0; r < 4; r++) o_acc[g][n][r] *= cq;
      }
#pragma unroll
      for (int c = 0; c < 2; c++) {
        bf16x8 pf[2];
#pragma unroll
        for (int g = 0; g < 2; g++)
          pf[g] = *(const bf16x8*)(P + (g * 16 + fr) * 128 +
                                   ((c * 64 + fq * 16) ^ swz));
#pragma unroll
        for (int n = 0; n < 4; n++) {
          bf16x8 vf = *(const bf16x8*)(Vb + (n * 16 + fr) * 128 +
                                       ((c * 64 + fq * 16) ^ swz));
#pragma unroll
          for (int g = 0; g < 2; g++)
            o_acc[g][n] = __builtin_amdgcn_mfma_f32_16x16x32_bf16(
                vf, pf[g], o_acc[g][n], 0, 0, 0);
        }
      }
    }
  }
  int rr = fr & 3;
  int srcl = (fr >> 2) << 4;
#pragma unroll
  for (int g = 0; g < 2; g++) {
    float l0 = __shfl(lrow[g][0], srcl);
    float l1 = __shfl(lrow[g][1], srcl);
    float l2 = __shfl(lrow[g][2], srcl);
    float l3 = __shfl(lrow[g][3], srcl);
    float lq = rr == 0 ? l0 : rr == 1 ? l1 : rr == 2 ? l2 : l3;
    float linv = 1.f / lq;
    size_t orow = qkbase + (size_t)(q0w + g * 16 + fr) * 1024;
#pragma unroll
    for (int n = 0; n < 4; n++) {
      bf16x4 ov;
#pragma unroll
      for (int r = 0; r < 4; r++) ov[r] = (bf16_t)(o_acc[g][n][r] * linv);
      *(bf16x4*)&O[orow + n * 16 + fq * 4] = ov;
    }
  }
#undef FSTAGE
}

// ======================= launch =======================

extern "C" void kernel_launch(void* const* d_in, const int* in_sizes, int n_in,
                              void* d_out, int out_size, void* d_ws,
                              size_t ws_size, hipStream_t stream) {
  (void)in_sizes; (void)n_in; (void)out_size; (void)ws_size;
  const float* x          = (const float*)d_in[0];
  const float* qk_emb     = (const float*)d_in[1];
  const float* v_emb      = (const float*)d_in[2];
  const float* know_emb   = (const float*)d_in[3];
  const float* qk_f       = (const float*)d_in[4];
  const float* qk_r       = (const float*)d_in[5];
  const float* v_f        = (const float*)d_in[6];
  const float* v_r        = (const float*)d_in[7];
  const float* know_f     = (const float*)d_in[8];
  const float* know_r     = (const float*)d_in[9];
  const float* proj_attn_k = (const float*)d_in[10];
  const float* proj_attn_b = (const float*)d_in[11];
  const float* tau_attn_k  = (const float*)d_in[12];
  const float* tau_attn_b  = (const float*)d_in[13];
  const float* proj_know_k = (const float*)d_in[14];
  const float* proj_know_b = (const float*)d_in[15];
  const float* tau_know_k  = (const float*)d_in[16];
  const float* tau_know_b  = (const float*)d_in[17];
  const float* expand_O    = (const float*)d_in[18];
  const float* ln1_scale   = (const float*)d_in[19];
  const float* ln1_bias    = (const float*)d_in[20];
  const float* ln2_scale   = (const float*)d_in[21];
  const float* ln2_bias    = (const float*)d_in[22];

  float* out = (float*)d_out;  // [T,D] + aux scalar
  float* aux = out + (size_t)T * D;

  // ---- workspace arena ----
  float* ws = (float*)d_ws;
  float* n_f   = ws;                       // 4M floats
  float* tau3  = n_f + 4194304;            // 16K
  float* gq_b  = tau3 + 16384;             // 64K
  float* gk_b  = gq_b + 65536;
  float* gv_b  = gk_b + 65536;
  float* gkn_b = gv_b + 65536;             // 128K
  float* csum  = gkn_b + 131072;           // 8192 (colsum acc, 3x2048 / 4096)
  float* hQ    = csum + 8192;              // 512K
  float* hK    = hQ + 524288;
  float* hV    = hK + 524288;
  float* qkvarena = hV + 524288;           // 12.58M floats
  float* buf_big = qkvarena + 12582912;    // 16.78M floats (67MB)

  bf16_t* Qbb = (bf16_t*)qkvarena;                 // T*1024 bf16 (8MB)
  bf16_t* Kbb = Qbb + (size_t)T * 1024;
  bf16_t* Vtb = Kbb + (size_t)T * 1024;            // [4][1024][1024]

  bf16_t* nb   = (bf16_t*)(buf_big + 16777216);  // T*1024
  bf16_t* hab  = nb + 4194304;                   // T*384 (know: T*128)
  bf16_t* embB = hab + 1572864;                  // 524288
  bf16_t* B2t  = embB + 524288;                  // 4096*1024
  bf16_t* wt   = B2t + 4194304;
  bf16_t* pa_t  = wt;                   // 384*1024
  bf16_t* qkr_t = pa_t + 393216;        // 1024*2048
  bf16_t* vr_t  = qkr_t + 2097152;      // 1024*2048
  bf16_t* knr_t = vr_t + 2097152;       // 1024*4096
  bf16_t* eo_t  = knr_t + 4194304;      // 1024*1024
  bf16_t* pk_t  = eo_t + 1048576;       // 128*1024
  bf16_t* B2t2  = pk_t + 131072;        // 4096*1024 (second feature B)

  // buf_big overlays (lifetimes checked):
  float* s_q = buf_big;                             // T*2048 f32 (0..33.5MB)
  float* s_k = buf_big + 8388608;                   // T*2048 f32 (33.5..67MB)
  float* s_v = (float*)qkvarena;                    // T*2048 f32 (restores later)
  bf16_t* allh_q = (bf16_t*)buf_big;                // T*2048 bf16 (0..16MB)
  bf16_t* allh_v = allh_q + (size_t)T * 2048;       // 16..32MB
  bf16_t* avbQ = (bf16_t*)buf_big;                  // [T,2048] bf16, 16MB
  bf16_t* avbK = avbQ + (size_t)T * 2048;
  bf16_t* avbV = avbK + (size_t)T * 2048;           // 32..48MB
  bf16_t* avbN = (bf16_t*)buf_big;                  // knowledge [T,4096] bf16
  bf16_t* allh_n = (bf16_t*)buf_big;                // knowledge all_h bf16
  float* kp0 = buf_big + 8388608;                   // 33.5..50MB f32 partial
  float* kp1 = kp0 + 4194304;                       // 50..67MB f32 partial
  bf16_t* attnb_b = (bf16_t*)(buf_big + 12582912);  // T*1024 bf16 (50..58MB)

  bf16_t* embQ = embB;
  bf16_t* embV = embB + 262144;

  dim3 blk(256);

  zero1_kernel<<<1, 1, 0, stream>>>(aux);

  // weight + feature-basis transposes to bf16 [N,K]
  transpose_to_bf16_kernel<<<dim3(12, 32, 1), blk, 0, stream>>>(
      proj_attn_k, pa_t, 1024, 384, 0, 0);
  transpose_to_bf16_kernel<<<dim3(32, 64, 1), blk, 0, stream>>>(
      qk_r, qkr_t, 2048, 1024, 0, 0);
  transpose_to_bf16_kernel<<<dim3(32, 64, 1), blk, 0, stream>>>(
      v_r, vr_t, 2048, 1024, 0, 0);
  transpose_to_bf16_kernel<<<dim3(32, 128, 1), blk, 0, stream>>>(
      know_r, knr_t, 4096, 1024, 0, 0);
  transpose_to_bf16_kernel<<<dim3(32, 32, 1), blk, 0, stream>>>(
      expand_O, eo_t, 1024, 1024, 0, 0);
  transpose_to_bf16_kernel<<<dim3(4, 32, 1), blk, 0, stream>>>(
      proj_know_k, pk_t, 1024, 128, 0, 0);
  transpose_to_bf16_kernel<<<dim3(4, 32, 16), blk, 0, stream>>>(
      qk_f, B2t, 1024, 128, 131072, 131072);
  transpose_to_bf16_kernel<<<dim3(4, 32, 16), blk, 0, stream>>>(
      v_f, B2t2, 1024, 128, 131072, 131072);

  // ---- attention circuit ----
  ln_kernel<<<T, blk, 0, stream>>>(x, ln1_scale, ln1_bias, n_f, nb);
  norm_rows_kernel<<<2048, 64, 0, stream>>>(qk_emb, embQ);
  norm_rows_kernel<<<2048, 64, 0, stream>>>(v_emb, embV);

  mfma_gemm_kernel<true, false, 1><<<dim3(3, 64), blk, 0, stream>>>(
      nb, 1024, pa_t, 1024, hab, 384, proj_attn_b, nullptr, 0, T, 384, 1024);
  tau_kernel<<<T, 64, 0, stream>>>(n_f, tau_attn_k, tau_attn_b, tau3, 3);

  // batched gate-score GEMMs (z = {q,k,v}, K=128)
  {
    ZArg zq{hab + 0, embQ, s_q, 0};
    ZArg zk{hab + 128, embQ, s_k, 0};
    ZArg zv{hab + 256, embV, s_v, 0};
    mfma_gemm_batched_kernel<<<dim3(16, 64, 3), blk, 0, stream>>>(
        zq, zk, zv, 384, 128, 2048, 128);
  }
  // batched gate + colsum + fin
  gate3_kernel<8><<<dim3(T, 3), blk, 0, stream>>>(
      s_q, s_k, s_v, tau3, gq_b, gk_b, gv_b, 2048, 16);
  hipMemsetAsync(csum, 0, 6144 * sizeof(float), stream);
  colsum_part3_kernel<<<dim3(8, 32, 3), blk, 0, stream>>>(s_q, s_k, s_v,
                                                          2048, csum);
  colsum_fin_kernel<<<24, blk, 0, stream>>>(csum, 2048, 1.f / 2048.f, aux);

  // batched feature GEMMs (z = {qk,v}, K=1024) -> bf16 all_h
  {
    ZArg zf1{nb, B2t, allh_q, 1};
    ZArg zf2{nb, B2t2, allh_v, 1};
    mfma_gemm_batched_kernel<<<dim3(16, 64, 2), blk, 0, stream>>>(
        zf1, zf2, zf1, 1024, 1024, 2048, 1024);
  }
  wsum2b_kernel<<<dim3(T, 2), 128, 0, stream>>>(allh_q, allh_v, gq_b, gk_b,
                                                gv_b, hQ, hK, hV, 16);

  // batched avirt + batched QKV restore
  avirt3_kernel<<<dim3(T, 3), blk, 0, stream>>>(hQ, hK, hV, gq_b, gk_b, gv_b,
                                                16, avbQ, avbK, avbV, 2048);
  {
    ZArg zq{avbQ, qkr_t, Qbb, 1};
    ZArg zk{avbK, qkr_t, Kbb, 1};
    ZArg zv{avbV, vr_t, Vtb, 2};
    mfma_gemm_batched_kernel<<<dim3(8, 64, 3), blk, 0, stream>>>(
        zq, zk, zv, 2048, 2048, 1024, 2048);
  }

  // MFMA flash attention (causal-paired, 512 thr) + output proj + residual
  flash_mfma_kernel<<<dim3(4, 16, 4), dim3(512), 0, stream>>>(Qbb, Kbb, Vtb,
                                                              attnb_b);
  mfma_gemm_kernel<false, true, 0><<<dim3(8, 64), blk, 0, stream>>>(
      attnb_b, 1024, eo_t, 1024, out, 1024, nullptr, x, 1024, T, 1024, 1024);

  // ---- knowledge circuit ----
  ln_kernel<<<T, blk, 0, stream>>>(out, ln2_scale, ln2_bias, n_f, nb);
  norm_rows_kernel<<<4096, 64, 0, stream>>>(know_emb, embB);
  mfma_gemm_kernel<true, false, 1><<<dim3(1, 64), blk, 0, stream>>>(
      nb, 1024, pk_t, 1024, hab, 128, proj_know_b, nullptr, 0, T, 128, 1024);
  tau_kernel<<<T, 64, 0, stream>>>(n_f, tau_know_k, tau_know_b, tau3, 1);

  mfma_gemm_kernel<false, false, 0><<<dim3(32, 64), blk, 0, stream>>>(
      hab, 128, embB, 128, buf_big, 4096, nullptr, nullptr, 0, T, 4096, 128);
  gate_kernel<16><<<T, blk, 0, stream>>>(buf_big, tau3, 1, 0, gkn_b, 4096, 32);
  hipMemsetAsync(csum, 0, 4096 * sizeof(float), stream);
  colsum_part_kernel<<<dim3(16, 32), blk, 0, stream>>>(buf_big, 4096, csum);
  colsum_fin_kernel<<<16, blk, 0, stream>>>(csum, 4096, 1.f / 4096.f, aux);

  transpose_to_bf16_kernel<<<dim3(4, 32, 32), blk, 0, stream>>>(
      know_f, B2t, 1024, 128, 131072, 131072);
  mfma_gemm_kernel<false, false, 1><<<dim3(32, 64), blk, 0, stream>>>(
      nb, 1024, B2t, 1024, allh_n, 4096, nullptr, nullptr, 0, T, 4096, 1024);
  wsum2_kernel<<<T, 128, 0, stream>>>(allh_n, gkn_b, nullptr, hQ, nullptr, 32);

  // knowledge restore: split-K=2 -> f32 partials + combine
  avirt_kernel<<<T, blk, 0, stream>>>(hQ, gkn_b, 32, avbN, 4096);
  {
    ZArg z0{avbN, knr_t, kp0, 0};
    ZArg z1{avbN + 2048, knr_t + 2048, kp1, 0};
    mfma_gemm_batched_kernel<<<dim3(8, 64, 2), blk, 0, stream>>>(
        z0, z1, z0, 4096, 4096, 1024, 2048);
  }
  combine2_kernel<<<4096, blk, 0, stream>>>(kp0, kp1, out);
}

// Round 12
// 589.306 us; speedup vs baseline: 6.6500x; 1.0660x over previous
//
#include <hip/hip_runtime.h>
#include <math.h>

static constexpr int T = 4096;   // B*S
static constexpr int D = 1024;

typedef __bf16 bf16_t;
typedef bf16_t bf16x8 __attribute__((ext_vector_type(8)));
typedef bf16_t bf16x4 __attribute__((ext_vector_type(4)));
typedef float f32x4 __attribute__((ext_vector_type(4)));

#define GLDS16(g, l)                                                        \
  __builtin_amdgcn_global_load_lds(                                         \
      (const __attribute__((address_space(1))) void*)(g),                   \
      (__attribute__((address_space(3))) void*)(l), 16, 0, 0)

// ======================= small kernels =======================

__global__ void zero1_kernel(float* p) { *p = 0.f; }

__global__ __launch_bounds__(256) void ln_kernel(
    const float* __restrict__ x, const float* __restrict__ scale,
    const float* __restrict__ bias, float* __restrict__ out_f,
    bf16_t* __restrict__ out_b)
{
  int t = blockIdx.x;
  const float* xr = x + (size_t)t * D;
  float v[4];
  float s1 = 0.f, s2 = 0.f;
#pragma unroll
  for (int i = 0; i < 4; i++) {
    v[i] = xr[threadIdx.x + i * 256];
    s1 += v[i];
    s2 += v[i] * v[i];
  }
#pragma unroll
  for (int o = 1; o < 64; o <<= 1) {
    s1 += __shfl_xor(s1, o);
    s2 += __shfl_xor(s2, o);
  }
  __shared__ float r1[4], r2[4];
  int wid = threadIdx.x >> 6;
  if ((threadIdx.x & 63) == 0) { r1[wid] = s1; r2[wid] = s2; }
  __syncthreads();
  s1 = r1[0] + r1[1] + r1[2] + r1[3];
  s2 = r2[0] + r2[1] + r2[2] + r2[3];
  float mean = s1 * (1.f / D);
  float var = s2 * (1.f / D) - mean * mean;
  float rstd = rsqrtf(var + 1e-6f);
  float* orow = out_f + (size_t)t * D;
  bf16_t* brow = out_b + (size_t)t * D;
#pragma unroll
  for (int i = 0; i < 4; i++) {
    int d = threadIdx.x + i * 256;
    float o = (v[i] - mean) * rstd * scale[d] + bias[d];
    orow[d] = o;
    brow[d] = (bf16_t)o;
  }
}

// rows of length 128, one wave per row; bf16 normalized output
__global__ __launch_bounds__(64) void norm_rows_kernel(
    const float* __restrict__ e, bf16_t* __restrict__ o)
{
  int r = blockIdx.x;
  const float* row = e + (size_t)r * 128;
  float a = row[threadIdx.x], b = row[threadIdx.x + 64];
  float ss = a * a + b * b;
#pragma unroll
  for (int m = 1; m < 64; m <<= 1) ss += __shfl_xor(ss, m);
  float inv = 1.f / (sqrtf(ss) + 1e-8f);
  bf16_t* orow = o + (size_t)r * 128;
  orow[threadIdx.x] = (bf16_t)(a * inv);
  orow[threadIdx.x + 64] = (bf16_t)(b * inv);
}

// tau = n @ W + b,  W: [D, J], J in {1,3}; one wave per token (fp32)
__global__ __launch_bounds__(64) void tau_kernel(
    const float* __restrict__ n, const float* __restrict__ W,
    const float* __restrict__ b, float* __restrict__ out, int J)
{
  int t = blockIdx.x;
  const float* nr = n + (size_t)t * D;
  for (int j = 0; j < J; j++) {
    float p = 0.f;
#pragma unroll 4
    for (int i = 0; i < 16; i++) {
      int d = threadIdx.x + i * 64;
      p += nr[d] * W[d * J + j];
    }
#pragma unroll
    for (int m = 1; m < 64; m <<= 1) p += __shfl_xor(p, m);
    if (threadIdx.x == 0) out[t * J + j] = p + b[j];
  }
}

// gate body shared by single & batched variants
template <int PER>
__device__ __forceinline__ void gate_body(
    float* __restrict__ row, float tv, float* __restrict__ gb, int G)
{
  float r[PER];
  int base = threadIdx.x * PER;
  float psum = 0.f;
#pragma unroll
  for (int i = 0; i < PER; i++) {
    float s = row[base + i] - tv;
    s = fmaxf(s, 0.f);
    r[i] = s;
    psum += s;
  }
  __shared__ float red[4];
  __shared__ float grp[32];
  if (threadIdx.x < 32) grp[threadIdx.x] = 0.f;
  float w = psum;
#pragma unroll
  for (int m = 1; m < 64; m <<= 1) w += __shfl_xor(w, m);
  int wid = threadIdx.x >> 6;
  if ((threadIdx.x & 63) == 0) red[wid] = w;
  __syncthreads();
  float Stot = red[0] + red[1] + red[2] + red[3];
  atomicAdd(&grp[base >> 7], psum);
  __syncthreads();
  float inv = 1.f / (Stot + 1e-8f);
#pragma unroll
  for (int i = 0; i < PER; i++) row[base + i] = r[i] * inv;
  if (threadIdx.x < G) {
    float Gj = grp[threadIdx.x] * inv;
    float gsum = Stot * inv;
    gb[threadIdx.x] = Gj / (gsum + 1e-8f);
  }
}

template <int PER>
__global__ __launch_bounds__(256) void gate_kernel(
    float* __restrict__ g, const float* __restrict__ tau, int tauStride,
    int tauOff, float* __restrict__ gb, int N, int G)
{
  int t = blockIdx.x;
  gate_body<PER>(g + (size_t)t * N, tau[t * tauStride + tauOff],
                 gb + (size_t)t * G, G);
}

template <int PER>
__global__ __launch_bounds__(256) void gate3_kernel(
    float* __restrict__ s0, float* __restrict__ s1, float* __restrict__ s2,
    const float* __restrict__ tau, float* __restrict__ g0,
    float* __restrict__ g1, float* __restrict__ g2, int N, int G)
{
  int t = blockIdx.x, y = blockIdx.y;
  float* g = y == 0 ? s0 : y == 1 ? s1 : s2;
  float* gb = y == 0 ? g0 : y == 1 ? g1 : g2;
  gate_body<PER>(g + (size_t)t * N, tau[t * 3 + y], gb + (size_t)t * G, G);
}

// stage 1: partial column sums of g [T,N] over 128-row chunks
__global__ __launch_bounds__(256) void colsum_part_kernel(
    const float* __restrict__ g, int N, float* __restrict__ colsum)
{
  int c = blockIdx.x * 256 + threadIdx.x;
  int r0 = blockIdx.y * 128;
  const float* p = g + (size_t)r0 * N + c;
  float s = 0.f;
#pragma unroll 8
  for (int t = 0; t < 128; t++) s += p[(size_t)t * N];
  atomicAdd(&colsum[c], s);
}

__global__ __launch_bounds__(256) void colsum_part3_kernel(
    const float* __restrict__ s0, const float* __restrict__ s1,
    const float* __restrict__ s2, int N, float* __restrict__ colsum)
{
  int z = blockIdx.z;
  const float* g = z == 0 ? s0 : z == 1 ? s1 : s2;
  int c = blockIdx.x * 256 + threadIdx.x;
  int r0 = blockIdx.y * 128;
  const float* p = g + (size_t)r0 * N + c;
  float s = 0.f;
#pragma unroll 8
  for (int t = 0; t < 128; t++) s += p[(size_t)t * N];
  atomicAdd(&colsum[z * N + c], s);
}

// stage 2: aux += sum_c (colsum[c]/T - tinv)^2 * N
__global__ __launch_bounds__(256) void colsum_fin_kernel(
    const float* __restrict__ colsum, int N, float tinv,
    float* __restrict__ aux)
{
  int c = blockIdx.x * 256 + threadIdx.x;
  float mdev = colsum[c] * (1.f / T) - tinv;
  float p = mdev * mdev * (float)N;
#pragma unroll
  for (int m = 1; m < 64; m <<= 1) p += __shfl_xor(p, m);
  __shared__ float red[4];
  if ((threadIdx.x & 63) == 0) red[threadIdx.x >> 6] = p;
  __syncthreads();
  if (threadIdx.x == 0) atomicAdd(aux, red[0] + red[1] + red[2] + red[3]);
}

// h1[t,r] = sum_n gb1[t,n]*all_h[t, n*128+r] (all_h bf16); optional 2nd out
__global__ __launch_bounds__(128) void wsum2_kernel(
    const bf16_t* __restrict__ all_h, const float* __restrict__ gb1,
    const float* __restrict__ gb2, float* __restrict__ h1,
    float* __restrict__ h2, int NB)
{
  int t = blockIdx.x;
  int r = threadIdx.x;
  const bf16_t* row = all_h + (size_t)t * NB * 128;
  float a1 = 0.f, a2 = 0.f;
  for (int n = 0; n < NB; n++) {
    float v = (float)row[n * 128 + r];
    a1 += gb1[(size_t)t * NB + n] * v;
    if (gb2) a2 += gb2[(size_t)t * NB + n] * v;
  }
  h1[(size_t)t * 128 + r] = a1;
  if (h2) h2[(size_t)t * 128 + r] = a2;
}

__global__ __launch_bounds__(128) void wsum2b_kernel(
    const bf16_t* __restrict__ aq, const bf16_t* __restrict__ av,
    const float* __restrict__ gq, const float* __restrict__ gk,
    const float* __restrict__ gv, float* __restrict__ hQ,
    float* __restrict__ hK, float* __restrict__ hV, int NB)
{
  int t = blockIdx.x, y = blockIdx.y;
  int r = threadIdx.x;
  const bf16_t* row = (y == 0 ? aq : av) + (size_t)t * NB * 128;
  const float* g1 = (y == 0 ? gq : gv) + (size_t)t * NB;
  const float* g2 = y == 0 ? gk + (size_t)t * NB : nullptr;
  float a1 = 0.f, a2 = 0.f;
  for (int n = 0; n < NB; n++) {
    float v = (float)row[n * 128 + r];
    a1 += g1[n] * v;
    if (g2) a2 += g2[n] * v;
  }
  if (y == 0) {
    hQ[(size_t)t * 128 + r] = a1;
    hK[(size_t)t * 128 + r] = a2;
  } else {
    hV[(size_t)t * 128 + r] = a1;
  }
}

// dst[c][r] = (bf16)src[r][c]; src [R,C] fp32, dst [C,R] bf16; batched
__global__ __launch_bounds__(256) void transpose_to_bf16_kernel(
    const float* __restrict__ src, bf16_t* __restrict__ dst,
    int R, int C, size_t sbs, size_t dbs)
{
  __shared__ float tile[32][33];
  int b = blockIdx.z;
  int c0 = blockIdx.x * 32, r0 = blockIdx.y * 32;
  int tx = threadIdx.x & 31, ty = threadIdx.x >> 5;
  const float* s = src + (size_t)b * sbs;
  bf16_t* d = dst + (size_t)b * dbs;
#pragma unroll
  for (int i = 0; i < 4; i++)
    tile[ty + i * 8][tx] = s[(size_t)(r0 + ty + i * 8) * C + c0 + tx];
  __syncthreads();
#pragma unroll
  for (int i = 0; i < 4; i++)
    d[(size_t)(c0 + ty + i * 8) * R + r0 + tx] = (bf16_t)tile[tx][ty + i * 8];
}

// A_virt[t,k] = (bf16)(gb[t,k>>7]*h[t,k&127]), row-major [T,K]
__device__ __forceinline__ void avirt_body(
    const float* hr, const float* gr, bf16_t* ar, int K)
{
  int noct = K >> 3;
  for (int o = threadIdx.x; o < noct; o += 256) {
    int k = o * 8;
    float g = gr[k >> 7];
    bf16x8 v;
#pragma unroll
    for (int i = 0; i < 8; i++) v[i] = (bf16_t)(hr[(k & 127) + i] * g);
    *(bf16x8*)(ar + k) = v;
  }
}

__global__ __launch_bounds__(256) void avirt_kernel(
    const float* __restrict__ h, const float* __restrict__ gb, int NB,
    bf16_t* __restrict__ A, int K)
{
  int t = blockIdx.x;
  avirt_body(h + (size_t)t * 128, gb + (size_t)t * NB, A + (size_t)t * K, K);
}

__global__ __launch_bounds__(256) void avirt3_kernel(
    const float* __restrict__ h0, const float* __restrict__ h1,
    const float* __restrict__ h2, const float* __restrict__ g0,
    const float* __restrict__ g1, const float* __restrict__ g2, int NB,
    bf16_t* __restrict__ A0, bf16_t* __restrict__ A1,
    bf16_t* __restrict__ A2, int K)
{
  int t = blockIdx.x, y = blockIdx.y;
  const float* h = y == 0 ? h0 : y == 1 ? h1 : h2;
  const float* g = y == 0 ? g0 : y == 1 ? g1 : g2;
  bf16_t* A = y == 0 ? A0 : y == 1 ? A1 : A2;
  avirt_body(h + (size_t)t * 128, g + (size_t)t * NB, A + (size_t)t * K, K);
}

// out[i] += p0[i] + p1[i]
__global__ __launch_bounds__(256) void combine2_kernel(
    const float* __restrict__ p0, const float* __restrict__ p1,
    float* __restrict__ out)
{
  int i = blockIdx.x * 256 + threadIdx.x;
  float4 a = ((const float4*)p0)[i];
  float4 b = ((const float4*)p1)[i];
  float4 o = ((float4*)out)[i];
  o.x += a.x + b.x;
  o.y += a.y + b.y;
  o.z += a.z + b.z;
  o.w += a.w + b.w;
  ((float4*)out)[i] = o;
}

// ======== epilogue helper (shared by all GEMM variants) ========
template <bool HAS_BIAS, bool HAS_RESID>
__device__ __forceinline__ void gemm_store(
    int mode, void* Cv, int ldc, const float* bias, const float* resid,
    int ldr, int rowb, int col, const f32x4& a)
{
  if (mode == 2) {
    bf16x4 v4;
#pragma unroll
    for (int r = 0; r < 4; r++) v4[r] = (bf16_t)a[r];
    bf16_t* dst = (bf16_t*)Cv +
        ((size_t)(rowb >> 10) * 1024 + col) * 1024 + (rowb & 1023);
    *(bf16x4*)dst = v4;
  } else {
#pragma unroll
    for (int r = 0; r < 4; r++) {
      int row = rowb + r;
      float v = a[r];
      if (HAS_BIAS) v += bias[col];
      if (HAS_RESID) v += resid[(size_t)row * ldr + col];
      if (mode == 1)
        ((bf16_t*)Cv)[(size_t)row * ldc + col] = (bf16_t)v;
      else
        ((float*)Cv)[(size_t)row * ldc + col] = v;
    }
  }
}

// ============== MFMA GEMM (64x128 tile) — narrow-N dispatches ==============
template <bool HAS_BIAS, bool HAS_RESID, int OUT_MODE>
__global__ __launch_bounds__(256) void mfma_gemm_kernel(
    const bf16_t* __restrict__ A, int lda,
    const bf16_t* __restrict__ Bt, int ldb,
    void* __restrict__ Cv, int ldc,
    const float* __restrict__ bias,
    const float* __restrict__ resid, int ldr,
    int M, int N, int K)
{
  __shared__ bf16_t As[2][64 * 32];
  __shared__ bf16_t Bs[2][128 * 32];
  int tid = threadIdx.x;
  int wave = tid >> 6, lane = tid & 63;

  unsigned lid = blockIdx.y * gridDim.x + blockIdx.x;
  unsigned nwg = gridDim.x * gridDim.y;
  unsigned swzb = lid;
  if ((nwg & 7u) == 0u) swzb = (lid & 7u) * (nwg >> 3) + (lid >> 3);
  int row0 = (int)(swzb / gridDim.x) * 64;
  int col0 = (int)(swzb % gridDim.x) * 128;

  int wr = (wave >> 1) * 32, wc = (wave & 1) * 64;
  f32x4 acc[2][4] = {};

  int srow = (wave << 4) + (lane >> 2);
  int g8 = (((lane & 3) ^ ((srow >> 1) & 3)) << 3);
  const bf16_t* gA = A + (size_t)(row0 + srow) * lda + g8;
  const bf16_t* gB = Bt + (size_t)(col0 + srow) * ldb + g8;
  size_t b64 = (size_t)64 * ldb;

  int fr = lane & 15, fq = lane >> 4;

#define GSTAGE(buf, k0s)                                  \
  {                                                       \
    GLDS16(gA + (k0s), &As[buf][wave * 512]);             \
    GLDS16(gB + (k0s), &Bs[buf][wave * 512]);             \
    GLDS16(gB + b64 + (k0s), &Bs[buf][2048 + wave * 512]);\
  }

  GSTAGE(0, 0);
  int cur = 0;
  for (int k0 = 0; k0 < K; k0 += 32) {
    __syncthreads();
    if (k0 + 32 < K) GSTAGE(cur ^ 1, k0 + 32);
    bf16x8 af[2], bfr[4];
#pragma unroll
    for (int m = 0; m < 2; m++) {
      int R = wr + m * 16 + fr;
      af[m] = *(const bf16x8*)&As[cur][R * 32 + ((fq ^ ((R >> 1) & 3)) << 3)];
    }
#pragma unroll
    for (int n = 0; n < 4; n++) {
      int R = wc + n * 16 + fr;
      bfr[n] = *(const bf16x8*)&Bs[cur][R * 32 + ((fq ^ ((R >> 1) & 3)) << 3)];
    }
#pragma unroll
    for (int m = 0; m < 2; m++)
#pragma unroll
      for (int n = 0; n < 4; n++)
        acc[m][n] = __builtin_amdgcn_mfma_f32_16x16x32_bf16(af[m], bfr[n],
                                                            acc[m][n], 0, 0, 0);
    cur ^= 1;
  }
#undef GSTAGE

#pragma unroll
  for (int m = 0; m < 2; m++)
#pragma unroll
    for (int n = 0; n < 4; n++)
      gemm_store<HAS_BIAS, HAS_RESID>(
          OUT_MODE, Cv, ldc, bias, resid, ldr,
          row0 + wr + m * 16 + fq * 4, col0 + wc + n * 16 + fr, acc[m][n]);
}

// ============== MFMA GEMM (128x128 tile) — wide dispatches ==============
// 4 waves 2x2 (64x64 each), 4x4 frags, 16 MFMA/K-step, dbuf + swizzle.
struct ZArg { const bf16_t* A; const bf16_t* Bt; void* C; int mode; };

__device__ __forceinline__ void gemm128_body(
    const bf16_t* __restrict__ A, int lda, const bf16_t* __restrict__ Bt,
    int ldb, void* __restrict__ Cv, int ldc, int mode, int row0, int col0,
    int K)
{
  __shared__ bf16_t As[2][128 * 32];
  __shared__ bf16_t Bs[2][128 * 32];
  int tid = threadIdx.x;
  int wave = tid >> 6, lane = tid & 63;
  int wr = (wave >> 1) * 64, wc = (wave & 1) * 64;
  f32x4 acc[4][4] = {};

  int srow = (wave << 4) + (lane >> 2);
  int g8 = (((lane & 3) ^ ((srow >> 1) & 3)) << 3);
  const bf16_t* gA = A + (size_t)(row0 + srow) * lda + g8;
  const bf16_t* gB = Bt + (size_t)(col0 + srow) * ldb + g8;
  size_t a64 = (size_t)64 * lda, b64 = (size_t)64 * ldb;

  int fr = lane & 15, fq = lane >> 4;

#define GSTAGE8(buf, k0s)                                  \
  {                                                        \
    GLDS16(gA + (k0s), &As[buf][wave * 512]);              \
    GLDS16(gA + a64 + (k0s), &As[buf][2048 + wave * 512]); \
    GLDS16(gB + (k0s), &Bs[buf][wave * 512]);              \
    GLDS16(gB + b64 + (k0s), &Bs[buf][2048 + wave * 512]); \
  }

  GSTAGE8(0, 0);
  int cur = 0;
  for (int k0 = 0; k0 < K; k0 += 32) {
    __syncthreads();
    if (k0 + 32 < K) GSTAGE8(cur ^ 1, k0 + 32);
    bf16x8 af[4], bfr[4];
#pragma unroll
    for (int m = 0; m < 4; m++) {
      int R = wr + m * 16 + fr;
      af[m] = *(const bf16x8*)&As[cur][R * 32 + ((fq ^ ((R >> 1) & 3)) << 3)];
    }
#pragma unroll
    for (int n = 0; n < 4; n++) {
      int R = wc + n * 16 + fr;
      bfr[n] = *(const bf16x8*)&Bs[cur][R * 32 + ((fq ^ ((R >> 1) & 3)) << 3)];
    }
#pragma unroll
    for (int m = 0; m < 4; m++)
#pragma unroll
      for (int n = 0; n < 4; n++)
        acc[m][n] = __builtin_amdgcn_mfma_f32_16x16x32_bf16(af[m], bfr[n],
                                                            acc[m][n], 0, 0, 0);
    cur ^= 1;
  }
#undef GSTAGE8

#pragma unroll
  for (int m = 0; m < 4; m++)
#pragma unroll
    for (int n = 0; n < 4; n++)
      gemm_store<false, false>(
          mode, Cv, ldc, nullptr, nullptr, 0,
          row0 + wr + m * 16 + fq * 4, col0 + wc + n * 16 + fr, acc[m][n]);
}

template <int OUT_MODE>
__global__ __launch_bounds__(256) void mfma_gemm128_kernel(
    const bf16_t* __restrict__ A, int lda,
    const bf16_t* __restrict__ Bt, int ldb,
    void* __restrict__ Cv, int ldc, int K)
{
  unsigned lid = blockIdx.y * gridDim.x + blockIdx.x;
  unsigned nwg = gridDim.x * gridDim.y;
  unsigned swzb = lid;
  if ((nwg & 7u) == 0u) swzb = (lid & 7u) * (nwg >> 3) + (lid >> 3);
  int row0 = (int)(swzb / gridDim.x) * 128;
  int col0 = (int)(swzb % gridDim.x) * 128;
  gemm128_body(A, lda, Bt, ldb, Cv, ldc, OUT_MODE, row0, col0, K);
}

__global__ __launch_bounds__(256) void mfma_gemm128b_kernel(
    ZArg za, ZArg zb, ZArg zc, int lda, int ldb, int ldc, int K)
{
  unsigned gx = gridDim.x;
  unsigned gxy = gridDim.x * gridDim.y;
  unsigned lid = (blockIdx.z * gridDim.y + blockIdx.y) * gx + blockIdx.x;
  unsigned nwg = gxy * gridDim.z;
  unsigned swzb = lid;
  if ((nwg & 7u) == 0u) swzb = (lid & 7u) * (nwg >> 3) + (lid >> 3);
  unsigned zi = swzb / gxy;
  unsigned rem = swzb % gxy;
  int row0 = (int)(rem / gx) * 128;
  int col0 = (int)(rem % gx) * 128;
  ZArg Z = (zi == 0) ? za : (zi == 1) ? zb : zc;
  gemm128_body(Z.A, lda, Z.Bt, ldb, Z.C, ldc, Z.mode, row0, col0, K);
}

// ======================= MFMA flash attention (bf16, LDS-staged) ============
// 8 waves (512 thr), causal-pair balancing.
__global__ __launch_bounds__(512) void flash_mfma_kernel(
    const bf16_t* __restrict__ Q, const bf16_t* __restrict__ K,
    const bf16_t* __restrict__ Vt, bf16_t* __restrict__ O)
{
  __shared__ bf16_t Ks[2][64 * 64];
  __shared__ bf16_t Vs[2][64 * 64];
  __shared__ bf16_t Pl[8][32 * 64];

  int tid = threadIdx.x;
  int wave = tid >> 6, lane = tid & 63;
  int fr = lane & 15, fq = lane >> 4;
  unsigned lid = blockIdx.x + blockIdx.y * 4 + blockIdx.z * 64;  // 256 wgs
  unsigned swz8 = (lid & 7u) * 32 + (lid >> 3);
  int s_slot = swz8 & 3;
  unsigned hb = swz8 >> 2;
  int h = hb & 15, b = hb >> 4;
  int half = wave >> 2, w4 = wave & 3;
  int qb = half ? (7 - s_slot) : s_slot;
  int q0w = qb * 128 + w4 * 32;
  int KT = 16 - 2 * s_slot;
  size_t qkbase = ((size_t)b * 1024) * 1024 + (size_t)h * 64;
  size_t vtbase = ((size_t)b * 1024 + (size_t)h * 64) * 1024;

  int srow8 = lane >> 3;
  int scb = (((lane & 7) << 4) ^ (srow8 << 4)) >> 1;

#define FSTAGE(buf, kt)                                                     \
  {                                                                         \
    int k0s = (kt) * 64;                                                    \
    int row = wave * 8 + srow8;                                             \
    GLDS16(&K[qkbase + (size_t)(k0s + row) * 1024 + scb],                   \
           &Ks[buf][wave * 512]);                                           \
    GLDS16(&Vt[vtbase + (size_t)row * 1024 + k0s + scb],                    \
           &Vs[buf][wave * 512]);                                           \
  }

  bf16x8 qf[2][2];
#pragma unroll
  for (int g = 0; g < 2; g++)
#pragma unroll
    for (int kh = 0; kh < 2; kh++)
      qf[g][kh] = *(const bf16x8*)&Q[qkbase +
                                     (size_t)(q0w + g * 16 + fr) * 1024 +
                                     kh * 32 + fq * 8];

  f32x4 o_acc[2][4] = {};
  float mrow[2][4], lrow[2][4];
#pragma unroll
  for (int g = 0; g < 2; g++)
#pragma unroll
    for (int r = 0; r < 4; r++) { mrow[g][r] = -INFINITY; lrow[g][r] = 0.f; }

  char* P = (char*)&Pl[wave][0];

  FSTAGE(0, 0);

  for (int kt = 0; kt < KT; kt++) {
    __syncthreads();
    if (kt + 1 < KT) FSTAGE((kt + 1) & 1, kt + 1);
    int k0 = kt * 64;
    if (k0 <= q0w + 31) {
      const char* Kb = (const char*)&Ks[kt & 1][0];
      const char* Vb = (const char*)&Vs[kt & 1][0];
      int swz = (fr & 7) << 4;
      f32x4 s[2][4] = {};
#pragma unroll
      for (int n = 0; n < 4; n++) {
        int rowo = (n * 16 + fr) * 128;
        bf16x8 kf0 = *(const bf16x8*)(Kb + rowo + ((fq * 16) ^ swz));
        bf16x8 kf1 = *(const bf16x8*)(Kb + rowo + ((64 + fq * 16) ^ swz));
#pragma unroll
        for (int g = 0; g < 2; g++) {
          s[g][n] = __builtin_amdgcn_mfma_f32_16x16x32_bf16(qf[g][0], kf0,
                                                            s[g][n], 0, 0, 0);
          s[g][n] = __builtin_amdgcn_mfma_f32_16x16x32_bf16(qf[g][1], kf1,
                                                            s[g][n], 0, 0, 0);
        }
      }
      const float scale = 0.125f;
#pragma unroll
      for (int g = 0; g < 2; g++) {
        bool dm = (k0 + 63 > q0w + g * 16);
#pragma unroll
        for (int n = 0; n < 4; n++)
#pragma unroll
          for (int r = 0; r < 4; r++) {
            float v = s[g][n][r] * scale;
            if (dm && (k0 + n * 16 + fr > q0w + g * 16 + fq * 4 + r))
              v = -INFINITY;
            s[g][n][r] = v;
          }
      }
      float corr[2][4];
#pragma unroll
      for (int g = 0; g < 2; g++)
#pragma unroll
        for (int r = 0; r < 4; r++) {
          float mx = fmaxf(fmaxf(s[g][0][r], s[g][1][r]),
                           fmaxf(s[g][2][r], s[g][3][r]));
#pragma unroll
          for (int msk = 1; msk < 16; msk <<= 1)
            mx = fmaxf(mx, __shfl_xor(mx, msk));
          float mnew = fmaxf(mrow[g][r], mx);
          corr[g][r] = __expf(mrow[g][r] - mnew);
          mrow[g][r] = mnew;
          float ps = 0.f;
#pragma unroll
          for (int n = 0; n < 4; n++) {
            float p = __expf(s[g][n][r] - mnew);
            s[g][n][r] = p;
            ps += p;
          }
#pragma unroll
          for (int msk = 1; msk < 16; msk <<= 1) ps += __shfl_xor(ps, msk);
          lrow[g][r] = lrow[g][r] * corr[g][r] + ps;
        }
#pragma unroll
      for (int g = 0; g < 2; g++)
#pragma unroll
        for (int n = 0; n < 4; n++)
#pragma unroll
          for (int r = 0; r < 4; r++) {
            int q = g * 16 + fq * 4 + r;
            int cb = ((n * 16 + fr) * 2) ^ ((q & 7) << 4);
            *(bf16_t*)(P + q * 128 + cb) = (bf16_t)s[g][n][r];
          }
      int rr = fr & 3;
      int srcl = (fr >> 2) << 4;
#pragma unroll
      for (int g = 0; g < 2; g++) {
        float c0 = __shfl(corr[g][0], srcl);
        float c1 = __shfl(corr[g][1], srcl);
        float c2 = __shfl(corr[g][2], srcl);
        float c3 = __shfl(corr[g][3], srcl);
        float cq = rr == 0 ? c0 : rr == 1 ? c1 : rr == 2 ? c2 : c3;
#pragma unroll
        for (int n = 0; n < 4; n++)
#pragma unroll
          for (int r = 0; r < 4; r++) o_acc[g][n][r] *= cq;
      }
#pragma unroll
      for (int c = 0; c < 2; c++) {
        bf16x8 pf[2];
#pragma unroll
        for (int g = 0; g < 2; g++)
          pf[g] = *(const bf16x8*)(P + (g * 16 + fr) * 128 +
                                   ((c * 64 + fq * 16) ^ swz));
#pragma unroll
        for (int n = 0; n < 4; n++) {
          bf16x8 vf = *(const bf16x8*)(Vb + (n * 16 + fr) * 128 +
                                       ((c * 64 + fq * 16) ^ swz));
#pragma unroll
          for (int g = 0; g < 2; g++)
            o_acc[g][n] = __builtin_amdgcn_mfma_f32_16x16x32_bf16(
                vf, pf[g], o_acc[g][n], 0, 0, 0);
        }
      }
    }
  }
  int rr = fr & 3;
  int srcl = (fr >> 2) << 4;
#pragma unroll
  for (int g = 0; g < 2; g++) {
    float l0 = __shfl(lrow[g][0], srcl);
    float l1 = __shfl(lrow[g][1], srcl);
    float l2 = __shfl(lrow[g][2], srcl);
    float l3 = __shfl(lrow[g][3], srcl);
    float lq = rr == 0 ? l0 : rr == 1 ? l1 : rr == 2 ? l2 : l3;
    float linv = 1.f / lq;
    size_t orow = qkbase + (size_t)(q0w + g * 16 + fr) * 1024;
#pragma unroll
    for (int n = 0; n < 4; n++) {
      bf16x4 ov;
#pragma unroll
      for (int r = 0; r < 4; r++) ov[r] = (bf16_t)(o_acc[g][n][r] * linv);
      *(bf16x4*)&O[orow + n * 16 + fq * 4] = ov;
    }
  }
#undef FSTAGE
}

// ======================= launch =======================

extern "C" void kernel_launch(void* const* d_in, const int* in_sizes, int n_in,
                              void* d_out, int out_size, void* d_ws,
                              size_t ws_size, hipStream_t stream) {
  (void)in_sizes; (void)n_in; (void)out_size; (void)ws_size;
  const float* x          = (const float*)d_in[0];
  const float* qk_emb     = (const float*)d_in[1];
  const float* v_emb      = (const float*)d_in[2];
  const float* know_emb   = (const float*)d_in[3];
  const float* qk_f       = (const float*)d_in[4];
  const float* qk_r       = (const float*)d_in[5];
  const float* v_f        = (const float*)d_in[6];
  const float* v_r        = (const float*)d_in[7];
  const float* know_f     = (const float*)d_in[8];
  const float* know_r     = (const float*)d_in[9];
  const float* proj_attn_k = (const float*)d_in[10];
  const float* proj_attn_b = (const float*)d_in[11];
  const float* tau_attn_k  = (const float*)d_in[12];
  const float* tau_attn_b  = (const float*)d_in[13];
  const float* proj_know_k = (const float*)d_in[14];
  const float* proj_know_b = (const float*)d_in[15];
  const float* tau_know_k  = (const float*)d_in[16];
  const float* tau_know_b  = (const float*)d_in[17];
  const float* expand_O    = (const float*)d_in[18];
  const float* ln1_scale   = (const float*)d_in[19];
  const float* ln1_bias    = (const float*)d_in[20];
  const float* ln2_scale   = (const float*)d_in[21];
  const float* ln2_bias    = (const float*)d_in[22];

  float* out = (float*)d_out;  // [T,D] + aux scalar
  float* aux = out + (size_t)T * D;

  // ---- workspace arena ----
  float* ws = (float*)d_ws;
  float* n_f   = ws;                       // 4M floats
  float* tau3  = n_f + 4194304;            // 16K
  float* gq_b  = tau3 + 16384;             // 64K
  float* gk_b  = gq_b + 65536;
  float* gv_b  = gk_b + 65536;
  float* gkn_b = gv_b + 65536;             // 128K
  float* csum  = gkn_b + 131072;           // 8192
  float* hQ    = csum + 8192;              // 512K
  float* hK    = hQ + 524288;
  float* hV    = hK + 524288;
  float* qkvarena = hV + 524288;           // 12.58M floats
  float* buf_big = qkvarena + 12582912;    // 16.78M floats (67MB)

  bf16_t* Qbb = (bf16_t*)qkvarena;                 // T*1024 bf16
  bf16_t* Kbb = Qbb + (size_t)T * 1024;
  bf16_t* Vtb = Kbb + (size_t)T * 1024;            // [4][1024][1024]

  bf16_t* nb   = (bf16_t*)(buf_big + 16777216);  // T*1024
  bf16_t* hab  = nb + 4194304;                   // T*384 (know: T*128)
  bf16_t* embB = hab + 1572864;                  // 524288
  bf16_t* B2t  = embB + 524288;                  // 4096*1024
  bf16_t* wt   = B2t + 4194304;
  bf16_t* pa_t  = wt;                   // 384*1024
  bf16_t* qkr_t = pa_t + 393216;        // 1024*2048
  bf16_t* vr_t  = qkr_t + 2097152;      // 1024*2048
  bf16_t* knr_t = vr_t + 2097152;       // 1024*4096
  bf16_t* eo_t  = knr_t + 4194304;      // 1024*1024
  bf16_t* pk_t  = eo_t + 1048576;       // 128*1024
  bf16_t* B2t2  = pk_t + 131072;        // 4096*1024

  // buf_big overlays (lifetimes checked):
  float* s_q = buf_big;                             // T*2048 f32
  float* s_k = buf_big + 8388608;
  float* s_v = (float*)qkvarena;                    // T*2048 f32
  bf16_t* allh_q = (bf16_t*)buf_big;                // T*2048 bf16
  bf16_t* allh_v = allh_q + (size_t)T * 2048;
  bf16_t* avbQ = (bf16_t*)buf_big;
  bf16_t* avbK = avbQ + (size_t)T * 2048;
  bf16_t* avbV = avbK + (size_t)T * 2048;
  bf16_t* avbN = (bf16_t*)buf_big;                  // [T,4096] bf16
  bf16_t* allh_n = (bf16_t*)buf_big;
  float* kp0 = buf_big + 8388608;
  float* kp1 = kp0 + 4194304;
  bf16_t* attnb_b = (bf16_t*)(buf_big + 12582912);  // T*1024 bf16

  bf16_t* embQ = embB;
  bf16_t* embV = embB + 262144;

  dim3 blk(256);

  zero1_kernel<<<1, 1, 0, stream>>>(aux);

  // weight + feature-basis transposes to bf16 [N,K]
  transpose_to_bf16_kernel<<<dim3(12, 32, 1), blk, 0, stream>>>(
      proj_attn_k, pa_t, 1024, 384, 0, 0);
  transpose_to_bf16_kernel<<<dim3(32, 64, 1), blk, 0, stream>>>(
      qk_r, qkr_t, 2048, 1024, 0, 0);
  transpose_to_bf16_kernel<<<dim3(32, 64, 1), blk, 0, stream>>>(
      v_r, vr_t, 2048, 1024, 0, 0);
  transpose_to_bf16_kernel<<<dim3(32, 128, 1), blk, 0, stream>>>(
      know_r, knr_t, 4096, 1024, 0, 0);
  transpose_to_bf16_kernel<<<dim3(32, 32, 1), blk, 0, stream>>>(
      expand_O, eo_t, 1024, 1024, 0, 0);
  transpose_to_bf16_kernel<<<dim3(4, 32, 1), blk, 0, stream>>>(
      proj_know_k, pk_t, 1024, 128, 0, 0);
  transpose_to_bf16_kernel<<<dim3(4, 32, 16), blk, 0, stream>>>(
      qk_f, B2t, 1024, 128, 131072, 131072);
  transpose_to_bf16_kernel<<<dim3(4, 32, 16), blk, 0, stream>>>(
      v_f, B2t2, 1024, 128, 131072, 131072);

  // ---- attention circuit ----
  ln_kernel<<<T, blk, 0, stream>>>(x, ln1_scale, ln1_bias, n_f, nb);
  norm_rows_kernel<<<2048, 64, 0, stream>>>(qk_emb, embQ);
  norm_rows_kernel<<<2048, 64, 0, stream>>>(v_emb, embV);

  mfma_gemm_kernel<true, false, 1><<<dim3(3, 64), blk, 0, stream>>>(
      nb, 1024, pa_t, 1024, hab, 384, proj_attn_b, nullptr, 0, T, 384, 1024);
  tau_kernel<<<T, 64, 0, stream>>>(n_f, tau_attn_k, tau_attn_b, tau3, 3);

  // batched gate-score GEMMs (z = {q,k,v}, K=128), 128^2 tile
  {
    ZArg zq{hab + 0, embQ, s_q, 0};
    ZArg zk{hab + 128, embQ, s_k, 0};
    ZArg zv{hab + 256, embV, s_v, 0};
    mfma_gemm128b_kernel<<<dim3(16, 32, 3), blk, 0, stream>>>(
        zq, zk, zv, 384, 128, 2048, 128);
  }
  gate3_kernel<8><<<dim3(T, 3), blk, 0, stream>>>(
      s_q, s_k, s_v, tau3, gq_b, gk_b, gv_b, 2048, 16);
  hipMemsetAsync(csum, 0, 6144 * sizeof(float), stream);
  colsum_part3_kernel<<<dim3(8, 32, 3), blk, 0, stream>>>(s_q, s_k, s_v,
                                                          2048, csum);
  colsum_fin_kernel<<<24, blk, 0, stream>>>(csum, 2048, 1.f / 2048.f, aux);

  // batched feature GEMMs (z = {qk,v}, K=1024) -> bf16 all_h, 128^2 tile
  {
    ZArg zf1{nb, B2t, allh_q, 1};
    ZArg zf2{nb, B2t2, allh_v, 1};
    mfma_gemm128b_kernel<<<dim3(16, 32, 2), blk, 0, stream>>>(
        zf1, zf2, zf1, 1024, 1024, 2048, 1024);
  }
  wsum2b_kernel<<<dim3(T, 2), 128, 0, stream>>>(allh_q, allh_v, gq_b, gk_b,
                                                gv_b, hQ, hK, hV, 16);

  // batched avirt + batched QKV restore (128^2 tile, 768 blocks = 3/CU)
  avirt3_kernel<<<dim3(T, 3), blk, 0, stream>>>(hQ, hK, hV, gq_b, gk_b, gv_b,
                                                16, avbQ, avbK, avbV, 2048);
  {
    ZArg zq{avbQ, qkr_t, Qbb, 1};
    ZArg zk{avbK, qkr_t, Kbb, 1};
    ZArg zv{avbV, vr_t, Vtb, 2};
    mfma_gemm128b_kernel<<<dim3(8, 32, 3), blk, 0, stream>>>(
        zq, zk, zv, 2048, 2048, 1024, 2048);
  }

  // MFMA flash attention (causal-paired, 512 thr) + output proj + residual
  flash_mfma_kernel<<<dim3(4, 16, 4), dim3(512), 0, stream>>>(Qbb, Kbb, Vtb,
                                                              attnb_b);
  mfma_gemm_kernel<false, true, 0><<<dim3(8, 64), blk, 0, stream>>>(
      attnb_b, 1024, eo_t, 1024, out, 1024, nullptr, x, 1024, T, 1024, 1024);

  // ---- knowledge circuit ----
  ln_kernel<<<T, blk, 0, stream>>>(out, ln2_scale, ln2_bias, n_f, nb);
  norm_rows_kernel<<<4096, 64, 0, stream>>>(know_emb, embB);
  mfma_gemm_kernel<true, false, 1><<<dim3(1, 64), blk, 0, stream>>>(
      nb, 1024, pk_t, 1024, hab, 128, proj_know_b, nullptr, 0, T, 128, 1024);
  tau_kernel<<<T, 64, 0, stream>>>(n_f, tau_know_k, tau_know_b, tau3, 1);

  mfma_gemm128_kernel<0><<<dim3(32, 32), blk, 0, stream>>>(
      hab, 128, embB, 128, buf_big, 4096, 128);
  gate_kernel<16><<<T, blk, 0, stream>>>(buf_big, tau3, 1, 0, gkn_b, 4096, 32);
  hipMemsetAsync(csum, 0, 4096 * sizeof(float), stream);
  colsum_part_kernel<<<dim3(16, 32), blk, 0, stream>>>(buf_big, 4096, csum);
  colsum_fin_kernel<<<16, blk, 0, stream>>>(csum, 4096, 1.f / 4096.f, aux);

  transpose_to_bf16_kernel<<<dim3(4, 32, 32), blk, 0, stream>>>(
      know_f, B2t, 1024, 128, 131072, 131072);
  mfma_gemm128_kernel<1><<<dim3(32, 32), blk, 0, stream>>>(
      nb, 1024, B2t, 1024, allh_n, 4096, 1024);
  wsum2_kernel<<<T, 128, 0, stream>>>(allh_n, gkn_b, nullptr, hQ, nullptr, 32);

  // knowledge restore: split-K=2 -> f32 partials + combine (128^2 tile)
  avirt_kernel<<<T, blk, 0, stream>>>(hQ, gkn_b, 32, avbN, 4096);
  {
    ZArg z0{avbN, knr_t, kp0, 0};
    ZArg z1{avbN + 2048, knr_t + 2048, kp1, 0};
    mfma_gemm128b_kernel<<<dim3(8, 32, 2), blk, 0, stream>>>(
        z0, z1, z0, 4096, 4096, 1024, 2048);
  }
  combine2_kernel<<<4096, blk, 0, stream>>>(kp0, kp1, out);
}

// Round 13
// 563.840 us; speedup vs baseline: 6.9504x; 1.0452x over previous
//
#include <hip/hip_runtime.h>
#include <math.h>

static constexpr int T = 4096;   // B*S
static constexpr int D = 1024;

typedef __bf16 bf16_t;
typedef bf16_t bf16x8 __attribute__((ext_vector_type(8)));
typedef bf16_t bf16x4 __attribute__((ext_vector_type(4)));
typedef float f32x4 __attribute__((ext_vector_type(4)));

#define GLDS16(g, l)                                                        \
  __builtin_amdgcn_global_load_lds(                                         \
      (const __attribute__((address_space(1))) void*)(g),                   \
      (__attribute__((address_space(3))) void*)(l), 16, 0, 0)

// ======================= small kernels =======================

__global__ void zero1_kernel(float* p) { *p = 0.f; }

__global__ __launch_bounds__(256) void ln_kernel(
    const float* __restrict__ x, const float* __restrict__ scale,
    const float* __restrict__ bias, float* __restrict__ out_f,
    bf16_t* __restrict__ out_b)
{
  int t = blockIdx.x;
  const float* xr = x + (size_t)t * D;
  float v[4];
  float s1 = 0.f, s2 = 0.f;
#pragma unroll
  for (int i = 0; i < 4; i++) {
    v[i] = xr[threadIdx.x + i * 256];
    s1 += v[i];
    s2 += v[i] * v[i];
  }
#pragma unroll
  for (int o = 1; o < 64; o <<= 1) {
    s1 += __shfl_xor(s1, o);
    s2 += __shfl_xor(s2, o);
  }
  __shared__ float r1[4], r2[4];
  int wid = threadIdx.x >> 6;
  if ((threadIdx.x & 63) == 0) { r1[wid] = s1; r2[wid] = s2; }
  __syncthreads();
  s1 = r1[0] + r1[1] + r1[2] + r1[3];
  s2 = r2[0] + r2[1] + r2[2] + r2[3];
  float mean = s1 * (1.f / D);
  float var = s2 * (1.f / D) - mean * mean;
  float rstd = rsqrtf(var + 1e-6f);
  float* orow = out_f + (size_t)t * D;
  bf16_t* brow = out_b + (size_t)t * D;
#pragma unroll
  for (int i = 0; i < 4; i++) {
    int d = threadIdx.x + i * 256;
    float o = (v[i] - mean) * rstd * scale[d] + bias[d];
    orow[d] = o;
    brow[d] = (bf16_t)o;
  }
}

// rows of length 128, one wave per row; bf16 normalized output
__global__ __launch_bounds__(64) void norm_rows_kernel(
    const float* __restrict__ e, bf16_t* __restrict__ o)
{
  int r = blockIdx.x;
  const float* row = e + (size_t)r * 128;
  float a = row[threadIdx.x], b = row[threadIdx.x + 64];
  float ss = a * a + b * b;
#pragma unroll
  for (int m = 1; m < 64; m <<= 1) ss += __shfl_xor(ss, m);
  float inv = 1.f / (sqrtf(ss) + 1e-8f);
  bf16_t* orow = o + (size_t)r * 128;
  orow[threadIdx.x] = (bf16_t)(a * inv);
  orow[threadIdx.x + 64] = (bf16_t)(b * inv);
}

// tau = n @ W + b,  W: [D, J], J in {1,3}; one wave per token (fp32)
__global__ __launch_bounds__(64) void tau_kernel(
    const float* __restrict__ n, const float* __restrict__ W,
    const float* __restrict__ b, float* __restrict__ out, int J)
{
  int t = blockIdx.x;
  const float* nr = n + (size_t)t * D;
  for (int j = 0; j < J; j++) {
    float p = 0.f;
#pragma unroll 4
    for (int i = 0; i < 16; i++) {
      int d = threadIdx.x + i * 64;
      p += nr[d] * W[d * J + j];
    }
#pragma unroll
    for (int m = 1; m < 64; m <<= 1) p += __shfl_xor(p, m);
    if (threadIdx.x == 0) out[t * J + j] = p + b[j];
  }
}

// ======== gate (bf16 scores, no write-back; emits gb + rowinv) ========
template <int PER>
__device__ __forceinline__ void gateb_body(
    const bf16_t* __restrict__ row, float tv, float* __restrict__ gb, int G,
    float* __restrict__ rowinv)
{
  int base = threadIdx.x * PER;
  float psum = 0.f;
#pragma unroll
  for (int i = 0; i < PER; i += 8) {
    bf16x8 v = *(const bf16x8*)(row + base + i);
#pragma unroll
    for (int j = 0; j < 8; j++) psum += fmaxf((float)v[j] - tv, 0.f);
  }
  __shared__ float red[4];
  __shared__ float grp[32];
  if (threadIdx.x < 32) grp[threadIdx.x] = 0.f;
  float w = psum;
#pragma unroll
  for (int m = 1; m < 64; m <<= 1) w += __shfl_xor(w, m);
  int wid = threadIdx.x >> 6;
  if ((threadIdx.x & 63) == 0) red[wid] = w;
  __syncthreads();
  float Stot = red[0] + red[1] + red[2] + red[3];
  atomicAdd(&grp[base >> 7], psum);
  __syncthreads();
  float inv = 1.f / (Stot + 1e-8f);
  if (threadIdx.x == 0) *rowinv = inv;
  if (threadIdx.x < G) {
    float Gj = grp[threadIdx.x] * inv;
    float gsum = Stot * inv;
    gb[threadIdx.x] = Gj / (gsum + 1e-8f);
  }
}

template <int PER>
__global__ __launch_bounds__(256) void gate3b_kernel(
    const bf16_t* __restrict__ s0, const bf16_t* __restrict__ s1,
    const bf16_t* __restrict__ s2, const float* __restrict__ tau,
    float* __restrict__ g0, float* __restrict__ g1, float* __restrict__ g2,
    float* __restrict__ ri, int N, int G)
{
  int t = blockIdx.x, y = blockIdx.y;
  const bf16_t* g = y == 0 ? s0 : y == 1 ? s1 : s2;
  float* gb = y == 0 ? g0 : y == 1 ? g1 : g2;
  gateb_body<PER>(g + (size_t)t * N, tau[t * 3 + y], gb + (size_t)t * G, G,
                  ri + (size_t)y * T + t);
}

template <int PER>
__global__ __launch_bounds__(256) void gateb_kernel(
    const bf16_t* __restrict__ s, const float* __restrict__ tau,
    float* __restrict__ gb, float* __restrict__ ri, int N, int G)
{
  int t = blockIdx.x;
  gateb_body<PER>(s + (size_t)t * N, tau[t], gb + (size_t)t * G, G, ri + t);
}

// column partial sums of normalized gates, recomputed from bf16 scores
__global__ __launch_bounds__(256) void colsumb_part3_kernel(
    const bf16_t* __restrict__ s0, const bf16_t* __restrict__ s1,
    const bf16_t* __restrict__ s2, const float* __restrict__ tau,
    const float* __restrict__ ri, int N, float* __restrict__ colsum)
{
  int z = blockIdx.z;
  const bf16_t* g = z == 0 ? s0 : z == 1 ? s1 : s2;
  const float* riz = ri + (size_t)z * T;
  int c = blockIdx.x * 256 + threadIdx.x;
  int r0 = blockIdx.y * 128;
  float s = 0.f;
#pragma unroll 4
  for (int t = 0; t < 128; t++) {
    int row = r0 + t;
    float v = (float)g[(size_t)row * N + c];
    s += fmaxf(v - tau[row * 3 + z], 0.f) * riz[row];
  }
  atomicAdd(&colsum[z * N + c], s);
}

__global__ __launch_bounds__(256) void colsumb_part_kernel(
    const bf16_t* __restrict__ g, const float* __restrict__ tau,
    const float* __restrict__ ri, int N, float* __restrict__ colsum)
{
  int c = blockIdx.x * 256 + threadIdx.x;
  int r0 = blockIdx.y * 128;
  float s = 0.f;
#pragma unroll 4
  for (int t = 0; t < 128; t++) {
    int row = r0 + t;
    float v = (float)g[(size_t)row * N + c];
    s += fmaxf(v - tau[row], 0.f) * ri[row];
  }
  atomicAdd(&colsum[c], s);
}

// stage 2: aux += sum_c (colsum[c]/T - tinv)^2 * N
__global__ __launch_bounds__(256) void colsum_fin_kernel(
    const float* __restrict__ colsum, int N, float tinv,
    float* __restrict__ aux)
{
  int c = blockIdx.x * 256 + threadIdx.x;
  float mdev = colsum[c] * (1.f / T) - tinv;
  float p = mdev * mdev * (float)N;
#pragma unroll
  for (int m = 1; m < 64; m <<= 1) p += __shfl_xor(p, m);
  __shared__ float red[4];
  if ((threadIdx.x & 63) == 0) red[threadIdx.x >> 6] = p;
  __syncthreads();
  if (threadIdx.x == 0) atomicAdd(aux, red[0] + red[1] + red[2] + red[3]);
}

// h1[t,r] = sum_n gb1[t,n]*all_h[t, n*128+r] (all_h bf16); optional 2nd out
__global__ __launch_bounds__(128) void wsum2_kernel(
    const bf16_t* __restrict__ all_h, const float* __restrict__ gb1,
    const float* __restrict__ gb2, float* __restrict__ h1,
    float* __restrict__ h2, int NB)
{
  int t = blockIdx.x;
  int r = threadIdx.x;
  const bf16_t* row = all_h + (size_t)t * NB * 128;
  float a1 = 0.f, a2 = 0.f;
  for (int n = 0; n < NB; n++) {
    float v = (float)row[n * 128 + r];
    a1 += gb1[(size_t)t * NB + n] * v;
    if (gb2) a2 += gb2[(size_t)t * NB + n] * v;
  }
  h1[(size_t)t * 128 + r] = a1;
  if (h2) h2[(size_t)t * 128 + r] = a2;
}

__global__ __launch_bounds__(128) void wsum2b_kernel(
    const bf16_t* __restrict__ aq, const bf16_t* __restrict__ av,
    const float* __restrict__ gq, const float* __restrict__ gk,
    const float* __restrict__ gv, float* __restrict__ hQ,
    float* __restrict__ hK, float* __restrict__ hV, int NB)
{
  int t = blockIdx.x, y = blockIdx.y;
  int r = threadIdx.x;
  const bf16_t* row = (y == 0 ? aq : av) + (size_t)t * NB * 128;
  const float* g1 = (y == 0 ? gq : gv) + (size_t)t * NB;
  const float* g2 = y == 0 ? gk + (size_t)t * NB : nullptr;
  float a1 = 0.f, a2 = 0.f;
  for (int n = 0; n < NB; n++) {
    float v = (float)row[n * 128 + r];
    a1 += g1[n] * v;
    if (g2) a2 += g2[n] * v;
  }
  if (y == 0) {
    hQ[(size_t)t * 128 + r] = a1;
    hK[(size_t)t * 128 + r] = a2;
  } else {
    hV[(size_t)t * 128 + r] = a1;
  }
}

// dst[c][r] = (bf16)src[r][c]; src [R,C] fp32, dst [C,R] bf16; batched
__global__ __launch_bounds__(256) void transpose_to_bf16_kernel(
    const float* __restrict__ src, bf16_t* __restrict__ dst,
    int R, int C, size_t sbs, size_t dbs)
{
  __shared__ float tile[32][33];
  int b = blockIdx.z;
  int c0 = blockIdx.x * 32, r0 = blockIdx.y * 32;
  int tx = threadIdx.x & 31, ty = threadIdx.x >> 5;
  const float* s = src + (size_t)b * sbs;
  bf16_t* d = dst + (size_t)b * dbs;
#pragma unroll
  for (int i = 0; i < 4; i++)
    tile[ty + i * 8][tx] = s[(size_t)(r0 + ty + i * 8) * C + c0 + tx];
  __syncthreads();
#pragma unroll
  for (int i = 0; i < 4; i++)
    d[(size_t)(c0 + ty + i * 8) * R + r0 + tx] = (bf16_t)tile[tx][ty + i * 8];
}

// A_virt[t,k] = (bf16)(gb[t,k>>7]*h[t,k&127]), row-major [T,K]
__device__ __forceinline__ void avirt_body(
    const float* hr, const float* gr, bf16_t* ar, int K)
{
  int noct = K >> 3;
  for (int o = threadIdx.x; o < noct; o += 256) {
    int k = o * 8;
    float g = gr[k >> 7];
    bf16x8 v;
#pragma unroll
    for (int i = 0; i < 8; i++) v[i] = (bf16_t)(hr[(k & 127) + i] * g);
    *(bf16x8*)(ar + k) = v;
  }
}

__global__ __launch_bounds__(256) void avirt_kernel(
    const float* __restrict__ h, const float* __restrict__ gb, int NB,
    bf16_t* __restrict__ A, int K)
{
  int t = blockIdx.x;
  avirt_body(h + (size_t)t * 128, gb + (size_t)t * NB, A + (size_t)t * K, K);
}

__global__ __launch_bounds__(256) void avirt3_kernel(
    const float* __restrict__ h0, const float* __restrict__ h1,
    const float* __restrict__ h2, const float* __restrict__ g0,
    const float* __restrict__ g1, const float* __restrict__ g2, int NB,
    bf16_t* __restrict__ A0, bf16_t* __restrict__ A1,
    bf16_t* __restrict__ A2, int K)
{
  int t = blockIdx.x, y = blockIdx.y;
  const float* h = y == 0 ? h0 : y == 1 ? h1 : h2;
  const float* g = y == 0 ? g0 : y == 1 ? g1 : g2;
  bf16_t* A = y == 0 ? A0 : y == 1 ? A1 : A2;
  avirt_body(h + (size_t)t * 128, g + (size_t)t * NB, A + (size_t)t * K, K);
}

// out[i] += p0[i] + p1[i]
__global__ __launch_bounds__(256) void combine2_kernel(
    const float* __restrict__ p0, const float* __restrict__ p1,
    float* __restrict__ out)
{
  int i = blockIdx.x * 256 + threadIdx.x;
  float4 a = ((const float4*)p0)[i];
  float4 b = ((const float4*)p1)[i];
  float4 o = ((float4*)out)[i];
  o.x += a.x + b.x;
  o.y += a.y + b.y;
  o.z += a.z + b.z;
  o.w += a.w + b.w;
  ((float4*)out)[i] = o;
}

// ======== epilogue helper (shared by all GEMM variants) ========
template <bool HAS_BIAS, bool HAS_RESID>
__device__ __forceinline__ void gemm_store(
    int mode, void* Cv, int ldc, const float* bias, const float* resid,
    int ldr, int rowb, int col, const f32x4& a)
{
  if (mode == 2) {
    bf16x4 v4;
#pragma unroll
    for (int r = 0; r < 4; r++) v4[r] = (bf16_t)a[r];
    bf16_t* dst = (bf16_t*)Cv +
        ((size_t)(rowb >> 10) * 1024 + col) * 1024 + (rowb & 1023);
    *(bf16x4*)dst = v4;
  } else {
#pragma unroll
    for (int r = 0; r < 4; r++) {
      int row = rowb + r;
      float v = a[r];
      if (HAS_BIAS) v += bias[col];
      if (HAS_RESID) v += resid[(size_t)row * ldr + col];
      if (mode == 1)
        ((bf16_t*)Cv)[(size_t)row * ldc + col] = (bf16_t)v;
      else
        ((float*)Cv)[(size_t)row * ldc + col] = v;
    }
  }
}

// ============== MFMA GEMM (64x128 tile) — narrow-N dispatches ==============
template <bool HAS_BIAS, bool HAS_RESID, int OUT_MODE>
__global__ __launch_bounds__(256) void mfma_gemm_kernel(
    const bf16_t* __restrict__ A, int lda,
    const bf16_t* __restrict__ Bt, int ldb,
    void* __restrict__ Cv, int ldc,
    const float* __restrict__ bias,
    const float* __restrict__ resid, int ldr,
    int M, int N, int K)
{
  __shared__ bf16_t As[2][64 * 32];
  __shared__ bf16_t Bs[2][128 * 32];
  int tid = threadIdx.x;
  int wave = tid >> 6, lane = tid & 63;

  unsigned lid = blockIdx.y * gridDim.x + blockIdx.x;
  unsigned nwg = gridDim.x * gridDim.y;
  unsigned swzb = lid;
  if ((nwg & 7u) == 0u) swzb = (lid & 7u) * (nwg >> 3) + (lid >> 3);
  int row0 = (int)(swzb / gridDim.x) * 64;
  int col0 = (int)(swzb % gridDim.x) * 128;

  int wr = (wave >> 1) * 32, wc = (wave & 1) * 64;
  f32x4 acc[2][4] = {};

  int srow = (wave << 4) + (lane >> 2);
  int g8 = (((lane & 3) ^ ((srow >> 1) & 3)) << 3);
  const bf16_t* gA = A + (size_t)(row0 + srow) * lda + g8;
  const bf16_t* gB = Bt + (size_t)(col0 + srow) * ldb + g8;
  size_t b64 = (size_t)64 * ldb;

  int fr = lane & 15, fq = lane >> 4;

#define GSTAGE(buf, k0s)                                  \
  {                                                       \
    GLDS16(gA + (k0s), &As[buf][wave * 512]);             \
    GLDS16(gB + (k0s), &Bs[buf][wave * 512]);             \
    GLDS16(gB + b64 + (k0s), &Bs[buf][2048 + wave * 512]);\
  }

  GSTAGE(0, 0);
  int cur = 0;
  for (int k0 = 0; k0 < K; k0 += 32) {
    __syncthreads();
    if (k0 + 32 < K) GSTAGE(cur ^ 1, k0 + 32);
    bf16x8 af[2], bfr[4];
#pragma unroll
    for (int m = 0; m < 2; m++) {
      int R = wr + m * 16 + fr;
      af[m] = *(const bf16x8*)&As[cur][R * 32 + ((fq ^ ((R >> 1) & 3)) << 3)];
    }
#pragma unroll
    for (int n = 0; n < 4; n++) {
      int R = wc + n * 16 + fr;
      bfr[n] = *(const bf16x8*)&Bs[cur][R * 32 + ((fq ^ ((R >> 1) & 3)) << 3)];
    }
#pragma unroll
    for (int m = 0; m < 2; m++)
#pragma unroll
      for (int n = 0; n < 4; n++)
        acc[m][n] = __builtin_amdgcn_mfma_f32_16x16x32_bf16(af[m], bfr[n],
                                                            acc[m][n], 0, 0, 0);
    cur ^= 1;
  }
#undef GSTAGE

#pragma unroll
  for (int m = 0; m < 2; m++)
#pragma unroll
    for (int n = 0; n < 4; n++)
      gemm_store<HAS_BIAS, HAS_RESID>(
          OUT_MODE, Cv, ldc, bias, resid, ldr,
          row0 + wr + m * 16 + fq * 4, col0 + wc + n * 16 + fr, acc[m][n]);
}

// ============== MFMA GEMM (128x128 tile) — wide dispatches ==============
struct ZArg { const bf16_t* A; const bf16_t* Bt; void* C; int mode; };

__device__ __forceinline__ void gemm128_body(
    const bf16_t* __restrict__ A, int lda, const bf16_t* __restrict__ Bt,
    int ldb, void* __restrict__ Cv, int ldc, int mode, int row0, int col0,
    int K)
{
  __shared__ bf16_t As[2][128 * 32];
  __shared__ bf16_t Bs[2][128 * 32];
  int tid = threadIdx.x;
  int wave = tid >> 6, lane = tid & 63;
  int wr = (wave >> 1) * 64, wc = (wave & 1) * 64;
  f32x4 acc[4][4] = {};

  int srow = (wave << 4) + (lane >> 2);
  int g8 = (((lane & 3) ^ ((srow >> 1) & 3)) << 3);
  const bf16_t* gA = A + (size_t)(row0 + srow) * lda + g8;
  const bf16_t* gB = Bt + (size_t)(col0 + srow) * ldb + g8;
  size_t a64 = (size_t)64 * lda, b64 = (size_t)64 * ldb;

  int fr = lane & 15, fq = lane >> 4;

#define GSTAGE8(buf, k0s)                                  \
  {                                                        \
    GLDS16(gA + (k0s), &As[buf][wave * 512]);              \
    GLDS16(gA + a64 + (k0s), &As[buf][2048 + wave * 512]); \
    GLDS16(gB + (k0s), &Bs[buf][wave * 512]);              \
    GLDS16(gB + b64 + (k0s), &Bs[buf][2048 + wave * 512]); \
  }

  GSTAGE8(0, 0);
  int cur = 0;
  for (int k0 = 0; k0 < K; k0 += 32) {
    __syncthreads();
    if (k0 + 32 < K) GSTAGE8(cur ^ 1, k0 + 32);
    bf16x8 af[4], bfr[4];
#pragma unroll
    for (int m = 0; m < 4; m++) {
      int R = wr + m * 16 + fr;
      af[m] = *(const bf16x8*)&As[cur][R * 32 + ((fq ^ ((R >> 1) & 3)) << 3)];
    }
#pragma unroll
    for (int n = 0; n < 4; n++) {
      int R = wc + n * 16 + fr;
      bfr[n] = *(const bf16x8*)&Bs[cur][R * 32 + ((fq ^ ((R >> 1) & 3)) << 3)];
    }
#pragma unroll
    for (int m = 0; m < 4; m++)
#pragma unroll
      for (int n = 0; n < 4; n++)
        acc[m][n] = __builtin_amdgcn_mfma_f32_16x16x32_bf16(af[m], bfr[n],
                                                            acc[m][n], 0, 0, 0);
    cur ^= 1;
  }
#undef GSTAGE8

#pragma unroll
  for (int m = 0; m < 4; m++)
#pragma unroll
    for (int n = 0; n < 4; n++)
      gemm_store<false, false>(
          mode, Cv, ldc, nullptr, nullptr, 0,
          row0 + wr + m * 16 + fq * 4, col0 + wc + n * 16 + fr, acc[m][n]);
}

template <int OUT_MODE>
__global__ __launch_bounds__(256) void mfma_gemm128_kernel(
    const bf16_t* __restrict__ A, int lda,
    const bf16_t* __restrict__ Bt, int ldb,
    void* __restrict__ Cv, int ldc, int K)
{
  unsigned lid = blockIdx.y * gridDim.x + blockIdx.x;
  unsigned nwg = gridDim.x * gridDim.y;
  unsigned swzb = lid;
  if ((nwg & 7u) == 0u) swzb = (lid & 7u) * (nwg >> 3) + (lid >> 3);
  int row0 = (int)(swzb / gridDim.x) * 128;
  int col0 = (int)(swzb % gridDim.x) * 128;
  gemm128_body(A, lda, Bt, ldb, Cv, ldc, OUT_MODE, row0, col0, K);
}

__global__ __launch_bounds__(256) void mfma_gemm128b_kernel(
    ZArg za, ZArg zb, ZArg zc, int lda, int ldb, int ldc, int K)
{
  unsigned gx = gridDim.x;
  unsigned gxy = gridDim.x * gridDim.y;
  unsigned lid = (blockIdx.z * gridDim.y + blockIdx.y) * gx + blockIdx.x;
  unsigned nwg = gxy * gridDim.z;
  unsigned swzb = lid;
  if ((nwg & 7u) == 0u) swzb = (lid & 7u) * (nwg >> 3) + (lid >> 3);
  unsigned zi = swzb / gxy;
  unsigned rem = swzb % gxy;
  int row0 = (int)(rem / gx) * 128;
  int col0 = (int)(rem % gx) * 128;
  ZArg Z = (zi == 0) ? za : (zi == 1) ? zb : zc;
  gemm128_body(Z.A, lda, Z.Bt, ldb, Z.C, ldc, Z.mode, row0, col0, K);
}

// ======================= MFMA flash attention (bf16, LDS-staged) ============
// 8 waves (512 thr), causal-pair balancing.
__global__ __launch_bounds__(512) void flash_mfma_kernel(
    const bf16_t* __restrict__ Q, const bf16_t* __restrict__ K,
    const bf16_t* __restrict__ Vt, bf16_t* __restrict__ O)
{
  __shared__ bf16_t Ks[2][64 * 64];
  __shared__ bf16_t Vs[2][64 * 64];
  __shared__ bf16_t Pl[8][32 * 64];

  int tid = threadIdx.x;
  int wave = tid >> 6, lane = tid & 63;
  int fr = lane & 15, fq = lane >> 4;
  unsigned lid = blockIdx.x + blockIdx.y * 4 + blockIdx.z * 64;  // 256 wgs
  unsigned swz8 = (lid & 7u) * 32 + (lid >> 3);
  int s_slot = swz8 & 3;
  unsigned hb = swz8 >> 2;
  int h = hb & 15, b = hb >> 4;
  int half = wave >> 2, w4 = wave & 3;
  int qb = half ? (7 - s_slot) : s_slot;
  int q0w = qb * 128 + w4 * 32;
  int KT = 16 - 2 * s_slot;
  size_t qkbase = ((size_t)b * 1024) * 1024 + (size_t)h * 64;
  size_t vtbase = ((size_t)b * 1024 + (size_t)h * 64) * 1024;

  int srow8 = lane >> 3;
  int scb = (((lane & 7) << 4) ^ (srow8 << 4)) >> 1;

#define FSTAGE(buf, kt)                                                     \
  {                                                                         \
    int k0s = (kt) * 64;                                                    \
    int row = wave * 8 + srow8;                                             \
    GLDS16(&K[qkbase + (size_t)(k0s + row) * 1024 + scb],                   \
           &Ks[buf][wave * 512]);                                           \
    GLDS16(&Vt[vtbase + (size_t)row * 1024 + k0s + scb],                    \
           &Vs[buf][wave * 512]);                                           \
  }

  bf16x8 qf[2][2];
#pragma unroll
  for (int g = 0; g < 2; g++)
#pragma unroll
    for (int kh = 0; kh < 2; kh++)
      qf[g][kh] = *(const bf16x8*)&Q[qkbase +
                                     (size_t)(q0w + g * 16 + fr) * 1024 +
                                     kh * 32 + fq * 8];

  f32x4 o_acc[2][4] = {};
  float mrow[2][4], lrow[2][4];
#pragma unroll
  for (int g = 0; g < 2; g++)
#pragma unroll
    for (int r = 0; r < 4; r++) { mrow[g][r] = -INFINITY; lrow[g][r] = 0.f; }

  char* P = (char*)&Pl[wave][0];

  FSTAGE(0, 0);

  for (int kt = 0; kt < KT; kt++) {
    __syncthreads();
    if (kt + 1 < KT) FSTAGE((kt + 1) & 1, kt + 1);
    int k0 = kt * 64;
    if (k0 <= q0w + 31) {
      const char* Kb = (const char*)&Ks[kt & 1][0];
      const char* Vb = (const char*)&Vs[kt & 1][0];
      int swz = (fr & 7) << 4;
      f32x4 s[2][4] = {};
#pragma unroll
      for (int n = 0; n < 4; n++) {
        int rowo = (n * 16 + fr) * 128;
        bf16x8 kf0 = *(const bf16x8*)(Kb + rowo + ((fq * 16) ^ swz));
        bf16x8 kf1 = *(const bf16x8*)(Kb + rowo + ((64 + fq * 16) ^ swz));
#pragma unroll
        for (int g = 0; g < 2; g++) {
          s[g][n] = __builtin_amdgcn_mfma_f32_16x16x32_bf16(qf[g][0], kf0,
                                                            s[g][n], 0, 0, 0);
          s[g][n] = __builtin_amdgcn_mfma_f32_16x16x32_bf16(qf[g][1], kf1,
                                                            s[g][n], 0, 0, 0);
        }
      }
      const float scale = 0.125f;
#pragma unroll
      for (int g = 0; g < 2; g++) {
        bool dm = (k0 + 63 > q0w + g * 16);
#pragma unroll
        for (int n = 0; n < 4; n++)
#pragma unroll
          for (int r = 0; r < 4; r++) {
            float v = s[g][n][r] * scale;
            if (dm && (k0 + n * 16 + fr > q0w + g * 16 + fq * 4 + r))
              v = -INFINITY;
            s[g][n][r] = v;
          }
      }
      float corr[2][4];
#pragma unroll
      for (int g = 0; g < 2; g++)
#pragma unroll
        for (int r = 0; r < 4; r++) {
          float mx = fmaxf(fmaxf(s[g][0][r], s[g][1][r]),
                           fmaxf(s[g][2][r], s[g][3][r]));
#pragma unroll
          for (int msk = 1; msk < 16; msk <<= 1)
            mx = fmaxf(mx, __shfl_xor(mx, msk));
          float mnew = fmaxf(mrow[g][r], mx);
          corr[g][r] = __expf(mrow[g][r] - mnew);
          mrow[g][r] = mnew;
          float ps = 0.f;
#pragma unroll
          for (int n = 0; n < 4; n++) {
            float p = __expf(s[g][n][r] - mnew);
            s[g][n][r] = p;
            ps += p;
          }
#pragma unroll
          for (int msk = 1; msk < 16; msk <<= 1) ps += __shfl_xor(ps, msk);
          lrow[g][r] = lrow[g][r] * corr[g][r] + ps;
        }
#pragma unroll
      for (int g = 0; g < 2; g++)
#pragma unroll
        for (int n = 0; n < 4; n++)
#pragma unroll
          for (int r = 0; r < 4; r++) {
            int q = g * 16 + fq * 4 + r;
            int cb = ((n * 16 + fr) * 2) ^ ((q & 7) << 4);
            *(bf16_t*)(P + q * 128 + cb) = (bf16_t)s[g][n][r];
          }
      int rr = fr & 3;
      int srcl = (fr >> 2) << 4;
#pragma unroll
      for (int g = 0; g < 2; g++) {
        float c0 = __shfl(corr[g][0], srcl);
        float c1 = __shfl(corr[g][1], srcl);
        float c2 = __shfl(corr[g][2], srcl);
        float c3 = __shfl(corr[g][3], srcl);
        float cq = rr == 0 ? c0 : rr == 1 ? c1 : rr == 2 ? c2 : c3;
#pragma unroll
        for (int n = 0; n < 4; n++)
#pragma unroll
          for (int r = 0; r < 4; r++) o_acc[g][n][r] *= cq;
      }
#pragma unroll
      for (int c = 0; c < 2; c++) {
        bf16x8 pf[2];
#pragma unroll
        for (int g = 0; g < 2; g++)
          pf[g] = *(const bf16x8*)(P + (g * 16 + fr) * 128 +
                                   ((c * 64 + fq * 16) ^ swz));
#pragma unroll
        for (int n = 0; n < 4; n++) {
          bf16x8 vf = *(const bf16x8*)(Vb + (n * 16 + fr) * 128 +
                                       ((c * 64 + fq * 16) ^ swz));
#pragma unroll
          for (int g = 0; g < 2; g++)
            o_acc[g][n] = __builtin_amdgcn_mfma_f32_16x16x32_bf16(
                vf, pf[g], o_acc[g][n], 0, 0, 0);
        }
      }
    }
  }
  int rr = fr & 3;
  int srcl = (fr >> 2) << 4;
#pragma unroll
  for (int g = 0; g < 2; g++) {
    float l0 = __shfl(lrow[g][0], srcl);
    float l1 = __shfl(lrow[g][1], srcl);
    float l2 = __shfl(lrow[g][2], srcl);
    float l3 = __shfl(lrow[g][3], srcl);
    float lq = rr == 0 ? l0 : rr == 1 ? l1 : rr == 2 ? l2 : l3;
    float linv = 1.f / lq;
    size_t orow = qkbase + (size_t)(q0w + g * 16 + fr) * 1024;
#pragma unroll
    for (int n = 0; n < 4; n++) {
      bf16x4 ov;
#pragma unroll
      for (int r = 0; r < 4; r++) ov[r] = (bf16_t)(o_acc[g][n][r] * linv);
      *(bf16x4*)&O[orow + n * 16 + fq * 4] = ov;
    }
  }
#undef FSTAGE
}

// ======================= launch =======================

extern "C" void kernel_launch(void* const* d_in, const int* in_sizes, int n_in,
                              void* d_out, int out_size, void* d_ws,
                              size_t ws_size, hipStream_t stream) {
  (void)in_sizes; (void)n_in; (void)out_size; (void)ws_size;
  const float* x          = (const float*)d_in[0];
  const float* qk_emb     = (const float*)d_in[1];
  const float* v_emb      = (const float*)d_in[2];
  const float* know_emb   = (const float*)d_in[3];
  const float* qk_f       = (const float*)d_in[4];
  const float* qk_r       = (const float*)d_in[5];
  const float* v_f        = (const float*)d_in[6];
  const float* v_r        = (const float*)d_in[7];
  const float* know_f     = (const float*)d_in[8];
  const float* know_r     = (const float*)d_in[9];
  const float* proj_attn_k = (const float*)d_in[10];
  const float* proj_attn_b = (const float*)d_in[11];
  const float* tau_attn_k  = (const float*)d_in[12];
  const float* tau_attn_b  = (const float*)d_in[13];
  const float* proj_know_k = (const float*)d_in[14];
  const float* proj_know_b = (const float*)d_in[15];
  const float* tau_know_k  = (const float*)d_in[16];
  const float* tau_know_b  = (const float*)d_in[17];
  const float* expand_O    = (const float*)d_in[18];
  const float* ln1_scale   = (const float*)d_in[19];
  const float* ln1_bias    = (const float*)d_in[20];
  const float* ln2_scale   = (const float*)d_in[21];
  const float* ln2_bias    = (const float*)d_in[22];

  float* out = (float*)d_out;  // [T,D] + aux scalar
  float* aux = out + (size_t)T * D;

  // ---- workspace arena ----
  float* ws = (float*)d_ws;
  float* n_f   = ws;                       // 4M floats
  float* tau3  = n_f + 4194304;            // 16K
  float* gq_b  = tau3 + 16384;             // 64K
  float* gk_b  = gq_b + 65536;
  float* gv_b  = gk_b + 65536;
  float* gkn_b = gv_b + 65536;             // 128K
  float* csum  = gkn_b + 131072;           // 8192
  float* rinv  = csum + 8192;              // 4*T (attn 3T + know T)
  float* hQ    = rinv + 16384;             // 512K
  float* hK    = hQ + 524288;
  float* hV    = hK + 524288;
  float* qkvarena = hV + 524288;           // 12.58M floats
  float* buf_big = qkvarena + 12582912;    // 16.78M floats (67MB)

  bf16_t* Qbb = (bf16_t*)qkvarena;                 // T*1024 bf16
  bf16_t* Kbb = Qbb + (size_t)T * 1024;
  bf16_t* Vtb = Kbb + (size_t)T * 1024;            // [4][1024][1024]

  bf16_t* nb   = (bf16_t*)(buf_big + 16777216);  // T*1024
  bf16_t* hab  = nb + 4194304;                   // T*384 (know: T*128)
  bf16_t* embB = hab + 1572864;                  // 524288
  bf16_t* B2t  = embB + 524288;                  // 4096*1024
  bf16_t* wt   = B2t + 4194304;
  bf16_t* pa_t  = wt;                   // 384*1024
  bf16_t* qkr_t = pa_t + 393216;        // 1024*2048
  bf16_t* vr_t  = qkr_t + 2097152;      // 1024*2048
  bf16_t* knr_t = vr_t + 2097152;       // 1024*4096
  bf16_t* eo_t  = knr_t + 4194304;      // 1024*1024
  bf16_t* pk_t  = eo_t + 1048576;       // 128*1024
  bf16_t* B2t2  = pk_t + 131072;        // 4096*1024

  // buf_big overlays (lifetimes checked):
  bf16_t* s_qb = (bf16_t*)buf_big;                  // [T,2048] bf16 16MB
  bf16_t* s_kb = s_qb + (size_t)T * 2048;           // 16..32MB
  bf16_t* s_vb = s_kb + (size_t)T * 2048;           // 32..48MB
  bf16_t* kscb = (bf16_t*)buf_big;                  // know scores [T,4096]
  bf16_t* allh_q = (bf16_t*)buf_big;                // T*2048 bf16
  bf16_t* allh_v = allh_q + (size_t)T * 2048;
  bf16_t* avbQ = (bf16_t*)buf_big;
  bf16_t* avbK = avbQ + (size_t)T * 2048;
  bf16_t* avbV = avbK + (size_t)T * 2048;
  bf16_t* avbN = (bf16_t*)buf_big;                  // [T,4096] bf16
  bf16_t* allh_n = (bf16_t*)buf_big;
  float* kp0 = buf_big + 8388608;
  float* kp1 = kp0 + 4194304;
  bf16_t* attnb_b = (bf16_t*)(buf_big + 12582912);  // T*1024 bf16

  bf16_t* embQ = embB;
  bf16_t* embV = embB + 262144;

  dim3 blk(256);

  zero1_kernel<<<1, 1, 0, stream>>>(aux);

  // weight + feature-basis transposes to bf16 [N,K]
  transpose_to_bf16_kernel<<<dim3(12, 32, 1), blk, 0, stream>>>(
      proj_attn_k, pa_t, 1024, 384, 0, 0);
  transpose_to_bf16_kernel<<<dim3(32, 64, 1), blk, 0, stream>>>(
      qk_r, qkr_t, 2048, 1024, 0, 0);
  transpose_to_bf16_kernel<<<dim3(32, 64, 1), blk, 0, stream>>>(
      v_r, vr_t, 2048, 1024, 0, 0);
  transpose_to_bf16_kernel<<<dim3(32, 128, 1), blk, 0, stream>>>(
      know_r, knr_t, 4096, 1024, 0, 0);
  transpose_to_bf16_kernel<<<dim3(32, 32, 1), blk, 0, stream>>>(
      expand_O, eo_t, 1024, 1024, 0, 0);
  transpose_to_bf16_kernel<<<dim3(4, 32, 1), blk, 0, stream>>>(
      proj_know_k, pk_t, 1024, 128, 0, 0);
  transpose_to_bf16_kernel<<<dim3(4, 32, 16), blk, 0, stream>>>(
      qk_f, B2t, 1024, 128, 131072, 131072);
  transpose_to_bf16_kernel<<<dim3(4, 32, 16), blk, 0, stream>>>(
      v_f, B2t2, 1024, 128, 131072, 131072);

  // ---- attention circuit ----
  ln_kernel<<<T, blk, 0, stream>>>(x, ln1_scale, ln1_bias, n_f, nb);
  norm_rows_kernel<<<2048, 64, 0, stream>>>(qk_emb, embQ);
  norm_rows_kernel<<<2048, 64, 0, stream>>>(v_emb, embV);

  mfma_gemm_kernel<true, false, 1><<<dim3(3, 64), blk, 0, stream>>>(
      nb, 1024, pa_t, 1024, hab, 384, proj_attn_b, nullptr, 0, T, 384, 1024);
  tau_kernel<<<T, 64, 0, stream>>>(n_f, tau_attn_k, tau_attn_b, tau3, 3);

  // batched gate-score GEMMs (z = {q,k,v}, K=128) -> bf16 scores
  {
    ZArg zq{hab + 0, embQ, s_qb, 1};
    ZArg zk{hab + 128, embQ, s_kb, 1};
    ZArg zv{hab + 256, embV, s_vb, 1};
    mfma_gemm128b_kernel<<<dim3(16, 32, 3), blk, 0, stream>>>(
        zq, zk, zv, 384, 128, 2048, 128);
  }
  // gate: row sums + group gates + rowinv (no score writeback)
  gate3b_kernel<8><<<dim3(T, 3), blk, 0, stream>>>(
      s_qb, s_kb, s_vb, tau3, gq_b, gk_b, gv_b, rinv, 2048, 16);
  hipMemsetAsync(csum, 0, 6144 * sizeof(float), stream);
  colsumb_part3_kernel<<<dim3(8, 32, 3), blk, 0, stream>>>(
      s_qb, s_kb, s_vb, tau3, rinv, 2048, csum);
  colsum_fin_kernel<<<24, blk, 0, stream>>>(csum, 2048, 1.f / 2048.f, aux);

  // batched feature GEMMs (z = {qk,v}, K=1024) -> bf16 all_h
  {
    ZArg zf1{nb, B2t, allh_q, 1};
    ZArg zf2{nb, B2t2, allh_v, 1};
    mfma_gemm128b_kernel<<<dim3(16, 32, 2), blk, 0, stream>>>(
        zf1, zf2, zf1, 1024, 1024, 2048, 1024);
  }
  wsum2b_kernel<<<dim3(T, 2), 128, 0, stream>>>(allh_q, allh_v, gq_b, gk_b,
                                                gv_b, hQ, hK, hV, 16);

  // batched avirt + batched QKV restore (128^2 tile)
  avirt3_kernel<<<dim3(T, 3), blk, 0, stream>>>(hQ, hK, hV, gq_b, gk_b, gv_b,
                                                16, avbQ, avbK, avbV, 2048);
  {
    ZArg zq{avbQ, qkr_t, Qbb, 1};
    ZArg zk{avbK, qkr_t, Kbb, 1};
    ZArg zv{avbV, vr_t, Vtb, 2};
    mfma_gemm128b_kernel<<<dim3(8, 32, 3), blk, 0, stream>>>(
        zq, zk, zv, 2048, 2048, 1024, 2048);
  }

  // MFMA flash attention (causal-paired, 512 thr) + output proj + residual
  flash_mfma_kernel<<<dim3(4, 16, 4), dim3(512), 0, stream>>>(Qbb, Kbb, Vtb,
                                                              attnb_b);
  mfma_gemm_kernel<false, true, 0><<<dim3(8, 64), blk, 0, stream>>>(
      attnb_b, 1024, eo_t, 1024, out, 1024, nullptr, x, 1024, T, 1024, 1024);

  // ---- knowledge circuit ----
  ln_kernel<<<T, blk, 0, stream>>>(out, ln2_scale, ln2_bias, n_f, nb);
  norm_rows_kernel<<<4096, 64, 0, stream>>>(know_emb, embB);
  mfma_gemm_kernel<true, false, 1><<<dim3(1, 64), blk, 0, stream>>>(
      nb, 1024, pk_t, 1024, hab, 128, proj_know_b, nullptr, 0, T, 128, 1024);
  tau_kernel<<<T, 64, 0, stream>>>(n_f, tau_know_k, tau_know_b, tau3, 1);

  // know scores -> bf16, gate + colsum via recompute
  mfma_gemm128_kernel<1><<<dim3(32, 32), blk, 0, stream>>>(
      hab, 128, embB, 128, kscb, 4096, 128);
  gateb_kernel<16><<<T, blk, 0, stream>>>(kscb, tau3, gkn_b, rinv + 3 * T,
                                          4096, 32);
  hipMemsetAsync(csum, 0, 4096 * sizeof(float), stream);
  colsumb_part_kernel<<<dim3(16, 32), blk, 0, stream>>>(
      kscb, tau3, rinv + 3 * T, 4096, csum);
  colsum_fin_kernel<<<16, blk, 0, stream>>>(csum, 4096, 1.f / 4096.f, aux);

  transpose_to_bf16_kernel<<<dim3(4, 32, 32), blk, 0, stream>>>(
      know_f, B2t, 1024, 128, 131072, 131072);
  mfma_gemm128_kernel<1><<<dim3(32, 32), blk, 0, stream>>>(
      nb, 1024, B2t, 1024, allh_n, 4096, 1024);
  wsum2_kernel<<<T, 128, 0, stream>>>(allh_n, gkn_b, nullptr, hQ, nullptr, 32);

  // knowledge restore: split-K=2 -> f32 partials + combine (128^2 tile)
  avirt_kernel<<<T, blk, 0, stream>>>(hQ, gkn_b, 32, avbN, 4096);
  {
    ZArg z0{avbN, knr_t, kp0, 0};
    ZArg z1{avbN + 2048, knr_t + 2048, kp1, 0};
    mfma_gemm128b_kernel<<<dim3(8, 32, 2), blk, 0, stream>>>(
        z0, z1, z0, 4096, 4096, 1024, 2048);
  }
  combine2_kernel<<<4096, blk, 0, stream>>>(kp0, kp1, out);
}